// Round 6
// baseline (6690.207 us; speedup 1.0000x reference)
//
#include <hip/hip_runtime.h>
#include <math.h>

#define CDIM 768
#define NHEADS 12
#define DHEAD 64
#define SEQ 577
#define NBATCH 32
#define MTOK (NBATCH*SEQ)      // 18464
#define NIMG 576
#define NMERGE 288
#define GB 4                   // batches per qkv group
#define NGROUP (NBATCH/GB)     // 8
#define MGRP (GB*SEQ)          // 2308 rows per group
#define MLPCH 1728             // MLP chunk rows

// ---- workspace layout (float offsets), peak ~154 MB ----
#define SZ_MC   ((size_t)MTOK*CDIM)              // 14,180,352
#define O_BH    ((size_t)0)                      // att fp32 -> h2 planes -> xn fp32
#define O_BA    (SZ_MC)                          // h planes -> x1/x2 fp32
#define O_BQ    (2*SZ_MC)                        // qkv grp fp32 / fc1o planes / sim half
#define SZ_BQ   ((size_t)GB*SEQ*3*CDIM)          // 5,317,632
#define O_BW    (O_BQ + SZ_BQ)                   // weight planes (ushort)
#define SZ_BW   ((size_t)4718592)                // fc1+fc2 planes float-space
#define O_MS    (O_BW + SZ_BW)
#define O_MASK  (O_MS + (size_t)NBATCH*NIMG)
#define O_POS   (O_MASK + (size_t)NBATCH*NIMG)
#define O_AVG   (O_POS + (size_t)NBATCH*NIMG)
#define O_END   (O_AVG + (size_t)NBATCH*CDIM)
#define NEED_BYTES (O_END * 4)

typedef __attribute__((ext_vector_type(8))) short bf16x8;
typedef __attribute__((ext_vector_type(4))) float f32x4;

__device__ __forceinline__ unsigned short f2bf(float f) {
    unsigned int u = __float_as_uint(f);
    u += 0x7fff + ((u >> 16) & 1);           // RNE
    return (unsigned short)(u >> 16);
}
__device__ __forceinline__ float bf2f(unsigned short h) {
    return __uint_as_float(((unsigned int)h) << 16);
}

// ---------------- block reduce (256 threads) ----------------
__device__ __forceinline__ float blk_sum256(float v, float* red) {
    #pragma unroll
    for (int o = 32; o; o >>= 1) v += __shfl_down(v, o);
    if ((threadIdx.x & 63) == 0) red[threadIdx.x >> 6] = v;
    __syncthreads();
    float tot = red[0] + red[1] + red[2] + red[3];
    __syncthreads();
    return tot;
}

// ---------------- LayerNorm -> bf16 hi/lo planes ----------------
__global__ __launch_bounds__(256) void ln_split(const float* __restrict__ x,
        const float* __restrict__ g, const float* __restrict__ b,
        unsigned short* __restrict__ oh, size_t pstride) {
    __shared__ float red[4];
    size_t row = blockIdx.x;
    const float* xr = x + row * CDIM;
    int t = threadIdx.x;
    float v0 = xr[t], v1 = xr[t + 256], v2 = xr[t + 512];
    float mu = blk_sum256(v0 + v1 + v2, red) * (1.f / CDIM);
    float d0 = v0 - mu, d1 = v1 - mu, d2 = v2 - mu;
    float var = blk_sum256(d0 * d0 + d1 * d1 + d2 * d2, red) * (1.f / CDIM);
    float e = var + 1e-5f;
    float rs = rsqrtf(e);
    rs = rs * (1.5f - 0.5f * e * rs * rs);
    float vals[3] = {d0 * rs * g[t] + b[t],
                     d1 * rs * g[t + 256] + b[t + 256],
                     d2 * rs * g[t + 512] + b[t + 512]};
    #pragma unroll
    for (int cc = 0; cc < 3; cc++) {
        size_t idx = row * CDIM + t + cc * 256;
        unsigned short hh = f2bf(vals[cc]);
        oh[idx] = hh;
        oh[pstride + idx] = f2bf(vals[cc] - bf2f(hh));
    }
}

// ---------------- fp32 array -> bf16 hi/lo planes ----------------
__global__ __launch_bounds__(256) void split_kernel(const float* __restrict__ in,
        unsigned short* __restrict__ out, size_t pstride, int n4) {
    int i = blockIdx.x * 256 + threadIdx.x;
    if (i >= n4) return;
    float4 v = ((const float4*)in)[i];
    unsigned short h0 = f2bf(v.x), h1 = f2bf(v.y), h2 = f2bf(v.z), h3 = f2bf(v.w);
    ((ushort4*)out)[i] = make_ushort4(h0, h1, h2, h3);
    ((ushort4*)(out + pstride))[i] = make_ushort4(
        f2bf(v.x - bf2f(h0)), f2bf(v.y - bf2f(h1)),
        f2bf(v.z - bf2f(h2)), f2bf(v.w - bf2f(h3)));
}

// ---------------- split-input MFMA GEMM: C = A(MxK) * B(NxK)^T ----------------
// A,B given as bf16 hi/lo planes (hi at ptr, lo at ptr + s?p). No in-loop
// conversion: pure LDS staging + 3 MFMA per fragment pair (hh + hl + lh).
// LDS image identical to the verified round-4 layout (XOR swizzle (r&7)<<4).
// EPI: 0 = +bias (fp32 C), 1 = +bias+res (fp32 C, res may alias C),
//      5 = gelu(+bias) -> bf16 hi/lo planes (C = ushort*, sCp = plane stride)
template<int EPI>
__global__ __launch_bounds__(256)
void gemm_sp(const unsigned short* __restrict__ Ah, size_t sAp, int lda,
             const unsigned short* __restrict__ Bh, size_t sBp, int ldb,
             void* __restrict__ Cv, size_t sCp, int ldc,
             const float* __restrict__ bias,
             const float* __restrict__ res,
             int M, int N, int K) {
    __shared__ unsigned short Asl[128 * 64];
    __shared__ unsigned short Bsl[128 * 64];
    const int m0 = blockIdx.x * 128, n0 = blockIdx.y * 128;
    const int t = threadIdx.x;
    const int lane = t & 63, wid = t >> 6;
    const int wr = wid >> 1, wc = wid & 1;
    const int srow = t >> 2;            // 0..63
    const int sj   = t & 3;             // 16B k-chunk (8 ushorts)
    const unsigned short* Al = Ah + sAp;
    const unsigned short* Bl = Bh + sBp;

    f32x4 acc[4][4];
    #pragma unroll
    for (int i = 0; i < 4; i++)
        #pragma unroll
        for (int j = 0; j < 4; j++) {
            f32x4 z = {0.f, 0.f, 0.f, 0.f};
            acc[i][j] = z;
        }

    const int nsteps = K >> 5;
    for (int ks = 0; ks < nsteps; ks++) {
        const int k0 = ks << 5;
        uint4 vah[2], val[2], vbh[2], vbl[2];
        #pragma unroll
        for (int i = 0; i < 2; i++) {
            int r = srow + i * 64;
            int ra = m0 + r; ra = ra < M ? ra : M - 1;
            int rb = n0 + r; rb = rb < N ? rb : N - 1;
            size_t oa = (size_t)ra * lda + k0 + sj * 8;
            size_t ob = (size_t)rb * ldb + k0 + sj * 8;
            vah[i] = *(const uint4*)(Ah + oa);
            val[i] = *(const uint4*)(Al + oa);
            vbh[i] = *(const uint4*)(Bh + ob);
            vbl[i] = *(const uint4*)(Bl + ob);
        }
        __syncthreads();
        #pragma unroll
        for (int i = 0; i < 2; i++) {
            int r = srow + i * 64;
            int swz = (r & 7) << 4;
            unsigned char* arow = (unsigned char*)Asl + r * 128;
            unsigned char* brow = (unsigned char*)Bsl + r * 128;
            *(uint4*)(arow + ((16 * sj) ^ swz))      = vah[i];
            *(uint4*)(arow + ((64 + 16 * sj) ^ swz)) = val[i];
            *(uint4*)(brow + ((16 * sj) ^ swz))      = vbh[i];
            *(uint4*)(brow + ((64 + 16 * sj) ^ swz)) = vbl[i];
        }
        __syncthreads();
        const int fr = lane & 15, kg = lane >> 4;
        bf16x8 ah[4], al[4], bh[4], bl[4];
        #pragma unroll
        for (int m = 0; m < 4; m++) {
            int r = wr * 64 + m * 16 + fr;
            int swz = (r & 7) << 4;
            const unsigned char* base = (const unsigned char*)Asl + r * 128;
            ah[m] = *(const bf16x8*)(base + ((16 * kg) ^ swz));
            al[m] = *(const bf16x8*)(base + ((64 + 16 * kg) ^ swz));
        }
        #pragma unroll
        for (int n = 0; n < 4; n++) {
            int r = wc * 64 + n * 16 + fr;
            int swz = (r & 7) << 4;
            const unsigned char* base = (const unsigned char*)Bsl + r * 128;
            bh[n] = *(const bf16x8*)(base + ((16 * kg) ^ swz));
            bl[n] = *(const bf16x8*)(base + ((64 + 16 * kg) ^ swz));
        }
        #pragma unroll
        for (int m = 0; m < 4; m++)
            #pragma unroll
            for (int n = 0; n < 4; n++) {
                acc[m][n] = __builtin_amdgcn_mfma_f32_16x16x32_bf16(ah[m], bh[n], acc[m][n], 0, 0, 0);
                acc[m][n] = __builtin_amdgcn_mfma_f32_16x16x32_bf16(ah[m], bl[n], acc[m][n], 0, 0, 0);
                acc[m][n] = __builtin_amdgcn_mfma_f32_16x16x32_bf16(al[m], bh[n], acc[m][n], 0, 0, 0);
            }
    }

    const int fr2 = lane & 15, fq = lane >> 4;
    #pragma unroll
    for (int m = 0; m < 4; m++) {
        #pragma unroll
        for (int rr = 0; rr < 4; rr++) {
            int row = m0 + wr * 64 + m * 16 + fq * 4 + rr;
            if (row >= M) continue;
            #pragma unroll
            for (int n = 0; n < 4; n++) {
                int col = n0 + wc * 64 + n * 16 + fr2;
                if (col >= N) continue;
                float v = acc[m][n][rr];
                size_t ci = (size_t)row * ldc + col;
                if (EPI == 0) {
                    ((float*)Cv)[ci] = v + bias[col];
                } else if (EPI == 1) {
                    ((float*)Cv)[ci] = v + bias[col] + res[ci];
                } else { // 5: gelu -> planes
                    v += bias[col];
                    v = 0.5f * v * (1.0f + erff(v * 0.70710678118654752f));
                    unsigned short hh = f2bf(v);
                    ((unsigned short*)Cv)[ci] = hh;
                    ((unsigned short*)Cv)[sCp + ci] = f2bf(v - bf2f(hh));
                }
            }
        }
    }
}

// ---------------- fused-convert MFMA GEMM (proj & sim) ----------------
// EPI: 1 = +bias+res (res may alias C), 3 = plain
template<int EPI>
__global__ __launch_bounds__(256)
void gemm_mfma(const float* __restrict__ A, long long sA, int lda,
               const float* __restrict__ Bm, long long sB, int ldb,
               float* __restrict__ C, long long sC, int ldc,
               const float* __restrict__ bias,
               const float* __restrict__ res,
               int M, int N, int K) {
    __shared__ unsigned short Asl[128 * 64];
    __shared__ unsigned short Bsl[128 * 64];
    int batch = blockIdx.z;
    A  += (size_t)batch * sA;
    Bm += (size_t)batch * sB;
    C  += (size_t)batch * sC;
    const int m0 = blockIdx.x * 128, n0 = blockIdx.y * 128;
    const int t = threadIdx.x;
    const int lane = t & 63, wid = t >> 6;
    const int wr = wid >> 1, wc = wid & 1;
    const int srow = t >> 3;
    const int sj   = t & 7;

    f32x4 acc[4][4];
    #pragma unroll
    for (int i = 0; i < 4; i++)
        #pragma unroll
        for (int j = 0; j < 4; j++) {
            f32x4 z = {0.f, 0.f, 0.f, 0.f};
            acc[i][j] = z;
        }

    const int nsteps = K >> 5;
    for (int ks = 0; ks < nsteps; ks++) {
        const int k0 = ks << 5;
        float4 va[4], vb[4];
        #pragma unroll
        for (int i = 0; i < 4; i++) {
            int r = srow + i * 32;
            int ra = m0 + r; ra = ra < M ? ra : M - 1;
            int rb = n0 + r; rb = rb < N ? rb : N - 1;
            va[i] = *(const float4*)(A  + (size_t)ra * lda + k0 + sj * 4);
            vb[i] = *(const float4*)(Bm + (size_t)rb * ldb + k0 + sj * 4);
        }
        __syncthreads();
        #pragma unroll
        for (int i = 0; i < 4; i++) {
            int r = srow + i * 32;
            int swz = (r & 7) << 4;
            float aa[4] = {va[i].x, va[i].y, va[i].z, va[i].w};
            float bb[4] = {vb[i].x, vb[i].y, vb[i].z, vb[i].w};
            ushort4 ahv, alv, bhv, blv;
            {
                unsigned short h0 = f2bf(aa[0]), h1 = f2bf(aa[1]), h2 = f2bf(aa[2]), h3 = f2bf(aa[3]);
                ahv = make_ushort4(h0, h1, h2, h3);
                alv = make_ushort4(f2bf(aa[0] - bf2f(h0)), f2bf(aa[1] - bf2f(h1)),
                                   f2bf(aa[2] - bf2f(h2)), f2bf(aa[3] - bf2f(h3)));
                unsigned short g0 = f2bf(bb[0]), g1 = f2bf(bb[1]), g2 = f2bf(bb[2]), g3 = f2bf(bb[3]);
                bhv = make_ushort4(g0, g1, g2, g3);
                blv = make_ushort4(f2bf(bb[0] - bf2f(g0)), f2bf(bb[1] - bf2f(g1)),
                                   f2bf(bb[2] - bf2f(g2)), f2bf(bb[3] - bf2f(g3)));
            }
            int ohi = ((8 * sj) ^ swz) >> 1;
            int olo = ((64 + 8 * sj) ^ swz) >> 1;
            *(ushort4*)&Asl[r * 64 + ohi] = ahv;
            *(ushort4*)&Asl[r * 64 + olo] = alv;
            *(ushort4*)&Bsl[r * 64 + ohi] = bhv;
            *(ushort4*)&Bsl[r * 64 + olo] = blv;
        }
        __syncthreads();
        const int fr = lane & 15, kg = lane >> 4;
        bf16x8 ah[4], al[4], bh[4], bl[4];
        #pragma unroll
        for (int m = 0; m < 4; m++) {
            int r = wr * 64 + m * 16 + fr;
            int swz = (r & 7) << 4;
            const unsigned char* base = (const unsigned char*)&Asl[r * 64];
            ah[m] = *(const bf16x8*)(base + ((16 * kg) ^ swz));
            al[m] = *(const bf16x8*)(base + ((64 + 16 * kg) ^ swz));
        }
        #pragma unroll
        for (int n = 0; n < 4; n++) {
            int r = wc * 64 + n * 16 + fr;
            int swz = (r & 7) << 4;
            const unsigned char* base = (const unsigned char*)&Bsl[r * 64];
            bh[n] = *(const bf16x8*)(base + ((16 * kg) ^ swz));
            bl[n] = *(const bf16x8*)(base + ((64 + 16 * kg) ^ swz));
        }
        #pragma unroll
        for (int m = 0; m < 4; m++)
            #pragma unroll
            for (int n = 0; n < 4; n++) {
                acc[m][n] = __builtin_amdgcn_mfma_f32_16x16x32_bf16(ah[m], bh[n], acc[m][n], 0, 0, 0);
                acc[m][n] = __builtin_amdgcn_mfma_f32_16x16x32_bf16(ah[m], bl[n], acc[m][n], 0, 0, 0);
                acc[m][n] = __builtin_amdgcn_mfma_f32_16x16x32_bf16(al[m], bh[n], acc[m][n], 0, 0, 0);
            }
    }

    const int fr = lane & 15, fq = lane >> 4;
    #pragma unroll
    for (int m = 0; m < 4; m++) {
        #pragma unroll
        for (int rr = 0; rr < 4; rr++) {
            int row = m0 + wr * 64 + m * 16 + fq * 4 + rr;
            if (row >= M) continue;
            #pragma unroll
            for (int n = 0; n < 4; n++) {
                int col = n0 + wc * 64 + n * 16 + fr;
                if (col >= N) continue;
                float v = acc[m][n][rr];
                size_t ci = (size_t)row * ldc + col;
                if (EPI == 1) {
                    C[ci] = v + bias[col] + res[ci];
                } else {
                    C[ci] = v;
                }
            }
        }
    }
}

// ---------------- MFMA flash attention (bf16x3-split, online softmax) ----------------
__global__ __launch_bounds__(256) void attn_mfma(const float* __restrict__ qkv,
                                                 float* __restrict__ att) {
    const int b = blockIdx.z, h = blockIdx.y, q0 = blockIdx.x * 64;
    const int t = threadIdx.x;
    const int lane = t & 63, wid = t >> 6;
    const int fr = lane & 15, kg = lane >> 4;
    __shared__ unsigned short Khl[64 * 128];
    __shared__ unsigned char SV[64 * 68 * 4];
    __shared__ unsigned short Vt[64 * 128];
    unsigned char* KhlB = (unsigned char*)Khl;
    float* V32 = (float*)SV;
    unsigned char* PwB = SV + wid * 4096;
    unsigned char* VtB = (unsigned char*)Vt;
    const size_t rowbase = (size_t)b * SEQ * (3 * CDIM);

    bf16x8 qh[2], qlo[2];
    {
        int qrow = q0 + wid * 16 + fr; qrow = qrow < SEQ ? qrow : SEQ - 1;
        const float* qbase = qkv + rowbase + (size_t)qrow * (3 * CDIM) + h * DHEAD;
        #pragma unroll
        for (int ds = 0; ds < 2; ds++) {
            float tmp[8];
            *(float4*)(tmp)     = *(const float4*)(qbase + ds * 32 + kg * 8);
            *(float4*)(tmp + 4) = *(const float4*)(qbase + ds * 32 + kg * 8 + 4);
            #pragma unroll
            for (int j = 0; j < 8; j++) {
                unsigned short hh = f2bf(tmp[j]);
                qh[ds][j]  = (short)hh;
                qlo[ds][j] = (short)f2bf(tmp[j] - bf2f(hh));
            }
        }
    }

    f32x4 acc_o[4];
    #pragma unroll
    for (int i = 0; i < 4; i++) { f32x4 z = {0.f,0.f,0.f,0.f}; acc_o[i] = z; }
    float m_run[4] = {-1e30f, -1e30f, -1e30f, -1e30f};
    float l_run[4] = {0.f, 0.f, 0.f, 0.f};

    const int srow = t >> 2;
    const int sq   = t & 3;

    for (int c0 = 0; c0 < SEQ; c0 += 64) {
        float4 kv[4], vv[4];
        {
            int krow = c0 + srow; krow = krow < SEQ ? krow : SEQ - 1;
            const float* base = qkv + rowbase + (size_t)krow * (3 * CDIM) + h * DHEAD;
            #pragma unroll
            for (int i = 0; i < 4; i++) {
                int dchunk = sq * 16 + i * 4;
                kv[i] = *(const float4*)(base + CDIM + dchunk);
                vv[i] = *(const float4*)(base + 2 * CDIM + dchunk);
            }
        }
        __syncthreads();
        {
            int swz = (srow & 7) << 4;
            #pragma unroll
            for (int i = 0; i < 4; i++) {
                int dchunk = sq * 16 + i * 4;
                float a[4] = {kv[i].x, kv[i].y, kv[i].z, kv[i].w};
                unsigned short h0 = f2bf(a[0]), h1 = f2bf(a[1]), h2 = f2bf(a[2]), h3 = f2bf(a[3]);
                ushort4 hv = make_ushort4(h0, h1, h2, h3);
                ushort4 lv = make_ushort4(f2bf(a[0] - bf2f(h0)), f2bf(a[1] - bf2f(h1)),
                                          f2bf(a[2] - bf2f(h2)), f2bf(a[3] - bf2f(h3)));
                *(ushort4*)(KhlB + srow * 256 + ((dchunk * 2) ^ swz)) = hv;
                *(ushort4*)(KhlB + srow * 256 + 128 + ((dchunk * 2) ^ swz)) = lv;
                *(float4*)&V32[srow * 68 + dchunk] = vv[i];
            }
        }
        __syncthreads();
        {
            int d = t >> 2, k0b = (t & 3) * 16;
            unsigned short hb[16], lb[16];
            #pragma unroll
            for (int i = 0; i < 16; i++) {
                float v = V32[(k0b + i) * 68 + d];
                unsigned short hh = f2bf(v);
                hb[i] = hh; lb[i] = f2bf(v - bf2f(hh));
            }
            int swz = (d & 7) << 4;
            #pragma unroll
            for (int c = 0; c < 4; c++) {
                ushort4 hv = make_ushort4(hb[4*c], hb[4*c+1], hb[4*c+2], hb[4*c+3]);
                ushort4 lv = make_ushort4(lb[4*c], lb[4*c+1], lb[4*c+2], lb[4*c+3]);
                *(ushort4*)(VtB + d * 256 + (((k0b + 4 * c) * 2) ^ swz)) = hv;
                *(ushort4*)(VtB + d * 256 + 128 + (((k0b + 4 * c) * 2) ^ swz)) = lv;
            }
        }
        f32x4 s[4];
        #pragma unroll
        for (int i = 0; i < 4; i++) { f32x4 z = {0.f,0.f,0.f,0.f}; s[i] = z; }
        #pragma unroll
        for (int ds = 0; ds < 2; ds++) {
            #pragma unroll
            for (int n = 0; n < 4; n++) {
                int r = n * 16 + fr;
                int swz = (r & 7) << 4;
                const unsigned char* rb = KhlB + r * 256;
                bf16x8 kh = *(const bf16x8*)(rb + ((ds * 64 + kg * 16) ^ swz));
                bf16x8 kl = *(const bf16x8*)(rb + 128 + ((ds * 64 + kg * 16) ^ swz));
                s[n] = __builtin_amdgcn_mfma_f32_16x16x32_bf16(qh[ds], kh, s[n], 0, 0, 0);
                s[n] = __builtin_amdgcn_mfma_f32_16x16x32_bf16(qh[ds], kl, s[n], 0, 0, 0);
                s[n] = __builtin_amdgcn_mfma_f32_16x16x32_bf16(qlo[ds], kh, s[n], 0, 0, 0);
            }
        }
        __syncthreads();
        float p[4][4];
        #pragma unroll
        for (int n = 0; n < 4; n++) {
            int kcol = c0 + n * 16 + fr;
            #pragma unroll
            for (int r = 0; r < 4; r++) {
                float sv = s[n][r] * 0.125f;
                if (kcol >= SEQ) sv = -1e30f;
                p[n][r] = sv;
            }
        }
        float corr[4];
        #pragma unroll
        for (int r = 0; r < 4; r++) {
            float mx = fmaxf(fmaxf(p[0][r], p[1][r]), fmaxf(p[2][r], p[3][r]));
            mx = fmaxf(mx, __shfl_xor(mx, 1));
            mx = fmaxf(mx, __shfl_xor(mx, 2));
            mx = fmaxf(mx, __shfl_xor(mx, 4));
            mx = fmaxf(mx, __shfl_xor(mx, 8));
            float mnew = fmaxf(m_run[r], mx);
            corr[r] = __expf(m_run[r] - mnew);
            m_run[r] = mnew;
            float ls = 0.f;
            #pragma unroll
            for (int n = 0; n < 4; n++) {
                p[n][r] = __expf(p[n][r] - mnew);
                ls += p[n][r];
            }
            ls += __shfl_xor(ls, 1);
            ls += __shfl_xor(ls, 2);
            ls += __shfl_xor(ls, 4);
            ls += __shfl_xor(ls, 8);
            l_run[r] = l_run[r] * corr[r] + ls;
        }
        #pragma unroll
        for (int nd = 0; nd < 4; nd++)
            #pragma unroll
            for (int r = 0; r < 4; r++)
                acc_o[nd][r] *= corr[r];
        {
            int qb = (lane >> 4) * 4;
            #pragma unroll
            for (int n = 0; n < 4; n++) {
                int kcol = n * 16 + fr;
                #pragma unroll
                for (int r = 0; r < 4; r++) {
                    int qq = qb + r;
                    unsigned short ph = f2bf(p[n][r]);
                    unsigned short pl = f2bf(p[n][r] - bf2f(ph));
                    int off = (kcol * 2) ^ ((qq & 7) << 4);
                    *(unsigned short*)(PwB + qq * 256 + off) = ph;
                    *(unsigned short*)(PwB + qq * 256 + 128 + off) = pl;
                }
            }
        }
        #pragma unroll
        for (int ks = 0; ks < 2; ks++) {
            int swzp = (fr & 7) << 4;
            bf16x8 pah = *(const bf16x8*)(PwB + fr * 256 + ((ks * 64 + kg * 16) ^ swzp));
            bf16x8 pal = *(const bf16x8*)(PwB + fr * 256 + 128 + ((ks * 64 + kg * 16) ^ swzp));
            #pragma unroll
            for (int nd = 0; nd < 4; nd++) {
                int rv = nd * 16 + fr;
                int swzv = (rv & 7) << 4;
                const unsigned char* rb = VtB + rv * 256;
                bf16x8 vh = *(const bf16x8*)(rb + ((ks * 64 + kg * 16) ^ swzv));
                bf16x8 vl = *(const bf16x8*)(rb + 128 + ((ks * 64 + kg * 16) ^ swzv));
                acc_o[nd] = __builtin_amdgcn_mfma_f32_16x16x32_bf16(pah, vh, acc_o[nd], 0, 0, 0);
                acc_o[nd] = __builtin_amdgcn_mfma_f32_16x16x32_bf16(pah, vl, acc_o[nd], 0, 0, 0);
                acc_o[nd] = __builtin_amdgcn_mfma_f32_16x16x32_bf16(pal, vh, acc_o[nd], 0, 0, 0);
            }
        }
    }
    #pragma unroll
    for (int r = 0; r < 4; r++) {
        int q = q0 + wid * 16 + (lane >> 4) * 4 + r;
        if (q >= SEQ) continue;
        float inv = 1.f / l_run[r];
        float* o = att + ((size_t)b * SEQ + q) * CDIM + h * DHEAD;
        #pragma unroll
        for (int nd = 0; nd < 4; nd++)
            o[nd * 16 + fr] = acc_o[nd][r] * inv;
    }
}

// ---------------- normalize img tokens ----------------
__global__ __launch_bounds__(256) void xn_kernel(const float* __restrict__ x2,
                                                 float* __restrict__ xn) {
    __shared__ float red[4];
    int tok = blockIdx.x;
    int b = tok / NIMG, n = tok % NIMG;
    const float* xr = x2 + ((size_t)b * SEQ + 1 + n) * CDIM;
    float* onr = xn + (size_t)tok * CDIM;
    int t = threadIdx.x;
    float v0 = xr[t], v1 = xr[t + 256], v2 = xr[t + 512];
    float ss = blk_sum256(v0 * v0 + v1 * v1 + v2 * v2, red);
    float nrm = fmaxf(sqrtf(ss), 1e-12f);
    float inv = 1.f / nrm;
    onr[t] = v0 * inv; onr[t + 256] = v1 * inv; onr[t + 512] = v2 * inv;
}

// ---------------- row max of symmetrized sim (excluding diagonal) ----------------
__global__ __launch_bounds__(64) void rowmax_kernel(const float* __restrict__ sim,
                                                    float* __restrict__ ms) {
    int row = blockIdx.x;                 // local: b_local*576 + n
    int b = row / NIMG, n = row % NIMG;
    const float* sb = sim + (size_t)b * NIMG * NIMG;
    int lane = threadIdx.x;
    float mx = -1e30f;
    #pragma unroll
    for (int i = 0; i < NIMG / 64; i++) {
        int m = lane + i * 64;
        if (m != n) {
            float v = 0.5f * (sb[(size_t)n * NIMG + m] + sb[(size_t)m * NIMG + n]);
            mx = fmaxf(mx, v);
        }
    }
    #pragma unroll
    for (int o = 32; o; o >>= 1) mx = fmaxf(mx, __shfl_down(mx, o));
    if (lane == 0) ms[row] = mx;
}

// ---------------- exact top-k selection with lax.top_k tie semantics ----------------
__global__ __launch_bounds__(576) void select_kernel(const float* __restrict__ ms,
        int* __restrict__ mergemask, int* __restrict__ keeppos) {
    __shared__ float v[NIMG];
    __shared__ int keepf[NIMG];
    int b = blockIdx.x;
    int n = threadIdx.x;
    v[n] = ms[b * NIMG + n];
    __syncthreads();
    float vn = v[n];
    int rank_desc = 0, rank_asc = 0;
    for (int m = 0; m < NIMG; m++) {
        float vm = v[m];
        int tie_lo = (vm == vn && m < n);
        rank_desc += (vm > vn) || tie_lo;
        rank_asc  += (vm < vn) || tie_lo;
    }
    int merge = rank_desc < NMERGE;
    int keep  = rank_asc  < NMERGE;
    mergemask[b * NIMG + n] = merge;
    keepf[n] = keep;
    __syncthreads();
    if (keep) {
        int pos = 0;
        for (int m = 0; m < n; m++) pos += keepf[m];
        keeppos[b * NIMG + n] = pos;
    } else {
        keeppos[b * NIMG + n] = -1;
    }
}

// ---------------- average of merged tokens (parallelized) ----------------
// grid: (NBATCH, 6). Block (b, cc) handles cols [cc*128, cc*128+128).
__global__ __launch_bounds__(256) void avg_kernel(const float* __restrict__ x2,
        const int* __restrict__ mask, float* __restrict__ avg) {
    __shared__ float4 red[8][33];
    int b = blockIdx.x, cc = blockIdx.y;
    int t = threadIdx.x;
    int rr = t >> 5, c4 = t & 31;
    int c = cc * 128 + c4 * 4;
    const int* mb = mask + b * NIMG;
    float4 s = make_float4(0.f, 0.f, 0.f, 0.f);
    for (int n = rr; n < NIMG; n += 8) {
        if (mb[n]) {
            float4 v = *(const float4*)(x2 + ((size_t)b * SEQ + 1 + n) * CDIM + c);
            s.x += v.x; s.y += v.y; s.z += v.z; s.w += v.w;
        }
    }
    red[rr][c4] = s;
    __syncthreads();
    if (rr == 0) {
        float4 tot = red[0][c4];
        #pragma unroll
        for (int i = 1; i < 8; i++) {
            float4 v = red[i][c4];
            tot.x += v.x; tot.y += v.y; tot.z += v.z; tot.w += v.w;
        }
        float sc1 = 1.f / (float)NMERGE, sc2 = 1.f / (float)(NIMG - NMERGE);
        tot.x = (tot.x * sc1) * sc2; tot.y = (tot.y * sc1) * sc2;
        tot.z = (tot.z * sc1) * sc2; tot.w = (tot.w * sc1) * sc2;
        *(float4*)(avg + (size_t)b * CDIM + c) = tot;
    }
}

// ---------------- assemble output ----------------
__global__ __launch_bounds__(192) void assemble_kernel(const float* __restrict__ x2,
        const int* __restrict__ keeppos, const float* __restrict__ avg,
        float* __restrict__ out) {
    int g = blockIdx.x;
    int b = g / SEQ, s_ = g % SEQ;
    int t = threadIdx.x;
    const float4* src = (const float4*)(x2 + (size_t)g * CDIM);
    if (s_ == 0) {
        float4* dst = (float4*)(out + (size_t)b * 289 * CDIM);
        dst[t] = src[t];
    } else {
        int n = s_ - 1;
        int pos = keeppos[b * NIMG + n];
        if (pos < 0) return;
        const float4* av = (const float4*)(avg + (size_t)b * CDIM);
        float4 v = src[t], a = av[t];
        v.x += a.x; v.y += a.y; v.z += a.z; v.w += a.w;
        float4* dst = (float4*)(out + ((size_t)b * 289 + 1 + pos) * CDIM);
        dst[t] = v;
    }
}

extern "C" void kernel_launch(void* const* d_in, const int* in_sizes, int n_in,
                              void* d_out, int out_size, void* d_ws, size_t ws_size,
                              hipStream_t stream) {
    const float* x      = (const float*)d_in[0];
    const float* qkv_w  = (const float*)d_in[1];
    const float* qkv_b  = (const float*)d_in[2];
    const float* proj_w = (const float*)d_in[3];
    const float* proj_b = (const float*)d_in[4];
    const float* ln1_g  = (const float*)d_in[5];
    const float* ln1_b  = (const float*)d_in[6];
    const float* ln2_g  = (const float*)d_in[7];
    const float* ln2_b  = (const float*)d_in[8];
    const float* fc1_w  = (const float*)d_in[9];
    const float* fc1_b  = (const float*)d_in[10];
    const float* fc2_w  = (const float*)d_in[11];
    const float* fc2_b  = (const float*)d_in[12];

    if (ws_size < NEED_BYTES) return;

    float* ws   = (float*)d_ws;
    float* bh   = ws + O_BH;
    float* ba   = ws + O_BA;
    float* bq   = ws + O_BQ;
    unsigned short* bw = (unsigned short*)(ws + O_BW);
    float* ms   = ws + O_MS;
    int*   mask = (int*)(ws + O_MASK);
    int*   pos  = (int*)(ws + O_POS);
    float* avg  = ws + O_AVG;
    float* outp = (float*)d_out;

    unsigned short* hpl  = (unsigned short*)ba;   // LN1 planes
    unsigned short* h2pl = (unsigned short*)bh;   // LN2 planes
    unsigned short* fopl = (unsigned short*)bq;   // fc1o planes

    // 1. split qkv_w -> BW; h = LN1(x) as planes -> BA
    split_kernel<<<1728, 256, 0, stream>>>(qkv_w, bw, 1769472, 442368);
    ln_split<<<MTOK, 256, 0, stream>>>(x, ln1_g, ln1_b, hpl, SZ_MC);

    // 2. per-group qkv GEMM (split) + MFMA attention -> att in BH
    for (int g = 0; g < NGROUP; g++) {
        gemm_sp<0><<<dim3(19, 18), 256, 0, stream>>>(
            hpl + (size_t)g * MGRP * CDIM, SZ_MC, CDIM, bw, 1769472, CDIM,
            (void*)bq, 0, 3 * CDIM, qkv_b, nullptr, MGRP, 3 * CDIM, CDIM);
        attn_mfma<<<dim3(10, NHEADS, GB), 256, 0, stream>>>(
            bq, bh + (size_t)g * MGRP * CDIM);
    }

    // 3. split fc1_w / fc2_w into BW (qkv_w planes dead)
    split_kernel<<<2304, 256, 0, stream>>>(fc1_w, bw, 2359296, 589824);
    split_kernel<<<2304, 256, 0, stream>>>(fc2_w, bw + 4718592, 2359296, 589824);

    // 4. x1 = x + att @ proj_w^T + proj_b -> BA (h planes dead)
    gemm_mfma<1><<<dim3(145, 6, 1), 256, 0, stream>>>(
        bh, 0, CDIM, proj_w, 0, CDIM, ba, 0, CDIM, proj_b, x, MTOK, CDIM, CDIM);

    // 5. h2 = LN2(x1) as planes -> BH (att dead)
    ln_split<<<MTOK, 256, 0, stream>>>(ba, ln2_g, ln2_b, h2pl, SZ_MC);

    // 6. MLP chunks: fc1 (split, gelu->planes in BQ), fc2 (split, +res in-place BA)
    for (int c0 = 0; c0 < MTOK; c0 += MLPCH) {
        int mc = (MTOK - c0 < MLPCH) ? (MTOK - c0) : MLPCH;
        gemm_sp<5><<<dim3((mc + 127) / 128, 24), 256, 0, stream>>>(
            h2pl + (size_t)c0 * CDIM, SZ_MC, CDIM, bw, 2359296, CDIM,
            (void*)fopl, 5308416, 3072, fc1_b, nullptr, mc, 3072, CDIM);
        gemm_sp<1><<<dim3((mc + 127) / 128, 6), 256, 0, stream>>>(
            fopl, 5308416, 3072, bw + 4718592, 2359296, 3072,
            (void*)(ba + (size_t)c0 * CDIM), 0, CDIM, fc2_b,
            ba + (size_t)c0 * CDIM, mc, CDIM, 3072);
    }

    // 7. normalize img tokens -> xn fp32 in BH (h2 planes dead)
    xn_kernel<<<NBATCH * NIMG, 256, 0, stream>>>(ba, bh);

    // 8. sim in two batch-halves (BQ), rowmax each
    for (int hf = 0; hf < 2; hf++) {
        gemm_mfma<3><<<dim3(5, 5, 16), 256, 0, stream>>>(
            bh + (size_t)hf * 16 * NIMG * CDIM, (long long)NIMG * CDIM, CDIM,
            bh + (size_t)hf * 16 * NIMG * CDIM, (long long)NIMG * CDIM, CDIM,
            bq, (long long)NIMG * NIMG, NIMG, nullptr, nullptr, NIMG, NIMG, CDIM);
        rowmax_kernel<<<16 * NIMG, 64, 0, stream>>>(bq, ms + (size_t)hf * 16 * NIMG);
    }

    // 9-11. selection, merged average, assemble (x2 = BA)
    select_kernel<<<NBATCH, NIMG, 0, stream>>>(ms, mask, pos);
    avg_kernel<<<dim3(NBATCH, 6), 256, 0, stream>>>(ba, mask, avg);
    assemble_kernel<<<MTOK, 192, 0, stream>>>(ba, pos, avg, outp);
}

// Round 7
// 3203.085 us; speedup vs baseline: 2.0887x; 2.0887x over previous
//
#include <hip/hip_runtime.h>
#include <math.h>

#define CDIM 768
#define NHEADS 12
#define DHEAD 64
#define SEQ 577
#define NBATCH 32
#define MTOK (NBATCH*SEQ)      // 18464
#define NIMG 576
#define NMERGE 288
#define GB 8                   // batches per qkv group
#define NGROUP (NBATCH/GB)     // 4
#define MGRP (GB*SEQ)          // 4616 rows per group
#define MLPCH 3456             // MLP chunk rows

// ---- workspace layout (float offsets), peak ~156 MB ----
#define SZ_MC   ((size_t)MTOK*CDIM)              // 14,180,352
#define O_BH    ((size_t)0)                      // h -> x1/x2 (in-place)
#define O_BA    (SZ_MC)                          // att -> h2 -> xn
#define O_BQ    (2*SZ_MC)                        // qkv group -> fc1o chunk -> sim
#define SZ_BQ   ((size_t)GB*SEQ*3*CDIM)          // 10,635,264
#define O_SM    (O_BQ + SZ_BQ)
#define O_MS    (O_SM)
#define O_MASK  (O_SM + (size_t)NBATCH*NIMG)
#define O_POS   (O_MASK + (size_t)NBATCH*NIMG)
#define O_AVG   (O_POS + (size_t)NBATCH*NIMG)
#define O_END   (O_AVG + (size_t)NBATCH*CDIM)
#define NEED_BYTES (O_END * 4)

typedef __attribute__((ext_vector_type(8))) short bf16x8;
typedef __attribute__((ext_vector_type(4))) float f32x4;

__device__ __forceinline__ unsigned short f2bf(float f) {
    unsigned int u = __float_as_uint(f);
    u += 0x7fff + ((u >> 16) & 1);           // RNE
    return (unsigned short)(u >> 16);
}
__device__ __forceinline__ float bf2f(unsigned short h) {
    return __uint_as_float(((unsigned int)h) << 16);
}

// ---------------- block reduce (256 threads) ----------------
__device__ __forceinline__ float blk_sum256(float v, float* red) {
    #pragma unroll
    for (int o = 32; o; o >>= 1) v += __shfl_down(v, o);
    if ((threadIdx.x & 63) == 0) red[threadIdx.x >> 6] = v;
    __syncthreads();
    float tot = red[0] + red[1] + red[2] + red[3];
    __syncthreads();
    return tot;
}

// ---------------- LayerNorm: one block per row ----------------
__global__ __launch_bounds__(256) void ln_kernel(const float* __restrict__ x,
        const float* __restrict__ g, const float* __restrict__ b,
        float* __restrict__ out) {
    __shared__ float red[4];
    size_t row = blockIdx.x;
    const float* xr = x + row * CDIM;
    float* orow = out + row * CDIM;
    int t = threadIdx.x;
    float v0 = xr[t], v1 = xr[t + 256], v2 = xr[t + 512];
    float mu = blk_sum256(v0 + v1 + v2, red) * (1.f / CDIM);
    float d0 = v0 - mu, d1 = v1 - mu, d2 = v2 - mu;
    float var = blk_sum256(d0 * d0 + d1 * d1 + d2 * d2, red) * (1.f / CDIM);
    float e = var + 1e-5f;
    float rs = rsqrtf(e);
    rs = rs * (1.5f - 0.5f * e * rs * rs);   // NR refine
    orow[t]       = d0 * rs * g[t]       + b[t];
    orow[t + 256] = d1 * rs * g[t + 256] + b[t + 256];
    orow[t + 512] = d2 * rs * g[t + 512] + b[t + 512];
}

// ---------------- MFMA bf16x3-split GEMM: C = A(MxK) * B(NxK)^T ----------------
// fp32-equivalent accuracy: A=Ah+Al, B=Bh+Bl (bf16), C ~= AhBh + AhBl + AlBh.
// 128x128 tile, BK=32, 4 waves (2x2), 16x16x32 MFMA.
// LDS row layout (128B): [hi k0..31 | lo k0..31], swizzle byte ^= (row&7)<<4.
// EPI: 0 = +bias, 1 = +bias+res (res may alias C), 2 = gelu(+bias), 3 = plain
template<int EPI>
__global__ __launch_bounds__(256)
void gemm_mfma(const float* __restrict__ A, long long sA, int lda,
               const float* __restrict__ Bm, long long sB, int ldb,
               float* __restrict__ C, long long sC, int ldc,
               const float* __restrict__ bias,
               const float* __restrict__ res,
               int M, int N, int K) {
    __shared__ unsigned short Asl[128 * 64];
    __shared__ unsigned short Bsl[128 * 64];
    int batch = blockIdx.z;
    A  += (size_t)batch * sA;
    Bm += (size_t)batch * sB;
    C  += (size_t)batch * sC;
    const int m0 = blockIdx.x * 128, n0 = blockIdx.y * 128;
    const int t = threadIdx.x;
    const int lane = t & 63, wid = t >> 6;
    const int wr = wid >> 1, wc = wid & 1;
    const int srow = t >> 3;
    const int sj   = t & 7;

    f32x4 acc[4][4];
    #pragma unroll
    for (int i = 0; i < 4; i++)
        #pragma unroll
        for (int j = 0; j < 4; j++) {
            f32x4 z = {0.f, 0.f, 0.f, 0.f};
            acc[i][j] = z;
        }

    const int nsteps = K >> 5;
    for (int ks = 0; ks < nsteps; ks++) {
        const int k0 = ks << 5;
        float4 va[4], vb[4];
        #pragma unroll
        for (int i = 0; i < 4; i++) {
            int r = srow + i * 32;
            int ra = m0 + r; ra = ra < M ? ra : M - 1;
            int rb = n0 + r; rb = rb < N ? rb : N - 1;
            va[i] = *(const float4*)(A  + (size_t)ra * lda + k0 + sj * 4);
            vb[i] = *(const float4*)(Bm + (size_t)rb * ldb + k0 + sj * 4);
        }
        __syncthreads();
        #pragma unroll
        for (int i = 0; i < 4; i++) {
            int r = srow + i * 32;
            int swz = (r & 7) << 4;
            float aa[4] = {va[i].x, va[i].y, va[i].z, va[i].w};
            float bb[4] = {vb[i].x, vb[i].y, vb[i].z, vb[i].w};
            ushort4 ahv, alv, bhv, blv;
            {
                unsigned short h0 = f2bf(aa[0]), h1 = f2bf(aa[1]), h2 = f2bf(aa[2]), h3 = f2bf(aa[3]);
                ahv = make_ushort4(h0, h1, h2, h3);
                alv = make_ushort4(f2bf(aa[0] - bf2f(h0)), f2bf(aa[1] - bf2f(h1)),
                                   f2bf(aa[2] - bf2f(h2)), f2bf(aa[3] - bf2f(h3)));
                unsigned short g0 = f2bf(bb[0]), g1 = f2bf(bb[1]), g2 = f2bf(bb[2]), g3 = f2bf(bb[3]);
                bhv = make_ushort4(g0, g1, g2, g3);
                blv = make_ushort4(f2bf(bb[0] - bf2f(g0)), f2bf(bb[1] - bf2f(g1)),
                                   f2bf(bb[2] - bf2f(g2)), f2bf(bb[3] - bf2f(g3)));
            }
            int ohi = ((8 * sj) ^ swz) >> 1;
            int olo = ((64 + 8 * sj) ^ swz) >> 1;
            *(ushort4*)&Asl[r * 64 + ohi] = ahv;
            *(ushort4*)&Asl[r * 64 + olo] = alv;
            *(ushort4*)&Bsl[r * 64 + ohi] = bhv;
            *(ushort4*)&Bsl[r * 64 + olo] = blv;
        }
        __syncthreads();
        const int fr = lane & 15, kg = lane >> 4;
        bf16x8 ah[4], al[4], bh[4], bl[4];
        #pragma unroll
        for (int m = 0; m < 4; m++) {
            int r = wr * 64 + m * 16 + fr;
            int swz = (r & 7) << 4;
            const unsigned char* base = (const unsigned char*)&Asl[r * 64];
            ah[m] = *(const bf16x8*)(base + ((16 * kg) ^ swz));
            al[m] = *(const bf16x8*)(base + ((64 + 16 * kg) ^ swz));
        }
        #pragma unroll
        for (int n = 0; n < 4; n++) {
            int r = wc * 64 + n * 16 + fr;
            int swz = (r & 7) << 4;
            const unsigned char* base = (const unsigned char*)&Bsl[r * 64];
            bh[n] = *(const bf16x8*)(base + ((16 * kg) ^ swz));
            bl[n] = *(const bf16x8*)(base + ((64 + 16 * kg) ^ swz));
        }
        #pragma unroll
        for (int m = 0; m < 4; m++)
            #pragma unroll
            for (int n = 0; n < 4; n++) {
                acc[m][n] = __builtin_amdgcn_mfma_f32_16x16x32_bf16(ah[m], bh[n], acc[m][n], 0, 0, 0);
                acc[m][n] = __builtin_amdgcn_mfma_f32_16x16x32_bf16(ah[m], bl[n], acc[m][n], 0, 0, 0);
                acc[m][n] = __builtin_amdgcn_mfma_f32_16x16x32_bf16(al[m], bh[n], acc[m][n], 0, 0, 0);
            }
    }

    const int fr = lane & 15, fq = lane >> 4;
    #pragma unroll
    for (int m = 0; m < 4; m++) {
        #pragma unroll
        for (int rr = 0; rr < 4; rr++) {
            int row = m0 + wr * 64 + m * 16 + fq * 4 + rr;
            if (row >= M) continue;
            #pragma unroll
            for (int n = 0; n < 4; n++) {
                int col = n0 + wc * 64 + n * 16 + fr;
                if (col >= N) continue;
                float v = acc[m][n][rr];
                size_t ci = (size_t)row * ldc + col;
                if (EPI == 0) {
                    C[ci] = v + bias[col];
                } else if (EPI == 1) {
                    C[ci] = v + bias[col] + res[ci];
                } else if (EPI == 2) {
                    v += bias[col];
                    C[ci] = 0.5f * v * (1.0f + erff(v * 0.70710678118654752f));
                } else {
                    C[ci] = v;
                }
            }
        }
    }
}

// ---------------- MFMA flash attention (bf16x3-split, online softmax) ----------------
__global__ __launch_bounds__(256) void attn_mfma(const float* __restrict__ qkv,
                                                 float* __restrict__ att) {
    const int b = blockIdx.z, h = blockIdx.y, q0 = blockIdx.x * 64;
    const int t = threadIdx.x;
    const int lane = t & 63, wid = t >> 6;
    const int fr = lane & 15, kg = lane >> 4;
    __shared__ unsigned short Khl[64 * 128];
    __shared__ unsigned char SV[64 * 68 * 4];
    __shared__ unsigned short Vt[64 * 128];
    unsigned char* KhlB = (unsigned char*)Khl;
    float* V32 = (float*)SV;
    unsigned char* PwB = SV + wid * 4096;
    unsigned char* VtB = (unsigned char*)Vt;
    const size_t rowbase = (size_t)b * SEQ * (3 * CDIM);

    bf16x8 qh[2], qlo[2];
    {
        int qrow = q0 + wid * 16 + fr; qrow = qrow < SEQ ? qrow : SEQ - 1;
        const float* qbase = qkv + rowbase + (size_t)qrow * (3 * CDIM) + h * DHEAD;
        #pragma unroll
        for (int ds = 0; ds < 2; ds++) {
            float tmp[8];
            *(float4*)(tmp)     = *(const float4*)(qbase + ds * 32 + kg * 8);
            *(float4*)(tmp + 4) = *(const float4*)(qbase + ds * 32 + kg * 8 + 4);
            #pragma unroll
            for (int j = 0; j < 8; j++) {
                unsigned short hh = f2bf(tmp[j]);
                qh[ds][j]  = (short)hh;
                qlo[ds][j] = (short)f2bf(tmp[j] - bf2f(hh));
            }
        }
    }

    f32x4 acc_o[4];
    #pragma unroll
    for (int i = 0; i < 4; i++) { f32x4 z = {0.f,0.f,0.f,0.f}; acc_o[i] = z; }
    float m_run[4] = {-1e30f, -1e30f, -1e30f, -1e30f};
    float l_run[4] = {0.f, 0.f, 0.f, 0.f};

    const int srow = t >> 2;
    const int sq   = t & 3;

    for (int c0 = 0; c0 < SEQ; c0 += 64) {
        float4 kv[4], vv[4];
        {
            int krow = c0 + srow; krow = krow < SEQ ? krow : SEQ - 1;
            const float* base = qkv + rowbase + (size_t)krow * (3 * CDIM) + h * DHEAD;
            #pragma unroll
            for (int i = 0; i < 4; i++) {
                int dchunk = sq * 16 + i * 4;
                kv[i] = *(const float4*)(base + CDIM + dchunk);
                vv[i] = *(const float4*)(base + 2 * CDIM + dchunk);
            }
        }
        __syncthreads();
        {
            int swz = (srow & 7) << 4;
            #pragma unroll
            for (int i = 0; i < 4; i++) {
                int dchunk = sq * 16 + i * 4;
                float a[4] = {kv[i].x, kv[i].y, kv[i].z, kv[i].w};
                unsigned short h0 = f2bf(a[0]), h1 = f2bf(a[1]), h2 = f2bf(a[2]), h3 = f2bf(a[3]);
                ushort4 hv = make_ushort4(h0, h1, h2, h3);
                ushort4 lv = make_ushort4(f2bf(a[0] - bf2f(h0)), f2bf(a[1] - bf2f(h1)),
                                          f2bf(a[2] - bf2f(h2)), f2bf(a[3] - bf2f(h3)));
                *(ushort4*)(KhlB + srow * 256 + ((dchunk * 2) ^ swz)) = hv;
                *(ushort4*)(KhlB + srow * 256 + 128 + ((dchunk * 2) ^ swz)) = lv;
                *(float4*)&V32[srow * 68 + dchunk] = vv[i];
            }
        }
        __syncthreads();
        {
            int d = t >> 2, k0b = (t & 3) * 16;
            unsigned short hb[16], lb[16];
            #pragma unroll
            for (int i = 0; i < 16; i++) {
                float v = V32[(k0b + i) * 68 + d];
                unsigned short hh = f2bf(v);
                hb[i] = hh; lb[i] = f2bf(v - bf2f(hh));
            }
            int swz = (d & 7) << 4;
            #pragma unroll
            for (int c = 0; c < 4; c++) {
                ushort4 hv = make_ushort4(hb[4*c], hb[4*c+1], hb[4*c+2], hb[4*c+3]);
                ushort4 lv = make_ushort4(lb[4*c], lb[4*c+1], lb[4*c+2], lb[4*c+3]);
                *(ushort4*)(VtB + d * 256 + (((k0b + 4 * c) * 2) ^ swz)) = hv;
                *(ushort4*)(VtB + d * 256 + 128 + (((k0b + 4 * c) * 2) ^ swz)) = lv;
            }
        }
        f32x4 s[4];
        #pragma unroll
        for (int i = 0; i < 4; i++) { f32x4 z = {0.f,0.f,0.f,0.f}; s[i] = z; }
        #pragma unroll
        for (int ds = 0; ds < 2; ds++) {
            #pragma unroll
            for (int n = 0; n < 4; n++) {
                int r = n * 16 + fr;
                int swz = (r & 7) << 4;
                const unsigned char* rb = KhlB + r * 256;
                bf16x8 kh = *(const bf16x8*)(rb + ((ds * 64 + kg * 16) ^ swz));
                bf16x8 kl = *(const bf16x8*)(rb + 128 + ((ds * 64 + kg * 16) ^ swz));
                s[n] = __builtin_amdgcn_mfma_f32_16x16x32_bf16(qh[ds], kh, s[n], 0, 0, 0);
                s[n] = __builtin_amdgcn_mfma_f32_16x16x32_bf16(qh[ds], kl, s[n], 0, 0, 0);
                s[n] = __builtin_amdgcn_mfma_f32_16x16x32_bf16(qlo[ds], kh, s[n], 0, 0, 0);
            }
        }
        __syncthreads();
        float p[4][4];
        #pragma unroll
        for (int n = 0; n < 4; n++) {
            int kcol = c0 + n * 16 + fr;
            #pragma unroll
            for (int r = 0; r < 4; r++) {
                float sv = s[n][r] * 0.125f;
                if (kcol >= SEQ) sv = -1e30f;
                p[n][r] = sv;
            }
        }
        float corr[4];
        #pragma unroll
        for (int r = 0; r < 4; r++) {
            float mx = fmaxf(fmaxf(p[0][r], p[1][r]), fmaxf(p[2][r], p[3][r]));
            mx = fmaxf(mx, __shfl_xor(mx, 1));
            mx = fmaxf(mx, __shfl_xor(mx, 2));
            mx = fmaxf(mx, __shfl_xor(mx, 4));
            mx = fmaxf(mx, __shfl_xor(mx, 8));
            float mnew = fmaxf(m_run[r], mx);
            corr[r] = __expf(m_run[r] - mnew);
            m_run[r] = mnew;
            float ls = 0.f;
            #pragma unroll
            for (int n = 0; n < 4; n++) {
                p[n][r] = __expf(p[n][r] - mnew);
                ls += p[n][r];
            }
            ls += __shfl_xor(ls, 1);
            ls += __shfl_xor(ls, 2);
            ls += __shfl_xor(ls, 4);
            ls += __shfl_xor(ls, 8);
            l_run[r] = l_run[r] * corr[r] + ls;
        }
        #pragma unroll
        for (int nd = 0; nd < 4; nd++)
            #pragma unroll
            for (int r = 0; r < 4; r++)
                acc_o[nd][r] *= corr[r];
        {
            int qb = (lane >> 4) * 4;
            #pragma unroll
            for (int n = 0; n < 4; n++) {
                int kcol = n * 16 + fr;
                #pragma unroll
                for (int r = 0; r < 4; r++) {
                    int qq = qb + r;
                    unsigned short ph = f2bf(p[n][r]);
                    unsigned short pl = f2bf(p[n][r] - bf2f(ph));
                    int off = (kcol * 2) ^ ((qq & 7) << 4);
                    *(unsigned short*)(PwB + qq * 256 + off) = ph;
                    *(unsigned short*)(PwB + qq * 256 + 128 + off) = pl;
                }
            }
        }
        #pragma unroll
        for (int ks = 0; ks < 2; ks++) {
            int swzp = (fr & 7) << 4;
            bf16x8 pah = *(const bf16x8*)(PwB + fr * 256 + ((ks * 64 + kg * 16) ^ swzp));
            bf16x8 pal = *(const bf16x8*)(PwB + fr * 256 + 128 + ((ks * 64 + kg * 16) ^ swzp));
            #pragma unroll
            for (int nd = 0; nd < 4; nd++) {
                int rv = nd * 16 + fr;
                int swzv = (rv & 7) << 4;
                const unsigned char* rb = VtB + rv * 256;
                bf16x8 vh = *(const bf16x8*)(rb + ((ks * 64 + kg * 16) ^ swzv));
                bf16x8 vl = *(const bf16x8*)(rb + 128 + ((ks * 64 + kg * 16) ^ swzv));
                acc_o[nd] = __builtin_amdgcn_mfma_f32_16x16x32_bf16(pah, vh, acc_o[nd], 0, 0, 0);
                acc_o[nd] = __builtin_amdgcn_mfma_f32_16x16x32_bf16(pah, vl, acc_o[nd], 0, 0, 0);
                acc_o[nd] = __builtin_amdgcn_mfma_f32_16x16x32_bf16(pal, vh, acc_o[nd], 0, 0, 0);
            }
        }
    }
    #pragma unroll
    for (int r = 0; r < 4; r++) {
        int q = q0 + wid * 16 + (lane >> 4) * 4 + r;
        if (q >= SEQ) continue;
        float inv = 1.f / l_run[r];
        float* o = att + ((size_t)b * SEQ + q) * CDIM + h * DHEAD;
        #pragma unroll
        for (int nd = 0; nd < 4; nd++)
            o[nd * 16 + fr] = acc_o[nd][r] * inv;
    }
}

// ---------------- normalize img tokens ----------------
__global__ __launch_bounds__(256) void xn_kernel(const float* __restrict__ x2,
                                                 float* __restrict__ xn) {
    __shared__ float red[4];
    int tok = blockIdx.x;
    int b = tok / NIMG, n = tok % NIMG;
    const float* xr = x2 + ((size_t)b * SEQ + 1 + n) * CDIM;
    float* onr = xn + (size_t)tok * CDIM;
    int t = threadIdx.x;
    float v0 = xr[t], v1 = xr[t + 256], v2 = xr[t + 512];
    float ss = blk_sum256(v0 * v0 + v1 * v1 + v2 * v2, red);
    float nrm = fmaxf(sqrtf(ss), 1e-12f);
    float inv = 1.f / nrm;
    onr[t] = v0 * inv; onr[t + 256] = v1 * inv; onr[t + 512] = v2 * inv;
}

// ---------------- row max of symmetrized sim (excluding diagonal) ----------------
__global__ __launch_bounds__(64) void rowmax_kernel(const float* __restrict__ sim,
                                                    float* __restrict__ ms) {
    int row = blockIdx.x;
    int b = row / NIMG, n = row % NIMG;
    const float* sb = sim + (size_t)b * NIMG * NIMG;
    int lane = threadIdx.x;
    float mx = -1e30f;
    #pragma unroll
    for (int i = 0; i < NIMG / 64; i++) {
        int m = lane + i * 64;
        if (m != n) {
            float v = 0.5f * (sb[(size_t)n * NIMG + m] + sb[(size_t)m * NIMG + n]);
            mx = fmaxf(mx, v);
        }
    }
    #pragma unroll
    for (int o = 32; o; o >>= 1) mx = fmaxf(mx, __shfl_down(mx, o));
    if (lane == 0) ms[row] = mx;
}

// ---------------- exact top-k selection with lax.top_k tie semantics ----------------
__global__ __launch_bounds__(576) void select_kernel(const float* __restrict__ ms,
        int* __restrict__ mergemask, int* __restrict__ keeppos) {
    __shared__ float v[NIMG];
    __shared__ int keepf[NIMG];
    int b = blockIdx.x;
    int n = threadIdx.x;
    v[n] = ms[b * NIMG + n];
    __syncthreads();
    float vn = v[n];
    int rank_desc = 0, rank_asc = 0;
    for (int m = 0; m < NIMG; m++) {
        float vm = v[m];
        int tie_lo = (vm == vn && m < n);
        rank_desc += (vm > vn) || tie_lo;
        rank_asc  += (vm < vn) || tie_lo;
    }
    int merge = rank_desc < NMERGE;
    int keep  = rank_asc  < NMERGE;
    mergemask[b * NIMG + n] = merge;
    keepf[n] = keep;
    __syncthreads();
    if (keep) {
        int pos = 0;
        for (int m = 0; m < n; m++) pos += keepf[m];
        keeppos[b * NIMG + n] = pos;
    } else {
        keeppos[b * NIMG + n] = -1;
    }
}

// ---------------- average of merged tokens (parallelized) ----------------
// grid: (NBATCH, 6). Block (b, cc) handles cols [cc*128, cc*128+128).
__global__ __launch_bounds__(256) void avg_kernel(const float* __restrict__ x2,
        const int* __restrict__ mask, float* __restrict__ avg) {
    __shared__ float4 red[8][33];
    int b = blockIdx.x, cc = blockIdx.y;
    int t = threadIdx.x;
    int rr = t >> 5, c4 = t & 31;
    int c = cc * 128 + c4 * 4;
    const int* mb = mask + b * NIMG;
    float4 s = make_float4(0.f, 0.f, 0.f, 0.f);
    for (int n = rr; n < NIMG; n += 8) {
        if (mb[n]) {
            float4 v = *(const float4*)(x2 + ((size_t)b * SEQ + 1 + n) * CDIM + c);
            s.x += v.x; s.y += v.y; s.z += v.z; s.w += v.w;
        }
    }
    red[rr][c4] = s;
    __syncthreads();
    if (rr == 0) {
        float4 tot = red[0][c4];
        #pragma unroll
        for (int i = 1; i < 8; i++) {
            float4 v = red[i][c4];
            tot.x += v.x; tot.y += v.y; tot.z += v.z; tot.w += v.w;
        }
        float sc1 = 1.f / (float)NMERGE, sc2 = 1.f / (float)(NIMG - NMERGE);
        tot.x = (tot.x * sc1) * sc2; tot.y = (tot.y * sc1) * sc2;
        tot.z = (tot.z * sc1) * sc2; tot.w = (tot.w * sc1) * sc2;
        *(float4*)(avg + (size_t)b * CDIM + c) = tot;
    }
}

// ---------------- assemble output ----------------
__global__ __launch_bounds__(192) void assemble_kernel(const float* __restrict__ x2,
        const int* __restrict__ keeppos, const float* __restrict__ avg,
        float* __restrict__ out) {
    int g = blockIdx.x;
    int b = g / SEQ, s_ = g % SEQ;
    int t = threadIdx.x;
    const float4* src = (const float4*)(x2 + (size_t)g * CDIM);
    if (s_ == 0) {
        float4* dst = (float4*)(out + (size_t)b * 289 * CDIM);
        dst[t] = src[t];
    } else {
        int n = s_ - 1;
        int pos = keeppos[b * NIMG + n];
        if (pos < 0) return;
        const float4* av = (const float4*)(avg + (size_t)b * CDIM);
        float4 v = src[t], a = av[t];
        v.x += a.x; v.y += a.y; v.z += a.z; v.w += a.w;
        float4* dst = (float4*)(out + ((size_t)b * 289 + 1 + pos) * CDIM);
        dst[t] = v;
    }
}

extern "C" void kernel_launch(void* const* d_in, const int* in_sizes, int n_in,
                              void* d_out, int out_size, void* d_ws, size_t ws_size,
                              hipStream_t stream) {
    const float* x      = (const float*)d_in[0];
    const float* qkv_w  = (const float*)d_in[1];
    const float* qkv_b  = (const float*)d_in[2];
    const float* proj_w = (const float*)d_in[3];
    const float* proj_b = (const float*)d_in[4];
    const float* ln1_g  = (const float*)d_in[5];
    const float* ln1_b  = (const float*)d_in[6];
    const float* ln2_g  = (const float*)d_in[7];
    const float* ln2_b  = (const float*)d_in[8];
    const float* fc1_w  = (const float*)d_in[9];
    const float* fc1_b  = (const float*)d_in[10];
    const float* fc2_w  = (const float*)d_in[11];
    const float* fc2_b  = (const float*)d_in[12];

    if (ws_size < NEED_BYTES) return;

    float* ws   = (float*)d_ws;
    float* bh   = ws + O_BH;
    float* ba   = ws + O_BA;
    float* bq   = ws + O_BQ;
    float* ms   = ws + O_MS;
    int*   mask = (int*)(ws + O_MASK);
    int*   pos  = (int*)(ws + O_POS);
    float* avg  = ws + O_AVG;
    float* outp = (float*)d_out;

    // 1. h = LN1(x)
    ln_kernel<<<MTOK, 256, 0, stream>>>(x, ln1_g, ln1_b, bh);

    // 2. per-group qkv GEMM + MFMA attention
    for (int g = 0; g < NGROUP; g++) {
        const float* hg = bh + (size_t)g * MGRP * CDIM;
        float* attg = ba + (size_t)g * MGRP * CDIM;
        gemm_mfma<0><<<dim3((MGRP + 127) / 128, 18, 1), 256, 0, stream>>>(
            hg, 0, CDIM, qkv_w, 0, CDIM, bq, 0, 3 * CDIM, qkv_b, nullptr,
            MGRP, 3 * CDIM, CDIM);
        attn_mfma<<<dim3((SEQ + 63) / 64, NHEADS, GB), 256, 0, stream>>>(
            bq, attg);
    }

    // 3. x1 = x + att @ proj_w^T + proj_b
    gemm_mfma<1><<<dim3((MTOK + 127) / 128, 6, 1), 256, 0, stream>>>(
        ba, 0, CDIM, proj_w, 0, CDIM, bh, 0, CDIM, proj_b, x, MTOK, CDIM, CDIM);

    // 4. h2 = LN2(x1)
    ln_kernel<<<MTOK, 256, 0, stream>>>(bh, ln2_g, ln2_b, ba);

    // 5. MLP in M-chunks
    for (int c0 = 0; c0 < MTOK; c0 += MLPCH) {
        int mc = (MTOK - c0 < MLPCH) ? (MTOK - c0) : MLPCH;
        const float* h2c = ba + (size_t)c0 * CDIM;
        float* x1c = bh + (size_t)c0 * CDIM;
        gemm_mfma<2><<<dim3((mc + 127) / 128, 24, 1), 256, 0, stream>>>(
            h2c, 0, CDIM, fc1_w, 0, CDIM, bq, 0, 3072, fc1_b, nullptr,
            mc, 3072, CDIM);
        gemm_mfma<1><<<dim3((mc + 127) / 128, 6, 1), 256, 0, stream>>>(
            bq, 0, 3072, fc2_w, 0, 3072, x1c, 0, CDIM, fc2_b, x1c,
            mc, CDIM, 3072);
    }

    // 6. normalize img tokens
    xn_kernel<<<NBATCH * NIMG, 256, 0, stream>>>(bh, ba);

    // 7. sim = xn @ xn^T per batch
    gemm_mfma<3><<<dim3(5, 5, NBATCH), 256, 0, stream>>>(
        ba, (long long)NIMG * CDIM, CDIM, ba, (long long)NIMG * CDIM, CDIM,
        bq, (long long)NIMG * NIMG, NIMG, nullptr, nullptr, NIMG, NIMG, CDIM);

    // 8. row max of symmetrized sim
    rowmax_kernel<<<NBATCH * NIMG, 64, 0, stream>>>(bq, ms);
    // 9. top-k selection
    select_kernel<<<NBATCH, NIMG, 0, stream>>>(ms, mask, pos);
    // 10. merged-token average (parallel)
    avg_kernel<<<dim3(NBATCH, 6), 256, 0, stream>>>(bh, mask, avg);
    // 11. assemble output
    assemble_kernel<<<MTOK, 192, 0, stream>>>(bh, pos, avg, outp);
}

// Round 8
// 2931.478 us; speedup vs baseline: 2.2822x; 1.0927x over previous
//
#include <hip/hip_runtime.h>
#include <math.h>

#define CDIM 768
#define NHEADS 12
#define DHEAD 64
#define SEQ 577
#define NBATCH 32
#define MTOK (NBATCH*SEQ)      // 18464
#define NIMG 576
#define NMERGE 288
#define GB 8                   // batches per qkv group
#define NGROUP (NBATCH/GB)     // 4
#define MGRP (GB*SEQ)          // 4616 rows per group
#define MLPCH 3456             // MLP chunk rows

// ---- workspace layout (float offsets), peak ~156 MB ----
#define SZ_MC   ((size_t)MTOK*CDIM)              // 14,180,352
#define O_BH    ((size_t)0)                      // h -> x1/x2 (in-place)
#define O_BA    (SZ_MC)                          // att -> h2 -> xn
#define O_BQ    (2*SZ_MC)                        // qkv group -> fc1o chunk -> sim
#define SZ_BQ   ((size_t)GB*SEQ*3*CDIM)          // 10,635,264
#define O_SM    (O_BQ + SZ_BQ)
#define O_MS    (O_SM)
#define O_MASK  (O_SM + (size_t)NBATCH*NIMG)
#define O_POS   (O_MASK + (size_t)NBATCH*NIMG)
#define O_AVG   (O_POS + (size_t)NBATCH*NIMG)
#define O_END   (O_AVG + (size_t)NBATCH*CDIM)
#define NEED_BYTES (O_END * 4)

typedef __attribute__((ext_vector_type(8))) short bf16x8;
typedef __attribute__((ext_vector_type(4))) float f32x4;

__device__ __forceinline__ unsigned short f2bf(float f) {
    unsigned int u = __float_as_uint(f);
    u += 0x7fff + ((u >> 16) & 1);           // RNE
    return (unsigned short)(u >> 16);
}
__device__ __forceinline__ float bf2f(unsigned short h) {
    return __uint_as_float(((unsigned int)h) << 16);
}

// ---------------- block reduce (256 threads) ----------------
__device__ __forceinline__ float blk_sum256(float v, float* red) {
    #pragma unroll
    for (int o = 32; o; o >>= 1) v += __shfl_down(v, o);
    if ((threadIdx.x & 63) == 0) red[threadIdx.x >> 6] = v;
    __syncthreads();
    float tot = red[0] + red[1] + red[2] + red[3];
    __syncthreads();
    return tot;
}

// ---------------- LayerNorm: one block per row ----------------
__global__ __launch_bounds__(256) void ln_kernel(const float* __restrict__ x,
        const float* __restrict__ g, const float* __restrict__ b,
        float* __restrict__ out) {
    __shared__ float red[4];
    size_t row = blockIdx.x;
    const float* xr = x + row * CDIM;
    float* orow = out + row * CDIM;
    int t = threadIdx.x;
    float v0 = xr[t], v1 = xr[t + 256], v2 = xr[t + 512];
    float mu = blk_sum256(v0 + v1 + v2, red) * (1.f / CDIM);
    float d0 = v0 - mu, d1 = v1 - mu, d2 = v2 - mu;
    float var = blk_sum256(d0 * d0 + d1 * d1 + d2 * d2, red) * (1.f / CDIM);
    float e = var + 1e-5f;
    float rs = rsqrtf(e);
    rs = rs * (1.5f - 0.5f * e * rs * rs);   // NR refine
    orow[t]       = d0 * rs * g[t]       + b[t];
    orow[t + 256] = d1 * rs * g[t + 256] + b[t + 256];
    orow[t + 512] = d2 * rs * g[t + 512] + b[t + 512];
}

// ---------------- MFMA bf16x3-split GEMM (software-pipelined) ----------------
// C = A(MxK) * B(NxK)^T, fp32-equivalent via hi/lo bf16 split (hh+hl+lh).
// 128x128 tile, BK=32, 4 waves (2x2). Pipeline: convert step k in regs ->
// barrier -> ds_write -> barrier -> ds_read frags -> ISSUE LOADS k+1 -> MFMA.
// Numerically bit-identical to the unpipelined version (same op order).
// EPI: 0 = +bias, 1 = +bias+res (res may alias C), 2 = gelu(+bias), 3 = plain
template<int EPI>
__global__ __launch_bounds__(256)
void gemm_mfma(const float* __restrict__ A, long long sA, int lda,
               const float* __restrict__ Bm, long long sB, int ldb,
               float* __restrict__ C, long long sC, int ldc,
               const float* __restrict__ bias,
               const float* __restrict__ res,
               int M, int N, int K) {
    __shared__ unsigned short Asl[128 * 64];
    __shared__ unsigned short Bsl[128 * 64];
    int batch = blockIdx.z;
    A  += (size_t)batch * sA;
    Bm += (size_t)batch * sB;
    C  += (size_t)batch * sC;
    const int m0 = blockIdx.x * 128, n0 = blockIdx.y * 128;
    const int t = threadIdx.x;
    const int lane = t & 63, wid = t >> 6;
    const int wr = wid >> 1, wc = wid & 1;
    const int srow = t >> 3;
    const int sj   = t & 7;

    // loop-invariant clamped source pointers (k=0 base)
    const float* pa[4];
    const float* pb[4];
    #pragma unroll
    for (int i = 0; i < 4; i++) {
        int r = srow + i * 32;
        int ra = m0 + r; ra = ra < M ? ra : M - 1;
        int rb = n0 + r; rb = rb < N ? rb : N - 1;
        pa[i] = A  + (size_t)ra * lda + sj * 4;
        pb[i] = Bm + (size_t)rb * ldb + sj * 4;
    }

    f32x4 acc[4][4];
    #pragma unroll
    for (int i = 0; i < 4; i++)
        #pragma unroll
        for (int j = 0; j < 4; j++) {
            f32x4 z = {0.f, 0.f, 0.f, 0.f};
            acc[i][j] = z;
        }

    const int nsteps = K >> 5;
    // prefetch step 0
    float4 va[4], vb[4];
    #pragma unroll
    for (int i = 0; i < 4; i++) {
        va[i] = *(const float4*)(pa[i]);
        vb[i] = *(const float4*)(pb[i]);
    }

    for (int ks = 0; ks < nsteps; ks++) {
        // ---- convert step ks in registers (no LDS hazard, pre-barrier) ----
        ushort4 cah[4], cal[4], cbh[4], cbl[4];
        #pragma unroll
        for (int i = 0; i < 4; i++) {
            float aa[4] = {va[i].x, va[i].y, va[i].z, va[i].w};
            float bb[4] = {vb[i].x, vb[i].y, vb[i].z, vb[i].w};
            unsigned short h0 = f2bf(aa[0]), h1 = f2bf(aa[1]), h2 = f2bf(aa[2]), h3 = f2bf(aa[3]);
            cah[i] = make_ushort4(h0, h1, h2, h3);
            cal[i] = make_ushort4(f2bf(aa[0] - bf2f(h0)), f2bf(aa[1] - bf2f(h1)),
                                  f2bf(aa[2] - bf2f(h2)), f2bf(aa[3] - bf2f(h3)));
            unsigned short g0 = f2bf(bb[0]), g1 = f2bf(bb[1]), g2 = f2bf(bb[2]), g3 = f2bf(bb[3]);
            cbh[i] = make_ushort4(g0, g1, g2, g3);
            cbl[i] = make_ushort4(f2bf(bb[0] - bf2f(g0)), f2bf(bb[1] - bf2f(g1)),
                                  f2bf(bb[2] - bf2f(g2)), f2bf(bb[3] - bf2f(g3)));
        }
        __syncthreads();   // previous step's LDS reads complete
        // ---- write LDS (swizzled, same image as verified layout) ----
        #pragma unroll
        for (int i = 0; i < 4; i++) {
            int r = srow + i * 32;
            int swz = (r & 7) << 4;
            int ohi = ((8 * sj) ^ swz) >> 1;
            int olo = ((64 + 8 * sj) ^ swz) >> 1;
            *(ushort4*)&Asl[r * 64 + ohi] = cah[i];
            *(ushort4*)&Asl[r * 64 + olo] = cal[i];
            *(ushort4*)&Bsl[r * 64 + ohi] = cbh[i];
            *(ushort4*)&Bsl[r * 64 + olo] = cbl[i];
        }
        __syncthreads();
        // ---- fragment loads ----
        const int fr = lane & 15, kg = lane >> 4;
        bf16x8 ah[4], al[4], bh[4], bl[4];
        #pragma unroll
        for (int m = 0; m < 4; m++) {
            int r = wr * 64 + m * 16 + fr;
            int swz = (r & 7) << 4;
            const unsigned char* base = (const unsigned char*)&Asl[r * 64];
            ah[m] = *(const bf16x8*)(base + ((16 * kg) ^ swz));
            al[m] = *(const bf16x8*)(base + ((64 + 16 * kg) ^ swz));
        }
        #pragma unroll
        for (int n = 0; n < 4; n++) {
            int r = wc * 64 + n * 16 + fr;
            int swz = (r & 7) << 4;
            const unsigned char* base = (const unsigned char*)&Bsl[r * 64];
            bh[n] = *(const bf16x8*)(base + ((16 * kg) ^ swz));
            bl[n] = *(const bf16x8*)(base + ((64 + 16 * kg) ^ swz));
        }
        // ---- prefetch step ks+1 (latency hides under the 48 MFMAs) ----
        if (ks + 1 < nsteps) {
            const int k0n = (ks + 1) << 5;
            #pragma unroll
            for (int i = 0; i < 4; i++) {
                va[i] = *(const float4*)(pa[i] + k0n);
                vb[i] = *(const float4*)(pb[i] + k0n);
            }
        }
        // ---- 48 MFMA ----
        #pragma unroll
        for (int m = 0; m < 4; m++)
            #pragma unroll
            for (int n = 0; n < 4; n++) {
                acc[m][n] = __builtin_amdgcn_mfma_f32_16x16x32_bf16(ah[m], bh[n], acc[m][n], 0, 0, 0);
                acc[m][n] = __builtin_amdgcn_mfma_f32_16x16x32_bf16(ah[m], bl[n], acc[m][n], 0, 0, 0);
                acc[m][n] = __builtin_amdgcn_mfma_f32_16x16x32_bf16(al[m], bh[n], acc[m][n], 0, 0, 0);
            }
    }

    const int fr = lane & 15, fq = lane >> 4;
    #pragma unroll
    for (int m = 0; m < 4; m++) {
        #pragma unroll
        for (int rr = 0; rr < 4; rr++) {
            int row = m0 + wr * 64 + m * 16 + fq * 4 + rr;
            if (row >= M) continue;
            #pragma unroll
            for (int n = 0; n < 4; n++) {
                int col = n0 + wc * 64 + n * 16 + fr;
                if (col >= N) continue;
                float v = acc[m][n][rr];
                size_t ci = (size_t)row * ldc + col;
                if (EPI == 0) {
                    C[ci] = v + bias[col];
                } else if (EPI == 1) {
                    C[ci] = v + bias[col] + res[ci];
                } else if (EPI == 2) {
                    v += bias[col];
                    C[ci] = 0.5f * v * (1.0f + erff(v * 0.70710678118654752f));
                } else {
                    C[ci] = v;
                }
            }
        }
    }
}

// ---------------- MFMA flash attention (bf16x3-split, online softmax) ----------------
__global__ __launch_bounds__(256) void attn_mfma(const float* __restrict__ qkv,
                                                 float* __restrict__ att) {
    const int b = blockIdx.z, h = blockIdx.y, q0 = blockIdx.x * 64;
    const int t = threadIdx.x;
    const int lane = t & 63, wid = t >> 6;
    const int fr = lane & 15, kg = lane >> 4;
    __shared__ unsigned short Khl[64 * 128];
    __shared__ unsigned char SV[64 * 68 * 4];
    __shared__ unsigned short Vt[64 * 128];
    unsigned char* KhlB = (unsigned char*)Khl;
    float* V32 = (float*)SV;
    unsigned char* PwB = SV + wid * 4096;
    unsigned char* VtB = (unsigned char*)Vt;
    const size_t rowbase = (size_t)b * SEQ * (3 * CDIM);

    bf16x8 qh[2], qlo[2];
    {
        int qrow = q0 + wid * 16 + fr; qrow = qrow < SEQ ? qrow : SEQ - 1;
        const float* qbase = qkv + rowbase + (size_t)qrow * (3 * CDIM) + h * DHEAD;
        #pragma unroll
        for (int ds = 0; ds < 2; ds++) {
            float tmp[8];
            *(float4*)(tmp)     = *(const float4*)(qbase + ds * 32 + kg * 8);
            *(float4*)(tmp + 4) = *(const float4*)(qbase + ds * 32 + kg * 8 + 4);
            #pragma unroll
            for (int j = 0; j < 8; j++) {
                unsigned short hh = f2bf(tmp[j]);
                qh[ds][j]  = (short)hh;
                qlo[ds][j] = (short)f2bf(tmp[j] - bf2f(hh));
            }
        }
    }

    f32x4 acc_o[4];
    #pragma unroll
    for (int i = 0; i < 4; i++) { f32x4 z = {0.f,0.f,0.f,0.f}; acc_o[i] = z; }
    float m_run[4] = {-1e30f, -1e30f, -1e30f, -1e30f};
    float l_run[4] = {0.f, 0.f, 0.f, 0.f};

    const int srow = t >> 2;
    const int sq   = t & 3;

    for (int c0 = 0; c0 < SEQ; c0 += 64) {
        float4 kv[4], vv[4];
        {
            int krow = c0 + srow; krow = krow < SEQ ? krow : SEQ - 1;
            const float* base = qkv + rowbase + (size_t)krow * (3 * CDIM) + h * DHEAD;
            #pragma unroll
            for (int i = 0; i < 4; i++) {
                int dchunk = sq * 16 + i * 4;
                kv[i] = *(const float4*)(base + CDIM + dchunk);
                vv[i] = *(const float4*)(base + 2 * CDIM + dchunk);
            }
        }
        __syncthreads();
        {
            int swz = (srow & 7) << 4;
            #pragma unroll
            for (int i = 0; i < 4; i++) {
                int dchunk = sq * 16 + i * 4;
                float a[4] = {kv[i].x, kv[i].y, kv[i].z, kv[i].w};
                unsigned short h0 = f2bf(a[0]), h1 = f2bf(a[1]), h2 = f2bf(a[2]), h3 = f2bf(a[3]);
                ushort4 hv = make_ushort4(h0, h1, h2, h3);
                ushort4 lv = make_ushort4(f2bf(a[0] - bf2f(h0)), f2bf(a[1] - bf2f(h1)),
                                          f2bf(a[2] - bf2f(h2)), f2bf(a[3] - bf2f(h3)));
                *(ushort4*)(KhlB + srow * 256 + ((dchunk * 2) ^ swz)) = hv;
                *(ushort4*)(KhlB + srow * 256 + 128 + ((dchunk * 2) ^ swz)) = lv;
                *(float4*)&V32[srow * 68 + dchunk] = vv[i];
            }
        }
        __syncthreads();
        {
            int d = t >> 2, k0b = (t & 3) * 16;
            unsigned short hb[16], lb[16];
            #pragma unroll
            for (int i = 0; i < 16; i++) {
                float v = V32[(k0b + i) * 68 + d];
                unsigned short hh = f2bf(v);
                hb[i] = hh; lb[i] = f2bf(v - bf2f(hh));
            }
            int swz = (d & 7) << 4;
            #pragma unroll
            for (int c = 0; c < 4; c++) {
                ushort4 hv = make_ushort4(hb[4*c], hb[4*c+1], hb[4*c+2], hb[4*c+3]);
                ushort4 lv = make_ushort4(lb[4*c], lb[4*c+1], lb[4*c+2], lb[4*c+3]);
                *(ushort4*)(VtB + d * 256 + (((k0b + 4 * c) * 2) ^ swz)) = hv;
                *(ushort4*)(VtB + d * 256 + 128 + (((k0b + 4 * c) * 2) ^ swz)) = lv;
            }
        }
        f32x4 s[4];
        #pragma unroll
        for (int i = 0; i < 4; i++) { f32x4 z = {0.f,0.f,0.f,0.f}; s[i] = z; }
        #pragma unroll
        for (int ds = 0; ds < 2; ds++) {
            #pragma unroll
            for (int n = 0; n < 4; n++) {
                int r = n * 16 + fr;
                int swz = (r & 7) << 4;
                const unsigned char* rb = KhlB + r * 256;
                bf16x8 kh = *(const bf16x8*)(rb + ((ds * 64 + kg * 16) ^ swz));
                bf16x8 kl = *(const bf16x8*)(rb + 128 + ((ds * 64 + kg * 16) ^ swz));
                s[n] = __builtin_amdgcn_mfma_f32_16x16x32_bf16(qh[ds], kh, s[n], 0, 0, 0);
                s[n] = __builtin_amdgcn_mfma_f32_16x16x32_bf16(qh[ds], kl, s[n], 0, 0, 0);
                s[n] = __builtin_amdgcn_mfma_f32_16x16x32_bf16(qlo[ds], kh, s[n], 0, 0, 0);
            }
        }
        __syncthreads();
        float p[4][4];
        #pragma unroll
        for (int n = 0; n < 4; n++) {
            int kcol = c0 + n * 16 + fr;
            #pragma unroll
            for (int r = 0; r < 4; r++) {
                float sv = s[n][r] * 0.125f;
                if (kcol >= SEQ) sv = -1e30f;
                p[n][r] = sv;
            }
        }
        float corr[4];
        #pragma unroll
        for (int r = 0; r < 4; r++) {
            float mx = fmaxf(fmaxf(p[0][r], p[1][r]), fmaxf(p[2][r], p[3][r]));
            mx = fmaxf(mx, __shfl_xor(mx, 1));
            mx = fmaxf(mx, __shfl_xor(mx, 2));
            mx = fmaxf(mx, __shfl_xor(mx, 4));
            mx = fmaxf(mx, __shfl_xor(mx, 8));
            float mnew = fmaxf(m_run[r], mx);
            corr[r] = __expf(m_run[r] - mnew);
            m_run[r] = mnew;
            float ls = 0.f;
            #pragma unroll
            for (int n = 0; n < 4; n++) {
                p[n][r] = __expf(p[n][r] - mnew);
                ls += p[n][r];
            }
            ls += __shfl_xor(ls, 1);
            ls += __shfl_xor(ls, 2);
            ls += __shfl_xor(ls, 4);
            ls += __shfl_xor(ls, 8);
            l_run[r] = l_run[r] * corr[r] + ls;
        }
        #pragma unroll
        for (int nd = 0; nd < 4; nd++)
            #pragma unroll
            for (int r = 0; r < 4; r++)
                acc_o[nd][r] *= corr[r];
        {
            int qb = (lane >> 4) * 4;
            #pragma unroll
            for (int n = 0; n < 4; n++) {
                int kcol = n * 16 + fr;
                #pragma unroll
                for (int r = 0; r < 4; r++) {
                    int qq = qb + r;
                    unsigned short ph = f2bf(p[n][r]);
                    unsigned short pl = f2bf(p[n][r] - bf2f(ph));
                    int off = (kcol * 2) ^ ((qq & 7) << 4);
                    *(unsigned short*)(PwB + qq * 256 + off) = ph;
                    *(unsigned short*)(PwB + qq * 256 + 128 + off) = pl;
                }
            }
        }
        #pragma unroll
        for (int ks = 0; ks < 2; ks++) {
            int swzp = (fr & 7) << 4;
            bf16x8 pah = *(const bf16x8*)(PwB + fr * 256 + ((ks * 64 + kg * 16) ^ swzp));
            bf16x8 pal = *(const bf16x8*)(PwB + fr * 256 + 128 + ((ks * 64 + kg * 16) ^ swzp));
            #pragma unroll
            for (int nd = 0; nd < 4; nd++) {
                int rv = nd * 16 + fr;
                int swzv = (rv & 7) << 4;
                const unsigned char* rb = VtB + rv * 256;
                bf16x8 vh = *(const bf16x8*)(rb + ((ks * 64 + kg * 16) ^ swzv));
                bf16x8 vl = *(const bf16x8*)(rb + 128 + ((ks * 64 + kg * 16) ^ swzv));
                acc_o[nd] = __builtin_amdgcn_mfma_f32_16x16x32_bf16(pah, vh, acc_o[nd], 0, 0, 0);
                acc_o[nd] = __builtin_amdgcn_mfma_f32_16x16x32_bf16(pah, vl, acc_o[nd], 0, 0, 0);
                acc_o[nd] = __builtin_amdgcn_mfma_f32_16x16x32_bf16(pal, vh, acc_o[nd], 0, 0, 0);
            }
        }
    }
    #pragma unroll
    for (int r = 0; r < 4; r++) {
        int q = q0 + wid * 16 + (lane >> 4) * 4 + r;
        if (q >= SEQ) continue;
        float inv = 1.f / l_run[r];
        float* o = att + ((size_t)b * SEQ + q) * CDIM + h * DHEAD;
        #pragma unroll
        for (int nd = 0; nd < 4; nd++)
            o[nd * 16 + fr] = acc_o[nd][r] * inv;
    }
}

// ---------------- normalize img tokens ----------------
__global__ __launch_bounds__(256) void xn_kernel(const float* __restrict__ x2,
                                                 float* __restrict__ xn) {
    __shared__ float red[4];
    int tok = blockIdx.x;
    int b = tok / NIMG, n = tok % NIMG;
    const float* xr = x2 + ((size_t)b * SEQ + 1 + n) * CDIM;
    float* onr = xn + (size_t)tok * CDIM;
    int t = threadIdx.x;
    float v0 = xr[t], v1 = xr[t + 256], v2 = xr[t + 512];
    float ss = blk_sum256(v0 * v0 + v1 * v1 + v2 * v2, red);
    float nrm = fmaxf(sqrtf(ss), 1e-12f);
    float inv = 1.f / nrm;
    onr[t] = v0 * inv; onr[t + 256] = v1 * inv; onr[t + 512] = v2 * inv;
}

// ---------------- row max of symmetrized sim (excluding diagonal) ----------------
__global__ __launch_bounds__(64) void rowmax_kernel(const float* __restrict__ sim,
                                                    float* __restrict__ ms) {
    int row = blockIdx.x;
    int b = row / NIMG, n = row % NIMG;
    const float* sb = sim + (size_t)b * NIMG * NIMG;
    int lane = threadIdx.x;
    float mx = -1e30f;
    #pragma unroll
    for (int i = 0; i < NIMG / 64; i++) {
        int m = lane + i * 64;
        if (m != n) {
            float v = 0.5f * (sb[(size_t)n * NIMG + m] + sb[(size_t)m * NIMG + n]);
            mx = fmaxf(mx, v);
        }
    }
    #pragma unroll
    for (int o = 32; o; o >>= 1) mx = fmaxf(mx, __shfl_down(mx, o));
    if (lane == 0) ms[row] = mx;
}

// ---------------- exact top-k selection with lax.top_k tie semantics ----------------
__global__ __launch_bounds__(576) void select_kernel(const float* __restrict__ ms,
        int* __restrict__ mergemask, int* __restrict__ keeppos) {
    __shared__ float v[NIMG];
    __shared__ int keepf[NIMG];
    int b = blockIdx.x;
    int n = threadIdx.x;
    v[n] = ms[b * NIMG + n];
    __syncthreads();
    float vn = v[n];
    int rank_desc = 0, rank_asc = 0;
    for (int m = 0; m < NIMG; m++) {
        float vm = v[m];
        int tie_lo = (vm == vn && m < n);
        rank_desc += (vm > vn) || tie_lo;
        rank_asc  += (vm < vn) || tie_lo;
    }
    int merge = rank_desc < NMERGE;
    int keep  = rank_asc  < NMERGE;
    mergemask[b * NIMG + n] = merge;
    keepf[n] = keep;
    __syncthreads();
    if (keep) {
        int pos = 0;
        for (int m = 0; m < n; m++) pos += keepf[m];
        keeppos[b * NIMG + n] = pos;
    } else {
        keeppos[b * NIMG + n] = -1;
    }
}

// ---------------- average of merged tokens (parallelized) ----------------
__global__ __launch_bounds__(256) void avg_kernel(const float* __restrict__ x2,
        const int* __restrict__ mask, float* __restrict__ avg) {
    __shared__ float4 red[8][33];
    int b = blockIdx.x, cc = blockIdx.y;
    int t = threadIdx.x;
    int rr = t >> 5, c4 = t & 31;
    int c = cc * 128 + c4 * 4;
    const int* mb = mask + b * NIMG;
    float4 s = make_float4(0.f, 0.f, 0.f, 0.f);
    for (int n = rr; n < NIMG; n += 8) {
        if (mb[n]) {
            float4 v = *(const float4*)(x2 + ((size_t)b * SEQ + 1 + n) * CDIM + c);
            s.x += v.x; s.y += v.y; s.z += v.z; s.w += v.w;
        }
    }
    red[rr][c4] = s;
    __syncthreads();
    if (rr == 0) {
        float4 tot = red[0][c4];
        #pragma unroll
        for (int i = 1; i < 8; i++) {
            float4 v = red[i][c4];
            tot.x += v.x; tot.y += v.y; tot.z += v.z; tot.w += v.w;
        }
        float sc1 = 1.f / (float)NMERGE, sc2 = 1.f / (float)(NIMG - NMERGE);
        tot.x = (tot.x * sc1) * sc2; tot.y = (tot.y * sc1) * sc2;
        tot.z = (tot.z * sc1) * sc2; tot.w = (tot.w * sc1) * sc2;
        *(float4*)(avg + (size_t)b * CDIM + c) = tot;
    }
}

// ---------------- assemble output ----------------
__global__ __launch_bounds__(192) void assemble_kernel(const float* __restrict__ x2,
        const int* __restrict__ keeppos, const float* __restrict__ avg,
        float* __restrict__ out) {
    int g = blockIdx.x;
    int b = g / SEQ, s_ = g % SEQ;
    int t = threadIdx.x;
    const float4* src = (const float4*)(x2 + (size_t)g * CDIM);
    if (s_ == 0) {
        float4* dst = (float4*)(out + (size_t)b * 289 * CDIM);
        dst[t] = src[t];
    } else {
        int n = s_ - 1;
        int pos = keeppos[b * NIMG + n];
        if (pos < 0) return;
        const float4* av = (const float4*)(avg + (size_t)b * CDIM);
        float4 v = src[t], a = av[t];
        v.x += a.x; v.y += a.y; v.z += a.z; v.w += a.w;
        float4* dst = (float4*)(out + ((size_t)b * 289 + 1 + pos) * CDIM);
        dst[t] = v;
    }
}

extern "C" void kernel_launch(void* const* d_in, const int* in_sizes, int n_in,
                              void* d_out, int out_size, void* d_ws, size_t ws_size,
                              hipStream_t stream) {
    const float* x      = (const float*)d_in[0];
    const float* qkv_w  = (const float*)d_in[1];
    const float* qkv_b  = (const float*)d_in[2];
    const float* proj_w = (const float*)d_in[3];
    const float* proj_b = (const float*)d_in[4];
    const float* ln1_g  = (const float*)d_in[5];
    const float* ln1_b  = (const float*)d_in[6];
    const float* ln2_g  = (const float*)d_in[7];
    const float* ln2_b  = (const float*)d_in[8];
    const float* fc1_w  = (const float*)d_in[9];
    const float* fc1_b  = (const float*)d_in[10];
    const float* fc2_w  = (const float*)d_in[11];
    const float* fc2_b  = (const float*)d_in[12];

    if (ws_size < NEED_BYTES) return;

    float* ws   = (float*)d_ws;
    float* bh   = ws + O_BH;
    float* ba   = ws + O_BA;
    float* bq   = ws + O_BQ;
    float* ms   = ws + O_MS;
    int*   mask = (int*)(ws + O_MASK);
    int*   pos  = (int*)(ws + O_POS);
    float* avg  = ws + O_AVG;
    float* outp = (float*)d_out;

    // 1. h = LN1(x)
    ln_kernel<<<MTOK, 256, 0, stream>>>(x, ln1_g, ln1_b, bh);

    // 2. per-group qkv GEMM + MFMA attention
    for (int g = 0; g < NGROUP; g++) {
        const float* hg = bh + (size_t)g * MGRP * CDIM;
        float* attg = ba + (size_t)g * MGRP * CDIM;
        gemm_mfma<0><<<dim3((MGRP + 127) / 128, 18, 1), 256, 0, stream>>>(
            hg, 0, CDIM, qkv_w, 0, CDIM, bq, 0, 3 * CDIM, qkv_b, nullptr,
            MGRP, 3 * CDIM, CDIM);
        attn_mfma<<<dim3((SEQ + 63) / 64, NHEADS, GB), 256, 0, stream>>>(
            bq, attg);
    }

    // 3. x1 = x + att @ proj_w^T + proj_b
    gemm_mfma<1><<<dim3((MTOK + 127) / 128, 6, 1), 256, 0, stream>>>(
        ba, 0, CDIM, proj_w, 0, CDIM, bh, 0, CDIM, proj_b, x, MTOK, CDIM, CDIM);

    // 4. h2 = LN2(x1)
    ln_kernel<<<MTOK, 256, 0, stream>>>(bh, ln2_g, ln2_b, ba);

    // 5. MLP in M-chunks
    for (int c0 = 0; c0 < MTOK; c0 += MLPCH) {
        int mc = (MTOK - c0 < MLPCH) ? (MTOK - c0) : MLPCH;
        const float* h2c = ba + (size_t)c0 * CDIM;
        float* x1c = bh + (size_t)c0 * CDIM;
        gemm_mfma<2><<<dim3((mc + 127) / 128, 24, 1), 256, 0, stream>>>(
            h2c, 0, CDIM, fc1_w, 0, CDIM, bq, 0, 3072, fc1_b, nullptr,
            mc, 3072, CDIM);
        gemm_mfma<1><<<dim3((mc + 127) / 128, 6, 1), 256, 0, stream>>>(
            bq, 0, 3072, fc2_w, 0, 3072, x1c, 0, CDIM, fc2_b, x1c,
            mc, CDIM, 3072);
    }

    // 6. normalize img tokens
    xn_kernel<<<NBATCH * NIMG, 256, 0, stream>>>(bh, ba);

    // 7. sim = xn @ xn^T per batch
    gemm_mfma<3><<<dim3(5, 5, NBATCH), 256, 0, stream>>>(
        ba, (long long)NIMG * CDIM, CDIM, ba, (long long)NIMG * CDIM, CDIM,
        bq, (long long)NIMG * NIMG, NIMG, nullptr, nullptr, NIMG, NIMG, CDIM);

    // 8. row max of symmetrized sim
    rowmax_kernel<<<NBATCH * NIMG, 64, 0, stream>>>(bq, ms);
    // 9. top-k selection
    select_kernel<<<NBATCH, NIMG, 0, stream>>>(ms, mask, pos);
    // 10. merged-token average (parallel)
    avg_kernel<<<dim3(NBATCH, 6), 256, 0, stream>>>(bh, mask, avg);
    // 11. assemble output
    assemble_kernel<<<MTOK, 192, 0, stream>>>(bh, pos, avg, outp);
}

// Round 9
// 2706.383 us; speedup vs baseline: 2.4720x; 1.0832x over previous
//
#include <hip/hip_runtime.h>
#include <math.h>

#define CDIM 768
#define NHEADS 12
#define DHEAD 64
#define SEQ 577
#define NBATCH 32
#define MTOK (NBATCH*SEQ)      // 18464
#define NIMG 576
#define NMERGE 288
#define GB 8                   // batches per qkv group
#define NGROUP (NBATCH/GB)     // 4
#define MGRP (GB*SEQ)          // 4616 rows per group
#define MLPCH 3456             // MLP chunk rows

// ---- workspace layout (float offsets), peak ~156 MB ----
#define SZ_MC   ((size_t)MTOK*CDIM)              // 14,180,352
#define O_BH    ((size_t)0)                      // h -> x1/x2 (in-place)
#define O_BA    (SZ_MC)                          // att -> h2 -> xn
#define O_BQ    (2*SZ_MC)                        // qkv group -> fc1o chunk -> sim
#define SZ_BQ   ((size_t)GB*SEQ*3*CDIM)          // 10,635,264
#define O_SM    (O_BQ + SZ_BQ)
#define O_MS    (O_SM)
#define O_MASK  (O_SM + (size_t)NBATCH*NIMG)
#define O_POS   (O_MASK + (size_t)NBATCH*NIMG)
#define O_AVG   (O_POS + (size_t)NBATCH*NIMG)
#define O_END   (O_AVG + (size_t)NBATCH*CDIM)
#define NEED_BYTES (O_END * 4)

typedef __attribute__((ext_vector_type(8))) short bf16x8;
typedef __attribute__((ext_vector_type(4))) float f32x4;

__device__ __forceinline__ unsigned short f2bf(float f) {
    unsigned int u = __float_as_uint(f);
    u += 0x7fff + ((u >> 16) & 1);           // RNE
    return (unsigned short)(u >> 16);
}
__device__ __forceinline__ float bf2f(unsigned short h) {
    return __uint_as_float(((unsigned int)h) << 16);
}

// ---- bijective XCD-chunked block remap (guide m204): each of the 8 XCDs
// (hardware round-robins workgroups by id%8) gets a CONTIGUOUS tile range,
// so shared A/B panels are filled into 1 L2 instead of 8. Bijective for any
// grid size -> every tile computed exactly once (zero correctness risk).
__device__ __forceinline__ void xcd_map(int& bx, int& by, int& bz) {
    int gx = gridDim.x, gy = gridDim.y;
    int nwg = gx * gy * gridDim.z;
    int orig = blockIdx.x + gx * (blockIdx.y + gy * blockIdx.z);
    int q = nwg >> 3, r = nwg & 7;
    int xcd = orig & 7, pos = orig >> 3;
    int wg = (xcd < r ? xcd * (q + 1) : r * (q + 1) + (xcd - r) * q) + pos;
    bx = wg % gx;
    int t2 = wg / gx;
    by = t2 % gy;
    bz = t2 / gy;
}

// ---------------- block reduce (256 threads) ----------------
__device__ __forceinline__ float blk_sum256(float v, float* red) {
    #pragma unroll
    for (int o = 32; o; o >>= 1) v += __shfl_down(v, o);
    if ((threadIdx.x & 63) == 0) red[threadIdx.x >> 6] = v;
    __syncthreads();
    float tot = red[0] + red[1] + red[2] + red[3];
    __syncthreads();
    return tot;
}

// ---------------- LayerNorm: one block per row ----------------
__global__ __launch_bounds__(256) void ln_kernel(const float* __restrict__ x,
        const float* __restrict__ g, const float* __restrict__ b,
        float* __restrict__ out) {
    __shared__ float red[4];
    size_t row = blockIdx.x;
    const float* xr = x + row * CDIM;
    float* orow = out + row * CDIM;
    int t = threadIdx.x;
    float v0 = xr[t], v1 = xr[t + 256], v2 = xr[t + 512];
    float mu = blk_sum256(v0 + v1 + v2, red) * (1.f / CDIM);
    float d0 = v0 - mu, d1 = v1 - mu, d2 = v2 - mu;
    float var = blk_sum256(d0 * d0 + d1 * d1 + d2 * d2, red) * (1.f / CDIM);
    float e = var + 1e-5f;
    float rs = rsqrtf(e);
    rs = rs * (1.5f - 0.5f * e * rs * rs);   // NR refine
    orow[t]       = d0 * rs * g[t]       + b[t];
    orow[t + 256] = d1 * rs * g[t + 256] + b[t + 256];
    orow[t + 512] = d2 * rs * g[t + 512] + b[t + 512];
}

// ---------------- MFMA bf16x3-split GEMM (pipelined + XCD-swizzled) ----------------
// C = A(MxK) * B(NxK)^T, fp32-equivalent via hi/lo bf16 split (hh+hl+lh).
// 128x128 tile, BK=32, 4 waves (2x2). Pipeline: convert step k (consumes
// prefetch regs) -> IMMEDIATELY issue loads k+1 (latency hides under
// barrier+ds_write+barrier+ds_read+MFMA, a full step) -> barrier -> ...
// Numerically bit-identical to round-7/8 versions (same op order).
// EPI: 0 = +bias, 1 = +bias+res (res may alias C), 2 = gelu(+bias), 3 = plain
template<int EPI>
__global__ __launch_bounds__(256)
void gemm_mfma(const float* __restrict__ A, long long sA, int lda,
               const float* __restrict__ Bm, long long sB, int ldb,
               float* __restrict__ C, long long sC, int ldc,
               const float* __restrict__ bias,
               const float* __restrict__ res,
               int M, int N, int K) {
    __shared__ unsigned short Asl[128 * 64];
    __shared__ unsigned short Bsl[128 * 64];
    int bx, by, bz;
    xcd_map(bx, by, bz);
    A  += (size_t)bz * sA;
    Bm += (size_t)bz * sB;
    C  += (size_t)bz * sC;
    const int m0 = bx * 128, n0 = by * 128;
    const int t = threadIdx.x;
    const int lane = t & 63, wid = t >> 6;
    const int wr = wid >> 1, wc = wid & 1;
    const int srow = t >> 3;
    const int sj   = t & 7;

    // loop-invariant clamped source pointers (k=0 base)
    const float* pa[4];
    const float* pb[4];
    #pragma unroll
    for (int i = 0; i < 4; i++) {
        int r = srow + i * 32;
        int ra = m0 + r; ra = ra < M ? ra : M - 1;
        int rb = n0 + r; rb = rb < N ? rb : N - 1;
        pa[i] = A  + (size_t)ra * lda + sj * 4;
        pb[i] = Bm + (size_t)rb * ldb + sj * 4;
    }

    f32x4 acc[4][4];
    #pragma unroll
    for (int i = 0; i < 4; i++)
        #pragma unroll
        for (int j = 0; j < 4; j++) {
            f32x4 z = {0.f, 0.f, 0.f, 0.f};
            acc[i][j] = z;
        }

    const int nsteps = K >> 5;
    // prefetch step 0
    float4 va[4], vb[4];
    #pragma unroll
    for (int i = 0; i < 4; i++) {
        va[i] = *(const float4*)(pa[i]);
        vb[i] = *(const float4*)(pb[i]);
    }

    for (int ks = 0; ks < nsteps; ks++) {
        // ---- convert step ks in registers (consumes va/vb) ----
        ushort4 cah[4], cal[4], cbh[4], cbl[4];
        #pragma unroll
        for (int i = 0; i < 4; i++) {
            float aa[4] = {va[i].x, va[i].y, va[i].z, va[i].w};
            float bb[4] = {vb[i].x, vb[i].y, vb[i].z, vb[i].w};
            unsigned short h0 = f2bf(aa[0]), h1 = f2bf(aa[1]), h2 = f2bf(aa[2]), h3 = f2bf(aa[3]);
            cah[i] = make_ushort4(h0, h1, h2, h3);
            cal[i] = make_ushort4(f2bf(aa[0] - bf2f(h0)), f2bf(aa[1] - bf2f(h1)),
                                  f2bf(aa[2] - bf2f(h2)), f2bf(aa[3] - bf2f(h3)));
            unsigned short g0 = f2bf(bb[0]), g1 = f2bf(bb[1]), g2 = f2bf(bb[2]), g3 = f2bf(bb[3]);
            cbh[i] = make_ushort4(g0, g1, g2, g3);
            cbl[i] = make_ushort4(f2bf(bb[0] - bf2f(g0)), f2bf(bb[1] - bf2f(g1)),
                                  f2bf(bb[2] - bf2f(g2)), f2bf(bb[3] - bf2f(g3)));
        }
        // ---- issue loads for ks+1 NOW: full-step latency window ----
        if (ks + 1 < nsteps) {
            const int k0n = (ks + 1) << 5;
            #pragma unroll
            for (int i = 0; i < 4; i++) {
                va[i] = *(const float4*)(pa[i] + k0n);
                vb[i] = *(const float4*)(pb[i] + k0n);
            }
        }
        __syncthreads();   // previous step's LDS reads complete
        // ---- write LDS (swizzled, same image as verified layout) ----
        #pragma unroll
        for (int i = 0; i < 4; i++) {
            int r = srow + i * 32;
            int swz = (r & 7) << 4;
            int ohi = ((8 * sj) ^ swz) >> 1;
            int olo = ((64 + 8 * sj) ^ swz) >> 1;
            *(ushort4*)&Asl[r * 64 + ohi] = cah[i];
            *(ushort4*)&Asl[r * 64 + olo] = cal[i];
            *(ushort4*)&Bsl[r * 64 + ohi] = cbh[i];
            *(ushort4*)&Bsl[r * 64 + olo] = cbl[i];
        }
        __syncthreads();
        // ---- fragment loads ----
        const int fr = lane & 15, kg = lane >> 4;
        bf16x8 ah[4], al[4], bh[4], bl[4];
        #pragma unroll
        for (int m = 0; m < 4; m++) {
            int r = wr * 64 + m * 16 + fr;
            int swz = (r & 7) << 4;
            const unsigned char* base = (const unsigned char*)&Asl[r * 64];
            ah[m] = *(const bf16x8*)(base + ((16 * kg) ^ swz));
            al[m] = *(const bf16x8*)(base + ((64 + 16 * kg) ^ swz));
        }
        #pragma unroll
        for (int n = 0; n < 4; n++) {
            int r = wc * 64 + n * 16 + fr;
            int swz = (r & 7) << 4;
            const unsigned char* base = (const unsigned char*)&Bsl[r * 64];
            bh[n] = *(const bf16x8*)(base + ((16 * kg) ^ swz));
            bl[n] = *(const bf16x8*)(base + ((64 + 16 * kg) ^ swz));
        }
        // ---- 48 MFMA ----
        #pragma unroll
        for (int m = 0; m < 4; m++)
            #pragma unroll
            for (int n = 0; n < 4; n++) {
                acc[m][n] = __builtin_amdgcn_mfma_f32_16x16x32_bf16(ah[m], bh[n], acc[m][n], 0, 0, 0);
                acc[m][n] = __builtin_amdgcn_mfma_f32_16x16x32_bf16(ah[m], bl[n], acc[m][n], 0, 0, 0);
                acc[m][n] = __builtin_amdgcn_mfma_f32_16x16x32_bf16(al[m], bh[n], acc[m][n], 0, 0, 0);
            }
    }

    const int fr = lane & 15, fq = lane >> 4;
    #pragma unroll
    for (int m = 0; m < 4; m++) {
        #pragma unroll
        for (int rr = 0; rr < 4; rr++) {
            int row = m0 + wr * 64 + m * 16 + fq * 4 + rr;
            if (row >= M) continue;
            #pragma unroll
            for (int n = 0; n < 4; n++) {
                int col = n0 + wc * 64 + n * 16 + fr;
                if (col >= N) continue;
                float v = acc[m][n][rr];
                size_t ci = (size_t)row * ldc + col;
                if (EPI == 0) {
                    C[ci] = v + bias[col];
                } else if (EPI == 1) {
                    C[ci] = v + bias[col] + res[ci];
                } else if (EPI == 2) {
                    v += bias[col];
                    C[ci] = 0.5f * v * (1.0f + erff(v * 0.70710678118654752f));
                } else {
                    C[ci] = v;
                }
            }
        }
    }
}

// ---------------- MFMA flash attention (bf16x3-split, online softmax) ----------------
__global__ __launch_bounds__(256) void attn_mfma(const float* __restrict__ qkv,
                                                 float* __restrict__ att) {
    int bx, by, bz;
    xcd_map(bx, by, bz);
    const int b = bz, h = by, q0 = bx * 64;
    const int t = threadIdx.x;
    const int lane = t & 63, wid = t >> 6;
    const int fr = lane & 15, kg = lane >> 4;
    __shared__ unsigned short Khl[64 * 128];
    __shared__ unsigned char SV[64 * 68 * 4];
    __shared__ unsigned short Vt[64 * 128];
    unsigned char* KhlB = (unsigned char*)Khl;
    float* V32 = (float*)SV;
    unsigned char* PwB = SV + wid * 4096;
    unsigned char* VtB = (unsigned char*)Vt;
    const size_t rowbase = (size_t)b * SEQ * (3 * CDIM);

    bf16x8 qh[2], qlo[2];
    {
        int qrow = q0 + wid * 16 + fr; qrow = qrow < SEQ ? qrow : SEQ - 1;
        const float* qbase = qkv + rowbase + (size_t)qrow * (3 * CDIM) + h * DHEAD;
        #pragma unroll
        for (int ds = 0; ds < 2; ds++) {
            float tmp[8];
            *(float4*)(tmp)     = *(const float4*)(qbase + ds * 32 + kg * 8);
            *(float4*)(tmp + 4) = *(const float4*)(qbase + ds * 32 + kg * 8 + 4);
            #pragma unroll
            for (int j = 0; j < 8; j++) {
                unsigned short hh = f2bf(tmp[j]);
                qh[ds][j]  = (short)hh;
                qlo[ds][j] = (short)f2bf(tmp[j] - bf2f(hh));
            }
        }
    }

    f32x4 acc_o[4];
    #pragma unroll
    for (int i = 0; i < 4; i++) { f32x4 z = {0.f,0.f,0.f,0.f}; acc_o[i] = z; }
    float m_run[4] = {-1e30f, -1e30f, -1e30f, -1e30f};
    float l_run[4] = {0.f, 0.f, 0.f, 0.f};

    const int srow = t >> 2;
    const int sq   = t & 3;

    for (int c0 = 0; c0 < SEQ; c0 += 64) {
        float4 kv[4], vv[4];
        {
            int krow = c0 + srow; krow = krow < SEQ ? krow : SEQ - 1;
            const float* base = qkv + rowbase + (size_t)krow * (3 * CDIM) + h * DHEAD;
            #pragma unroll
            for (int i = 0; i < 4; i++) {
                int dchunk = sq * 16 + i * 4;
                kv[i] = *(const float4*)(base + CDIM + dchunk);
                vv[i] = *(const float4*)(base + 2 * CDIM + dchunk);
            }
        }
        __syncthreads();
        {
            int swz = (srow & 7) << 4;
            #pragma unroll
            for (int i = 0; i < 4; i++) {
                int dchunk = sq * 16 + i * 4;
                float a[4] = {kv[i].x, kv[i].y, kv[i].z, kv[i].w};
                unsigned short h0 = f2bf(a[0]), h1 = f2bf(a[1]), h2 = f2bf(a[2]), h3 = f2bf(a[3]);
                ushort4 hv = make_ushort4(h0, h1, h2, h3);
                ushort4 lv = make_ushort4(f2bf(a[0] - bf2f(h0)), f2bf(a[1] - bf2f(h1)),
                                          f2bf(a[2] - bf2f(h2)), f2bf(a[3] - bf2f(h3)));
                *(ushort4*)(KhlB + srow * 256 + ((dchunk * 2) ^ swz)) = hv;
                *(ushort4*)(KhlB + srow * 256 + 128 + ((dchunk * 2) ^ swz)) = lv;
                *(float4*)&V32[srow * 68 + dchunk] = vv[i];
            }
        }
        __syncthreads();
        {
            int d = t >> 2, k0b = (t & 3) * 16;
            unsigned short hb[16], lb[16];
            #pragma unroll
            for (int i = 0; i < 16; i++) {
                float v = V32[(k0b + i) * 68 + d];
                unsigned short hh = f2bf(v);
                hb[i] = hh; lb[i] = f2bf(v - bf2f(hh));
            }
            int swz = (d & 7) << 4;
            #pragma unroll
            for (int c = 0; c < 4; c++) {
                ushort4 hv = make_ushort4(hb[4*c], hb[4*c+1], hb[4*c+2], hb[4*c+3]);
                ushort4 lv = make_ushort4(lb[4*c], lb[4*c+1], lb[4*c+2], lb[4*c+3]);
                *(ushort4*)(VtB + d * 256 + (((k0b + 4 * c) * 2) ^ swz)) = hv;
                *(ushort4*)(VtB + d * 256 + 128 + (((k0b + 4 * c) * 2) ^ swz)) = lv;
            }
        }
        f32x4 s[4];
        #pragma unroll
        for (int i = 0; i < 4; i++) { f32x4 z = {0.f,0.f,0.f,0.f}; s[i] = z; }
        #pragma unroll
        for (int ds = 0; ds < 2; ds++) {
            #pragma unroll
            for (int n = 0; n < 4; n++) {
                int r = n * 16 + fr;
                int swz = (r & 7) << 4;
                const unsigned char* rb = KhlB + r * 256;
                bf16x8 kh = *(const bf16x8*)(rb + ((ds * 64 + kg * 16) ^ swz));
                bf16x8 kl = *(const bf16x8*)(rb + 128 + ((ds * 64 + kg * 16) ^ swz));
                s[n] = __builtin_amdgcn_mfma_f32_16x16x32_bf16(qh[ds], kh, s[n], 0, 0, 0);
                s[n] = __builtin_amdgcn_mfma_f32_16x16x32_bf16(qh[ds], kl, s[n], 0, 0, 0);
                s[n] = __builtin_amdgcn_mfma_f32_16x16x32_bf16(qlo[ds], kh, s[n], 0, 0, 0);
            }
        }
        __syncthreads();
        float p[4][4];
        #pragma unroll
        for (int n = 0; n < 4; n++) {
            int kcol = c0 + n * 16 + fr;
            #pragma unroll
            for (int r = 0; r < 4; r++) {
                float sv = s[n][r] * 0.125f;
                if (kcol >= SEQ) sv = -1e30f;
                p[n][r] = sv;
            }
        }
        float corr[4];
        #pragma unroll
        for (int r = 0; r < 4; r++) {
            float mx = fmaxf(fmaxf(p[0][r], p[1][r]), fmaxf(p[2][r], p[3][r]));
            mx = fmaxf(mx, __shfl_xor(mx, 1));
            mx = fmaxf(mx, __shfl_xor(mx, 2));
            mx = fmaxf(mx, __shfl_xor(mx, 4));
            mx = fmaxf(mx, __shfl_xor(mx, 8));
            float mnew = fmaxf(m_run[r], mx);
            corr[r] = __expf(m_run[r] - mnew);
            m_run[r] = mnew;
            float ls = 0.f;
            #pragma unroll
            for (int n = 0; n < 4; n++) {
                p[n][r] = __expf(p[n][r] - mnew);
                ls += p[n][r];
            }
            ls += __shfl_xor(ls, 1);
            ls += __shfl_xor(ls, 2);
            ls += __shfl_xor(ls, 4);
            ls += __shfl_xor(ls, 8);
            l_run[r] = l_run[r] * corr[r] + ls;
        }
        #pragma unroll
        for (int nd = 0; nd < 4; nd++)
            #pragma unroll
            for (int r = 0; r < 4; r++)
                acc_o[nd][r] *= corr[r];
        {
            int qb = (lane >> 4) * 4;
            #pragma unroll
            for (int n = 0; n < 4; n++) {
                int kcol = n * 16 + fr;
                #pragma unroll
                for (int r = 0; r < 4; r++) {
                    int qq = qb + r;
                    unsigned short ph = f2bf(p[n][r]);
                    unsigned short pl = f2bf(p[n][r] - bf2f(ph));
                    int off = (kcol * 2) ^ ((qq & 7) << 4);
                    *(unsigned short*)(PwB + qq * 256 + off) = ph;
                    *(unsigned short*)(PwB + qq * 256 + 128 + off) = pl;
                }
            }
        }
        #pragma unroll
        for (int ks = 0; ks < 2; ks++) {
            int swzp = (fr & 7) << 4;
            bf16x8 pah = *(const bf16x8*)(PwB + fr * 256 + ((ks * 64 + kg * 16) ^ swzp));
            bf16x8 pal = *(const bf16x8*)(PwB + fr * 256 + 128 + ((ks * 64 + kg * 16) ^ swzp));
            #pragma unroll
            for (int nd = 0; nd < 4; nd++) {
                int rv = nd * 16 + fr;
                int swzv = (rv & 7) << 4;
                const unsigned char* rb = VtB + rv * 256;
                bf16x8 vh = *(const bf16x8*)(rb + ((ks * 64 + kg * 16) ^ swzv));
                bf16x8 vl = *(const bf16x8*)(rb + 128 + ((ks * 64 + kg * 16) ^ swzv));
                acc_o[nd] = __builtin_amdgcn_mfma_f32_16x16x32_bf16(pah, vh, acc_o[nd], 0, 0, 0);
                acc_o[nd] = __builtin_amdgcn_mfma_f32_16x16x32_bf16(pah, vl, acc_o[nd], 0, 0, 0);
                acc_o[nd] = __builtin_amdgcn_mfma_f32_16x16x32_bf16(pal, vh, acc_o[nd], 0, 0, 0);
            }
        }
    }
    #pragma unroll
    for (int r = 0; r < 4; r++) {
        int q = q0 + wid * 16 + (lane >> 4) * 4 + r;
        if (q >= SEQ) continue;
        float inv = 1.f / l_run[r];
        float* o = att + ((size_t)b * SEQ + q) * CDIM + h * DHEAD;
        #pragma unroll
        for (int nd = 0; nd < 4; nd++)
            o[nd * 16 + fr] = acc_o[nd][r] * inv;
    }
}

// ---------------- normalize img tokens ----------------
__global__ __launch_bounds__(256) void xn_kernel(const float* __restrict__ x2,
                                                 float* __restrict__ xn) {
    __shared__ float red[4];
    int tok = blockIdx.x;
    int b = tok / NIMG, n = tok % NIMG;
    const float* xr = x2 + ((size_t)b * SEQ + 1 + n) * CDIM;
    float* onr = xn + (size_t)tok * CDIM;
    int t = threadIdx.x;
    float v0 = xr[t], v1 = xr[t + 256], v2 = xr[t + 512];
    float ss = blk_sum256(v0 * v0 + v1 * v1 + v2 * v2, red);
    float nrm = fmaxf(sqrtf(ss), 1e-12f);
    float inv = 1.f / nrm;
    onr[t] = v0 * inv; onr[t + 256] = v1 * inv; onr[t + 512] = v2 * inv;
}

// ---------------- row max of symmetrized sim (excluding diagonal) ----------------
__global__ __launch_bounds__(64) void rowmax_kernel(const float* __restrict__ sim,
                                                    float* __restrict__ ms) {
    int row = blockIdx.x;
    int b = row / NIMG, n = row % NIMG;
    const float* sb = sim + (size_t)b * NIMG * NIMG;
    int lane = threadIdx.x;
    float mx = -1e30f;
    #pragma unroll
    for (int i = 0; i < NIMG / 64; i++) {
        int m = lane + i * 64;
        if (m != n) {
            float v = 0.5f * (sb[(size_t)n * NIMG + m] + sb[(size_t)m * NIMG + n]);
            mx = fmaxf(mx, v);
        }
    }
    #pragma unroll
    for (int o = 32; o; o >>= 1) mx = fmaxf(mx, __shfl_down(mx, o));
    if (lane == 0) ms[row] = mx;
}

// ---------------- exact top-k selection with lax.top_k tie semantics ----------------
__global__ __launch_bounds__(576) void select_kernel(const float* __restrict__ ms,
        int* __restrict__ mergemask, int* __restrict__ keeppos) {
    __shared__ float v[NIMG];
    __shared__ int keepf[NIMG];
    int b = blockIdx.x;
    int n = threadIdx.x;
    v[n] = ms[b * NIMG + n];
    __syncthreads();
    float vn = v[n];
    int rank_desc = 0, rank_asc = 0;
    for (int m = 0; m < NIMG; m++) {
        float vm = v[m];
        int tie_lo = (vm == vn && m < n);
        rank_desc += (vm > vn) || tie_lo;
        rank_asc  += (vm < vn) || tie_lo;
    }
    int merge = rank_desc < NMERGE;
    int keep  = rank_asc  < NMERGE;
    mergemask[b * NIMG + n] = merge;
    keepf[n] = keep;
    __syncthreads();
    if (keep) {
        int pos = 0;
        for (int m = 0; m < n; m++) pos += keepf[m];
        keeppos[b * NIMG + n] = pos;
    } else {
        keeppos[b * NIMG + n] = -1;
    }
}

// ---------------- average of merged tokens (parallelized) ----------------
__global__ __launch_bounds__(256) void avg_kernel(const float* __restrict__ x2,
        const int* __restrict__ mask, float* __restrict__ avg) {
    __shared__ float4 red[8][33];
    int b = blockIdx.x, cc = blockIdx.y;
    int t = threadIdx.x;
    int rr = t >> 5, c4 = t & 31;
    int c = cc * 128 + c4 * 4;
    const int* mb = mask + b * NIMG;
    float4 s = make_float4(0.f, 0.f, 0.f, 0.f);
    for (int n = rr; n < NIMG; n += 8) {
        if (mb[n]) {
            float4 v = *(const float4*)(x2 + ((size_t)b * SEQ + 1 + n) * CDIM + c);
            s.x += v.x; s.y += v.y; s.z += v.z; s.w += v.w;
        }
    }
    red[rr][c4] = s;
    __syncthreads();
    if (rr == 0) {
        float4 tot = red[0][c4];
        #pragma unroll
        for (int i = 1; i < 8; i++) {
            float4 v = red[i][c4];
            tot.x += v.x; tot.y += v.y; tot.z += v.z; tot.w += v.w;
        }
        float sc1 = 1.f / (float)NMERGE, sc2 = 1.f / (float)(NIMG - NMERGE);
        tot.x = (tot.x * sc1) * sc2; tot.y = (tot.y * sc1) * sc2;
        tot.z = (tot.z * sc1) * sc2; tot.w = (tot.w * sc1) * sc2;
        *(float4*)(avg + (size_t)b * CDIM + c) = tot;
    }
}

// ---------------- assemble output ----------------
__global__ __launch_bounds__(192) void assemble_kernel(const float* __restrict__ x2,
        const int* __restrict__ keeppos, const float* __restrict__ avg,
        float* __restrict__ out) {
    int g = blockIdx.x;
    int b = g / SEQ, s_ = g % SEQ;
    int t = threadIdx.x;
    const float4* src = (const float4*)(x2 + (size_t)g * CDIM);
    if (s_ == 0) {
        float4* dst = (float4*)(out + (size_t)b * 289 * CDIM);
        dst[t] = src[t];
    } else {
        int n = s_ - 1;
        int pos = keeppos[b * NIMG + n];
        if (pos < 0) return;
        const float4* av = (const float4*)(avg + (size_t)b * CDIM);
        float4 v = src[t], a = av[t];
        v.x += a.x; v.y += a.y; v.z += a.z; v.w += a.w;
        float4* dst = (float4*)(out + ((size_t)b * 289 + 1 + pos) * CDIM);
        dst[t] = v;
    }
}

extern "C" void kernel_launch(void* const* d_in, const int* in_sizes, int n_in,
                              void* d_out, int out_size, void* d_ws, size_t ws_size,
                              hipStream_t stream) {
    const float* x      = (const float*)d_in[0];
    const float* qkv_w  = (const float*)d_in[1];
    const float* qkv_b  = (const float*)d_in[2];
    const float* proj_w = (const float*)d_in[3];
    const float* proj_b = (const float*)d_in[4];
    const float* ln1_g  = (const float*)d_in[5];
    const float* ln1_b  = (const float*)d_in[6];
    const float* ln2_g  = (const float*)d_in[7];
    const float* ln2_b  = (const float*)d_in[8];
    const float* fc1_w  = (const float*)d_in[9];
    const float* fc1_b  = (const float*)d_in[10];
    const float* fc2_w  = (const float*)d_in[11];
    const float* fc2_b  = (const float*)d_in[12];

    if (ws_size < NEED_BYTES) return;

    float* ws   = (float*)d_ws;
    float* bh   = ws + O_BH;
    float* ba   = ws + O_BA;
    float* bq   = ws + O_BQ;
    float* ms   = ws + O_MS;
    int*   mask = (int*)(ws + O_MASK);
    int*   pos  = (int*)(ws + O_POS);
    float* avg  = ws + O_AVG;
    float* outp = (float*)d_out;

    // 1. h = LN1(x)
    ln_kernel<<<MTOK, 256, 0, stream>>>(x, ln1_g, ln1_b, bh);

    // 2. per-group qkv GEMM + MFMA attention
    for (int g = 0; g < NGROUP; g++) {
        const float* hg = bh + (size_t)g * MGRP * CDIM;
        float* attg = ba + (size_t)g * MGRP * CDIM;
        gemm_mfma<0><<<dim3((MGRP + 127) / 128, 18, 1), 256, 0, stream>>>(
            hg, 0, CDIM, qkv_w, 0, CDIM, bq, 0, 3 * CDIM, qkv_b, nullptr,
            MGRP, 3 * CDIM, CDIM);
        attn_mfma<<<dim3((SEQ + 63) / 64, NHEADS, GB), 256, 0, stream>>>(
            bq, attg);
    }

    // 3. x1 = x + att @ proj_w^T + proj_b
    gemm_mfma<1><<<dim3((MTOK + 127) / 128, 6, 1), 256, 0, stream>>>(
        ba, 0, CDIM, proj_w, 0, CDIM, bh, 0, CDIM, proj_b, x, MTOK, CDIM, CDIM);

    // 4. h2 = LN2(x1)
    ln_kernel<<<MTOK, 256, 0, stream>>>(bh, ln2_g, ln2_b, ba);

    // 5. MLP in M-chunks
    for (int c0 = 0; c0 < MTOK; c0 += MLPCH) {
        int mc = (MTOK - c0 < MLPCH) ? (MTOK - c0) : MLPCH;
        const float* h2c = ba + (size_t)c0 * CDIM;
        float* x1c = bh + (size_t)c0 * CDIM;
        gemm_mfma<2><<<dim3((mc + 127) / 128, 24, 1), 256, 0, stream>>>(
            h2c, 0, CDIM, fc1_w, 0, CDIM, bq, 0, 3072, fc1_b, nullptr,
            mc, 3072, CDIM);
        gemm_mfma<1><<<dim3((mc + 127) / 128, 6, 1), 256, 0, stream>>>(
            bq, 0, 3072, fc2_w, 0, 3072, x1c, 0, CDIM, fc2_b, x1c,
            mc, CDIM, 3072);
    }

    // 6. normalize img tokens
    xn_kernel<<<NBATCH * NIMG, 256, 0, stream>>>(bh, ba);

    // 7. sim = xn @ xn^T per batch
    gemm_mfma<3><<<dim3(5, 5, NBATCH), 256, 0, stream>>>(
        ba, (long long)NIMG * CDIM, CDIM, ba, (long long)NIMG * CDIM, CDIM,
        bq, (long long)NIMG * NIMG, NIMG, nullptr, nullptr, NIMG, NIMG, CDIM);

    // 8. row max of symmetrized sim
    rowmax_kernel<<<NBATCH * NIMG, 64, 0, stream>>>(bq, ms);
    // 9. top-k selection
    select_kernel<<<NBATCH, NIMG, 0, stream>>>(ms, mask, pos);
    // 10. merged-token average (parallel)
    avg_kernel<<<dim3(NBATCH, 6), 256, 0, stream>>>(bh, mask, avg);
    // 11. assemble output
    assemble_kernel<<<MTOK, 192, 0, stream>>>(bh, pos, avg, outp);
}

// Round 10
// 2340.173 us; speedup vs baseline: 2.8589x; 1.1565x over previous
//
#include <hip/hip_runtime.h>
#include <math.h>

#define CDIM 768
#define NHEADS 12
#define DHEAD 64
#define SEQ 577
#define NBATCH 32
#define MTOK (NBATCH*SEQ)      // 18464
#define NIMG 576
#define NMERGE 288
#define GB 8                   // batches per qkv group
#define NGROUP (NBATCH/GB)     // 4
#define MGRP (GB*SEQ)          // 4616 rows per group
#define MLPCH 3456             // MLP chunk rows (27 tiles, aligned)

// ---- workspace layout (float offsets), peak ~156 MB (unchanged) ----
#define SZ_MC   ((size_t)MTOK*CDIM)              // 14,180,352
#define O_BH    ((size_t)0)                      // h -> x1/x2 (in-place)
#define O_BA    (SZ_MC)                          // att -> h2 -> xn
#define O_BQ    (2*SZ_MC)                        // qkv group -> fc1o chunk -> sim
#define SZ_BQ   ((size_t)GB*SEQ*3*CDIM)          // 10,635,264
#define O_SM    (O_BQ + SZ_BQ)
#define O_MS    (O_SM)
#define O_MASK  (O_SM + (size_t)NBATCH*NIMG)
#define O_POS   (O_MASK + (size_t)NBATCH*NIMG)
#define O_AVG   (O_POS + (size_t)NBATCH*NIMG)
#define O_END   (O_AVG + (size_t)NBATCH*CDIM)
#define NEED_BYTES (O_END * 4)

// ---- weight-plane scratch inside d_out (float offsets; d_out = 7.09M floats,
// fully overwritten by assemble_kernel at the end) ----
#define OW_QKV  ((size_t)0)           // 18nt*24ks images = 1,769,472 floats
#define OW_FC1  ((size_t)1769472)     // 24nt*24ks images = 2,359,296 floats
#define OW_FC2  ((size_t)4128768)     // 6nt*96ks images  = 2,359,296 floats

typedef __attribute__((ext_vector_type(8))) short bf16x8;
typedef __attribute__((ext_vector_type(4))) float f32x4;
typedef __attribute__((address_space(1))) const void GAS_cv;
typedef __attribute__((address_space(3))) void LAS_v;

__device__ __forceinline__ unsigned short f2bf(float f) {
    unsigned int u = __float_as_uint(f);
    u += 0x7fff + ((u >> 16) & 1);           // RNE
    return (unsigned short)(u >> 16);
}
__device__ __forceinline__ float bf2f(unsigned short h) {
    return __uint_as_float(((unsigned int)h) << 16);
}

// ---- bijective XCD-chunked block remap (m204) ----
__device__ __forceinline__ void xcd_map(int& bx, int& by, int& bz) {
    int gx = gridDim.x, gy = gridDim.y;
    int nwg = gx * gy * gridDim.z;
    int orig = blockIdx.x + gx * (blockIdx.y + gy * blockIdx.z);
    int q = nwg >> 3, r = nwg & 7;
    int xcd = orig & 7, pos = orig >> 3;
    int wg = (xcd < r ? xcd * (q + 1) : r * (q + 1) + (xcd - r) * q) + pos;
    bx = wg % gx;
    int t2 = wg / gx;
    by = t2 % gy;
    bz = t2 / gy;
}

// ---------------- block reduce (256 threads) ----------------
__device__ __forceinline__ float blk_sum256(float v, float* red) {
    #pragma unroll
    for (int o = 32; o; o >>= 1) v += __shfl_down(v, o);
    if ((threadIdx.x & 63) == 0) red[threadIdx.x >> 6] = v;
    __syncthreads();
    float tot = red[0] + red[1] + red[2] + red[3];
    __syncthreads();
    return tot;
}

// ---------------- LayerNorm: one block per row ----------------
__global__ __launch_bounds__(256) void ln_kernel(const float* __restrict__ x,
        const float* __restrict__ g, const float* __restrict__ b,
        float* __restrict__ out) {
    __shared__ float red[4];
    size_t row = blockIdx.x;
    const float* xr = x + row * CDIM;
    float* orow = out + row * CDIM;
    int t = threadIdx.x;
    float v0 = xr[t], v1 = xr[t + 256], v2 = xr[t + 512];
    float mu = blk_sum256(v0 + v1 + v2, red) * (1.f / CDIM);
    float d0 = v0 - mu, d1 = v1 - mu, d2 = v2 - mu;
    float var = blk_sum256(d0 * d0 + d1 * d1 + d2 * d2, red) * (1.f / CDIM);
    float e = var + 1e-5f;
    float rs = rsqrtf(e);
    rs = rs * (1.5f - 0.5f * e * rs * rs);   // NR refine
    orow[t]       = d0 * rs * g[t]       + b[t];
    orow[t + 256] = d1 * rs * g[t + 256] + b[t + 256];
    orow[t + 512] = d2 * rs * g[t + 512] + b[t + 512];
}

// ---------------- weight split: fp32 -> bf16 hi/lo LDS-image planes ----------------
// One block per (ntile, kstep): writes the 16KB image EXACTLY as gemm staging
// would build it in LDS (rows 0..127 x [hi 64B | lo 64B], XOR swz (r&7)<<4).
// gemm then copies it linearly with global_load_lds -> identical LDS bytes.
__global__ __launch_bounds__(256) void wsplit_kernel(const float* __restrict__ w,
        unsigned short* __restrict__ wp, int nksteps, int ldw) {
    int bid = blockIdx.x;
    int nt = bid / nksteps, ks = bid % nksteps;
    int t = threadIdx.x;
    int srow = t >> 3, sj = t & 7;
    unsigned short* img = wp + ((size_t)bid << 13);   // 8192 ushorts / image
    #pragma unroll
    for (int i = 0; i < 4; i++) {
        int r = srow + i * 32;
        float4 v = *(const float4*)(w + (size_t)(nt * 128 + r) * ldw + ks * 32 + sj * 4);
        unsigned short h0 = f2bf(v.x), h1 = f2bf(v.y), h2 = f2bf(v.z), h3 = f2bf(v.w);
        ushort4 hv = make_ushort4(h0, h1, h2, h3);
        ushort4 lv = make_ushort4(f2bf(v.x - bf2f(h0)), f2bf(v.y - bf2f(h1)),
                                  f2bf(v.z - bf2f(h2)), f2bf(v.w - bf2f(h3)));
        int swz = (r & 7) << 4;
        int ohi = ((8 * sj) ^ swz) >> 1;
        int olo = ((64 + 8 * sj) ^ swz) >> 1;
        *(ushort4*)&img[r * 64 + ohi] = hv;
        *(ushort4*)&img[r * 64 + olo] = lv;
    }
}

// ---------------- GEMM, A fp32 fused-convert + B pre-split planes via glds ----------
// C = A(MxK) * B(NxK)^T. B images (16KB per (ntile,kstep)) copied direct to LDS
// with global_load_lds width=16 -> no VGPR trip, no convert, same LDS bytes as
// the fused path => bit-identical results. N must be a multiple of 128.
// EPI: 0 = +bias, 1 = +bias+res (res may alias C), 2 = gelu(+bias)
template<int EPI>
__global__ __launch_bounds__(256)
void gemm_wp(const float* __restrict__ A, int lda,
             const unsigned short* __restrict__ Bp, int nksteps,
             float* __restrict__ C, int ldc,
             const float* __restrict__ bias,
             const float* __restrict__ res,
             int M, int N, int K) {
    __shared__ unsigned short Asl[128 * 64];
    __shared__ unsigned short Bsl[128 * 64];
    int bx, by, bz;
    xcd_map(bx, by, bz);
    const int m0 = bx * 128;
    const int t = threadIdx.x;
    const int lane = t & 63, wid = t >> 6;
    const int wr = wid >> 1, wc = wid & 1;
    const int srow = t >> 3;
    const int sj   = t & 7;
    const unsigned char* BpB = (const unsigned char*)Bp;

    const float* pa[4];
    #pragma unroll
    for (int i = 0; i < 4; i++) {
        int r = srow + i * 32;
        int ra = m0 + r; ra = ra < M ? ra : M - 1;
        pa[i] = A + (size_t)ra * lda + sj * 4;
    }

    f32x4 acc[4][4];
    #pragma unroll
    for (int i = 0; i < 4; i++)
        #pragma unroll
        for (int j = 0; j < 4; j++) {
            f32x4 z = {0.f, 0.f, 0.f, 0.f};
            acc[i][j] = z;
        }

    const int nsteps = K >> 5;
    float4 va[4];
    #pragma unroll
    for (int i = 0; i < 4; i++) va[i] = *(const float4*)(pa[i]);

    for (int ks = 0; ks < nsteps; ks++) {
        // ---- convert A step ks in registers ----
        ushort4 cah[4], cal[4];
        #pragma unroll
        for (int i = 0; i < 4; i++) {
            float aa[4] = {va[i].x, va[i].y, va[i].z, va[i].w};
            unsigned short h0 = f2bf(aa[0]), h1 = f2bf(aa[1]), h2 = f2bf(aa[2]), h3 = f2bf(aa[3]);
            cah[i] = make_ushort4(h0, h1, h2, h3);
            cal[i] = make_ushort4(f2bf(aa[0] - bf2f(h0)), f2bf(aa[1] - bf2f(h1)),
                                  f2bf(aa[2] - bf2f(h2)), f2bf(aa[3] - bf2f(h3)));
        }
        __syncthreads();   // barrier1: previous step's LDS reads complete
        // ---- B: async copy image(by, ks) -> Bsl (16 x 1KB wave-chunks) ----
        {
            const unsigned char* img = BpB + (((size_t)by * nksteps + ks) << 14);
            #pragma unroll
            for (int i = 0; i < 4; i++) {
                int chunk = (i << 2) | wid;
                const unsigned char* gsrc = img + chunk * 1024 + lane * 16;
                __builtin_amdgcn_global_load_lds((GAS_cv*)gsrc,
                    (LAS_v*)((unsigned char*)Bsl + chunk * 1024), 16, 0, 0);
            }
        }
        // ---- A: write LDS (swizzled) ----
        #pragma unroll
        for (int i = 0; i < 4; i++) {
            int r = srow + i * 32;
            int swz = (r & 7) << 4;
            int ohi = ((8 * sj) ^ swz) >> 1;
            int olo = ((64 + 8 * sj) ^ swz) >> 1;
            *(ushort4*)&Asl[r * 64 + ohi] = cah[i];
            *(ushort4*)&Asl[r * 64 + olo] = cal[i];
        }
        __syncthreads();   // barrier2: drains glds (vmcnt) + ds_writes
        // ---- fragment loads ----
        const int fr = lane & 15, kg = lane >> 4;
        bf16x8 ah[4], al[4], bh[4], bl[4];
        #pragma unroll
        for (int m = 0; m < 4; m++) {
            int r = wr * 64 + m * 16 + fr;
            int swz = (r & 7) << 4;
            const unsigned char* base = (const unsigned char*)&Asl[r * 64];
            ah[m] = *(const bf16x8*)(base + ((16 * kg) ^ swz));
            al[m] = *(const bf16x8*)(base + ((64 + 16 * kg) ^ swz));
        }
        #pragma unroll
        for (int n = 0; n < 4; n++) {
            int r = wc * 64 + n * 16 + fr;
            int swz = (r & 7) << 4;
            const unsigned char* base = (const unsigned char*)&Bsl[r * 64];
            bh[n] = *(const bf16x8*)(base + ((16 * kg) ^ swz));
            bl[n] = *(const bf16x8*)(base + ((64 + 16 * kg) ^ swz));
        }
        // ---- A prefetch ks+1 (reg loads survive barriers; waited at convert) ----
        if (ks + 1 < nsteps) {
            const int k0n = (ks + 1) << 5;
            #pragma unroll
            for (int i = 0; i < 4; i++) va[i] = *(const float4*)(pa[i] + k0n);
        }
        // ---- 48 MFMA ----
        #pragma unroll
        for (int m = 0; m < 4; m++)
            #pragma unroll
            for (int n = 0; n < 4; n++) {
                acc[m][n] = __builtin_amdgcn_mfma_f32_16x16x32_bf16(ah[m], bh[n], acc[m][n], 0, 0, 0);
                acc[m][n] = __builtin_amdgcn_mfma_f32_16x16x32_bf16(ah[m], bl[n], acc[m][n], 0, 0, 0);
                acc[m][n] = __builtin_amdgcn_mfma_f32_16x16x32_bf16(al[m], bh[n], acc[m][n], 0, 0, 0);
            }
    }

    const int fr = lane & 15, fq = lane >> 4;
    const int n0 = by * 128;
    #pragma unroll
    for (int m = 0; m < 4; m++) {
        #pragma unroll
        for (int rr = 0; rr < 4; rr++) {
            int row = m0 + wr * 64 + m * 16 + fq * 4 + rr;
            if (row >= M) continue;
            #pragma unroll
            for (int n = 0; n < 4; n++) {
                int col = n0 + wc * 64 + n * 16 + fr;
                float v = acc[m][n][rr];
                size_t ci = (size_t)row * ldc + col;
                if (EPI == 0) {
                    C[ci] = v + bias[col];
                } else if (EPI == 1) {
                    C[ci] = v + bias[col] + res[ci];
                } else {
                    v += bias[col];
                    C[ci] = 0.5f * v * (1.0f + erff(v * 0.70710678118654752f));
                }
            }
        }
    }
}

// ---------------- fused-convert MFMA GEMM (proj & sim), round-9 proven ----------------
// EPI: 1 = +bias+res (res may alias C), 3 = plain
template<int EPI>
__global__ __launch_bounds__(256)
void gemm_mfma(const float* __restrict__ A, long long sA, int lda,
               const float* __restrict__ Bm, long long sB, int ldb,
               float* __restrict__ C, long long sC, int ldc,
               const float* __restrict__ bias,
               const float* __restrict__ res,
               int M, int N, int K) {
    __shared__ unsigned short Asl[128 * 64];
    __shared__ unsigned short Bsl[128 * 64];
    int bx, by, bz;
    xcd_map(bx, by, bz);
    A  += (size_t)bz * sA;
    Bm += (size_t)bz * sB;
    C  += (size_t)bz * sC;
    const int m0 = bx * 128, n0 = by * 128;
    const int t = threadIdx.x;
    const int lane = t & 63, wid = t >> 6;
    const int wr = wid >> 1, wc = wid & 1;
    const int srow = t >> 3;
    const int sj   = t & 7;

    const float* pa[4];
    const float* pb[4];
    #pragma unroll
    for (int i = 0; i < 4; i++) {
        int r = srow + i * 32;
        int ra = m0 + r; ra = ra < M ? ra : M - 1;
        int rb = n0 + r; rb = rb < N ? rb : N - 1;
        pa[i] = A  + (size_t)ra * lda + sj * 4;
        pb[i] = Bm + (size_t)rb * ldb + sj * 4;
    }

    f32x4 acc[4][4];
    #pragma unroll
    for (int i = 0; i < 4; i++)
        #pragma unroll
        for (int j = 0; j < 4; j++) {
            f32x4 z = {0.f, 0.f, 0.f, 0.f};
            acc[i][j] = z;
        }

    const int nsteps = K >> 5;
    float4 va[4], vb[4];
    #pragma unroll
    for (int i = 0; i < 4; i++) {
        va[i] = *(const float4*)(pa[i]);
        vb[i] = *(const float4*)(pb[i]);
    }

    for (int ks = 0; ks < nsteps; ks++) {
        ushort4 cah[4], cal[4], cbh[4], cbl[4];
        #pragma unroll
        for (int i = 0; i < 4; i++) {
            float aa[4] = {va[i].x, va[i].y, va[i].z, va[i].w};
            float bb[4] = {vb[i].x, vb[i].y, vb[i].z, vb[i].w};
            unsigned short h0 = f2bf(aa[0]), h1 = f2bf(aa[1]), h2 = f2bf(aa[2]), h3 = f2bf(aa[3]);
            cah[i] = make_ushort4(h0, h1, h2, h3);
            cal[i] = make_ushort4(f2bf(aa[0] - bf2f(h0)), f2bf(aa[1] - bf2f(h1)),
                                  f2bf(aa[2] - bf2f(h2)), f2bf(aa[3] - bf2f(h3)));
            unsigned short g0 = f2bf(bb[0]), g1 = f2bf(bb[1]), g2 = f2bf(bb[2]), g3 = f2bf(bb[3]);
            cbh[i] = make_ushort4(g0, g1, g2, g3);
            cbl[i] = make_ushort4(f2bf(bb[0] - bf2f(g0)), f2bf(bb[1] - bf2f(g1)),
                                  f2bf(bb[2] - bf2f(g2)), f2bf(bb[3] - bf2f(g3)));
        }
        if (ks + 1 < nsteps) {
            const int k0n = (ks + 1) << 5;
            #pragma unroll
            for (int i = 0; i < 4; i++) {
                va[i] = *(const float4*)(pa[i] + k0n);
                vb[i] = *(const float4*)(pb[i] + k0n);
            }
        }
        __syncthreads();
        #pragma unroll
        for (int i = 0; i < 4; i++) {
            int r = srow + i * 32;
            int swz = (r & 7) << 4;
            int ohi = ((8 * sj) ^ swz) >> 1;
            int olo = ((64 + 8 * sj) ^ swz) >> 1;
            *(ushort4*)&Asl[r * 64 + ohi] = cah[i];
            *(ushort4*)&Asl[r * 64 + olo] = cal[i];
            *(ushort4*)&Bsl[r * 64 + ohi] = cbh[i];
            *(ushort4*)&Bsl[r * 64 + olo] = cbl[i];
        }
        __syncthreads();
        const int fr = lane & 15, kg = lane >> 4;
        bf16x8 ah[4], al[4], bh[4], bl[4];
        #pragma unroll
        for (int m = 0; m < 4; m++) {
            int r = wr * 64 + m * 16 + fr;
            int swz = (r & 7) << 4;
            const unsigned char* base = (const unsigned char*)&Asl[r * 64];
            ah[m] = *(const bf16x8*)(base + ((16 * kg) ^ swz));
            al[m] = *(const bf16x8*)(base + ((64 + 16 * kg) ^ swz));
        }
        #pragma unroll
        for (int n = 0; n < 4; n++) {
            int r = wc * 64 + n * 16 + fr;
            int swz = (r & 7) << 4;
            const unsigned char* base = (const unsigned char*)&Bsl[r * 64];
            bh[n] = *(const bf16x8*)(base + ((16 * kg) ^ swz));
            bl[n] = *(const bf16x8*)(base + ((64 + 16 * kg) ^ swz));
        }
        #pragma unroll
        for (int m = 0; m < 4; m++)
            #pragma unroll
            for (int n = 0; n < 4; n++) {
                acc[m][n] = __builtin_amdgcn_mfma_f32_16x16x32_bf16(ah[m], bh[n], acc[m][n], 0, 0, 0);
                acc[m][n] = __builtin_amdgcn_mfma_f32_16x16x32_bf16(ah[m], bl[n], acc[m][n], 0, 0, 0);
                acc[m][n] = __builtin_amdgcn_mfma_f32_16x16x32_bf16(al[m], bh[n], acc[m][n], 0, 0, 0);
            }
    }

    const int fr = lane & 15, fq = lane >> 4;
    #pragma unroll
    for (int m = 0; m < 4; m++) {
        #pragma unroll
        for (int rr = 0; rr < 4; rr++) {
            int row = m0 + wr * 64 + m * 16 + fq * 4 + rr;
            if (row >= M) continue;
            #pragma unroll
            for (int n = 0; n < 4; n++) {
                int col = n0 + wc * 64 + n * 16 + fr;
                if (col >= N) continue;
                float v = acc[m][n][rr];
                size_t ci = (size_t)row * ldc + col;
                if (EPI == 1) {
                    C[ci] = v + bias[col] + res[ci];
                } else {
                    C[ci] = v;
                }
            }
        }
    }
}

// ---------------- MFMA flash attention (bf16x3-split, online softmax) ----------------
__global__ __launch_bounds__(256) void attn_mfma(const float* __restrict__ qkv,
                                                 float* __restrict__ att) {
    int bx, by, bz;
    xcd_map(bx, by, bz);
    const int b = bz, h = by, q0 = bx * 64;
    const int t = threadIdx.x;
    const int lane = t & 63, wid = t >> 6;
    const int fr = lane & 15, kg = lane >> 4;
    __shared__ unsigned short Khl[64 * 128];
    __shared__ unsigned char SV[64 * 68 * 4];
    __shared__ unsigned short Vt[64 * 128];
    unsigned char* KhlB = (unsigned char*)Khl;
    float* V32 = (float*)SV;
    unsigned char* PwB = SV + wid * 4096;
    unsigned char* VtB = (unsigned char*)Vt;
    const size_t rowbase = (size_t)b * SEQ * (3 * CDIM);

    bf16x8 qh[2], qlo[2];
    {
        int qrow = q0 + wid * 16 + fr; qrow = qrow < SEQ ? qrow : SEQ - 1;
        const float* qbase = qkv + rowbase + (size_t)qrow * (3 * CDIM) + h * DHEAD;
        #pragma unroll
        for (int ds = 0; ds < 2; ds++) {
            float tmp[8];
            *(float4*)(tmp)     = *(const float4*)(qbase + ds * 32 + kg * 8);
            *(float4*)(tmp + 4) = *(const float4*)(qbase + ds * 32 + kg * 8 + 4);
            #pragma unroll
            for (int j = 0; j < 8; j++) {
                unsigned short hh = f2bf(tmp[j]);
                qh[ds][j]  = (short)hh;
                qlo[ds][j] = (short)f2bf(tmp[j] - bf2f(hh));
            }
        }
    }

    f32x4 acc_o[4];
    #pragma unroll
    for (int i = 0; i < 4; i++) { f32x4 z = {0.f,0.f,0.f,0.f}; acc_o[i] = z; }
    float m_run[4] = {-1e30f, -1e30f, -1e30f, -1e30f};
    float l_run[4] = {0.f, 0.f, 0.f, 0.f};

    const int srow = t >> 2;
    const int sq   = t & 3;

    for (int c0 = 0; c0 < SEQ; c0 += 64) {
        float4 kv[4], vv[4];
        {
            int krow = c0 + srow; krow = krow < SEQ ? krow : SEQ - 1;
            const float* base = qkv + rowbase + (size_t)krow * (3 * CDIM) + h * DHEAD;
            #pragma unroll
            for (int i = 0; i < 4; i++) {
                int dchunk = sq * 16 + i * 4;
                kv[i] = *(const float4*)(base + CDIM + dchunk);
                vv[i] = *(const float4*)(base + 2 * CDIM + dchunk);
            }
        }
        __syncthreads();
        {
            int swz = (srow & 7) << 4;
            #pragma unroll
            for (int i = 0; i < 4; i++) {
                int dchunk = sq * 16 + i * 4;
                float a[4] = {kv[i].x, kv[i].y, kv[i].z, kv[i].w};
                unsigned short h0 = f2bf(a[0]), h1 = f2bf(a[1]), h2 = f2bf(a[2]), h3 = f2bf(a[3]);
                ushort4 hv = make_ushort4(h0, h1, h2, h3);
                ushort4 lv = make_ushort4(f2bf(a[0] - bf2f(h0)), f2bf(a[1] - bf2f(h1)),
                                          f2bf(a[2] - bf2f(h2)), f2bf(a[3] - bf2f(h3)));
                *(ushort4*)(KhlB + srow * 256 + ((dchunk * 2) ^ swz)) = hv;
                *(ushort4*)(KhlB + srow * 256 + 128 + ((dchunk * 2) ^ swz)) = lv;
                *(float4*)&V32[srow * 68 + dchunk] = vv[i];
            }
        }
        __syncthreads();
        {
            int d = t >> 2, k0b = (t & 3) * 16;
            unsigned short hb[16], lb[16];
            #pragma unroll
            for (int i = 0; i < 16; i++) {
                float v = V32[(k0b + i) * 68 + d];
                unsigned short hh = f2bf(v);
                hb[i] = hh; lb[i] = f2bf(v - bf2f(hh));
            }
            int swz = (d & 7) << 4;
            #pragma unroll
            for (int c = 0; c < 4; c++) {
                ushort4 hv = make_ushort4(hb[4*c], hb[4*c+1], hb[4*c+2], hb[4*c+3]);
                ushort4 lv = make_ushort4(lb[4*c], lb[4*c+1], lb[4*c+2], lb[4*c+3]);
                *(ushort4*)(VtB + d * 256 + (((k0b + 4 * c) * 2) ^ swz)) = hv;
                *(ushort4*)(VtB + d * 256 + 128 + (((k0b + 4 * c) * 2) ^ swz)) = lv;
            }
        }
        f32x4 s[4];
        #pragma unroll
        for (int i = 0; i < 4; i++) { f32x4 z = {0.f,0.f,0.f,0.f}; s[i] = z; }
        #pragma unroll
        for (int ds = 0; ds < 2; ds++) {
            #pragma unroll
            for (int n = 0; n < 4; n++) {
                int r = n * 16 + fr;
                int swz = (r & 7) << 4;
                const unsigned char* rb = KhlB + r * 256;
                bf16x8 kh = *(const bf16x8*)(rb + ((ds * 64 + kg * 16) ^ swz));
                bf16x8 kl = *(const bf16x8*)(rb + 128 + ((ds * 64 + kg * 16) ^ swz));
                s[n] = __builtin_amdgcn_mfma_f32_16x16x32_bf16(qh[ds], kh, s[n], 0, 0, 0);
                s[n] = __builtin_amdgcn_mfma_f32_16x16x32_bf16(qh[ds], kl, s[n], 0, 0, 0);
                s[n] = __builtin_amdgcn_mfma_f32_16x16x32_bf16(qlo[ds], kh, s[n], 0, 0, 0);
            }
        }
        __syncthreads();
        float p[4][4];
        #pragma unroll
        for (int n = 0; n < 4; n++) {
            int kcol = c0 + n * 16 + fr;
            #pragma unroll
            for (int r = 0; r < 4; r++) {
                float sv = s[n][r] * 0.125f;
                if (kcol >= SEQ) sv = -1e30f;
                p[n][r] = sv;
            }
        }
        float corr[4];
        #pragma unroll
        for (int r = 0; r < 4; r++) {
            float mx = fmaxf(fmaxf(p[0][r], p[1][r]), fmaxf(p[2][r], p[3][r]));
            mx = fmaxf(mx, __shfl_xor(mx, 1));
            mx = fmaxf(mx, __shfl_xor(mx, 2));
            mx = fmaxf(mx, __shfl_xor(mx, 4));
            mx = fmaxf(mx, __shfl_xor(mx, 8));
            float mnew = fmaxf(m_run[r], mx);
            corr[r] = __expf(m_run[r] - mnew);
            m_run[r] = mnew;
            float ls = 0.f;
            #pragma unroll
            for (int n = 0; n < 4; n++) {
                p[n][r] = __expf(p[n][r] - mnew);
                ls += p[n][r];
            }
            ls += __shfl_xor(ls, 1);
            ls += __shfl_xor(ls, 2);
            ls += __shfl_xor(ls, 4);
            ls += __shfl_xor(ls, 8);
            l_run[r] = l_run[r] * corr[r] + ls;
        }
        #pragma unroll
        for (int nd = 0; nd < 4; nd++)
            #pragma unroll
            for (int r = 0; r < 4; r++)
                acc_o[nd][r] *= corr[r];
        {
            int qb = (lane >> 4) * 4;
            #pragma unroll
            for (int n = 0; n < 4; n++) {
                int kcol = n * 16 + fr;
                #pragma unroll
                for (int r = 0; r < 4; r++) {
                    int qq = qb + r;
                    unsigned short ph = f2bf(p[n][r]);
                    unsigned short pl = f2bf(p[n][r] - bf2f(ph));
                    int off = (kcol * 2) ^ ((qq & 7) << 4);
                    *(unsigned short*)(PwB + qq * 256 + off) = ph;
                    *(unsigned short*)(PwB + qq * 256 + 128 + off) = pl;
                }
            }
        }
        #pragma unroll
        for (int ks = 0; ks < 2; ks++) {
            int swzp = (fr & 7) << 4;
            bf16x8 pah = *(const bf16x8*)(PwB + fr * 256 + ((ks * 64 + kg * 16) ^ swzp));
            bf16x8 pal = *(const bf16x8*)(PwB + fr * 256 + 128 + ((ks * 64 + kg * 16) ^ swzp));
            #pragma unroll
            for (int nd = 0; nd < 4; nd++) {
                int rv = nd * 16 + fr;
                int swzv = (rv & 7) << 4;
                const unsigned char* rb = VtB + rv * 256;
                bf16x8 vh = *(const bf16x8*)(rb + ((ks * 64 + kg * 16) ^ swzv));
                bf16x8 vl = *(const bf16x8*)(rb + 128 + ((ks * 64 + kg * 16) ^ swzv));
                acc_o[nd] = __builtin_amdgcn_mfma_f32_16x16x32_bf16(pah, vh, acc_o[nd], 0, 0, 0);
                acc_o[nd] = __builtin_amdgcn_mfma_f32_16x16x32_bf16(pah, vl, acc_o[nd], 0, 0, 0);
                acc_o[nd] = __builtin_amdgcn_mfma_f32_16x16x32_bf16(pal, vh, acc_o[nd], 0, 0, 0);
            }
        }
    }
    #pragma unroll
    for (int r = 0; r < 4; r++) {
        int q = q0 + wid * 16 + (lane >> 4) * 4 + r;
        if (q >= SEQ) continue;
        float inv = 1.f / l_run[r];
        float* o = att + ((size_t)b * SEQ + q) * CDIM + h * DHEAD;
        #pragma unroll
        for (int nd = 0; nd < 4; nd++)
            o[nd * 16 + fr] = acc_o[nd][r] * inv;
    }
}

// ---------------- normalize img tokens ----------------
__global__ __launch_bounds__(256) void xn_kernel(const float* __restrict__ x2,
                                                 float* __restrict__ xn) {
    __shared__ float red[4];
    int tok = blockIdx.x;
    int b = tok / NIMG, n = tok % NIMG;
    const float* xr = x2 + ((size_t)b * SEQ + 1 + n) * CDIM;
    float* onr = xn + (size_t)tok * CDIM;
    int t = threadIdx.x;
    float v0 = xr[t], v1 = xr[t + 256], v2 = xr[t + 512];
    float ss = blk_sum256(v0 * v0 + v1 * v1 + v2 * v2, red);
    float nrm = fmaxf(sqrtf(ss), 1e-12f);
    float inv = 1.f / nrm;
    onr[t] = v0 * inv; onr[t + 256] = v1 * inv; onr[t + 512] = v2 * inv;
}

// ---------------- row max of symmetrized sim (excluding diagonal) ----------------
__global__ __launch_bounds__(64) void rowmax_kernel(const float* __restrict__ sim,
                                                    float* __restrict__ ms) {
    int row = blockIdx.x;
    int b = row / NIMG, n = row % NIMG;
    const float* sb = sim + (size_t)b * NIMG * NIMG;
    int lane = threadIdx.x;
    float mx = -1e30f;
    #pragma unroll
    for (int i = 0; i < NIMG / 64; i++) {
        int m = lane + i * 64;
        if (m != n) {
            float v = 0.5f * (sb[(size_t)n * NIMG + m] + sb[(size_t)m * NIMG + n]);
            mx = fmaxf(mx, v);
        }
    }
    #pragma unroll
    for (int o = 32; o; o >>= 1) mx = fmaxf(mx, __shfl_down(mx, o));
    if (lane == 0) ms[row] = mx;
}

// ---------------- exact top-k selection with lax.top_k tie semantics ----------------
__global__ __launch_bounds__(576) void select_kernel(const float* __restrict__ ms,
        int* __restrict__ mergemask, int* __restrict__ keeppos) {
    __shared__ float v[NIMG];
    __shared__ int keepf[NIMG];
    int b = blockIdx.x;
    int n = threadIdx.x;
    v[n] = ms[b * NIMG + n];
    __syncthreads();
    float vn = v[n];
    int rank_desc = 0, rank_asc = 0;
    for (int m = 0; m < NIMG; m++) {
        float vm = v[m];
        int tie_lo = (vm == vn && m < n);
        rank_desc += (vm > vn) || tie_lo;
        rank_asc  += (vm < vn) || tie_lo;
    }
    int merge = rank_desc < NMERGE;
    int keep  = rank_asc  < NMERGE;
    mergemask[b * NIMG + n] = merge;
    keepf[n] = keep;
    __syncthreads();
    if (keep) {
        int pos = 0;
        for (int m = 0; m < n; m++) pos += keepf[m];
        keeppos[b * NIMG + n] = pos;
    } else {
        keeppos[b * NIMG + n] = -1;
    }
}

// ---------------- average of merged tokens (parallelized) ----------------
__global__ __launch_bounds__(256) void avg_kernel(const float* __restrict__ x2,
        const int* __restrict__ mask, float* __restrict__ avg) {
    __shared__ float4 red[8][33];
    int b = blockIdx.x, cc = blockIdx.y;
    int t = threadIdx.x;
    int rr = t >> 5, c4 = t & 31;
    int c = cc * 128 + c4 * 4;
    const int* mb = mask + b * NIMG;
    float4 s = make_float4(0.f, 0.f, 0.f, 0.f);
    for (int n = rr; n < NIMG; n += 8) {
        if (mb[n]) {
            float4 v = *(const float4*)(x2 + ((size_t)b * SEQ + 1 + n) * CDIM + c);
            s.x += v.x; s.y += v.y; s.z += v.z; s.w += v.w;
        }
    }
    red[rr][c4] = s;
    __syncthreads();
    if (rr == 0) {
        float4 tot = red[0][c4];
        #pragma unroll
        for (int i = 1; i < 8; i++) {
            float4 v = red[i][c4];
            tot.x += v.x; tot.y += v.y; tot.z += v.z; tot.w += v.w;
        }
        float sc1 = 1.f / (float)NMERGE, sc2 = 1.f / (float)(NIMG - NMERGE);
        tot.x = (tot.x * sc1) * sc2; tot.y = (tot.y * sc1) * sc2;
        tot.z = (tot.z * sc1) * sc2; tot.w = (tot.w * sc1) * sc2;
        *(float4*)(avg + (size_t)b * CDIM + c) = tot;
    }
}

// ---------------- assemble output ----------------
__global__ __launch_bounds__(192) void assemble_kernel(const float* __restrict__ x2,
        const int* __restrict__ keeppos, const float* __restrict__ avg,
        float* __restrict__ out) {
    int g = blockIdx.x;
    int b = g / SEQ, s_ = g % SEQ;
    int t = threadIdx.x;
    const float4* src = (const float4*)(x2 + (size_t)g * CDIM);
    if (s_ == 0) {
        float4* dst = (float4*)(out + (size_t)b * 289 * CDIM);
        dst[t] = src[t];
    } else {
        int n = s_ - 1;
        int pos = keeppos[b * NIMG + n];
        if (pos < 0) return;
        const float4* av = (const float4*)(avg + (size_t)b * CDIM);
        float4 v = src[t], a = av[t];
        v.x += a.x; v.y += a.y; v.z += a.z; v.w += a.w;
        float4* dst = (float4*)(out + ((size_t)b * 289 + 1 + pos) * CDIM);
        dst[t] = v;
    }
}

extern "C" void kernel_launch(void* const* d_in, const int* in_sizes, int n_in,
                              void* d_out, int out_size, void* d_ws, size_t ws_size,
                              hipStream_t stream) {
    const float* x      = (const float*)d_in[0];
    const float* qkv_w  = (const float*)d_in[1];
    const float* qkv_b  = (const float*)d_in[2];
    const float* proj_w = (const float*)d_in[3];
    const float* proj_b = (const float*)d_in[4];
    const float* ln1_g  = (const float*)d_in[5];
    const float* ln1_b  = (const float*)d_in[6];
    const float* ln2_g  = (const float*)d_in[7];
    const float* ln2_b  = (const float*)d_in[8];
    const float* fc1_w  = (const float*)d_in[9];
    const float* fc1_b  = (const float*)d_in[10];
    const float* fc2_w  = (const float*)d_in[11];
    const float* fc2_b  = (const float*)d_in[12];

    if (ws_size < NEED_BYTES) return;

    float* ws   = (float*)d_ws;
    float* bh   = ws + O_BH;
    float* ba   = ws + O_BA;
    float* bq   = ws + O_BQ;
    float* ms   = ws + O_MS;
    int*   mask = (int*)(ws + O_MASK);
    int*   pos  = (int*)(ws + O_POS);
    float* avg  = ws + O_AVG;
    float* outp = (float*)d_out;

    // weight planes in d_out (scratch until assemble overwrites it)
    unsigned short* qkvp = (unsigned short*)(outp + OW_QKV);
    unsigned short* fc1p = (unsigned short*)(outp + OW_FC1);
    unsigned short* fc2p = (unsigned short*)(outp + OW_FC2);

    // 0. split weights into swizzled LDS-image planes (once per call)
    wsplit_kernel<<<18 * 24, 256, 0, stream>>>(qkv_w, qkvp, 24, CDIM);
    wsplit_kernel<<<24 * 24, 256, 0, stream>>>(fc1_w, fc1p, 24, CDIM);
    wsplit_kernel<<<6 * 96, 256, 0, stream>>>(fc2_w, fc2p, 96, 3072);

    // 1. h = LN1(x)
    ln_kernel<<<MTOK, 256, 0, stream>>>(x, ln1_g, ln1_b, bh);

    // 2. per-group qkv GEMM (B planes + glds) + MFMA attention
    for (int g = 0; g < NGROUP; g++) {
        const float* hg = bh + (size_t)g * MGRP * CDIM;
        float* attg = ba + (size_t)g * MGRP * CDIM;
        gemm_wp<0><<<dim3((MGRP + 127) / 128, 18), 256, 0, stream>>>(
            hg, CDIM, qkvp, 24, bq, 3 * CDIM, qkv_b, nullptr,
            MGRP, 3 * CDIM, CDIM);
        attn_mfma<<<dim3((SEQ + 63) / 64, NHEADS, GB), 256, 0, stream>>>(
            bq, attg);
    }

    // 3. x1 = x + att @ proj_w^T + proj_b (fused path)
    gemm_mfma<1><<<dim3((MTOK + 127) / 128, 6, 1), 256, 0, stream>>>(
        ba, 0, CDIM, proj_w, 0, CDIM, bh, 0, CDIM, proj_b, x, MTOK, CDIM, CDIM);

    // 4. h2 = LN2(x1)
    ln_kernel<<<MTOK, 256, 0, stream>>>(bh, ln2_g, ln2_b, ba);

    // 5. MLP in M-chunks (B planes + glds)
    for (int c0 = 0; c0 < MTOK; c0 += MLPCH) {
        int mc = (MTOK - c0 < MLPCH) ? (MTOK - c0) : MLPCH;
        const float* h2c = ba + (size_t)c0 * CDIM;
        float* x1c = bh + (size_t)c0 * CDIM;
        gemm_wp<2><<<dim3((mc + 127) / 128, 24), 256, 0, stream>>>(
            h2c, CDIM, fc1p, 24, bq, 3072, fc1_b, nullptr, mc, 3072, CDIM);
        gemm_wp<1><<<dim3((mc + 127) / 128, 6), 256, 0, stream>>>(
            bq, 3072, fc2p, 96, x1c, CDIM, fc2_b, x1c, mc, CDIM, 3072);
    }

    // 6. normalize img tokens
    xn_kernel<<<NBATCH * NIMG, 256, 0, stream>>>(bh, ba);

    // 7. sim = xn @ xn^T per batch (fused path)
    gemm_mfma<3><<<dim3(5, 5, NBATCH), 256, 0, stream>>>(
        ba, (long long)NIMG * CDIM, CDIM, ba, (long long)NIMG * CDIM, CDIM,
        bq, (long long)NIMG * NIMG, NIMG, nullptr, nullptr, NIMG, NIMG, CDIM);

    // 8. row max of symmetrized sim
    rowmax_kernel<<<NBATCH * NIMG, 64, 0, stream>>>(bq, ms);
    // 9. top-k selection
    select_kernel<<<NBATCH, NIMG, 0, stream>>>(ms, mask, pos);
    // 10. merged-token average (parallel)
    avg_kernel<<<dim3(NBATCH, 6), 256, 0, stream>>>(bh, mask, avg);
    // 11. assemble output (overwrites weight-plane scratch in d_out)
    assemble_kernel<<<MTOK, 192, 0, stream>>>(bh, pos, avg, outp);
}

// Round 11
// 2285.103 us; speedup vs baseline: 2.9277x; 1.0241x over previous
//
#include <hip/hip_runtime.h>
#include <math.h>

#define CDIM 768
#define NHEADS 12
#define DHEAD 64
#define SEQ 577
#define NBATCH 32
#define MTOK (NBATCH*SEQ)      // 18464
#define NIMG 576
#define NMERGE 288
#define GB 8                   // batches per qkv group
#define NGROUP (NBATCH/GB)     // 4
#define MGRP (GB*SEQ)          // 4616 rows per group
#define MLPCH 3456             // MLP chunk rows (27 tiles)

// ---- workspace layout (float offsets), peak ~156 MB (unchanged) ----
#define SZ_MC   ((size_t)MTOK*CDIM)              // 14,180,352
#define O_BH    ((size_t)0)                      // h -> x1/x2 (in-place)
#define O_BA    (SZ_MC)                          // att -> h2 -> xn
#define O_BQ    (2*SZ_MC)                        // qkv group -> fc1o planes -> sim
#define SZ_BQ   ((size_t)GB*SEQ*3*CDIM)          // 10,635,264
#define O_SM    (O_BQ + SZ_BQ)
#define O_MS    (O_SM)
#define O_MASK  (O_SM + (size_t)NBATCH*NIMG)
#define O_POS   (O_MASK + (size_t)NBATCH*NIMG)
#define O_AVG   (O_POS + (size_t)NBATCH*NIMG)
#define O_END   (O_AVG + (size_t)NBATCH*CDIM)
#define NEED_BYTES (O_END * 4)

// ---- weight-plane scratch inside d_out (float offsets; 7,077,888 of
// 7,096,832 used; fully overwritten by assemble_kernel at the end) ----
#define OW_QKV  ((size_t)0)           // 18nt*24ks = 1,769,472 floats
#define OW_FC1  ((size_t)1769472)     // 24nt*24ks = 2,359,296 floats
#define OW_FC2  ((size_t)4128768)     // 6nt*96ks  = 2,359,296 floats
#define OW_PROJ ((size_t)6488064)     // 6nt*24ks  =   589,824 floats

typedef __attribute__((ext_vector_type(8))) short bf16x8;
typedef __attribute__((ext_vector_type(4))) float f32x4;
typedef __attribute__((address_space(1))) const void GAS_cv;
typedef __attribute__((address_space(3))) void LAS_v;

__device__ __forceinline__ unsigned short f2bf(float f) {
    unsigned int u = __float_as_uint(f);
    u += 0x7fff + ((u >> 16) & 1);           // RNE
    return (unsigned short)(u >> 16);
}
__device__ __forceinline__ float bf2f(unsigned short h) {
    return __uint_as_float(((unsigned int)h) << 16);
}

// ---- XCD chunking. HW assigns workgroups round-robin by LINEAR id (%8).
// Map each XCD's id-class to a contiguous logical range (bijective, m204).
// xcd_map:   chunk walks bx fastest (attn: q-tiles share K/V).
// xcd_map_nf: chunk walks by fastest (gemm: N-tiles share the A panel ->
//             A fetched into ~1 L2 instead of gy of them).
__device__ __forceinline__ void xcd_map(int& bx, int& by, int& bz) {
    int gx = gridDim.x, gy = gridDim.y;
    int nwg = gx * gy * gridDim.z;
    int orig = blockIdx.x + gx * (blockIdx.y + gy * blockIdx.z);
    int q = nwg >> 3, r = nwg & 7;
    int xcd = orig & 7, pos = orig >> 3;
    int wg = (xcd < r ? xcd * (q + 1) : r * (q + 1) + (xcd - r) * q) + pos;
    bx = wg % gx;
    int t2 = wg / gx;
    by = t2 % gy;
    bz = t2 / gy;
}
__device__ __forceinline__ void xcd_map_nf(int& bx, int& by, int& bz) {
    int gx = gridDim.x, gy = gridDim.y;
    int nwg = gx * gy * gridDim.z;
    int orig = blockIdx.x + gx * (blockIdx.y + gy * blockIdx.z);
    int q = nwg >> 3, r = nwg & 7;
    int xcd = orig & 7, pos = orig >> 3;
    int wg = (xcd < r ? xcd * (q + 1) : r * (q + 1) + (xcd - r) * q) + pos;
    by = wg % gy;
    int t2 = wg / gy;
    bx = t2 % gx;
    bz = t2 / gx;
}

// ---------------- block reduce (256 threads) ----------------
__device__ __forceinline__ float blk_sum256(float v, float* red) {
    #pragma unroll
    for (int o = 32; o; o >>= 1) v += __shfl_down(v, o);
    if ((threadIdx.x & 63) == 0) red[threadIdx.x >> 6] = v;
    __syncthreads();
    float tot = red[0] + red[1] + red[2] + red[3];
    __syncthreads();
    return tot;
}

// ---------------- LayerNorm: one block per row ----------------
__global__ __launch_bounds__(256) void ln_kernel(const float* __restrict__ x,
        const float* __restrict__ g, const float* __restrict__ b,
        float* __restrict__ out) {
    __shared__ float red[4];
    size_t row = blockIdx.x;
    const float* xr = x + row * CDIM;
    float* orow = out + row * CDIM;
    int t = threadIdx.x;
    float v0 = xr[t], v1 = xr[t + 256], v2 = xr[t + 512];
    float mu = blk_sum256(v0 + v1 + v2, red) * (1.f / CDIM);
    float d0 = v0 - mu, d1 = v1 - mu, d2 = v2 - mu;
    float var = blk_sum256(d0 * d0 + d1 * d1 + d2 * d2, red) * (1.f / CDIM);
    float e = var + 1e-5f;
    float rs = rsqrtf(e);
    rs = rs * (1.5f - 0.5f * e * rs * rs);   // NR refine
    orow[t]       = d0 * rs * g[t]       + b[t];
    orow[t + 256] = d1 * rs * g[t + 256] + b[t + 256];
    orow[t + 512] = d2 * rs * g[t + 512] + b[t + 512];
}

// ---------------- weight split: fp32 -> bf16 hi/lo LDS-image planes ----------------
__global__ __launch_bounds__(256) void wsplit_kernel(const float* __restrict__ w,
        unsigned short* __restrict__ wp, int nksteps, int ldw) {
    int bid = blockIdx.x;
    int nt = bid / nksteps, ks = bid % nksteps;
    int t = threadIdx.x;
    int srow = t >> 3, sj = t & 7;
    unsigned short* img = wp + ((size_t)bid << 13);   // 8192 ushorts / image
    #pragma unroll
    for (int i = 0; i < 4; i++) {
        int r = srow + i * 32;
        float4 v = *(const float4*)(w + (size_t)(nt * 128 + r) * ldw + ks * 32 + sj * 4);
        unsigned short h0 = f2bf(v.x), h1 = f2bf(v.y), h2 = f2bf(v.z), h3 = f2bf(v.w);
        ushort4 hv = make_ushort4(h0, h1, h2, h3);
        ushort4 lv = make_ushort4(f2bf(v.x - bf2f(h0)), f2bf(v.y - bf2f(h1)),
                                  f2bf(v.z - bf2f(h2)), f2bf(v.w - bf2f(h3)));
        int swz = (r & 7) << 4;
        int ohi = ((8 * sj) ^ swz) >> 1;
        int olo = ((64 + 8 * sj) ^ swz) >> 1;
        *(ushort4*)&img[r * 64 + ohi] = hv;
        *(ushort4*)&img[r * 64 + olo] = lv;
    }
}

// ---------------- GEMM, A fp32 fused-convert + B pre-split planes via glds ----------
// EPI: 0 = +bias (fp32 C), 1 = +bias+res (fp32 C, res may alias C),
//      5 = gelu(+bias) -> bf16 hi/lo plane IMAGES (Cv = image base, ldc = N)
template<int EPI>
__global__ __launch_bounds__(256)
void gemm_wp(const float* __restrict__ A, int lda,
             const unsigned short* __restrict__ Bp, int nksteps,
             void* __restrict__ Cv, int ldc,
             const float* __restrict__ bias,
             const float* __restrict__ res,
             int M, int N, int K) {
    __shared__ unsigned short Asl[128 * 64];
    __shared__ unsigned short Bsl[128 * 64];
    int bx, by, bz;
    xcd_map_nf(bx, by, bz);
    const int m0 = bx * 128;
    const int t = threadIdx.x;
    const int lane = t & 63, wid = t >> 6;
    const int wr = wid >> 1, wc = wid & 1;
    const int srow = t >> 3;
    const int sj   = t & 7;
    const unsigned char* BpB = (const unsigned char*)Bp;

    const float* pa[4];
    #pragma unroll
    for (int i = 0; i < 4; i++) {
        int r = srow + i * 32;
        int ra = m0 + r; ra = ra < M ? ra : M - 1;
        pa[i] = A + (size_t)ra * lda + sj * 4;
    }

    f32x4 acc[4][4];
    #pragma unroll
    for (int i = 0; i < 4; i++)
        #pragma unroll
        for (int j = 0; j < 4; j++) {
            f32x4 z = {0.f, 0.f, 0.f, 0.f};
            acc[i][j] = z;
        }

    const int nsteps = K >> 5;
    float4 va[4];
    #pragma unroll
    for (int i = 0; i < 4; i++) va[i] = *(const float4*)(pa[i]);

    for (int ks = 0; ks < nsteps; ks++) {
        ushort4 cah[4], cal[4];
        #pragma unroll
        for (int i = 0; i < 4; i++) {
            float aa[4] = {va[i].x, va[i].y, va[i].z, va[i].w};
            unsigned short h0 = f2bf(aa[0]), h1 = f2bf(aa[1]), h2 = f2bf(aa[2]), h3 = f2bf(aa[3]);
            cah[i] = make_ushort4(h0, h1, h2, h3);
            cal[i] = make_ushort4(f2bf(aa[0] - bf2f(h0)), f2bf(aa[1] - bf2f(h1)),
                                  f2bf(aa[2] - bf2f(h2)), f2bf(aa[3] - bf2f(h3)));
        }
        __syncthreads();   // barrier1: previous step's LDS reads complete
        {
            const unsigned char* img = BpB + (((size_t)by * nksteps + ks) << 14);
            #pragma unroll
            for (int i = 0; i < 4; i++) {
                int chunk = (i << 2) | wid;
                __builtin_amdgcn_global_load_lds((GAS_cv*)(img + chunk * 1024 + lane * 16),
                    (LAS_v*)((unsigned char*)Bsl + chunk * 1024), 16, 0, 0);
            }
        }
        #pragma unroll
        for (int i = 0; i < 4; i++) {
            int r = srow + i * 32;
            int swz = (r & 7) << 4;
            int ohi = ((8 * sj) ^ swz) >> 1;
            int olo = ((64 + 8 * sj) ^ swz) >> 1;
            *(ushort4*)&Asl[r * 64 + ohi] = cah[i];
            *(ushort4*)&Asl[r * 64 + olo] = cal[i];
        }
        __syncthreads();   // barrier2: drains glds + ds_writes
        const int fr = lane & 15, kg = lane >> 4;
        bf16x8 ah[4], al[4], bh[4], bl[4];
        #pragma unroll
        for (int m = 0; m < 4; m++) {
            int r = wr * 64 + m * 16 + fr;
            int swz = (r & 7) << 4;
            const unsigned char* base = (const unsigned char*)&Asl[r * 64];
            ah[m] = *(const bf16x8*)(base + ((16 * kg) ^ swz));
            al[m] = *(const bf16x8*)(base + ((64 + 16 * kg) ^ swz));
        }
        #pragma unroll
        for (int n = 0; n < 4; n++) {
            int r = wc * 64 + n * 16 + fr;
            int swz = (r & 7) << 4;
            const unsigned char* base = (const unsigned char*)&Bsl[r * 64];
            bh[n] = *(const bf16x8*)(base + ((16 * kg) ^ swz));
            bl[n] = *(const bf16x8*)(base + ((64 + 16 * kg) ^ swz));
        }
        if (ks + 1 < nsteps) {
            const int k0n = (ks + 1) << 5;
            #pragma unroll
            for (int i = 0; i < 4; i++) va[i] = *(const float4*)(pa[i] + k0n);
        }
        #pragma unroll
        for (int m = 0; m < 4; m++)
            #pragma unroll
            for (int n = 0; n < 4; n++) {
                acc[m][n] = __builtin_amdgcn_mfma_f32_16x16x32_bf16(ah[m], bh[n], acc[m][n], 0, 0, 0);
                acc[m][n] = __builtin_amdgcn_mfma_f32_16x16x32_bf16(ah[m], bl[n], acc[m][n], 0, 0, 0);
                acc[m][n] = __builtin_amdgcn_mfma_f32_16x16x32_bf16(al[m], bh[n], acc[m][n], 0, 0, 0);
            }
    }

    const int fr = lane & 15, fq = lane >> 4;
    const int n0 = by * 128;
    #pragma unroll
    for (int m = 0; m < 4; m++) {
        #pragma unroll
        for (int rr = 0; rr < 4; rr++) {
            int row = m0 + wr * 64 + m * 16 + fq * 4 + rr;
            if (row >= M) continue;
            #pragma unroll
            for (int n = 0; n < 4; n++) {
                int col = n0 + wc * 64 + n * 16 + fr;
                float v = acc[m][n][rr];
                size_t ci = (size_t)row * ldc + col;
                if (EPI == 0) {
                    ((float*)Cv)[ci] = v + bias[col];
                } else if (EPI == 1) {
                    ((float*)Cv)[ci] = v + bias[col] + res[ci];
                } else { // 5: gelu -> plane images (chunk-local rows)
                    v += bias[col];
                    v = 0.5f * v * (1.0f + erff(v * 0.70710678118654752f));
                    unsigned short hh = f2bf(v);
                    unsigned short ll = f2bf(v - bf2f(hh));
                    unsigned char* img = (unsigned char*)Cv +
                        (((size_t)(row >> 7) * (ldc >> 5) + (col >> 5)) << 14);
                    int r2 = row & 127, swz2 = (r2 & 7) << 4, kc = col & 31;
                    *(unsigned short*)(img + r2 * 128 + ((2 * kc) ^ swz2)) = hh;
                    *(unsigned short*)(img + r2 * 128 + ((64 + 2 * kc) ^ swz2)) = ll;
                }
            }
        }
    }
}

// ---------------- GEMM, BOTH operands pre-split plane images via glds ----------
// K-loop: glds-issue -> barrier -> ds_read -> 48 MFMA. Zero staging VALU.
// EPI: 1 = +bias+res (res may alias C)
template<int EPI>
__global__ __launch_bounds__(256)
void gemm_pp(const unsigned short* __restrict__ Ap,
             const unsigned short* __restrict__ Bp,
             float* __restrict__ C, int ldc,
             const float* __restrict__ bias,
             const float* __restrict__ res,
             int M, int N, int K) {
    __shared__ unsigned short Asl[128 * 64];
    __shared__ unsigned short Bsl[128 * 64];
    int bx, by, bz;
    xcd_map_nf(bx, by, bz);
    const int t = threadIdx.x;
    const int lane = t & 63, wid = t >> 6;
    const int wr = wid >> 1, wc = wid & 1;
    const unsigned char* ApB = (const unsigned char*)Ap;
    const unsigned char* BpB = (const unsigned char*)Bp;

    f32x4 acc[4][4];
    #pragma unroll
    for (int i = 0; i < 4; i++)
        #pragma unroll
        for (int j = 0; j < 4; j++) {
            f32x4 z = {0.f, 0.f, 0.f, 0.f};
            acc[i][j] = z;
        }

    const int nsteps = K >> 5;
    for (int ks = 0; ks < nsteps; ks++) {
        __syncthreads();   // previous step's LDS reads complete
        const unsigned char* imgA = ApB + (((size_t)bx * nsteps + ks) << 14);
        const unsigned char* imgB = BpB + (((size_t)by * nsteps + ks) << 14);
        #pragma unroll
        for (int i = 0; i < 4; i++) {
            int chunk = (i << 2) | wid;
            __builtin_amdgcn_global_load_lds((GAS_cv*)(imgA + chunk * 1024 + lane * 16),
                (LAS_v*)((unsigned char*)Asl + chunk * 1024), 16, 0, 0);
            __builtin_amdgcn_global_load_lds((GAS_cv*)(imgB + chunk * 1024 + lane * 16),
                (LAS_v*)((unsigned char*)Bsl + chunk * 1024), 16, 0, 0);
        }
        __syncthreads();   // drains glds
        const int fr = lane & 15, kg = lane >> 4;
        bf16x8 ah[4], al[4], bh[4], bl[4];
        #pragma unroll
        for (int m = 0; m < 4; m++) {
            int r = wr * 64 + m * 16 + fr;
            int swz = (r & 7) << 4;
            const unsigned char* base = (const unsigned char*)&Asl[r * 64];
            ah[m] = *(const bf16x8*)(base + ((16 * kg) ^ swz));
            al[m] = *(const bf16x8*)(base + ((64 + 16 * kg) ^ swz));
        }
        #pragma unroll
        for (int n = 0; n < 4; n++) {
            int r = wc * 64 + n * 16 + fr;
            int swz = (r & 7) << 4;
            const unsigned char* base = (const unsigned char*)&Bsl[r * 64];
            bh[n] = *(const bf16x8*)(base + ((16 * kg) ^ swz));
            bl[n] = *(const bf16x8*)(base + ((64 + 16 * kg) ^ swz));
        }
        #pragma unroll
        for (int m = 0; m < 4; m++)
            #pragma unroll
            for (int n = 0; n < 4; n++) {
                acc[m][n] = __builtin_amdgcn_mfma_f32_16x16x32_bf16(ah[m], bh[n], acc[m][n], 0, 0, 0);
                acc[m][n] = __builtin_amdgcn_mfma_f32_16x16x32_bf16(ah[m], bl[n], acc[m][n], 0, 0, 0);
                acc[m][n] = __builtin_amdgcn_mfma_f32_16x16x32_bf16(al[m], bh[n], acc[m][n], 0, 0, 0);
            }
    }

    const int fr = lane & 15, fq = lane >> 4;
    const int m0 = bx * 128, n0 = by * 128;
    #pragma unroll
    for (int m = 0; m < 4; m++) {
        #pragma unroll
        for (int rr = 0; rr < 4; rr++) {
            int row = m0 + wr * 64 + m * 16 + fq * 4 + rr;
            if (row >= M) continue;
            #pragma unroll
            for (int n = 0; n < 4; n++) {
                int col = n0 + wc * 64 + n * 16 + fr;
                float v = acc[m][n][rr];
                size_t ci = (size_t)row * ldc + col;
                C[ci] = v + bias[col] + res[ci];
            }
        }
    }
}

// ---------------- fused-convert MFMA GEMM (sim), round-9 proven ----------------
// EPI: 3 = plain
template<int EPI>
__global__ __launch_bounds__(256)
void gemm_mfma(const float* __restrict__ A, long long sA, int lda,
               const float* __restrict__ Bm, long long sB, int ldb,
               float* __restrict__ C, long long sC, int ldc,
               const float* __restrict__ bias,
               const float* __restrict__ res,
               int M, int N, int K) {
    __shared__ unsigned short Asl[128 * 64];
    __shared__ unsigned short Bsl[128 * 64];
    int bx, by, bz;
    xcd_map_nf(bx, by, bz);
    A  += (size_t)bz * sA;
    Bm += (size_t)bz * sB;
    C  += (size_t)bz * sC;
    const int m0 = bx * 128, n0 = by * 128;
    const int t = threadIdx.x;
    const int lane = t & 63, wid = t >> 6;
    const int wr = wid >> 1, wc = wid & 1;
    const int srow = t >> 3;
    const int sj   = t & 7;

    const float* pa[4];
    const float* pb[4];
    #pragma unroll
    for (int i = 0; i < 4; i++) {
        int r = srow + i * 32;
        int ra = m0 + r; ra = ra < M ? ra : M - 1;
        int rb = n0 + r; rb = rb < N ? rb : N - 1;
        pa[i] = A  + (size_t)ra * lda + sj * 4;
        pb[i] = Bm + (size_t)rb * ldb + sj * 4;
    }

    f32x4 acc[4][4];
    #pragma unroll
    for (int i = 0; i < 4; i++)
        #pragma unroll
        for (int j = 0; j < 4; j++) {
            f32x4 z = {0.f, 0.f, 0.f, 0.f};
            acc[i][j] = z;
        }

    const int nsteps = K >> 5;
    float4 va[4], vb[4];
    #pragma unroll
    for (int i = 0; i < 4; i++) {
        va[i] = *(const float4*)(pa[i]);
        vb[i] = *(const float4*)(pb[i]);
    }

    for (int ks = 0; ks < nsteps; ks++) {
        ushort4 cah[4], cal[4], cbh[4], cbl[4];
        #pragma unroll
        for (int i = 0; i < 4; i++) {
            float aa[4] = {va[i].x, va[i].y, va[i].z, va[i].w};
            float bb[4] = {vb[i].x, vb[i].y, vb[i].z, vb[i].w};
            unsigned short h0 = f2bf(aa[0]), h1 = f2bf(aa[1]), h2 = f2bf(aa[2]), h3 = f2bf(aa[3]);
            cah[i] = make_ushort4(h0, h1, h2, h3);
            cal[i] = make_ushort4(f2bf(aa[0] - bf2f(h0)), f2bf(aa[1] - bf2f(h1)),
                                  f2bf(aa[2] - bf2f(h2)), f2bf(aa[3] - bf2f(h3)));
            unsigned short g0 = f2bf(bb[0]), g1 = f2bf(bb[1]), g2 = f2bf(bb[2]), g3 = f2bf(bb[3]);
            cbh[i] = make_ushort4(g0, g1, g2, g3);
            cbl[i] = make_ushort4(f2bf(bb[0] - bf2f(g0)), f2bf(bb[1] - bf2f(g1)),
                                  f2bf(bb[2] - bf2f(g2)), f2bf(bb[3] - bf2f(g3)));
        }
        if (ks + 1 < nsteps) {
            const int k0n = (ks + 1) << 5;
            #pragma unroll
            for (int i = 0; i < 4; i++) {
                va[i] = *(const float4*)(pa[i] + k0n);
                vb[i] = *(const float4*)(pb[i] + k0n);
            }
        }
        __syncthreads();
        #pragma unroll
        for (int i = 0; i < 4; i++) {
            int r = srow + i * 32;
            int swz = (r & 7) << 4;
            int ohi = ((8 * sj) ^ swz) >> 1;
            int olo = ((64 + 8 * sj) ^ swz) >> 1;
            *(ushort4*)&Asl[r * 64 + ohi] = cah[i];
            *(ushort4*)&Asl[r * 64 + olo] = cal[i];
            *(ushort4*)&Bsl[r * 64 + ohi] = cbh[i];
            *(ushort4*)&Bsl[r * 64 + olo] = cbl[i];
        }
        __syncthreads();
        const int fr = lane & 15, kg = lane >> 4;
        bf16x8 ah[4], al[4], bh[4], bl[4];
        #pragma unroll
        for (int m = 0; m < 4; m++) {
            int r = wr * 64 + m * 16 + fr;
            int swz = (r & 7) << 4;
            const unsigned char* base = (const unsigned char*)&Asl[r * 64];
            ah[m] = *(const bf16x8*)(base + ((16 * kg) ^ swz));
            al[m] = *(const bf16x8*)(base + ((64 + 16 * kg) ^ swz));
        }
        #pragma unroll
        for (int n = 0; n < 4; n++) {
            int r = wc * 64 + n * 16 + fr;
            int swz = (r & 7) << 4;
            const unsigned char* base = (const unsigned char*)&Bsl[r * 64];
            bh[n] = *(const bf16x8*)(base + ((16 * kg) ^ swz));
            bl[n] = *(const bf16x8*)(base + ((64 + 16 * kg) ^ swz));
        }
        #pragma unroll
        for (int m = 0; m < 4; m++)
            #pragma unroll
            for (int n = 0; n < 4; n++) {
                acc[m][n] = __builtin_amdgcn_mfma_f32_16x16x32_bf16(ah[m], bh[n], acc[m][n], 0, 0, 0);
                acc[m][n] = __builtin_amdgcn_mfma_f32_16x16x32_bf16(ah[m], bl[n], acc[m][n], 0, 0, 0);
                acc[m][n] = __builtin_amdgcn_mfma_f32_16x16x32_bf16(al[m], bh[n], acc[m][n], 0, 0, 0);
            }
    }

    const int fr = lane & 15, fq = lane >> 4;
    #pragma unroll
    for (int m = 0; m < 4; m++) {
        #pragma unroll
        for (int rr = 0; rr < 4; rr++) {
            int row = m0 + wr * 64 + m * 16 + fq * 4 + rr;
            if (row >= M) continue;
            #pragma unroll
            for (int n = 0; n < 4; n++) {
                int col = n0 + wc * 64 + n * 16 + fr;
                if (col >= N) continue;
                C[(size_t)row * ldc + col] = acc[m][n][rr];
            }
        }
    }
}

// ---------------- MFMA flash attention (bf16x3-split, online softmax) ----------------
__global__ __launch_bounds__(256) void attn_mfma(const float* __restrict__ qkv,
                                                 float* __restrict__ att) {
    int bx, by, bz;
    xcd_map(bx, by, bz);
    const int b = bz, h = by, q0 = bx * 64;
    const int t = threadIdx.x;
    const int lane = t & 63, wid = t >> 6;
    const int fr = lane & 15, kg = lane >> 4;
    __shared__ unsigned short Khl[64 * 128];
    __shared__ unsigned char SV[64 * 68 * 4];
    __shared__ unsigned short Vt[64 * 128];
    unsigned char* KhlB = (unsigned char*)Khl;
    float* V32 = (float*)SV;
    unsigned char* PwB = SV + wid * 4096;
    unsigned char* VtB = (unsigned char*)Vt;
    const size_t rowbase = (size_t)b * SEQ * (3 * CDIM);

    bf16x8 qh[2], qlo[2];
    {
        int qrow = q0 + wid * 16 + fr; qrow = qrow < SEQ ? qrow : SEQ - 1;
        const float* qbase = qkv + rowbase + (size_t)qrow * (3 * CDIM) + h * DHEAD;
        #pragma unroll
        for (int ds = 0; ds < 2; ds++) {
            float tmp[8];
            *(float4*)(tmp)     = *(const float4*)(qbase + ds * 32 + kg * 8);
            *(float4*)(tmp + 4) = *(const float4*)(qbase + ds * 32 + kg * 8 + 4);
            #pragma unroll
            for (int j = 0; j < 8; j++) {
                unsigned short hh = f2bf(tmp[j]);
                qh[ds][j]  = (short)hh;
                qlo[ds][j] = (short)f2bf(tmp[j] - bf2f(hh));
            }
        }
    }

    f32x4 acc_o[4];
    #pragma unroll
    for (int i = 0; i < 4; i++) { f32x4 z = {0.f,0.f,0.f,0.f}; acc_o[i] = z; }
    float m_run[4] = {-1e30f, -1e30f, -1e30f, -1e30f};
    float l_run[4] = {0.f, 0.f, 0.f, 0.f};

    const int srow = t >> 2;
    const int sq   = t & 3;

    for (int c0 = 0; c0 < SEQ; c0 += 64) {
        float4 kv[4], vv[4];
        {
            int krow = c0 + srow; krow = krow < SEQ ? krow : SEQ - 1;
            const float* base = qkv + rowbase + (size_t)krow * (3 * CDIM) + h * DHEAD;
            #pragma unroll
            for (int i = 0; i < 4; i++) {
                int dchunk = sq * 16 + i * 4;
                kv[i] = *(const float4*)(base + CDIM + dchunk);
                vv[i] = *(const float4*)(base + 2 * CDIM + dchunk);
            }
        }
        __syncthreads();
        {
            int swz = (srow & 7) << 4;
            #pragma unroll
            for (int i = 0; i < 4; i++) {
                int dchunk = sq * 16 + i * 4;
                float a[4] = {kv[i].x, kv[i].y, kv[i].z, kv[i].w};
                unsigned short h0 = f2bf(a[0]), h1 = f2bf(a[1]), h2 = f2bf(a[2]), h3 = f2bf(a[3]);
                ushort4 hv = make_ushort4(h0, h1, h2, h3);
                ushort4 lv = make_ushort4(f2bf(a[0] - bf2f(h0)), f2bf(a[1] - bf2f(h1)),
                                          f2bf(a[2] - bf2f(h2)), f2bf(a[3] - bf2f(h3)));
                *(ushort4*)(KhlB + srow * 256 + ((dchunk * 2) ^ swz)) = hv;
                *(ushort4*)(KhlB + srow * 256 + 128 + ((dchunk * 2) ^ swz)) = lv;
                *(float4*)&V32[srow * 68 + dchunk] = vv[i];
            }
        }
        __syncthreads();
        {
            int d = t >> 2, k0b = (t & 3) * 16;
            unsigned short hb[16], lb[16];
            #pragma unroll
            for (int i = 0; i < 16; i++) {
                float v = V32[(k0b + i) * 68 + d];
                unsigned short hh = f2bf(v);
                hb[i] = hh; lb[i] = f2bf(v - bf2f(hh));
            }
            int swz = (d & 7) << 4;
            #pragma unroll
            for (int c = 0; c < 4; c++) {
                ushort4 hv = make_ushort4(hb[4*c], hb[4*c+1], hb[4*c+2], hb[4*c+3]);
                ushort4 lv = make_ushort4(lb[4*c], lb[4*c+1], lb[4*c+2], lb[4*c+3]);
                *(ushort4*)(VtB + d * 256 + (((k0b + 4 * c) * 2) ^ swz)) = hv;
                *(ushort4*)(VtB + d * 256 + 128 + (((k0b + 4 * c) * 2) ^ swz)) = lv;
            }
        }
        f32x4 s[4];
        #pragma unroll
        for (int i = 0; i < 4; i++) { f32x4 z = {0.f,0.f,0.f,0.f}; s[i] = z; }
        #pragma unroll
        for (int ds = 0; ds < 2; ds++) {
            #pragma unroll
            for (int n = 0; n < 4; n++) {
                int r = n * 16 + fr;
                int swz = (r & 7) << 4;
                const unsigned char* rb = KhlB + r * 256;
                bf16x8 kh = *(const bf16x8*)(rb + ((ds * 64 + kg * 16) ^ swz));
                bf16x8 kl = *(const bf16x8*)(rb + 128 + ((ds * 64 + kg * 16) ^ swz));
                s[n] = __builtin_amdgcn_mfma_f32_16x16x32_bf16(qh[ds], kh, s[n], 0, 0, 0);
                s[n] = __builtin_amdgcn_mfma_f32_16x16x32_bf16(qh[ds], kl, s[n], 0, 0, 0);
                s[n] = __builtin_amdgcn_mfma_f32_16x16x32_bf16(qlo[ds], kh, s[n], 0, 0, 0);
            }
        }
        __syncthreads();
        float p[4][4];
        #pragma unroll
        for (int n = 0; n < 4; n++) {
            int kcol = c0 + n * 16 + fr;
            #pragma unroll
            for (int r = 0; r < 4; r++) {
                float sv = s[n][r] * 0.125f;
                if (kcol >= SEQ) sv = -1e30f;
                p[n][r] = sv;
            }
        }
        float corr[4];
        #pragma unroll
        for (int r = 0; r < 4; r++) {
            float mx = fmaxf(fmaxf(p[0][r], p[1][r]), fmaxf(p[2][r], p[3][r]));
            mx = fmaxf(mx, __shfl_xor(mx, 1));
            mx = fmaxf(mx, __shfl_xor(mx, 2));
            mx = fmaxf(mx, __shfl_xor(mx, 4));
            mx = fmaxf(mx, __shfl_xor(mx, 8));
            float mnew = fmaxf(m_run[r], mx);
            corr[r] = __expf(m_run[r] - mnew);
            m_run[r] = mnew;
            float ls = 0.f;
            #pragma unroll
            for (int n = 0; n < 4; n++) {
                p[n][r] = __expf(p[n][r] - mnew);
                ls += p[n][r];
            }
            ls += __shfl_xor(ls, 1);
            ls += __shfl_xor(ls, 2);
            ls += __shfl_xor(ls, 4);
            ls += __shfl_xor(ls, 8);
            l_run[r] = l_run[r] * corr[r] + ls;
        }
        #pragma unroll
        for (int nd = 0; nd < 4; nd++)
            #pragma unroll
            for (int r = 0; r < 4; r++)
                acc_o[nd][r] *= corr[r];
        {
            int qb = (lane >> 4) * 4;
            #pragma unroll
            for (int n = 0; n < 4; n++) {
                int kcol = n * 16 + fr;
                #pragma unroll
                for (int r = 0; r < 4; r++) {
                    int qq = qb + r;
                    unsigned short ph = f2bf(p[n][r]);
                    unsigned short pl = f2bf(p[n][r] - bf2f(ph));
                    int off = (kcol * 2) ^ ((qq & 7) << 4);
                    *(unsigned short*)(PwB + qq * 256 + off) = ph;
                    *(unsigned short*)(PwB + qq * 256 + 128 + off) = pl;
                }
            }
        }
        #pragma unroll
        for (int ks = 0; ks < 2; ks++) {
            int swzp = (fr & 7) << 4;
            bf16x8 pah = *(const bf16x8*)(PwB + fr * 256 + ((ks * 64 + kg * 16) ^ swzp));
            bf16x8 pal = *(const bf16x8*)(PwB + fr * 256 + 128 + ((ks * 64 + kg * 16) ^ swzp));
            #pragma unroll
            for (int nd = 0; nd < 4; nd++) {
                int rv = nd * 16 + fr;
                int swzv = (rv & 7) << 4;
                const unsigned char* rb = VtB + rv * 256;
                bf16x8 vh = *(const bf16x8*)(rb + ((ks * 64 + kg * 16) ^ swzv));
                bf16x8 vl = *(const bf16x8*)(rb + 128 + ((ks * 64 + kg * 16) ^ swzv));
                acc_o[nd] = __builtin_amdgcn_mfma_f32_16x16x32_bf16(pah, vh, acc_o[nd], 0, 0, 0);
                acc_o[nd] = __builtin_amdgcn_mfma_f32_16x16x32_bf16(pah, vl, acc_o[nd], 0, 0, 0);
                acc_o[nd] = __builtin_amdgcn_mfma_f32_16x16x32_bf16(pal, vh, acc_o[nd], 0, 0, 0);
            }
        }
    }
    #pragma unroll
    for (int r = 0; r < 4; r++) {
        int q = q0 + wid * 16 + (lane >> 4) * 4 + r;
        if (q >= SEQ) continue;
        float inv = 1.f / l_run[r];
        float* o = att + ((size_t)b * SEQ + q) * CDIM + h * DHEAD;
        #pragma unroll
        for (int nd = 0; nd < 4; nd++)
            o[nd * 16 + fr] = acc_o[nd][r] * inv;
    }
}

// ---------------- normalize img tokens ----------------
__global__ __launch_bounds__(256) void xn_kernel(const float* __restrict__ x2,
                                                 float* __restrict__ xn) {
    __shared__ float red[4];
    int tok = blockIdx.x;
    int b = tok / NIMG, n = tok % NIMG;
    const float* xr = x2 + ((size_t)b * SEQ + 1 + n) * CDIM;
    float* onr = xn + (size_t)tok * CDIM;
    int t = threadIdx.x;
    float v0 = xr[t], v1 = xr[t + 256], v2 = xr[t + 512];
    float ss = blk_sum256(v0 * v0 + v1 * v1 + v2 * v2, red);
    float nrm = fmaxf(sqrtf(ss), 1e-12f);
    float inv = 1.f / nrm;
    onr[t] = v0 * inv; onr[t + 256] = v1 * inv; onr[t + 512] = v2 * inv;
}

// ---------------- row max of symmetrized sim (excluding diagonal) ----------------
__global__ __launch_bounds__(64) void rowmax_kernel(const float* __restrict__ sim,
                                                    float* __restrict__ ms) {
    int row = blockIdx.x;
    int b = row / NIMG, n = row % NIMG;
    const float* sb = sim + (size_t)b * NIMG * NIMG;
    int lane = threadIdx.x;
    float mx = -1e30f;
    #pragma unroll
    for (int i = 0; i < NIMG / 64; i++) {
        int m = lane + i * 64;
        if (m != n) {
            float v = 0.5f * (sb[(size_t)n * NIMG + m] + sb[(size_t)m * NIMG + n]);
            mx = fmaxf(mx, v);
        }
    }
    #pragma unroll
    for (int o = 32; o; o >>= 1) mx = fmaxf(mx, __shfl_down(mx, o));
    if (lane == 0) ms[row] = mx;
}

// ---------------- exact top-k selection with lax.top_k tie semantics ----------------
__global__ __launch_bounds__(576) void select_kernel(const float* __restrict__ ms,
        int* __restrict__ mergemask, int* __restrict__ keeppos) {
    __shared__ float v[NIMG];
    __shared__ int keepf[NIMG];
    int b = blockIdx.x;
    int n = threadIdx.x;
    v[n] = ms[b * NIMG + n];
    __syncthreads();
    float vn = v[n];
    int rank_desc = 0, rank_asc = 0;
    for (int m = 0; m < NIMG; m++) {
        float vm = v[m];
        int tie_lo = (vm == vn && m < n);
        rank_desc += (vm > vn) || tie_lo;
        rank_asc  += (vm < vn) || tie_lo;
    }
    int merge = rank_desc < NMERGE;
    int keep  = rank_asc  < NMERGE;
    mergemask[b * NIMG + n] = merge;
    keepf[n] = keep;
    __syncthreads();
    if (keep) {
        int pos = 0;
        for (int m = 0; m < n; m++) pos += keepf[m];
        keeppos[b * NIMG + n] = pos;
    } else {
        keeppos[b * NIMG + n] = -1;
    }
}

// ---------------- average of merged tokens (parallelized) ----------------
__global__ __launch_bounds__(256) void avg_kernel(const float* __restrict__ x2,
        const int* __restrict__ mask, float* __restrict__ avg) {
    __shared__ float4 red[8][33];
    int b = blockIdx.x, cc = blockIdx.y;
    int t = threadIdx.x;
    int rr = t >> 5, c4 = t & 31;
    int c = cc * 128 + c4 * 4;
    const int* mb = mask + b * NIMG;
    float4 s = make_float4(0.f, 0.f, 0.f, 0.f);
    for (int n = rr; n < NIMG; n += 8) {
        if (mb[n]) {
            float4 v = *(const float4*)(x2 + ((size_t)b * SEQ + 1 + n) * CDIM + c);
            s.x += v.x; s.y += v.y; s.z += v.z; s.w += v.w;
        }
    }
    red[rr][c4] = s;
    __syncthreads();
    if (rr == 0) {
        float4 tot = red[0][c4];
        #pragma unroll
        for (int i = 1; i < 8; i++) {
            float4 v = red[i][c4];
            tot.x += v.x; tot.y += v.y; tot.z += v.z; tot.w += v.w;
        }
        float sc1 = 1.f / (float)NMERGE, sc2 = 1.f / (float)(NIMG - NMERGE);
        tot.x = (tot.x * sc1) * sc2; tot.y = (tot.y * sc1) * sc2;
        tot.z = (tot.z * sc1) * sc2; tot.w = (tot.w * sc1) * sc2;
        *(float4*)(avg + (size_t)b * CDIM + c) = tot;
    }
}

// ---------------- assemble output ----------------
__global__ __launch_bounds__(192) void assemble_kernel(const float* __restrict__ x2,
        const int* __restrict__ keeppos, const float* __restrict__ avg,
        float* __restrict__ out) {
    int g = blockIdx.x;
    int b = g / SEQ, s_ = g % SEQ;
    int t = threadIdx.x;
    const float4* src = (const float4*)(x2 + (size_t)g * CDIM);
    if (s_ == 0) {
        float4* dst = (float4*)(out + (size_t)b * 289 * CDIM);
        dst[t] = src[t];
    } else {
        int n = s_ - 1;
        int pos = keeppos[b * NIMG + n];
        if (pos < 0) return;
        const float4* av = (const float4*)(avg + (size_t)b * CDIM);
        float4 v = src[t], a = av[t];
        v.x += a.x; v.y += a.y; v.z += a.z; v.w += a.w;
        float4* dst = (float4*)(out + ((size_t)b * 289 + 1 + pos) * CDIM);
        dst[t] = v;
    }
}

extern "C" void kernel_launch(void* const* d_in, const int* in_sizes, int n_in,
                              void* d_out, int out_size, void* d_ws, size_t ws_size,
                              hipStream_t stream) {
    const float* x      = (const float*)d_in[0];
    const float* qkv_w  = (const float*)d_in[1];
    const float* qkv_b  = (const float*)d_in[2];
    const float* proj_w = (const float*)d_in[3];
    const float* proj_b = (const float*)d_in[4];
    const float* ln1_g  = (const float*)d_in[5];
    const float* ln1_b  = (const float*)d_in[6];
    const float* ln2_g  = (const float*)d_in[7];
    const float* ln2_b  = (const float*)d_in[8];
    const float* fc1_w  = (const float*)d_in[9];
    const float* fc1_b  = (const float*)d_in[10];
    const float* fc2_w  = (const float*)d_in[11];
    const float* fc2_b  = (const float*)d_in[12];

    if (ws_size < NEED_BYTES) return;

    float* ws   = (float*)d_ws;
    float* bh   = ws + O_BH;
    float* ba   = ws + O_BA;
    float* bq   = ws + O_BQ;
    float* ms   = ws + O_MS;
    int*   mask = (int*)(ws + O_MASK);
    int*   pos  = (int*)(ws + O_POS);
    float* avg  = ws + O_AVG;
    float* outp = (float*)d_out;

    unsigned short* qkvp  = (unsigned short*)(outp + OW_QKV);
    unsigned short* fc1p  = (unsigned short*)(outp + OW_FC1);
    unsigned short* fc2p  = (unsigned short*)(outp + OW_FC2);
    unsigned short* projp = (unsigned short*)(outp + OW_PROJ);

    // 0. split weights into swizzled LDS-image planes
    wsplit_kernel<<<18 * 24, 256, 0, stream>>>(qkv_w, qkvp, 24, CDIM);
    wsplit_kernel<<<24 * 24, 256, 0, stream>>>(fc1_w, fc1p, 24, CDIM);
    wsplit_kernel<<<6 * 96, 256, 0, stream>>>(fc2_w, fc2p, 96, 3072);
    wsplit_kernel<<<6 * 24, 256, 0, stream>>>(proj_w, projp, 24, CDIM);

    // 1. h = LN1(x)
    ln_kernel<<<MTOK, 256, 0, stream>>>(x, ln1_g, ln1_b, bh);

    // 2. per-group qkv GEMM (B planes + glds) + MFMA attention
    for (int g = 0; g < NGROUP; g++) {
        const float* hg = bh + (size_t)g * MGRP * CDIM;
        float* attg = ba + (size_t)g * MGRP * CDIM;
        gemm_wp<0><<<dim3((MGRP + 127) / 128, 18), 256, 0, stream>>>(
            hg, CDIM, qkvp, 24, (void*)bq, 3 * CDIM, qkv_b, nullptr,
            MGRP, 3 * CDIM, CDIM);
        attn_mfma<<<dim3((SEQ + 63) / 64, NHEADS, GB), 256, 0, stream>>>(
            bq, attg);
    }

    // 3. x1 = x + att @ proj_w^T + proj_b (B planes + glds)
    gemm_wp<1><<<dim3((MTOK + 127) / 128, 6), 256, 0, stream>>>(
        ba, CDIM, projp, 24, (void*)bh, CDIM, proj_b, x, MTOK, CDIM, CDIM);

    // 4. h2 = LN2(x1)
    ln_kernel<<<MTOK, 256, 0, stream>>>(bh, ln2_g, ln2_b, ba);

    // 5. MLP chunks: fc1 (gelu -> plane images in BQ), fc2 (dual-glds)
    for (int c0 = 0; c0 < MTOK; c0 += MLPCH) {
        int mc = (MTOK - c0 < MLPCH) ? (MTOK - c0) : MLPCH;
        const float* h2c = ba + (size_t)c0 * CDIM;
        float* x1c = bh + (size_t)c0 * CDIM;
        gemm_wp<5><<<dim3((mc + 127) / 128, 24), 256, 0, stream>>>(
            h2c, CDIM, fc1p, 24, (void*)bq, 3072, fc1_b, nullptr, mc, 3072, CDIM);
        gemm_pp<1><<<dim3((mc + 127) / 128, 6), 256, 0, stream>>>(
            (const unsigned short*)bq, fc2p, x1c, CDIM, fc2_b, x1c,
            mc, CDIM, 3072);
    }

    // 6. normalize img tokens
    xn_kernel<<<NBATCH * NIMG, 256, 0, stream>>>(bh, ba);

    // 7. sim = xn @ xn^T per batch
    gemm_mfma<3><<<dim3(5, 5, NBATCH), 256, 0, stream>>>(
        ba, (long long)NIMG * CDIM, CDIM, ba, (long long)NIMG * CDIM, CDIM,
        bq, (long long)NIMG * NIMG, NIMG, nullptr, nullptr, NIMG, NIMG, CDIM);

    // 8. row max of symmetrized sim
    rowmax_kernel<<<NBATCH * NIMG, 64, 0, stream>>>(bq, ms);
    // 9. top-k selection
    select_kernel<<<NBATCH, NIMG, 0, stream>>>(ms, mask, pos);
    // 10. merged-token average (parallel)
    avg_kernel<<<dim3(NBATCH, 6), 256, 0, stream>>>(bh, mask, avg);
    // 11. assemble output (overwrites weight-plane scratch in d_out)
    assemble_kernel<<<MTOK, 192, 0, stream>>>(bh, pos, avg, outp);
}

// Round 13
// 2215.286 us; speedup vs baseline: 3.0200x; 1.0315x over previous
//
#include <hip/hip_runtime.h>
#include <math.h>

#define CDIM 768
#define NHEADS 12
#define DHEAD 64
#define SEQ 577
#define NBATCH 32
#define MTOK (NBATCH*SEQ)      // 18464
#define NIMG 576
#define NMERGE 288
#define GB 8                   // batches per qkv group
#define NGROUP (NBATCH/GB)     // 4
#define MGRP (GB*SEQ)          // 4616 rows per group
#define MLPCH 3456             // MLP chunk rows (27 tiles)
#define NKT 10                 // k-tiles per (b,h) in attention

// ---- workspace layout (float offsets), peak ~159.4 MB ----
#define SZ_MC   ((size_t)MTOK*CDIM)              // 14,180,352
#define O_BH    ((size_t)0)                      // h -> x1/x2 (in-place)
#define O_BA    (SZ_MC)                          // att -> h2 -> xn
#define O_BQ    (2*SZ_MC)                        // Q+KV images / fc1o planes / sim
#define SZ_Q    ((size_t)MGRP*CDIM)              // 3,545,088
#define SZ_IMG  ((size_t)GB*NHEADS*NKT*4096)     // 3,932,160 floats (960 x 16KB)
#define O_KIMG  (O_BQ + SZ_Q)
#define O_VIMG  (O_KIMG + SZ_IMG)
#define O_SM    (O_VIMG + SZ_IMG)
#define O_MS    (O_SM)
#define O_MASK  (O_SM + (size_t)NBATCH*NIMG)
#define O_POS   (O_MASK + (size_t)NBATCH*NIMG)
#define O_AVG   (O_POS + (size_t)NBATCH*NIMG)
#define O_END   (O_AVG + (size_t)NBATCH*CDIM)
#define NEED_BYTES (O_END * 4)

// ---- weight-plane scratch inside d_out ----
#define OW_QKV  ((size_t)0)           // 18nt*24ks = 1,769,472 floats
#define OW_FC1  ((size_t)1769472)     // 24nt*24ks = 2,359,296 floats
#define OW_FC2  ((size_t)4128768)     // 6nt*96ks  = 2,359,296 floats
#define OW_PROJ ((size_t)6488064)     // 6nt*24ks  =   589,824 floats

typedef __attribute__((ext_vector_type(8))) short bf16x8;
typedef __attribute__((ext_vector_type(4))) float f32x4;
typedef __attribute__((address_space(1))) const void GAS_cv;
typedef __attribute__((address_space(3))) void LAS_v;

__device__ __forceinline__ unsigned short f2bf(float f) {
    unsigned int u = __float_as_uint(f);
    u += 0x7fff + ((u >> 16) & 1);           // RNE
    return (unsigned short)(u >> 16);
}
__device__ __forceinline__ float bf2f(unsigned short h) {
    return __uint_as_float(((unsigned int)h) << 16);
}

// ---- bijective XCD chunk remaps (m204) ----
__device__ __forceinline__ void xcd_map(int& bx, int& by, int& bz) {
    int gx = gridDim.x, gy = gridDim.y;
    int nwg = gx * gy * gridDim.z;
    int orig = blockIdx.x + gx * (blockIdx.y + gy * blockIdx.z);
    int q = nwg >> 3, r = nwg & 7;
    int xcd = orig & 7, pos = orig >> 3;
    int wg = (xcd < r ? xcd * (q + 1) : r * (q + 1) + (xcd - r) * q) + pos;
    bx = wg % gx;
    int t2 = wg / gx;
    by = t2 % gy;
    bz = t2 / gy;
}
__device__ __forceinline__ void xcd_map_nf(int& bx, int& by, int& bz) {
    int gx = gridDim.x, gy = gridDim.y;
    int nwg = gx * gy * gridDim.z;
    int orig = blockIdx.x + gx * (blockIdx.y + gy * blockIdx.z);
    int q = nwg >> 3, r = nwg & 7;
    int xcd = orig & 7, pos = orig >> 3;
    int wg = (xcd < r ? xcd * (q + 1) : r * (q + 1) + (xcd - r) * q) + pos;
    by = wg % gy;
    int t2 = wg / gy;
    bx = t2 % gx;
    bz = t2 / gx;
}

// ---------------- block reduce (256 threads) ----------------
__device__ __forceinline__ float blk_sum256(float v, float* red) {
    #pragma unroll
    for (int o = 32; o; o >>= 1) v += __shfl_down(v, o);
    if ((threadIdx.x & 63) == 0) red[threadIdx.x >> 6] = v;
    __syncthreads();
    float tot = red[0] + red[1] + red[2] + red[3];
    __syncthreads();
    return tot;
}

// ---------------- LayerNorm ----------------
__global__ __launch_bounds__(256) void ln_kernel(const float* __restrict__ x,
        const float* __restrict__ g, const float* __restrict__ b,
        float* __restrict__ out) {
    __shared__ float red[4];
    size_t row = blockIdx.x;
    const float* xr = x + row * CDIM;
    float* orow = out + row * CDIM;
    int t = threadIdx.x;
    float v0 = xr[t], v1 = xr[t + 256], v2 = xr[t + 512];
    float mu = blk_sum256(v0 + v1 + v2, red) * (1.f / CDIM);
    float d0 = v0 - mu, d1 = v1 - mu, d2 = v2 - mu;
    float var = blk_sum256(d0 * d0 + d1 * d1 + d2 * d2, red) * (1.f / CDIM);
    float e = var + 1e-5f;
    float rs = rsqrtf(e);
    rs = rs * (1.5f - 0.5f * e * rs * rs);
    orow[t]       = d0 * rs * g[t]       + b[t];
    orow[t + 256] = d1 * rs * g[t + 256] + b[t + 256];
    orow[t + 512] = d2 * rs * g[t + 512] + b[t + 512];
}

// ---------------- weight split: fp32 -> bf16 hi/lo LDS-image planes ----------------
__global__ __launch_bounds__(256) void wsplit_kernel(const float* __restrict__ w,
        unsigned short* __restrict__ wp, int nksteps, int ldw) {
    int bid = blockIdx.x;
    int nt = bid / nksteps, ks = bid % nksteps;
    int t = threadIdx.x;
    int srow = t >> 3, sj = t & 7;
    unsigned short* img = wp + ((size_t)bid << 13);
    #pragma unroll
    for (int i = 0; i < 4; i++) {
        int r = srow + i * 32;
        float4 v = *(const float4*)(w + (size_t)(nt * 128 + r) * ldw + ks * 32 + sj * 4);
        unsigned short h0 = f2bf(v.x), h1 = f2bf(v.y), h2 = f2bf(v.z), h3 = f2bf(v.w);
        ushort4 hv = make_ushort4(h0, h1, h2, h3);
        ushort4 lv = make_ushort4(f2bf(v.x - bf2f(h0)), f2bf(v.y - bf2f(h1)),
                                  f2bf(v.z - bf2f(h2)), f2bf(v.w - bf2f(h3)));
        int swz = (r & 7) << 4;
        int ohi = ((8 * sj) ^ swz) >> 1;
        int olo = ((64 + 8 * sj) ^ swz) >> 1;
        *(ushort4*)&img[r * 64 + ohi] = hv;
        *(ushort4*)&img[r * 64 + olo] = lv;
    }
}

// ---------------- GEMM, A fp32 fused-convert + B pre-split planes via glds ----------
// EPI: 0 = +bias (fp32 C), 1 = +bias+res (fp32 C, res may alias C),
//      5 = gelu(+bias) -> bf16 hi/lo plane IMAGES (Cv = image base, ldc = N)
//      6 = qkv scatter: Q -> fp32 rows (Cv), K -> Kimg images, V -> TRANSPOSED
//          Vimg images; layouts byte-identical to attn's verified LDS staging.
template<int EPI>
__global__ __launch_bounds__(256)
void gemm_wp(const float* __restrict__ A, int lda,
             const unsigned short* __restrict__ Bp, int nksteps,
             void* __restrict__ Cv, int ldc,
             const float* __restrict__ bias,
             const float* __restrict__ res,
             int M, int N, int K,
             unsigned short* __restrict__ Kimg,
             unsigned short* __restrict__ Vimg) {
    __shared__ unsigned short Asl[128 * 64];
    __shared__ unsigned short Bsl[128 * 64];
    int bx, by, bz;
    xcd_map_nf(bx, by, bz);
    const int m0 = bx * 128;
    const int t = threadIdx.x;
    const int lane = t & 63, wid = t >> 6;
    const int wr = wid >> 1, wc = wid & 1;
    const int srow = t >> 3;
    const int sj   = t & 7;
    const unsigned char* BpB = (const unsigned char*)Bp;

    const float* pa[4];
    #pragma unroll
    for (int i = 0; i < 4; i++) {
        int r = srow + i * 32;
        int ra = m0 + r; ra = ra < M ? ra : M - 1;
        pa[i] = A + (size_t)ra * lda + sj * 4;
    }

    f32x4 acc[4][4];
    #pragma unroll
    for (int i = 0; i < 4; i++)
        #pragma unroll
        for (int j = 0; j < 4; j++) {
            f32x4 z = {0.f, 0.f, 0.f, 0.f};
            acc[i][j] = z;
        }

    const int nsteps = K >> 5;
    float4 va[4];
    #pragma unroll
    for (int i = 0; i < 4; i++) va[i] = *(const float4*)(pa[i]);

    for (int ks = 0; ks < nsteps; ks++) {
        ushort4 cah[4], cal[4];
        #pragma unroll
        for (int i = 0; i < 4; i++) {
            float aa[4] = {va[i].x, va[i].y, va[i].z, va[i].w};
            unsigned short h0 = f2bf(aa[0]), h1 = f2bf(aa[1]), h2 = f2bf(aa[2]), h3 = f2bf(aa[3]);
            cah[i] = make_ushort4(h0, h1, h2, h3);
            cal[i] = make_ushort4(f2bf(aa[0] - bf2f(h0)), f2bf(aa[1] - bf2f(h1)),
                                  f2bf(aa[2] - bf2f(h2)), f2bf(aa[3] - bf2f(h3)));
        }
        __syncthreads();
        {
            const unsigned char* img = BpB + (((size_t)by * nksteps + ks) << 14);
            #pragma unroll
            for (int i = 0; i < 4; i++) {
                int chunk = (i << 2) | wid;
                __builtin_amdgcn_global_load_lds((GAS_cv*)(img + chunk * 1024 + lane * 16),
                    (LAS_v*)((unsigned char*)Bsl + chunk * 1024), 16, 0, 0);
            }
        }
        #pragma unroll
        for (int i = 0; i < 4; i++) {
            int r = srow + i * 32;
            int swz = (r & 7) << 4;
            int ohi = ((8 * sj) ^ swz) >> 1;
            int olo = ((64 + 8 * sj) ^ swz) >> 1;
            *(ushort4*)&Asl[r * 64 + ohi] = cah[i];
            *(ushort4*)&Asl[r * 64 + olo] = cal[i];
        }
        __syncthreads();
        const int fr = lane & 15, kg = lane >> 4;
        bf16x8 ah[4], al[4], bh[4], bl[4];
        #pragma unroll
        for (int m = 0; m < 4; m++) {
            int r = wr * 64 + m * 16 + fr;
            int swz = (r & 7) << 4;
            const unsigned char* base = (const unsigned char*)&Asl[r * 64];
            ah[m] = *(const bf16x8*)(base + ((16 * kg) ^ swz));
            al[m] = *(const bf16x8*)(base + ((64 + 16 * kg) ^ swz));
        }
        #pragma unroll
        for (int n = 0; n < 4; n++) {
            int r = wc * 64 + n * 16 + fr;
            int swz = (r & 7) << 4;
            const unsigned char* base = (const unsigned char*)&Bsl[r * 64];
            bh[n] = *(const bf16x8*)(base + ((16 * kg) ^ swz));
            bl[n] = *(const bf16x8*)(base + ((64 + 16 * kg) ^ swz));
        }
        if (ks + 1 < nsteps) {
            const int k0n = (ks + 1) << 5;
            #pragma unroll
            for (int i = 0; i < 4; i++) va[i] = *(const float4*)(pa[i] + k0n);
        }
        #pragma unroll
        for (int m = 0; m < 4; m++)
            #pragma unroll
            for (int n = 0; n < 4; n++) {
                acc[m][n] = __builtin_amdgcn_mfma_f32_16x16x32_bf16(ah[m], bh[n], acc[m][n], 0, 0, 0);
                acc[m][n] = __builtin_amdgcn_mfma_f32_16x16x32_bf16(ah[m], bl[n], acc[m][n], 0, 0, 0);
                acc[m][n] = __builtin_amdgcn_mfma_f32_16x16x32_bf16(al[m], bh[n], acc[m][n], 0, 0, 0);
            }
    }

    const int fr = lane & 15, fq = lane >> 4;
    const int n0 = by * 128;
    #pragma unroll
    for (int m = 0; m < 4; m++) {
        #pragma unroll
        for (int rr = 0; rr < 4; rr++) {
            int row = m0 + wr * 64 + m * 16 + fq * 4 + rr;
            if (row >= M) continue;
            #pragma unroll
            for (int n = 0; n < 4; n++) {
                int col = n0 + wc * 64 + n * 16 + fr;
                float v = acc[m][n][rr];
                size_t ci = (size_t)row * ldc + col;
                if (EPI == 0) {
                    ((float*)Cv)[ci] = v + bias[col];
                } else if (EPI == 1) {
                    ((float*)Cv)[ci] = v + bias[col] + res[ci];
                } else if (EPI == 5) {
                    v += bias[col];
                    v = 0.5f * v * (1.0f + erff(v * 0.70710678118654752f));
                    unsigned short hh = f2bf(v);
                    unsigned short ll = f2bf(v - bf2f(hh));
                    unsigned char* img = (unsigned char*)Cv +
                        (((size_t)(row >> 7) * (ldc >> 5) + (col >> 5)) << 14);
                    int r2 = row & 127, swz2 = (r2 & 7) << 4, kc = col & 31;
                    *(unsigned short*)(img + r2 * 128 + ((2 * kc) ^ swz2)) = hh;
                    *(unsigned short*)(img + r2 * 128 + ((64 + 2 * kc) ^ swz2)) = ll;
                } else { // 6: qkv scatter (head = (col>>6)-12 for K, -24 for V;
                         //  NOTE: col&767 is WRONG, 768 is not pow2 — round-12 bug)
                    float v2 = v + bias[col];
                    if (col < 768) {
                        ((float*)Cv)[(size_t)row * 768 + col] = v2;
                    } else {
                        int b_local = row / SEQ;
                        int s = row - b_local * SEQ;
                        int dloc = col & 63;
                        int kt = s >> 6, r2 = s & 63;
                        unsigned short hh = f2bf(v2);
                        unsigned short ll = f2bf(v2 - bf2f(hh));
                        if (col < 1536) {   // K: head = (col>>6)-12
                            int hh_i = (col >> 6) - 12;
                            size_t imgi = (((size_t)b_local * NHEADS + hh_i) * NKT + kt) << 14;
                            unsigned char* img = (unsigned char*)Kimg + imgi;
                            int off = (2 * dloc) ^ ((r2 & 7) << 4);
                            *(unsigned short*)(img + r2 * 256 + off) = hh;
                            *(unsigned short*)(img + r2 * 256 + 128 + off) = ll;
                        } else {            // V transposed: head = (col>>6)-24
                            int hh_i = (col >> 6) - 24;
                            size_t imgi = (((size_t)b_local * NHEADS + hh_i) * NKT + kt) << 14;
                            unsigned char* img = (unsigned char*)Vimg + imgi;
                            int off = (2 * r2) ^ ((dloc & 7) << 4);
                            *(unsigned short*)(img + dloc * 256 + off) = hh;
                            *(unsigned short*)(img + dloc * 256 + 128 + off) = ll;
                        }
                    }
                }
            }
        }
    }
}

// ---------------- GEMM, BOTH operands pre-split plane images via glds ----------
template<int EPI>
__global__ __launch_bounds__(256)
void gemm_pp(const unsigned short* __restrict__ Ap,
             const unsigned short* __restrict__ Bp,
             float* __restrict__ C, int ldc,
             const float* __restrict__ bias,
             const float* __restrict__ res,
             int M, int N, int K) {
    __shared__ unsigned short Asl[128 * 64];
    __shared__ unsigned short Bsl[128 * 64];
    int bx, by, bz;
    xcd_map_nf(bx, by, bz);
    const int t = threadIdx.x;
    const int lane = t & 63, wid = t >> 6;
    const int wr = wid >> 1, wc = wid & 1;
    const unsigned char* ApB = (const unsigned char*)Ap;
    const unsigned char* BpB = (const unsigned char*)Bp;

    f32x4 acc[4][4];
    #pragma unroll
    for (int i = 0; i < 4; i++)
        #pragma unroll
        for (int j = 0; j < 4; j++) {
            f32x4 z = {0.f, 0.f, 0.f, 0.f};
            acc[i][j] = z;
        }

    const int nsteps = K >> 5;
    for (int ks = 0; ks < nsteps; ks++) {
        __syncthreads();
        const unsigned char* imgA = ApB + (((size_t)bx * nsteps + ks) << 14);
        const unsigned char* imgB = BpB + (((size_t)by * nsteps + ks) << 14);
        #pragma unroll
        for (int i = 0; i < 4; i++) {
            int chunk = (i << 2) | wid;
            __builtin_amdgcn_global_load_lds((GAS_cv*)(imgA + chunk * 1024 + lane * 16),
                (LAS_v*)((unsigned char*)Asl + chunk * 1024), 16, 0, 0);
            __builtin_amdgcn_global_load_lds((GAS_cv*)(imgB + chunk * 1024 + lane * 16),
                (LAS_v*)((unsigned char*)Bsl + chunk * 1024), 16, 0, 0);
        }
        __syncthreads();
        const int fr = lane & 15, kg = lane >> 4;
        bf16x8 ah[4], al[4], bh[4], bl[4];
        #pragma unroll
        for (int m = 0; m < 4; m++) {
            int r = wr * 64 + m * 16 + fr;
            int swz = (r & 7) << 4;
            const unsigned char* base = (const unsigned char*)&Asl[r * 64];
            ah[m] = *(const bf16x8*)(base + ((16 * kg) ^ swz));
            al[m] = *(const bf16x8*)(base + ((64 + 16 * kg) ^ swz));
        }
        #pragma unroll
        for (int n = 0; n < 4; n++) {
            int r = wc * 64 + n * 16 + fr;
            int swz = (r & 7) << 4;
            const unsigned char* base = (const unsigned char*)&Bsl[r * 64];
            bh[n] = *(const bf16x8*)(base + ((16 * kg) ^ swz));
            bl[n] = *(const bf16x8*)(base + ((64 + 16 * kg) ^ swz));
        }
        #pragma unroll
        for (int m = 0; m < 4; m++)
            #pragma unroll
            for (int n = 0; n < 4; n++) {
                acc[m][n] = __builtin_amdgcn_mfma_f32_16x16x32_bf16(ah[m], bh[n], acc[m][n], 0, 0, 0);
                acc[m][n] = __builtin_amdgcn_mfma_f32_16x16x32_bf16(ah[m], bl[n], acc[m][n], 0, 0, 0);
                acc[m][n] = __builtin_amdgcn_mfma_f32_16x16x32_bf16(al[m], bh[n], acc[m][n], 0, 0, 0);
            }
    }

    const int fr = lane & 15, fq = lane >> 4;
    const int m0 = bx * 128, n0 = by * 128;
    #pragma unroll
    for (int m = 0; m < 4; m++) {
        #pragma unroll
        for (int rr = 0; rr < 4; rr++) {
            int row = m0 + wr * 64 + m * 16 + fq * 4 + rr;
            if (row >= M) continue;
            #pragma unroll
            for (int n = 0; n < 4; n++) {
                int col = n0 + wc * 64 + n * 16 + fr;
                float v = acc[m][n][rr];
                size_t ci = (size_t)row * ldc + col;
                C[ci] = v + bias[col] + res[ci];
            }
        }
    }
}

// ---------------- fused-convert MFMA GEMM (sim) ----------------
template<int EPI>
__global__ __launch_bounds__(256)
void gemm_mfma(const float* __restrict__ A, long long sA, int lda,
               const float* __restrict__ Bm, long long sB, int ldb,
               float* __restrict__ C, long long sC, int ldc,
               const float* __restrict__ bias,
               const float* __restrict__ res,
               int M, int N, int K) {
    __shared__ unsigned short Asl[128 * 64];
    __shared__ unsigned short Bsl[128 * 64];
    int bx, by, bz;
    xcd_map_nf(bx, by, bz);
    A  += (size_t)bz * sA;
    Bm += (size_t)bz * sB;
    C  += (size_t)bz * sC;
    const int m0 = bx * 128, n0 = by * 128;
    const int t = threadIdx.x;
    const int lane = t & 63, wid = t >> 6;
    const int wr = wid >> 1, wc = wid & 1;
    const int srow = t >> 3;
    const int sj   = t & 7;

    const float* pa[4];
    const float* pb[4];
    #pragma unroll
    for (int i = 0; i < 4; i++) {
        int r = srow + i * 32;
        int ra = m0 + r; ra = ra < M ? ra : M - 1;
        int rb = n0 + r; rb = rb < N ? rb : N - 1;
        pa[i] = A  + (size_t)ra * lda + sj * 4;
        pb[i] = Bm + (size_t)rb * ldb + sj * 4;
    }

    f32x4 acc[4][4];
    #pragma unroll
    for (int i = 0; i < 4; i++)
        #pragma unroll
        for (int j = 0; j < 4; j++) {
            f32x4 z = {0.f, 0.f, 0.f, 0.f};
            acc[i][j] = z;
        }

    const int nsteps = K >> 5;
    float4 va[4], vb[4];
    #pragma unroll
    for (int i = 0; i < 4; i++) {
        va[i] = *(const float4*)(pa[i]);
        vb[i] = *(const float4*)(pb[i]);
    }

    for (int ks = 0; ks < nsteps; ks++) {
        ushort4 cah[4], cal[4], cbh[4], cbl[4];
        #pragma unroll
        for (int i = 0; i < 4; i++) {
            float aa[4] = {va[i].x, va[i].y, va[i].z, va[i].w};
            float bb[4] = {vb[i].x, vb[i].y, vb[i].z, vb[i].w};
            unsigned short h0 = f2bf(aa[0]), h1 = f2bf(aa[1]), h2 = f2bf(aa[2]), h3 = f2bf(aa[3]);
            cah[i] = make_ushort4(h0, h1, h2, h3);
            cal[i] = make_ushort4(f2bf(aa[0] - bf2f(h0)), f2bf(aa[1] - bf2f(h1)),
                                  f2bf(aa[2] - bf2f(h2)), f2bf(aa[3] - bf2f(h3)));
            unsigned short g0 = f2bf(bb[0]), g1 = f2bf(bb[1]), g2 = f2bf(bb[2]), g3 = f2bf(bb[3]);
            cbh[i] = make_ushort4(g0, g1, g2, g3);
            cbl[i] = make_ushort4(f2bf(bb[0] - bf2f(g0)), f2bf(bb[1] - bf2f(g1)),
                                  f2bf(bb[2] - bf2f(g2)), f2bf(bb[3] - bf2f(g3)));
        }
        if (ks + 1 < nsteps) {
            const int k0n = (ks + 1) << 5;
            #pragma unroll
            for (int i = 0; i < 4; i++) {
                va[i] = *(const float4*)(pa[i] + k0n);
                vb[i] = *(const float4*)(pb[i] + k0n);
            }
        }
        __syncthreads();
        #pragma unroll
        for (int i = 0; i < 4; i++) {
            int r = srow + i * 32;
            int swz = (r & 7) << 4;
            int ohi = ((8 * sj) ^ swz) >> 1;
            int olo = ((64 + 8 * sj) ^ swz) >> 1;
            *(ushort4*)&Asl[r * 64 + ohi] = cah[i];
            *(ushort4*)&Asl[r * 64 + olo] = cal[i];
            *(ushort4*)&Bsl[r * 64 + ohi] = cbh[i];
            *(ushort4*)&Bsl[r * 64 + olo] = cbl[i];
        }
        __syncthreads();
        const int fr = lane & 15, kg = lane >> 4;
        bf16x8 ah[4], al[4], bh[4], bl[4];
        #pragma unroll
        for (int m = 0; m < 4; m++) {
            int r = wr * 64 + m * 16 + fr;
            int swz = (r & 7) << 4;
            const unsigned char* base = (const unsigned char*)&Asl[r * 64];
            ah[m] = *(const bf16x8*)(base + ((16 * kg) ^ swz));
            al[m] = *(const bf16x8*)(base + ((64 + 16 * kg) ^ swz));
        }
        #pragma unroll
        for (int n = 0; n < 4; n++) {
            int r = wc * 64 + n * 16 + fr;
            int swz = (r & 7) << 4;
            const unsigned char* base = (const unsigned char*)&Bsl[r * 64];
            bh[n] = *(const bf16x8*)(base + ((16 * kg) ^ swz));
            bl[n] = *(const bf16x8*)(base + ((64 + 16 * kg) ^ swz));
        }
        #pragma unroll
        for (int m = 0; m < 4; m++)
            #pragma unroll
            for (int n = 0; n < 4; n++) {
                acc[m][n] = __builtin_amdgcn_mfma_f32_16x16x32_bf16(ah[m], bh[n], acc[m][n], 0, 0, 0);
                acc[m][n] = __builtin_amdgcn_mfma_f32_16x16x32_bf16(ah[m], bl[n], acc[m][n], 0, 0, 0);
                acc[m][n] = __builtin_amdgcn_mfma_f32_16x16x32_bf16(al[m], bh[n], acc[m][n], 0, 0, 0);
            }
    }

    const int fr = lane & 15, fq = lane >> 4;
    #pragma unroll
    for (int m = 0; m < 4; m++) {
        #pragma unroll
        for (int rr = 0; rr < 4; rr++) {
            int row = m0 + wr * 64 + m * 16 + fq * 4 + rr;
            if (row >= M) continue;
            #pragma unroll
            for (int n = 0; n < 4; n++) {
                int col = n0 + wc * 64 + n * 16 + fr;
                if (col >= N) continue;
                C[(size_t)row * ldc + col] = acc[m][n][rr];
            }
        }
    }
}

// ---------------- MFMA flash attention: K/Vt pre-split images via glds ----------------
__global__ __launch_bounds__(256) void attn_glds(const float* __restrict__ Qb,
        const unsigned short* __restrict__ Kimg, const unsigned short* __restrict__ Vimg,
        float* __restrict__ att) {
    int bx, by, bz;
    xcd_map(bx, by, bz);
    const int b = bz, h = by, q0 = bx * 64;
    const int t = threadIdx.x;
    const int lane = t & 63, wid = t >> 6;
    const int fr = lane & 15, kg = lane >> 4;
    __shared__ unsigned short Khl[64 * 128];
    __shared__ unsigned short Vt[64 * 128];
    __shared__ unsigned char Pbuf[16384];
    unsigned char* KhlB = (unsigned char*)Khl;
    unsigned char* VtB = (unsigned char*)Vt;
    unsigned char* PwB = Pbuf + wid * 4096;
    const unsigned char* KiB = (const unsigned char*)Kimg + (((size_t)b * NHEADS + h) * NKT << 14);
    const unsigned char* ViB = (const unsigned char*)Vimg + (((size_t)b * NHEADS + h) * NKT << 14);

    bf16x8 qh[2], qlo[2];
    {
        int qrow = q0 + wid * 16 + fr; qrow = qrow < SEQ ? qrow : SEQ - 1;
        const float* qbase = Qb + ((size_t)b * SEQ + qrow) * CDIM + h * DHEAD;
        #pragma unroll
        for (int ds = 0; ds < 2; ds++) {
            float tmp[8];
            *(float4*)(tmp)     = *(const float4*)(qbase + ds * 32 + kg * 8);
            *(float4*)(tmp + 4) = *(const float4*)(qbase + ds * 32 + kg * 8 + 4);
            #pragma unroll
            for (int j = 0; j < 8; j++) {
                unsigned short hh = f2bf(tmp[j]);
                qh[ds][j]  = (short)hh;
                qlo[ds][j] = (short)f2bf(tmp[j] - bf2f(hh));
            }
        }
    }

    f32x4 acc_o[4];
    #pragma unroll
    for (int i = 0; i < 4; i++) { f32x4 z = {0.f,0.f,0.f,0.f}; acc_o[i] = z; }
    float m_run[4] = {-1e30f, -1e30f, -1e30f, -1e30f};
    float l_run[4] = {0.f, 0.f, 0.f, 0.f};

    for (int kt = 0; kt < NKT; kt++) {
        const int c0 = kt * 64;
        __syncthreads();   // prev tile's LDS reads complete
        {
            const unsigned char* ki = KiB + ((size_t)kt << 14);
            const unsigned char* vi = ViB + ((size_t)kt << 14);
            #pragma unroll
            for (int i = 0; i < 4; i++) {
                int chunk = (i << 2) | wid;
                __builtin_amdgcn_global_load_lds((GAS_cv*)(ki + chunk * 1024 + lane * 16),
                    (LAS_v*)(KhlB + chunk * 1024), 16, 0, 0);
                __builtin_amdgcn_global_load_lds((GAS_cv*)(vi + chunk * 1024 + lane * 16),
                    (LAS_v*)(VtB + chunk * 1024), 16, 0, 0);
            }
        }
        __syncthreads();   // drain glds
        // QK^T
        f32x4 s[4];
        #pragma unroll
        for (int i = 0; i < 4; i++) { f32x4 z = {0.f,0.f,0.f,0.f}; s[i] = z; }
        #pragma unroll
        for (int ds = 0; ds < 2; ds++) {
            #pragma unroll
            for (int n = 0; n < 4; n++) {
                int r = n * 16 + fr;
                int swz = (r & 7) << 4;
                const unsigned char* rb = KhlB + r * 256;
                bf16x8 kh = *(const bf16x8*)(rb + ((ds * 64 + kg * 16) ^ swz));
                bf16x8 kl = *(const bf16x8*)(rb + 128 + ((ds * 64 + kg * 16) ^ swz));
                s[n] = __builtin_amdgcn_mfma_f32_16x16x32_bf16(qh[ds], kh, s[n], 0, 0, 0);
                s[n] = __builtin_amdgcn_mfma_f32_16x16x32_bf16(qh[ds], kl, s[n], 0, 0, 0);
                s[n] = __builtin_amdgcn_mfma_f32_16x16x32_bf16(qlo[ds], kh, s[n], 0, 0, 0);
            }
        }
        // online softmax
        float p[4][4];
        #pragma unroll
        for (int n = 0; n < 4; n++) {
            int kcol = c0 + n * 16 + fr;
            #pragma unroll
            for (int r = 0; r < 4; r++) {
                float sv = s[n][r] * 0.125f;
                if (kcol >= SEQ) sv = -1e30f;
                p[n][r] = sv;
            }
        }
        float corr[4];
        #pragma unroll
        for (int r = 0; r < 4; r++) {
            float mx = fmaxf(fmaxf(p[0][r], p[1][r]), fmaxf(p[2][r], p[3][r]));
            mx = fmaxf(mx, __shfl_xor(mx, 1));
            mx = fmaxf(mx, __shfl_xor(mx, 2));
            mx = fmaxf(mx, __shfl_xor(mx, 4));
            mx = fmaxf(mx, __shfl_xor(mx, 8));
            float mnew = fmaxf(m_run[r], mx);
            corr[r] = __expf(m_run[r] - mnew);
            m_run[r] = mnew;
            float ls = 0.f;
            #pragma unroll
            for (int n = 0; n < 4; n++) {
                p[n][r] = __expf(p[n][r] - mnew);
                ls += p[n][r];
            }
            ls += __shfl_xor(ls, 1);
            ls += __shfl_xor(ls, 2);
            ls += __shfl_xor(ls, 4);
            ls += __shfl_xor(ls, 8);
            l_run[r] = l_run[r] * corr[r] + ls;
        }
        #pragma unroll
        for (int nd = 0; nd < 4; nd++)
            #pragma unroll
            for (int r = 0; r < 4; r++)
                acc_o[nd][r] *= corr[r];
        // P -> per-wave LDS (bf16 hi/lo)
        {
            int qb = (lane >> 4) * 4;
            #pragma unroll
            for (int n = 0; n < 4; n++) {
                int kcol = n * 16 + fr;
                #pragma unroll
                for (int r = 0; r < 4; r++) {
                    int qq = qb + r;
                    unsigned short ph = f2bf(p[n][r]);
                    unsigned short pl = f2bf(p[n][r] - bf2f(ph));
                    int off = (kcol * 2) ^ ((qq & 7) << 4);
                    *(unsigned short*)(PwB + qq * 256 + off) = ph;
                    *(unsigned short*)(PwB + qq * 256 + 128 + off) = pl;
                }
            }
        }
        // PV
        #pragma unroll
        for (int ks = 0; ks < 2; ks++) {
            int swzp = (fr & 7) << 4;
            bf16x8 pah = *(const bf16x8*)(PwB + fr * 256 + ((ks * 64 + kg * 16) ^ swzp));
            bf16x8 pal = *(const bf16x8*)(PwB + fr * 256 + 128 + ((ks * 64 + kg * 16) ^ swzp));
            #pragma unroll
            for (int nd = 0; nd < 4; nd++) {
                int rv = nd * 16 + fr;
                int swzv = (rv & 7) << 4;
                const unsigned char* rb = VtB + rv * 256;
                bf16x8 vh = *(const bf16x8*)(rb + ((ks * 64 + kg * 16) ^ swzv));
                bf16x8 vl = *(const bf16x8*)(rb + 128 + ((ks * 64 + kg * 16) ^ swzv));
                acc_o[nd] = __builtin_amdgcn_mfma_f32_16x16x32_bf16(pah, vh, acc_o[nd], 0, 0, 0);
                acc_o[nd] = __builtin_amdgcn_mfma_f32_16x16x32_bf16(pah, vl, acc_o[nd], 0, 0, 0);
                acc_o[nd] = __builtin_amdgcn_mfma_f32_16x16x32_bf16(pal, vh, acc_o[nd], 0, 0, 0);
            }
        }
    }
    #pragma unroll
    for (int r = 0; r < 4; r++) {
        int q = q0 + wid * 16 + (lane >> 4) * 4 + r;
        if (q >= SEQ) continue;
        float inv = 1.f / l_run[r];
        float* o = att + ((size_t)b * SEQ + q) * CDIM + h * DHEAD;
        #pragma unroll
        for (int nd = 0; nd < 4; nd++)
            o[nd * 16 + fr] = acc_o[nd][r] * inv;
    }
}

// ---------------- normalize img tokens ----------------
__global__ __launch_bounds__(256) void xn_kernel(const float* __restrict__ x2,
                                                 float* __restrict__ xn) {
    __shared__ float red[4];
    int tok = blockIdx.x;
    int b = tok / NIMG, n = tok % NIMG;
    const float* xr = x2 + ((size_t)b * SEQ + 1 + n) * CDIM;
    float* onr = xn + (size_t)tok * CDIM;
    int t = threadIdx.x;
    float v0 = xr[t], v1 = xr[t + 256], v2 = xr[t + 512];
    float ss = blk_sum256(v0 * v0 + v1 * v1 + v2 * v2, red);
    float nrm = fmaxf(sqrtf(ss), 1e-12f);
    float inv = 1.f / nrm;
    onr[t] = v0 * inv; onr[t + 256] = v1 * inv; onr[t + 512] = v2 * inv;
}

// ---------------- row max of symmetrized sim (excluding diagonal) ----------------
__global__ __launch_bounds__(64) void rowmax_kernel(const float* __restrict__ sim,
                                                    float* __restrict__ ms) {
    int row = blockIdx.x;
    int b = row / NIMG, n = row % NIMG;
    const float* sb = sim + (size_t)b * NIMG * NIMG;
    int lane = threadIdx.x;
    float mx = -1e30f;
    #pragma unroll
    for (int i = 0; i < NIMG / 64; i++) {
        int m = lane + i * 64;
        if (m != n) {
            float v = 0.5f * (sb[(size_t)n * NIMG + m] + sb[(size_t)m * NIMG + n]);
            mx = fmaxf(mx, v);
        }
    }
    #pragma unroll
    for (int o = 32; o; o >>= 1) mx = fmaxf(mx, __shfl_down(mx, o));
    if (lane == 0) ms[row] = mx;
}

// ---------------- exact top-k selection with lax.top_k tie semantics ----------------
__global__ __launch_bounds__(576) void select_kernel(const float* __restrict__ ms,
        int* __restrict__ mergemask, int* __restrict__ keeppos) {
    __shared__ float v[NIMG];
    __shared__ int keepf[NIMG];
    int b = blockIdx.x;
    int n = threadIdx.x;
    v[n] = ms[b * NIMG + n];
    __syncthreads();
    float vn = v[n];
    int rank_desc = 0, rank_asc = 0;
    for (int m = 0; m < NIMG; m++) {
        float vm = v[m];
        int tie_lo = (vm == vn && m < n);
        rank_desc += (vm > vn) || tie_lo;
        rank_asc  += (vm < vn) || tie_lo;
    }
    int merge = rank_desc < NMERGE;
    int keep  = rank_asc  < NMERGE;
    mergemask[b * NIMG + n] = merge;
    keepf[n] = keep;
    __syncthreads();
    if (keep) {
        int pos = 0;
        for (int m = 0; m < n; m++) pos += keepf[m];
        keeppos[b * NIMG + n] = pos;
    } else {
        keeppos[b * NIMG + n] = -1;
    }
}

// ---------------- average of merged tokens (parallelized) ----------------
__global__ __launch_bounds__(256) void avg_kernel(const float* __restrict__ x2,
        const int* __restrict__ mask, float* __restrict__ avg) {
    __shared__ float4 red[8][33];
    int b = blockIdx.x, cc = blockIdx.y;
    int t = threadIdx.x;
    int rr = t >> 5, c4 = t & 31;
    int c = cc * 128 + c4 * 4;
    const int* mb = mask + b * NIMG;
    float4 s = make_float4(0.f, 0.f, 0.f, 0.f);
    for (int n = rr; n < NIMG; n += 8) {
        if (mb[n]) {
            float4 v = *(const float4*)(x2 + ((size_t)b * SEQ + 1 + n) * CDIM + c);
            s.x += v.x; s.y += v.y; s.z += v.z; s.w += v.w;
        }
    }
    red[rr][c4] = s;
    __syncthreads();
    if (rr == 0) {
        float4 tot = red[0][c4];
        #pragma unroll
        for (int i = 1; i < 8; i++) {
            float4 v = red[i][c4];
            tot.x += v.x; tot.y += v.y; tot.z += v.z; tot.w += v.w;
        }
        float sc1 = 1.f / (float)NMERGE, sc2 = 1.f / (float)(NIMG - NMERGE);
        tot.x = (tot.x * sc1) * sc2; tot.y = (tot.y * sc1) * sc2;
        tot.z = (tot.z * sc1) * sc2; tot.w = (tot.w * sc1) * sc2;
        *(float4*)(avg + (size_t)b * CDIM + c) = tot;
    }
}

// ---------------- assemble output ----------------
__global__ __launch_bounds__(192) void assemble_kernel(const float* __restrict__ x2,
        const int* __restrict__ keeppos, const float* __restrict__ avg,
        float* __restrict__ out) {
    int g = blockIdx.x;
    int b = g / SEQ, s_ = g % SEQ;
    int t = threadIdx.x;
    const float4* src = (const float4*)(x2 + (size_t)g * CDIM);
    if (s_ == 0) {
        float4* dst = (float4*)(out + (size_t)b * 289 * CDIM);
        dst[t] = src[t];
    } else {
        int n = s_ - 1;
        int pos = keeppos[b * NIMG + n];
        if (pos < 0) return;
        const float4* av = (const float4*)(avg + (size_t)b * CDIM);
        float4 v = src[t], a = av[t];
        v.x += a.x; v.y += a.y; v.z += a.z; v.w += a.w;
        float4* dst = (float4*)(out + ((size_t)b * 289 + 1 + pos) * CDIM);
        dst[t] = v;
    }
}

extern "C" void kernel_launch(void* const* d_in, const int* in_sizes, int n_in,
                              void* d_out, int out_size, void* d_ws, size_t ws_size,
                              hipStream_t stream) {
    const float* x      = (const float*)d_in[0];
    const float* qkv_w  = (const float*)d_in[1];
    const float* qkv_b  = (const float*)d_in[2];
    const float* proj_w = (const float*)d_in[3];
    const float* proj_b = (const float*)d_in[4];
    const float* ln1_g  = (const float*)d_in[5];
    const float* ln1_b  = (const float*)d_in[6];
    const float* ln2_g  = (const float*)d_in[7];
    const float* ln2_b  = (const float*)d_in[8];
    const float* fc1_w  = (const float*)d_in[9];
    const float* fc1_b  = (const float*)d_in[10];
    const float* fc2_w  = (const float*)d_in[11];
    const float* fc2_b  = (const float*)d_in[12];

    if (ws_size < NEED_BYTES) return;

    float* ws   = (float*)d_ws;
    float* bh   = ws + O_BH;
    float* ba   = ws + O_BA;
    float* bq   = ws + O_BQ;
    float* qbuf = ws + O_BQ;                       // group Q rows
    unsigned short* kimg = (unsigned short*)(ws + O_KIMG);
    unsigned short* vimg = (unsigned short*)(ws + O_VIMG);
    float* ms   = ws + O_MS;
    int*   mask = (int*)(ws + O_MASK);
    int*   pos  = (int*)(ws + O_POS);
    float* avg  = ws + O_AVG;
    float* outp = (float*)d_out;

    unsigned short* qkvp  = (unsigned short*)(outp + OW_QKV);
    unsigned short* fc1p  = (unsigned short*)(outp + OW_FC1);
    unsigned short* fc2p  = (unsigned short*)(outp + OW_FC2);
    unsigned short* projp = (unsigned short*)(outp + OW_PROJ);

    // 0. split weights; zero V-image scratch (tail rows must be 0, not stale)
    wsplit_kernel<<<18 * 24, 256, 0, stream>>>(qkv_w, qkvp, 24, CDIM);
    wsplit_kernel<<<24 * 24, 256, 0, stream>>>(fc1_w, fc1p, 24, CDIM);
    wsplit_kernel<<<6 * 96, 256, 0, stream>>>(fc2_w, fc2p, 96, 3072);
    wsplit_kernel<<<6 * 24, 256, 0, stream>>>(proj_w, projp, 24, CDIM);
    hipMemsetAsync(vimg, 0, SZ_IMG * 4, stream);

    // 1. h = LN1(x)
    ln_kernel<<<MTOK, 256, 0, stream>>>(x, ln1_g, ln1_b, bh);

    // 2. per-group qkv GEMM (scatter epilogue: Q rows + K/Vt images) + attention
    for (int g = 0; g < NGROUP; g++) {
        const float* hg = bh + (size_t)g * MGRP * CDIM;
        float* attg = ba + (size_t)g * MGRP * CDIM;
        gemm_wp<6><<<dim3((MGRP + 127) / 128, 18), 256, 0, stream>>>(
            hg, CDIM, qkvp, 24, (void*)qbuf, 3 * CDIM, qkv_b, nullptr,
            MGRP, 3 * CDIM, CDIM, kimg, vimg);
        attn_glds<<<dim3(NKT, NHEADS, GB), 256, 0, stream>>>(
            qbuf, kimg, vimg, attg);
    }

    // 3. x1 = x + att @ proj_w^T + proj_b
    gemm_wp<1><<<dim3((MTOK + 127) / 128, 6), 256, 0, stream>>>(
        ba, CDIM, projp, 24, (void*)bh, CDIM, proj_b, x, MTOK, CDIM, CDIM,
        nullptr, nullptr);

    // 4. h2 = LN2(x1)
    ln_kernel<<<MTOK, 256, 0, stream>>>(bh, ln2_g, ln2_b, ba);

    // 5. MLP chunks: fc1 (gelu -> plane images in BQ), fc2 (dual-glds)
    for (int c0 = 0; c0 < MTOK; c0 += MLPCH) {
        int mc = (MTOK - c0 < MLPCH) ? (MTOK - c0) : MLPCH;
        const float* h2c = ba + (size_t)c0 * CDIM;
        float* x1c = bh + (size_t)c0 * CDIM;
        gemm_wp<5><<<dim3((mc + 127) / 128, 24), 256, 0, stream>>>(
            h2c, CDIM, fc1p, 24, (void*)bq, 3072, fc1_b, nullptr, mc, 3072, CDIM,
            nullptr, nullptr);
        gemm_pp<1><<<dim3((mc + 127) / 128, 6), 256, 0, stream>>>(
            (const unsigned short*)bq, fc2p, x1c, CDIM, fc2_b, x1c,
            mc, CDIM, 3072);
    }

    // 6. normalize img tokens
    xn_kernel<<<NBATCH * NIMG, 256, 0, stream>>>(bh, ba);

    // 7. sim = xn @ xn^T per batch
    gemm_mfma<3><<<dim3(5, 5, NBATCH), 256, 0, stream>>>(
        ba, (long long)NIMG * CDIM, CDIM, ba, (long long)NIMG * CDIM, CDIM,
        bq, (long long)NIMG * NIMG, NIMG, nullptr, nullptr, NIMG, NIMG, CDIM);

    // 8. row max of symmetrized sim
    rowmax_kernel<<<NBATCH * NIMG, 64, 0, stream>>>(bq, ms);
    // 9. top-k selection
    select_kernel<<<NBATCH, NIMG, 0, stream>>>(ms, mask, pos);
    // 10. merged-token average (parallel)
    avg_kernel<<<dim3(NBATCH, 6), 256, 0, stream>>>(bh, mask, avg);
    // 11. assemble output (overwrites weight-plane scratch in d_out)
    assemble_kernel<<<MTOK, 192, 0, stream>>>(bh, pos, avg, outp);
}

// Round 14
// 1958.825 us; speedup vs baseline: 3.4154x; 1.1309x over previous
//
#include <hip/hip_runtime.h>
#include <math.h>

#define CDIM 768
#define NHEADS 12
#define DHEAD 64
#define SEQ 577
#define NBATCH 32
#define MTOK (NBATCH*SEQ)      // 18464
#define NIMG 576
#define NMERGE 288
#define GB 8                   // batches per qkv group
#define NGROUP (NBATCH/GB)     // 4
#define MGRP (GB*SEQ)          // 4616 rows per group
#define MLPCH 3456             // MLP chunk rows (27 tiles)
#define NKT 10                 // k-tiles per (b,h) in attention

// ---- workspace layout (float offsets), peak ~159.4 MB ----
#define SZ_MC   ((size_t)MTOK*CDIM)              // 14,180,352
#define O_BH    ((size_t)0)                      // h -> x1/x2 (in-place)
#define O_BA    (SZ_MC)                          // att -> h2 -> xn
#define O_BQ    (2*SZ_MC)                        // Q+KV images / fc1o planes / sim
#define SZ_Q    ((size_t)MGRP*CDIM)              // 3,545,088
#define SZ_IMG  ((size_t)GB*NHEADS*NKT*4096)     // 3,932,160 floats (960 x 16KB)
#define O_KIMG  (O_BQ + SZ_Q)
#define O_VIMG  (O_KIMG + SZ_IMG)
#define O_SM    (O_VIMG + SZ_IMG)
#define O_MS    (O_SM)
#define O_MASK  (O_SM + (size_t)NBATCH*NIMG)
#define O_POS   (O_MASK + (size_t)NBATCH*NIMG)
#define O_AVG   (O_POS + (size_t)NBATCH*NIMG)
#define O_END   (O_AVG + (size_t)NBATCH*CDIM)
#define NEED_BYTES (O_END * 4)

// ---- weight-plane scratch inside d_out ----
#define OW_QKV  ((size_t)0)           // 18nt*24ks = 1,769,472 floats
#define OW_FC1  ((size_t)1769472)     // 24nt*24ks = 2,359,296 floats
#define OW_FC2  ((size_t)4128768)     // 6nt*96ks  = 2,359,296 floats
#define OW_PROJ ((size_t)6488064)     // 6nt*24ks  =   589,824 floats

typedef __attribute__((ext_vector_type(8))) short bf16x8;
typedef __attribute__((ext_vector_type(4))) float f32x4;
typedef __attribute__((address_space(1))) const void GAS_cv;
typedef __attribute__((address_space(3))) void LAS_v;

__device__ __forceinline__ unsigned short f2bf(float f) {
    unsigned int u = __float_as_uint(f);
    u += 0x7fff + ((u >> 16) & 1);           // RNE
    return (unsigned short)(u >> 16);
}
__device__ __forceinline__ float bf2f(unsigned short h) {
    return __uint_as_float(((unsigned int)h) << 16);
}

// ---- bijective XCD chunk remaps (m204) ----
__device__ __forceinline__ void xcd_map(int& bx, int& by, int& bz) {
    int gx = gridDim.x, gy = gridDim.y;
    int nwg = gx * gy * gridDim.z;
    int orig = blockIdx.x + gx * (blockIdx.y + gy * blockIdx.z);
    int q = nwg >> 3, r = nwg & 7;
    int xcd = orig & 7, pos = orig >> 3;
    int wg = (xcd < r ? xcd * (q + 1) : r * (q + 1) + (xcd - r) * q) + pos;
    bx = wg % gx;
    int t2 = wg / gx;
    by = t2 % gy;
    bz = t2 / gy;
}
__device__ __forceinline__ void xcd_map_nf(int& bx, int& by, int& bz) {
    int gx = gridDim.x, gy = gridDim.y;
    int nwg = gx * gy * gridDim.z;
    int orig = blockIdx.x + gx * (blockIdx.y + gy * blockIdx.z);
    int q = nwg >> 3, r = nwg & 7;
    int xcd = orig & 7, pos = orig >> 3;
    int wg = (xcd < r ? xcd * (q + 1) : r * (q + 1) + (xcd - r) * q) + pos;
    by = wg % gy;
    int t2 = wg / gy;
    bx = t2 % gx;
    bz = t2 / gx;
}

// ---------------- block reduce (256 threads) ----------------
__device__ __forceinline__ float blk_sum256(float v, float* red) {
    #pragma unroll
    for (int o = 32; o; o >>= 1) v += __shfl_down(v, o);
    if ((threadIdx.x & 63) == 0) red[threadIdx.x >> 6] = v;
    __syncthreads();
    float tot = red[0] + red[1] + red[2] + red[3];
    __syncthreads();
    return tot;
}

// ---------------- LayerNorm ----------------
__global__ __launch_bounds__(256) void ln_kernel(const float* __restrict__ x,
        const float* __restrict__ g, const float* __restrict__ b,
        float* __restrict__ out) {
    __shared__ float red[4];
    size_t row = blockIdx.x;
    const float* xr = x + row * CDIM;
    float* orow = out + row * CDIM;
    int t = threadIdx.x;
    float v0 = xr[t], v1 = xr[t + 256], v2 = xr[t + 512];
    float mu = blk_sum256(v0 + v1 + v2, red) * (1.f / CDIM);
    float d0 = v0 - mu, d1 = v1 - mu, d2 = v2 - mu;
    float var = blk_sum256(d0 * d0 + d1 * d1 + d2 * d2, red) * (1.f / CDIM);
    float e = var + 1e-5f;
    float rs = rsqrtf(e);
    rs = rs * (1.5f - 0.5f * e * rs * rs);
    orow[t]       = d0 * rs * g[t]       + b[t];
    orow[t + 256] = d1 * rs * g[t + 256] + b[t + 256];
    orow[t + 512] = d2 * rs * g[t + 512] + b[t + 512];
}

// ---------------- weight split: fp32 -> bf16 hi/lo LDS-image planes ----------------
__global__ __launch_bounds__(256) void wsplit_kernel(const float* __restrict__ w,
        unsigned short* __restrict__ wp, int nksteps, int ldw) {
    int bid = blockIdx.x;
    int nt = bid / nksteps, ks = bid % nksteps;
    int t = threadIdx.x;
    int srow = t >> 3, sj = t & 7;
    unsigned short* img = wp + ((size_t)bid << 13);
    #pragma unroll
    for (int i = 0; i < 4; i++) {
        int r = srow + i * 32;
        float4 v = *(const float4*)(w + (size_t)(nt * 128 + r) * ldw + ks * 32 + sj * 4);
        unsigned short h0 = f2bf(v.x), h1 = f2bf(v.y), h2 = f2bf(v.z), h3 = f2bf(v.w);
        ushort4 hv = make_ushort4(h0, h1, h2, h3);
        ushort4 lv = make_ushort4(f2bf(v.x - bf2f(h0)), f2bf(v.y - bf2f(h1)),
                                  f2bf(v.z - bf2f(h2)), f2bf(v.w - bf2f(h3)));
        int swz = (r & 7) << 4;
        int ohi = ((8 * sj) ^ swz) >> 1;
        int olo = ((64 + 8 * sj) ^ swz) >> 1;
        *(ushort4*)&img[r * 64 + ohi] = hv;
        *(ushort4*)&img[r * 64 + olo] = lv;
    }
}

// ---------------- GEMM, A fp32 fused-convert + B pre-split planes via glds ----------
// EPI: 0 = +bias (fp32 C), 1 = +bias+res (fp32 C, res may alias C),
//      5 = gelu(+bias) -> bf16 hi/lo plane IMAGES (Cv = image base, ldc = N)
//      6 = qkv scatter: Q -> fp32 rows (Cv), K -> Kimg images, V -> TRANSPOSED
//          Vimg images; layouts byte-identical to attn's verified LDS staging.
template<int EPI>
__global__ __launch_bounds__(256)
void gemm_wp(const float* __restrict__ A, int lda,
             const unsigned short* __restrict__ Bp, int nksteps,
             void* __restrict__ Cv, int ldc,
             const float* __restrict__ bias,
             const float* __restrict__ res,
             int M, int N, int K,
             unsigned short* __restrict__ Kimg,
             unsigned short* __restrict__ Vimg) {
    __shared__ unsigned short Asl[128 * 64];
    __shared__ unsigned short Bsl[128 * 64];
    int bx, by, bz;
    xcd_map_nf(bx, by, bz);
    const int m0 = bx * 128;
    const int t = threadIdx.x;
    const int lane = t & 63, wid = t >> 6;
    const int wr = wid >> 1, wc = wid & 1;
    const int srow = t >> 3;
    const int sj   = t & 7;
    const unsigned char* BpB = (const unsigned char*)Bp;

    const float* pa[4];
    #pragma unroll
    for (int i = 0; i < 4; i++) {
        int r = srow + i * 32;
        int ra = m0 + r; ra = ra < M ? ra : M - 1;
        pa[i] = A + (size_t)ra * lda + sj * 4;
    }

    f32x4 acc[4][4];
    #pragma unroll
    for (int i = 0; i < 4; i++)
        #pragma unroll
        for (int j = 0; j < 4; j++) {
            f32x4 z = {0.f, 0.f, 0.f, 0.f};
            acc[i][j] = z;
        }

    const int nsteps = K >> 5;
    float4 va[4];
    #pragma unroll
    for (int i = 0; i < 4; i++) va[i] = *(const float4*)(pa[i]);

    for (int ks = 0; ks < nsteps; ks++) {
        ushort4 cah[4], cal[4];
        #pragma unroll
        for (int i = 0; i < 4; i++) {
            float aa[4] = {va[i].x, va[i].y, va[i].z, va[i].w};
            unsigned short h0 = f2bf(aa[0]), h1 = f2bf(aa[1]), h2 = f2bf(aa[2]), h3 = f2bf(aa[3]);
            cah[i] = make_ushort4(h0, h1, h2, h3);
            cal[i] = make_ushort4(f2bf(aa[0] - bf2f(h0)), f2bf(aa[1] - bf2f(h1)),
                                  f2bf(aa[2] - bf2f(h2)), f2bf(aa[3] - bf2f(h3)));
        }
        __syncthreads();
        {
            const unsigned char* img = BpB + (((size_t)by * nksteps + ks) << 14);
            #pragma unroll
            for (int i = 0; i < 4; i++) {
                int chunk = (i << 2) | wid;
                __builtin_amdgcn_global_load_lds((GAS_cv*)(img + chunk * 1024 + lane * 16),
                    (LAS_v*)((unsigned char*)Bsl + chunk * 1024), 16, 0, 0);
            }
        }
        #pragma unroll
        for (int i = 0; i < 4; i++) {
            int r = srow + i * 32;
            int swz = (r & 7) << 4;
            int ohi = ((8 * sj) ^ swz) >> 1;
            int olo = ((64 + 8 * sj) ^ swz) >> 1;
            *(ushort4*)&Asl[r * 64 + ohi] = cah[i];
            *(ushort4*)&Asl[r * 64 + olo] = cal[i];
        }
        __syncthreads();
        const int fr = lane & 15, kg = lane >> 4;
        bf16x8 ah[4], al[4], bh[4], bl[4];
        #pragma unroll
        for (int m = 0; m < 4; m++) {
            int r = wr * 64 + m * 16 + fr;
            int swz = (r & 7) << 4;
            const unsigned char* base = (const unsigned char*)&Asl[r * 64];
            ah[m] = *(const bf16x8*)(base + ((16 * kg) ^ swz));
            al[m] = *(const bf16x8*)(base + ((64 + 16 * kg) ^ swz));
        }
        #pragma unroll
        for (int n = 0; n < 4; n++) {
            int r = wc * 64 + n * 16 + fr;
            int swz = (r & 7) << 4;
            const unsigned char* base = (const unsigned char*)&Bsl[r * 64];
            bh[n] = *(const bf16x8*)(base + ((16 * kg) ^ swz));
            bl[n] = *(const bf16x8*)(base + ((64 + 16 * kg) ^ swz));
        }
        if (ks + 1 < nsteps) {
            const int k0n = (ks + 1) << 5;
            #pragma unroll
            for (int i = 0; i < 4; i++) va[i] = *(const float4*)(pa[i] + k0n);
        }
        #pragma unroll
        for (int m = 0; m < 4; m++)
            #pragma unroll
            for (int n = 0; n < 4; n++) {
                acc[m][n] = __builtin_amdgcn_mfma_f32_16x16x32_bf16(ah[m], bh[n], acc[m][n], 0, 0, 0);
                acc[m][n] = __builtin_amdgcn_mfma_f32_16x16x32_bf16(ah[m], bl[n], acc[m][n], 0, 0, 0);
                acc[m][n] = __builtin_amdgcn_mfma_f32_16x16x32_bf16(al[m], bh[n], acc[m][n], 0, 0, 0);
            }
    }

    const int fr = lane & 15, fq = lane >> 4;
    const int n0 = by * 128;
    #pragma unroll
    for (int m = 0; m < 4; m++) {
        #pragma unroll
        for (int rr = 0; rr < 4; rr++) {
            int row = m0 + wr * 64 + m * 16 + fq * 4 + rr;
            if (row >= M) continue;
            #pragma unroll
            for (int n = 0; n < 4; n++) {
                int col = n0 + wc * 64 + n * 16 + fr;
                float v = acc[m][n][rr];
                size_t ci = (size_t)row * ldc + col;
                if (EPI == 0) {
                    ((float*)Cv)[ci] = v + bias[col];
                } else if (EPI == 1) {
                    ((float*)Cv)[ci] = v + bias[col] + res[ci];
                } else if (EPI == 5) {
                    v += bias[col];
                    v = 0.5f * v * (1.0f + erff(v * 0.70710678118654752f));
                    unsigned short hh = f2bf(v);
                    unsigned short ll = f2bf(v - bf2f(hh));
                    unsigned char* img = (unsigned char*)Cv +
                        (((size_t)(row >> 7) * (ldc >> 5) + (col >> 5)) << 14);
                    int r2 = row & 127, swz2 = (r2 & 7) << 4, kc = col & 31;
                    *(unsigned short*)(img + r2 * 128 + ((2 * kc) ^ swz2)) = hh;
                    *(unsigned short*)(img + r2 * 128 + ((64 + 2 * kc) ^ swz2)) = ll;
                } else { // 6: qkv scatter (head = (col>>6)-12 for K, -24 for V)
                    float v2 = v + bias[col];
                    if (col < 768) {
                        ((float*)Cv)[(size_t)row * 768 + col] = v2;
                    } else {
                        int b_local = row / SEQ;
                        int s = row - b_local * SEQ;
                        int dloc = col & 63;
                        int kt = s >> 6, r2 = s & 63;
                        unsigned short hh = f2bf(v2);
                        unsigned short ll = f2bf(v2 - bf2f(hh));
                        if (col < 1536) {   // K: head = (col>>6)-12
                            int hh_i = (col >> 6) - 12;
                            size_t imgi = (((size_t)b_local * NHEADS + hh_i) * NKT + kt) << 14;
                            unsigned char* img = (unsigned char*)Kimg + imgi;
                            int off = (2 * dloc) ^ ((r2 & 7) << 4);
                            *(unsigned short*)(img + r2 * 256 + off) = hh;
                            *(unsigned short*)(img + r2 * 256 + 128 + off) = ll;
                        } else {            // V transposed: head = (col>>6)-24
                            int hh_i = (col >> 6) - 24;
                            size_t imgi = (((size_t)b_local * NHEADS + hh_i) * NKT + kt) << 14;
                            unsigned char* img = (unsigned char*)Vimg + imgi;
                            int off = (2 * r2) ^ ((dloc & 7) << 4);
                            *(unsigned short*)(img + dloc * 256 + off) = hh;
                            *(unsigned short*)(img + dloc * 256 + 128 + off) = ll;
                        }
                    }
                }
            }
        }
    }
}

// ---------------- GEMM, BOTH operands pre-split images, 64x64 tiles ----------
// 4x the blocks of the 128x128 variant (fixes fc2's 0.63 blocks/CU).
// 64-row/col sub-tile of a [128][128B] image = contiguous 8KB half-image;
// swizzle (r&7)<<4 invariant under 64-aligned slicing => bytes identical.
// Per-element K-walk unchanged => bit-identical results.
// EPI: 1 = +bias+res (res may alias C)
template<int EPI>
__global__ __launch_bounds__(256)
void gemm_pp(const unsigned short* __restrict__ Ap,
             const unsigned short* __restrict__ Bp,
             float* __restrict__ C, int ldc,
             const float* __restrict__ bias,
             const float* __restrict__ res,
             int M, int N, int K) {
    __shared__ unsigned short Asl[64 * 64];   // 8 KB
    __shared__ unsigned short Bsl[64 * 64];   // 8 KB
    int bx, by, bz;
    xcd_map_nf(bx, by, bz);
    const int t = threadIdx.x;
    const int lane = t & 63, wid = t >> 6;
    const int wr = wid >> 1, wc = wid & 1;    // wave covers 32x32
    const unsigned char* ApB = (const unsigned char*)Ap;
    const unsigned char* BpB = (const unsigned char*)Bp;

    f32x4 acc[2][2];
    #pragma unroll
    for (int i = 0; i < 2; i++)
        #pragma unroll
        for (int j = 0; j < 2; j++) {
            f32x4 z = {0.f, 0.f, 0.f, 0.f};
            acc[i][j] = z;
        }

    const int nsteps = K >> 5;
    const size_t offA = ((size_t)(bx >> 1) * nsteps << 14) + ((size_t)(bx & 1) << 13);
    const size_t offB = ((size_t)(by >> 1) * nsteps << 14) + ((size_t)(by & 1) << 13);
    for (int ks = 0; ks < nsteps; ks++) {
        __syncthreads();
        const unsigned char* imgA = ApB + offA + ((size_t)ks << 14);
        const unsigned char* imgB = BpB + offB + ((size_t)ks << 14);
        #pragma unroll
        for (int i = 0; i < 2; i++) {
            int chunk = (i << 2) | wid;       // 0..7
            __builtin_amdgcn_global_load_lds((GAS_cv*)(imgA + chunk * 1024 + lane * 16),
                (LAS_v*)((unsigned char*)Asl + chunk * 1024), 16, 0, 0);
            __builtin_amdgcn_global_load_lds((GAS_cv*)(imgB + chunk * 1024 + lane * 16),
                (LAS_v*)((unsigned char*)Bsl + chunk * 1024), 16, 0, 0);
        }
        __syncthreads();
        const int fr = lane & 15, kg = lane >> 4;
        bf16x8 ah[2], al[2], bh[2], bl[2];
        #pragma unroll
        for (int m = 0; m < 2; m++) {
            int r = wr * 32 + m * 16 + fr;
            int swz = (r & 7) << 4;
            const unsigned char* base = (const unsigned char*)&Asl[r * 64];
            ah[m] = *(const bf16x8*)(base + ((16 * kg) ^ swz));
            al[m] = *(const bf16x8*)(base + ((64 + 16 * kg) ^ swz));
        }
        #pragma unroll
        for (int n = 0; n < 2; n++) {
            int r = wc * 32 + n * 16 + fr;
            int swz = (r & 7) << 4;
            const unsigned char* base = (const unsigned char*)&Bsl[r * 64];
            bh[n] = *(const bf16x8*)(base + ((16 * kg) ^ swz));
            bl[n] = *(const bf16x8*)(base + ((64 + 16 * kg) ^ swz));
        }
        #pragma unroll
        for (int m = 0; m < 2; m++)
            #pragma unroll
            for (int n = 0; n < 2; n++) {
                acc[m][n] = __builtin_amdgcn_mfma_f32_16x16x32_bf16(ah[m], bh[n], acc[m][n], 0, 0, 0);
                acc[m][n] = __builtin_amdgcn_mfma_f32_16x16x32_bf16(ah[m], bl[n], acc[m][n], 0, 0, 0);
                acc[m][n] = __builtin_amdgcn_mfma_f32_16x16x32_bf16(al[m], bh[n], acc[m][n], 0, 0, 0);
            }
    }

    const int fr = lane & 15, fq = lane >> 4;
    const int m0 = bx * 64, n0 = by * 64;
    #pragma unroll
    for (int m = 0; m < 2; m++) {
        #pragma unroll
        for (int rr = 0; rr < 4; rr++) {
            int row = m0 + wr * 32 + m * 16 + fq * 4 + rr;
            if (row >= M) continue;
            #pragma unroll
            for (int n = 0; n < 2; n++) {
                int col = n0 + wc * 32 + n * 16 + fr;
                float v = acc[m][n][rr];
                size_t ci = (size_t)row * ldc + col;
                C[ci] = v + bias[col] + res[ci];
            }
        }
    }
}

// ---------------- fused-convert MFMA GEMM (sim) ----------------
template<int EPI>
__global__ __launch_bounds__(256)
void gemm_mfma(const float* __restrict__ A, long long sA, int lda,
               const float* __restrict__ Bm, long long sB, int ldb,
               float* __restrict__ C, long long sC, int ldc,
               const float* __restrict__ bias,
               const float* __restrict__ res,
               int M, int N, int K) {
    __shared__ unsigned short Asl[128 * 64];
    __shared__ unsigned short Bsl[128 * 64];
    int bx, by, bz;
    xcd_map_nf(bx, by, bz);
    A  += (size_t)bz * sA;
    Bm += (size_t)bz * sB;
    C  += (size_t)bz * sC;
    const int m0 = bx * 128, n0 = by * 128;
    const int t = threadIdx.x;
    const int lane = t & 63, wid = t >> 6;
    const int wr = wid >> 1, wc = wid & 1;
    const int srow = t >> 3;
    const int sj   = t & 7;

    const float* pa[4];
    const float* pb[4];
    #pragma unroll
    for (int i = 0; i < 4; i++) {
        int r = srow + i * 32;
        int ra = m0 + r; ra = ra < M ? ra : M - 1;
        int rb = n0 + r; rb = rb < N ? rb : N - 1;
        pa[i] = A  + (size_t)ra * lda + sj * 4;
        pb[i] = Bm + (size_t)rb * ldb + sj * 4;
    }

    f32x4 acc[4][4];
    #pragma unroll
    for (int i = 0; i < 4; i++)
        #pragma unroll
        for (int j = 0; j < 4; j++) {
            f32x4 z = {0.f, 0.f, 0.f, 0.f};
            acc[i][j] = z;
        }

    const int nsteps = K >> 5;
    float4 va[4], vb[4];
    #pragma unroll
    for (int i = 0; i < 4; i++) {
        va[i] = *(const float4*)(pa[i]);
        vb[i] = *(const float4*)(pb[i]);
    }

    for (int ks = 0; ks < nsteps; ks++) {
        ushort4 cah[4], cal[4], cbh[4], cbl[4];
        #pragma unroll
        for (int i = 0; i < 4; i++) {
            float aa[4] = {va[i].x, va[i].y, va[i].z, va[i].w};
            float bb[4] = {vb[i].x, vb[i].y, vb[i].z, vb[i].w};
            unsigned short h0 = f2bf(aa[0]), h1 = f2bf(aa[1]), h2 = f2bf(aa[2]), h3 = f2bf(aa[3]);
            cah[i] = make_ushort4(h0, h1, h2, h3);
            cal[i] = make_ushort4(f2bf(aa[0] - bf2f(h0)), f2bf(aa[1] - bf2f(h1)),
                                  f2bf(aa[2] - bf2f(h2)), f2bf(aa[3] - bf2f(h3)));
            unsigned short g0 = f2bf(bb[0]), g1 = f2bf(bb[1]), g2 = f2bf(bb[2]), g3 = f2bf(bb[3]);
            cbh[i] = make_ushort4(g0, g1, g2, g3);
            cbl[i] = make_ushort4(f2bf(bb[0] - bf2f(g0)), f2bf(bb[1] - bf2f(g1)),
                                  f2bf(bb[2] - bf2f(g2)), f2bf(bb[3] - bf2f(g3)));
        }
        if (ks + 1 < nsteps) {
            const int k0n = (ks + 1) << 5;
            #pragma unroll
            for (int i = 0; i < 4; i++) {
                va[i] = *(const float4*)(pa[i] + k0n);
                vb[i] = *(const float4*)(pb[i] + k0n);
            }
        }
        __syncthreads();
        #pragma unroll
        for (int i = 0; i < 4; i++) {
            int r = srow + i * 32;
            int swz = (r & 7) << 4;
            int ohi = ((8 * sj) ^ swz) >> 1;
            int olo = ((64 + 8 * sj) ^ swz) >> 1;
            *(ushort4*)&Asl[r * 64 + ohi] = cah[i];
            *(ushort4*)&Asl[r * 64 + olo] = cal[i];
            *(ushort4*)&Bsl[r * 64 + ohi] = cbh[i];
            *(ushort4*)&Bsl[r * 64 + olo] = cbl[i];
        }
        __syncthreads();
        const int fr = lane & 15, kg = lane >> 4;
        bf16x8 ah[4], al[4], bh[4], bl[4];
        #pragma unroll
        for (int m = 0; m < 4; m++) {
            int r = wr * 64 + m * 16 + fr;
            int swz = (r & 7) << 4;
            const unsigned char* base = (const unsigned char*)&Asl[r * 64];
            ah[m] = *(const bf16x8*)(base + ((16 * kg) ^ swz));
            al[m] = *(const bf16x8*)(base + ((64 + 16 * kg) ^ swz));
        }
        #pragma unroll
        for (int n = 0; n < 4; n++) {
            int r = wc * 64 + n * 16 + fr;
            int swz = (r & 7) << 4;
            const unsigned char* base = (const unsigned char*)&Bsl[r * 64];
            bh[n] = *(const bf16x8*)(base + ((16 * kg) ^ swz));
            bl[n] = *(const bf16x8*)(base + ((64 + 16 * kg) ^ swz));
        }
        #pragma unroll
        for (int m = 0; m < 4; m++)
            #pragma unroll
            for (int n = 0; n < 4; n++) {
                acc[m][n] = __builtin_amdgcn_mfma_f32_16x16x32_bf16(ah[m], bh[n], acc[m][n], 0, 0, 0);
                acc[m][n] = __builtin_amdgcn_mfma_f32_16x16x32_bf16(ah[m], bl[n], acc[m][n], 0, 0, 0);
                acc[m][n] = __builtin_amdgcn_mfma_f32_16x16x32_bf16(al[m], bh[n], acc[m][n], 0, 0, 0);
            }
    }

    const int fr = lane & 15, fq = lane >> 4;
    #pragma unroll
    for (int m = 0; m < 4; m++) {
        #pragma unroll
        for (int rr = 0; rr < 4; rr++) {
            int row = m0 + wr * 64 + m * 16 + fq * 4 + rr;
            if (row >= M) continue;
            #pragma unroll
            for (int n = 0; n < 4; n++) {
                int col = n0 + wc * 64 + n * 16 + fr;
                if (col >= N) continue;
                C[(size_t)row * ldc + col] = acc[m][n][rr];
            }
        }
    }
}

// ---------------- MFMA flash attention: K/Vt pre-split images via glds ----------------
__global__ __launch_bounds__(256) void attn_glds(const float* __restrict__ Qb,
        const unsigned short* __restrict__ Kimg, const unsigned short* __restrict__ Vimg,
        float* __restrict__ att) {
    int bx, by, bz;
    xcd_map(bx, by, bz);
    const int b = bz, h = by, q0 = bx * 64;
    const int t = threadIdx.x;
    const int lane = t & 63, wid = t >> 6;
    const int fr = lane & 15, kg = lane >> 4;
    __shared__ unsigned short Khl[64 * 128];
    __shared__ unsigned short Vt[64 * 128];
    __shared__ unsigned char Pbuf[16384];
    unsigned char* KhlB = (unsigned char*)Khl;
    unsigned char* VtB = (unsigned char*)Vt;
    unsigned char* PwB = Pbuf + wid * 4096;
    const unsigned char* KiB = (const unsigned char*)Kimg + (((size_t)b * NHEADS + h) * NKT << 14);
    const unsigned char* ViB = (const unsigned char*)Vimg + (((size_t)b * NHEADS + h) * NKT << 14);

    bf16x8 qh[2], qlo[2];
    {
        int qrow = q0 + wid * 16 + fr; qrow = qrow < SEQ ? qrow : SEQ - 1;
        const float* qbase = Qb + ((size_t)b * SEQ + qrow) * CDIM + h * DHEAD;
        #pragma unroll
        for (int ds = 0; ds < 2; ds++) {
            float tmp[8];
            *(float4*)(tmp)     = *(const float4*)(qbase + ds * 32 + kg * 8);
            *(float4*)(tmp + 4) = *(const float4*)(qbase + ds * 32 + kg * 8 + 4);
            #pragma unroll
            for (int j = 0; j < 8; j++) {
                unsigned short hh = f2bf(tmp[j]);
                qh[ds][j]  = (short)hh;
                qlo[ds][j] = (short)f2bf(tmp[j] - bf2f(hh));
            }
        }
    }

    f32x4 acc_o[4];
    #pragma unroll
    for (int i = 0; i < 4; i++) { f32x4 z = {0.f,0.f,0.f,0.f}; acc_o[i] = z; }
    float m_run[4] = {-1e30f, -1e30f, -1e30f, -1e30f};
    float l_run[4] = {0.f, 0.f, 0.f, 0.f};

    for (int kt = 0; kt < NKT; kt++) {
        const int c0 = kt * 64;
        __syncthreads();
        {
            const unsigned char* ki = KiB + ((size_t)kt << 14);
            const unsigned char* vi = ViB + ((size_t)kt << 14);
            #pragma unroll
            for (int i = 0; i < 4; i++) {
                int chunk = (i << 2) | wid;
                __builtin_amdgcn_global_load_lds((GAS_cv*)(ki + chunk * 1024 + lane * 16),
                    (LAS_v*)(KhlB + chunk * 1024), 16, 0, 0);
                __builtin_amdgcn_global_load_lds((GAS_cv*)(vi + chunk * 1024 + lane * 16),
                    (LAS_v*)(VtB + chunk * 1024), 16, 0, 0);
            }
        }
        __syncthreads();
        f32x4 s[4];
        #pragma unroll
        for (int i = 0; i < 4; i++) { f32x4 z = {0.f,0.f,0.f,0.f}; s[i] = z; }
        #pragma unroll
        for (int ds = 0; ds < 2; ds++) {
            #pragma unroll
            for (int n = 0; n < 4; n++) {
                int r = n * 16 + fr;
                int swz = (r & 7) << 4;
                const unsigned char* rb = KhlB + r * 256;
                bf16x8 kh = *(const bf16x8*)(rb + ((ds * 64 + kg * 16) ^ swz));
                bf16x8 kl = *(const bf16x8*)(rb + 128 + ((ds * 64 + kg * 16) ^ swz));
                s[n] = __builtin_amdgcn_mfma_f32_16x16x32_bf16(qh[ds], kh, s[n], 0, 0, 0);
                s[n] = __builtin_amdgcn_mfma_f32_16x16x32_bf16(qh[ds], kl, s[n], 0, 0, 0);
                s[n] = __builtin_amdgcn_mfma_f32_16x16x32_bf16(qlo[ds], kh, s[n], 0, 0, 0);
            }
        }
        float p[4][4];
        #pragma unroll
        for (int n = 0; n < 4; n++) {
            int kcol = c0 + n * 16 + fr;
            #pragma unroll
            for (int r = 0; r < 4; r++) {
                float sv = s[n][r] * 0.125f;
                if (kcol >= SEQ) sv = -1e30f;
                p[n][r] = sv;
            }
        }
        float corr[4];
        #pragma unroll
        for (int r = 0; r < 4; r++) {
            float mx = fmaxf(fmaxf(p[0][r], p[1][r]), fmaxf(p[2][r], p[3][r]));
            mx = fmaxf(mx, __shfl_xor(mx, 1));
            mx = fmaxf(mx, __shfl_xor(mx, 2));
            mx = fmaxf(mx, __shfl_xor(mx, 4));
            mx = fmaxf(mx, __shfl_xor(mx, 8));
            float mnew = fmaxf(m_run[r], mx);
            corr[r] = __expf(m_run[r] - mnew);
            m_run[r] = mnew;
            float ls = 0.f;
            #pragma unroll
            for (int n = 0; n < 4; n++) {
                p[n][r] = __expf(p[n][r] - mnew);
                ls += p[n][r];
            }
            ls += __shfl_xor(ls, 1);
            ls += __shfl_xor(ls, 2);
            ls += __shfl_xor(ls, 4);
            ls += __shfl_xor(ls, 8);
            l_run[r] = l_run[r] * corr[r] + ls;
        }
        #pragma unroll
        for (int nd = 0; nd < 4; nd++)
            #pragma unroll
            for (int r = 0; r < 4; r++)
                acc_o[nd][r] *= corr[r];
        {
            int qb = (lane >> 4) * 4;
            #pragma unroll
            for (int n = 0; n < 4; n++) {
                int kcol = n * 16 + fr;
                #pragma unroll
                for (int r = 0; r < 4; r++) {
                    int qq = qb + r;
                    unsigned short ph = f2bf(p[n][r]);
                    unsigned short pl = f2bf(p[n][r] - bf2f(ph));
                    int off = (kcol * 2) ^ ((qq & 7) << 4);
                    *(unsigned short*)(PwB + qq * 256 + off) = ph;
                    *(unsigned short*)(PwB + qq * 256 + 128 + off) = pl;
                }
            }
        }
        #pragma unroll
        for (int ks = 0; ks < 2; ks++) {
            int swzp = (fr & 7) << 4;
            bf16x8 pah = *(const bf16x8*)(PwB + fr * 256 + ((ks * 64 + kg * 16) ^ swzp));
            bf16x8 pal = *(const bf16x8*)(PwB + fr * 256 + 128 + ((ks * 64 + kg * 16) ^ swzp));
            #pragma unroll
            for (int nd = 0; nd < 4; nd++) {
                int rv = nd * 16 + fr;
                int swzv = (rv & 7) << 4;
                const unsigned char* rb = VtB + rv * 256;
                bf16x8 vh = *(const bf16x8*)(rb + ((ks * 64 + kg * 16) ^ swzv));
                bf16x8 vl = *(const bf16x8*)(rb + 128 + ((ks * 64 + kg * 16) ^ swzv));
                acc_o[nd] = __builtin_amdgcn_mfma_f32_16x16x32_bf16(pah, vh, acc_o[nd], 0, 0, 0);
                acc_o[nd] = __builtin_amdgcn_mfma_f32_16x16x32_bf16(pah, vl, acc_o[nd], 0, 0, 0);
                acc_o[nd] = __builtin_amdgcn_mfma_f32_16x16x32_bf16(pal, vh, acc_o[nd], 0, 0, 0);
            }
        }
    }
    #pragma unroll
    for (int r = 0; r < 4; r++) {
        int q = q0 + wid * 16 + (lane >> 4) * 4 + r;
        if (q >= SEQ) continue;
        float inv = 1.f / l_run[r];
        float* o = att + ((size_t)b * SEQ + q) * CDIM + h * DHEAD;
        #pragma unroll
        for (int nd = 0; nd < 4; nd++)
            o[nd * 16 + fr] = acc_o[nd][r] * inv;
    }
}

// ---------------- normalize img tokens ----------------
__global__ __launch_bounds__(256) void xn_kernel(const float* __restrict__ x2,
                                                 float* __restrict__ xn) {
    __shared__ float red[4];
    int tok = blockIdx.x;
    int b = tok / NIMG, n = tok % NIMG;
    const float* xr = x2 + ((size_t)b * SEQ + 1 + n) * CDIM;
    float* onr = xn + (size_t)tok * CDIM;
    int t = threadIdx.x;
    float v0 = xr[t], v1 = xr[t + 256], v2 = xr[t + 512];
    float ss = blk_sum256(v0 * v0 + v1 * v1 + v2 * v2, red);
    float nrm = fmaxf(sqrtf(ss), 1e-12f);
    float inv = 1.f / nrm;
    onr[t] = v0 * inv; onr[t + 256] = v1 * inv; onr[t + 512] = v2 * inv;
}

// ---------------- row max of symmetrized sim (excluding diagonal) ----------------
__global__ __launch_bounds__(64) void rowmax_kernel(const float* __restrict__ sim,
                                                    float* __restrict__ ms) {
    int row = blockIdx.x;
    int b = row / NIMG, n = row % NIMG;
    const float* sb = sim + (size_t)b * NIMG * NIMG;
    int lane = threadIdx.x;
    float mx = -1e30f;
    #pragma unroll
    for (int i = 0; i < NIMG / 64; i++) {
        int m = lane + i * 64;
        if (m != n) {
            float v = 0.5f * (sb[(size_t)n * NIMG + m] + sb[(size_t)m * NIMG + n]);
            mx = fmaxf(mx, v);
        }
    }
    #pragma unroll
    for (int o = 32; o; o >>= 1) mx = fmaxf(mx, __shfl_down(mx, o));
    if (lane == 0) ms[row] = mx;
}

// ---------------- exact top-k selection with lax.top_k tie semantics ----------------
__global__ __launch_bounds__(576) void select_kernel(const float* __restrict__ ms,
        int* __restrict__ mergemask, int* __restrict__ keeppos) {
    __shared__ float v[NIMG];
    __shared__ int keepf[NIMG];
    int b = blockIdx.x;
    int n = threadIdx.x;
    v[n] = ms[b * NIMG + n];
    __syncthreads();
    float vn = v[n];
    int rank_desc = 0, rank_asc = 0;
    for (int m = 0; m < NIMG; m++) {
        float vm = v[m];
        int tie_lo = (vm == vn && m < n);
        rank_desc += (vm > vn) || tie_lo;
        rank_asc  += (vm < vn) || tie_lo;
    }
    int merge = rank_desc < NMERGE;
    int keep  = rank_asc  < NMERGE;
    mergemask[b * NIMG + n] = merge;
    keepf[n] = keep;
    __syncthreads();
    if (keep) {
        int pos = 0;
        for (int m = 0; m < n; m++) pos += keepf[m];
        keeppos[b * NIMG + n] = pos;
    } else {
        keeppos[b * NIMG + n] = -1;
    }
}

// ---------------- average of merged tokens (parallelized) ----------------
__global__ __launch_bounds__(256) void avg_kernel(const float* __restrict__ x2,
        const int* __restrict__ mask, float* __restrict__ avg) {
    __shared__ float4 red[8][33];
    int b = blockIdx.x, cc = blockIdx.y;
    int t = threadIdx.x;
    int rr = t >> 5, c4 = t & 31;
    int c = cc * 128 + c4 * 4;
    const int* mb = mask + b * NIMG;
    float4 s = make_float4(0.f, 0.f, 0.f, 0.f);
    for (int n = rr; n < NIMG; n += 8) {
        if (mb[n]) {
            float4 v = *(const float4*)(x2 + ((size_t)b * SEQ + 1 + n) * CDIM + c);
            s.x += v.x; s.y += v.y; s.z += v.z; s.w += v.w;
        }
    }
    red[rr][c4] = s;
    __syncthreads();
    if (rr == 0) {
        float4 tot = red[0][c4];
        #pragma unroll
        for (int i = 1; i < 8; i++) {
            float4 v = red[i][c4];
            tot.x += v.x; tot.y += v.y; tot.z += v.z; tot.w += v.w;
        }
        float sc1 = 1.f / (float)NMERGE, sc2 = 1.f / (float)(NIMG - NMERGE);
        tot.x = (tot.x * sc1) * sc2; tot.y = (tot.y * sc1) * sc2;
        tot.z = (tot.z * sc1) * sc2; tot.w = (tot.w * sc1) * sc2;
        *(float4*)(avg + (size_t)b * CDIM + c) = tot;
    }
}

// ---------------- assemble output ----------------
__global__ __launch_bounds__(192) void assemble_kernel(const float* __restrict__ x2,
        const int* __restrict__ keeppos, const float* __restrict__ avg,
        float* __restrict__ out) {
    int g = blockIdx.x;
    int b = g / SEQ, s_ = g % SEQ;
    int t = threadIdx.x;
    const float4* src = (const float4*)(x2 + (size_t)g * CDIM);
    if (s_ == 0) {
        float4* dst = (float4*)(out + (size_t)b * 289 * CDIM);
        dst[t] = src[t];
    } else {
        int n = s_ - 1;
        int pos = keeppos[b * NIMG + n];
        if (pos < 0) return;
        const float4* av = (const float4*)(avg + (size_t)b * CDIM);
        float4 v = src[t], a = av[t];
        v.x += a.x; v.y += a.y; v.z += a.z; v.w += a.w;
        float4* dst = (float4*)(out + ((size_t)b * 289 + 1 + pos) * CDIM);
        dst[t] = v;
    }
}

extern "C" void kernel_launch(void* const* d_in, const int* in_sizes, int n_in,
                              void* d_out, int out_size, void* d_ws, size_t ws_size,
                              hipStream_t stream) {
    const float* x      = (const float*)d_in[0];
    const float* qkv_w  = (const float*)d_in[1];
    const float* qkv_b  = (const float*)d_in[2];
    const float* proj_w = (const float*)d_in[3];
    const float* proj_b = (const float*)d_in[4];
    const float* ln1_g  = (const float*)d_in[5];
    const float* ln1_b  = (const float*)d_in[6];
    const float* ln2_g  = (const float*)d_in[7];
    const float* ln2_b  = (const float*)d_in[8];
    const float* fc1_w  = (const float*)d_in[9];
    const float* fc1_b  = (const float*)d_in[10];
    const float* fc2_w  = (const float*)d_in[11];
    const float* fc2_b  = (const float*)d_in[12];

    if (ws_size < NEED_BYTES) return;

    float* ws   = (float*)d_ws;
    float* bh   = ws + O_BH;
    float* ba   = ws + O_BA;
    float* bq   = ws + O_BQ;
    float* qbuf = ws + O_BQ;                       // group Q rows
    unsigned short* kimg = (unsigned short*)(ws + O_KIMG);
    unsigned short* vimg = (unsigned short*)(ws + O_VIMG);
    float* ms   = ws + O_MS;
    int*   mask = (int*)(ws + O_MASK);
    int*   pos  = (int*)(ws + O_POS);
    float* avg  = ws + O_AVG;
    float* outp = (float*)d_out;

    unsigned short* qkvp  = (unsigned short*)(outp + OW_QKV);
    unsigned short* fc1p  = (unsigned short*)(outp + OW_FC1);
    unsigned short* fc2p  = (unsigned short*)(outp + OW_FC2);
    unsigned short* projp = (unsigned short*)(outp + OW_PROJ);

    // 0. split weights; zero V-image scratch (tail rows must be 0, not stale)
    wsplit_kernel<<<18 * 24, 256, 0, stream>>>(qkv_w, qkvp, 24, CDIM);
    wsplit_kernel<<<24 * 24, 256, 0, stream>>>(fc1_w, fc1p, 24, CDIM);
    wsplit_kernel<<<6 * 96, 256, 0, stream>>>(fc2_w, fc2p, 96, 3072);
    wsplit_kernel<<<6 * 24, 256, 0, stream>>>(proj_w, projp, 24, CDIM);
    hipMemsetAsync(vimg, 0, SZ_IMG * 4, stream);

    // 1. h = LN1(x)
    ln_kernel<<<MTOK, 256, 0, stream>>>(x, ln1_g, ln1_b, bh);

    // 2. per-group qkv GEMM (scatter epilogue: Q rows + K/Vt images) + attention
    for (int g = 0; g < NGROUP; g++) {
        const float* hg = bh + (size_t)g * MGRP * CDIM;
        float* attg = ba + (size_t)g * MGRP * CDIM;
        gemm_wp<6><<<dim3((MGRP + 127) / 128, 18), 256, 0, stream>>>(
            hg, CDIM, qkvp, 24, (void*)qbuf, 3 * CDIM, qkv_b, nullptr,
            MGRP, 3 * CDIM, CDIM, kimg, vimg);
        attn_glds<<<dim3(NKT, NHEADS, GB), 256, 0, stream>>>(
            qbuf, kimg, vimg, attg);
    }

    // 3. x1 = x + att @ proj_w^T + proj_b
    gemm_wp<1><<<dim3((MTOK + 127) / 128, 6), 256, 0, stream>>>(
        ba, CDIM, projp, 24, (void*)bh, CDIM, proj_b, x, MTOK, CDIM, CDIM,
        nullptr, nullptr);

    // 4. h2 = LN2(x1)
    ln_kernel<<<MTOK, 256, 0, stream>>>(bh, ln2_g, ln2_b, ba);

    // 5. MLP chunks: fc1 (gelu -> plane images in BQ), fc2 (dual-glds, 64x64)
    for (int c0 = 0; c0 < MTOK; c0 += MLPCH) {
        int mc = (MTOK - c0 < MLPCH) ? (MTOK - c0) : MLPCH;
        const float* h2c = ba + (size_t)c0 * CDIM;
        float* x1c = bh + (size_t)c0 * CDIM;
        gemm_wp<5><<<dim3((mc + 127) / 128, 24), 256, 0, stream>>>(
            h2c, CDIM, fc1p, 24, (void*)bq, 3072, fc1_b, nullptr, mc, 3072, CDIM,
            nullptr, nullptr);
        gemm_pp<1><<<dim3((mc + 63) / 64, 12), 256, 0, stream>>>(
            (const unsigned short*)bq, fc2p, x1c, CDIM, fc2_b, x1c,
            mc, CDIM, 3072);
    }

    // 6. normalize img tokens
    xn_kernel<<<NBATCH * NIMG, 256, 0, stream>>>(bh, ba);

    // 7. sim = xn @ xn^T per batch
    gemm_mfma<3><<<dim3(5, 5, NBATCH), 256, 0, stream>>>(
        ba, (long long)NIMG * CDIM, CDIM, ba, (long long)NIMG * CDIM, CDIM,
        bq, (long long)NIMG * NIMG, NIMG, nullptr, nullptr, NIMG, NIMG, CDIM);

    // 8. row max of symmetrized sim
    rowmax_kernel<<<NBATCH * NIMG, 64, 0, stream>>>(bq, ms);
    // 9. top-k selection
    select_kernel<<<NBATCH, NIMG, 0, stream>>>(ms, mask, pos);
    // 10. merged-token average (parallel)
    avg_kernel<<<dim3(NBATCH, 6), 256, 0, stream>>>(bh, mask, avg);
    // 11. assemble output (overwrites weight-plane scratch in d_out)
    assemble_kernel<<<MTOK, 192, 0, stream>>>(bh, pos, avg, outp);
}

// Round 15
// 1943.019 us; speedup vs baseline: 3.4432x; 1.0081x over previous
//
#include <hip/hip_runtime.h>
#include <math.h>

#define CDIM 768
#define NHEADS 12
#define DHEAD 64
#define SEQ 577
#define NBATCH 32
#define MTOK (NBATCH*SEQ)      // 18464
#define NIMG 576
#define NMERGE 288
#define GB 8                   // batches per qkv group
#define NGROUP (NBATCH/GB)     // 4
#define MGRP (GB*SEQ)          // 4616 rows per group
#define MLPCH 3456             // MLP chunk rows (27 tiles)
#define NKT 10                 // k-tiles per (b,h) in attention

// ---- workspace layout (float offsets), peak ~159.4 MB ----
#define SZ_MC   ((size_t)MTOK*CDIM)              // 14,180,352
#define O_BH    ((size_t)0)                      // h -> x1/x2 (in-place)
#define O_BA    (SZ_MC)                          // att -> h2 -> xn
#define O_BQ    (2*SZ_MC)                        // Q+KV images / fc1o planes / sim
#define SZ_Q    ((size_t)MGRP*CDIM)              // 3,545,088
#define SZ_IMG  ((size_t)GB*NHEADS*NKT*4096)     // 3,932,160 floats (960 x 16KB)
#define O_KIMG  (O_BQ + SZ_Q)
#define O_VIMG  (O_KIMG + SZ_IMG)
#define O_SM    (O_VIMG + SZ_IMG)
#define O_MS    (O_SM)
#define O_MASK  (O_SM + (size_t)NBATCH*NIMG)
#define O_POS   (O_MASK + (size_t)NBATCH*NIMG)
#define O_AVG   (O_POS + (size_t)NBATCH*NIMG)
#define O_END   (O_AVG + (size_t)NBATCH*CDIM)
#define NEED_BYTES (O_END * 4)

// ---- weight-plane scratch inside d_out ----
#define OW_QKV  ((size_t)0)           // 18nt*24ks = 1,769,472 floats
#define OW_FC1  ((size_t)1769472)     // 24nt*24ks = 2,359,296 floats
#define OW_FC2  ((size_t)4128768)     // 6nt*96ks  = 2,359,296 floats
#define OW_PROJ ((size_t)6488064)     // 6nt*24ks  =   589,824 floats

typedef __attribute__((ext_vector_type(8))) short bf16x8;
typedef __attribute__((ext_vector_type(4))) float f32x4;
typedef __attribute__((address_space(1))) const void GAS_cv;
typedef __attribute__((address_space(3))) void LAS_v;

// raw barrier (no implicit vmcnt(0) drain); asm memory fences stop LDS-op
// reordering at the compiler level without emitting hardware waits.
#define RAW_BAR() do { asm volatile("" ::: "memory"); \
    __builtin_amdgcn_s_barrier(); asm volatile("" ::: "memory"); } while (0)

__device__ __forceinline__ unsigned short f2bf(float f) {
    unsigned int u = __float_as_uint(f);
    u += 0x7fff + ((u >> 16) & 1);           // RNE
    return (unsigned short)(u >> 16);
}
__device__ __forceinline__ float bf2f(unsigned short h) {
    return __uint_as_float(((unsigned int)h) << 16);
}

// ---- bijective XCD chunk remaps (m204) ----
__device__ __forceinline__ void xcd_map(int& bx, int& by, int& bz) {
    int gx = gridDim.x, gy = gridDim.y;
    int nwg = gx * gy * gridDim.z;
    int orig = blockIdx.x + gx * (blockIdx.y + gy * blockIdx.z);
    int q = nwg >> 3, r = nwg & 7;
    int xcd = orig & 7, pos = orig >> 3;
    int wg = (xcd < r ? xcd * (q + 1) : r * (q + 1) + (xcd - r) * q) + pos;
    bx = wg % gx;
    int t2 = wg / gx;
    by = t2 % gy;
    bz = t2 / gy;
}
__device__ __forceinline__ void xcd_map_nf(int& bx, int& by, int& bz) {
    int gx = gridDim.x, gy = gridDim.y;
    int nwg = gx * gy * gridDim.z;
    int orig = blockIdx.x + gx * (blockIdx.y + gy * blockIdx.z);
    int q = nwg >> 3, r = nwg & 7;
    int xcd = orig & 7, pos = orig >> 3;
    int wg = (xcd < r ? xcd * (q + 1) : r * (q + 1) + (xcd - r) * q) + pos;
    by = wg % gy;
    int t2 = wg / gy;
    bx = t2 % gx;
    bz = t2 / gx;
}

// ---------------- block reduce (256 threads) ----------------
__device__ __forceinline__ float blk_sum256(float v, float* red) {
    #pragma unroll
    for (int o = 32; o; o >>= 1) v += __shfl_down(v, o);
    if ((threadIdx.x & 63) == 0) red[threadIdx.x >> 6] = v;
    __syncthreads();
    float tot = red[0] + red[1] + red[2] + red[3];
    __syncthreads();
    return tot;
}

// ---------------- LayerNorm ----------------
__global__ __launch_bounds__(256) void ln_kernel(const float* __restrict__ x,
        const float* __restrict__ g, const float* __restrict__ b,
        float* __restrict__ out) {
    __shared__ float red[4];
    size_t row = blockIdx.x;
    const float* xr = x + row * CDIM;
    float* orow = out + row * CDIM;
    int t = threadIdx.x;
    float v0 = xr[t], v1 = xr[t + 256], v2 = xr[t + 512];
    float mu = blk_sum256(v0 + v1 + v2, red) * (1.f / CDIM);
    float d0 = v0 - mu, d1 = v1 - mu, d2 = v2 - mu;
    float var = blk_sum256(d0 * d0 + d1 * d1 + d2 * d2, red) * (1.f / CDIM);
    float e = var + 1e-5f;
    float rs = rsqrtf(e);
    rs = rs * (1.5f - 0.5f * e * rs * rs);
    orow[t]       = d0 * rs * g[t]       + b[t];
    orow[t + 256] = d1 * rs * g[t + 256] + b[t + 256];
    orow[t + 512] = d2 * rs * g[t + 512] + b[t + 512];
}

// ---------------- weight split: fp32 -> bf16 hi/lo LDS-image planes ----------------
__global__ __launch_bounds__(256) void wsplit_kernel(const float* __restrict__ w,
        unsigned short* __restrict__ wp, int nksteps, int ldw) {
    int bid = blockIdx.x;
    int nt = bid / nksteps, ks = bid % nksteps;
    int t = threadIdx.x;
    int srow = t >> 3, sj = t & 7;
    unsigned short* img = wp + ((size_t)bid << 13);
    #pragma unroll
    for (int i = 0; i < 4; i++) {
        int r = srow + i * 32;
        float4 v = *(const float4*)(w + (size_t)(nt * 128 + r) * ldw + ks * 32 + sj * 4);
        unsigned short h0 = f2bf(v.x), h1 = f2bf(v.y), h2 = f2bf(v.z), h3 = f2bf(v.w);
        ushort4 hv = make_ushort4(h0, h1, h2, h3);
        ushort4 lv = make_ushort4(f2bf(v.x - bf2f(h0)), f2bf(v.y - bf2f(h1)),
                                  f2bf(v.z - bf2f(h2)), f2bf(v.w - bf2f(h3)));
        int swz = (r & 7) << 4;
        int ohi = ((8 * sj) ^ swz) >> 1;
        int olo = ((64 + 8 * sj) ^ swz) >> 1;
        *(ushort4*)&img[r * 64 + ohi] = hv;
        *(ushort4*)&img[r * 64 + olo] = lv;
    }
}

// ---------------- GEMM, A fused-convert + B planes (counted-vmcnt pipeline) ------
// Raw barriers + s_waitcnt vmcnt(8): the 8 loads issued THIS step (4 A-reg +
// 4 B-glds into the other B buffer) stay in flight across the barrier; only
// the PREVIOUS step's loads are waited. MFMA order identical -> bit-identical.
// EPI: 0 = +bias, 1 = +bias+res (res may alias C),
//      5 = gelu(+bias) -> plane images, 6 = qkv scatter (Q rows + K/Vt images)
template<int EPI>
__global__ __launch_bounds__(256)
void gemm_wp(const float* __restrict__ A, int lda,
             const unsigned short* __restrict__ Bp, int nksteps,
             void* __restrict__ Cv, int ldc,
             const float* __restrict__ bias,
             const float* __restrict__ res,
             int M, int N, int K,
             unsigned short* __restrict__ Kimg,
             unsigned short* __restrict__ Vimg) {
    __shared__ unsigned short Asl[128 * 64];        // 16 KB
    __shared__ unsigned short Bsl[2][128 * 64];     // 32 KB (double buffer)
    int bx, by, bz;
    xcd_map_nf(bx, by, bz);
    const int m0 = bx * 128;
    const int t = threadIdx.x;
    const int lane = t & 63, wid = t >> 6;
    const int wr = wid >> 1, wc = wid & 1;
    const int srow = t >> 3;
    const int sj   = t & 7;
    const unsigned char* BpB = (const unsigned char*)Bp;

    const float* pa[4];
    #pragma unroll
    for (int i = 0; i < 4; i++) {
        int r = srow + i * 32;
        int ra = m0 + r; ra = ra < M ? ra : M - 1;
        pa[i] = A + (size_t)ra * lda + sj * 4;
    }

    f32x4 acc[4][4];
    #pragma unroll
    for (int i = 0; i < 4; i++)
        #pragma unroll
        for (int j = 0; j < 4; j++) {
            f32x4 z = {0.f, 0.f, 0.f, 0.f};
            acc[i][j] = z;
        }

    const int nsteps = K >> 5;
    // prologue: A(0) reg loads + B(0) glds -> Bsl[0]
    float4 va[4];
    #pragma unroll
    for (int i = 0; i < 4; i++) va[i] = *(const float4*)(pa[i]);
    {
        const unsigned char* img = BpB + (((size_t)by * nksteps) << 14);
        #pragma unroll
        for (int i = 0; i < 4; i++) {
            int chunk = (i << 2) | wid;
            __builtin_amdgcn_global_load_lds((GAS_cv*)(img + chunk * 1024 + lane * 16),
                (LAS_v*)((unsigned char*)Bsl[0] + chunk * 1024), 16, 0, 0);
        }
    }

    for (int ks = 0; ks < nsteps; ks++) {
        // convert A(ks) (compiler waits the va loads, leaving B glds in flight)
        ushort4 cah[4], cal[4];
        #pragma unroll
        for (int i = 0; i < 4; i++) {
            float aa[4] = {va[i].x, va[i].y, va[i].z, va[i].w};
            unsigned short h0 = f2bf(aa[0]), h1 = f2bf(aa[1]), h2 = f2bf(aa[2]), h3 = f2bf(aa[3]);
            cah[i] = make_ushort4(h0, h1, h2, h3);
            cal[i] = make_ushort4(f2bf(aa[0] - bf2f(h0)), f2bf(aa[1] - bf2f(h1)),
                                  f2bf(aa[2] - bf2f(h2)), f2bf(aa[3] - bf2f(h3)));
        }
        const int kn = (ks + 1 < nsteps) ? ks + 1 : nsteps - 1;   // clamp: vmcnt const
        // A(kn) reg prefetch (latency hidden until next iter's convert)
        {
            const int k0n = kn << 5;
            #pragma unroll
            for (int i = 0; i < 4; i++) va[i] = *(const float4*)(pa[i] + k0n);
        }
        RAW_BAR();   // bar1: all waves done reading Asl / Bsl[(ks+1)&1] from prior iters
        // B(kn) glds -> other buffer (safe: consumers finished at bar1)
        {
            const unsigned char* img = BpB + (((size_t)by * nksteps + kn) << 14);
            #pragma unroll
            for (int i = 0; i < 4; i++) {
                int chunk = (i << 2) | wid;
                __builtin_amdgcn_global_load_lds((GAS_cv*)(img + chunk * 1024 + lane * 16),
                    (LAS_v*)((unsigned char*)Bsl[(ks + 1) & 1] + chunk * 1024), 16, 0, 0);
            }
        }
        // A(ks) -> Asl (swizzled)
        #pragma unroll
        for (int i = 0; i < 4; i++) {
            int r = srow + i * 32;
            int swz = (r & 7) << 4;
            int ohi = ((8 * sj) ^ swz) >> 1;
            int olo = ((64 + 8 * sj) ^ swz) >> 1;
            *(ushort4*)&Asl[r * 64 + ohi] = cah[i];
            *(ushort4*)&Asl[r * 64 + olo] = cal[i];
        }
        asm volatile("s_waitcnt lgkmcnt(0)" ::: "memory");   // own ds_writes done
        __builtin_amdgcn_sched_barrier(0);
        asm volatile("s_waitcnt vmcnt(8)" ::: "memory");     // B(ks) glds done; 8 newer in flight
        __builtin_amdgcn_sched_barrier(0);
        RAW_BAR();   // bar2: Asl + Bsl[ks&1] fully populated for all waves
        const int fr = lane & 15, kg = lane >> 4;
        bf16x8 ah[4], al[4], bh[4], bl[4];
        #pragma unroll
        for (int m = 0; m < 4; m++) {
            int r = wr * 64 + m * 16 + fr;
            int swz = (r & 7) << 4;
            const unsigned char* base = (const unsigned char*)&Asl[r * 64];
            ah[m] = *(const bf16x8*)(base + ((16 * kg) ^ swz));
            al[m] = *(const bf16x8*)(base + ((64 + 16 * kg) ^ swz));
        }
        #pragma unroll
        for (int n = 0; n < 4; n++) {
            int r = wc * 64 + n * 16 + fr;
            int swz = (r & 7) << 4;
            const unsigned char* base = (const unsigned char*)Bsl[ks & 1] + r * 128;
            bh[n] = *(const bf16x8*)(base + ((16 * kg) ^ swz));
            bl[n] = *(const bf16x8*)(base + ((64 + 16 * kg) ^ swz));
        }
        #pragma unroll
        for (int m = 0; m < 4; m++)
            #pragma unroll
            for (int n = 0; n < 4; n++) {
                acc[m][n] = __builtin_amdgcn_mfma_f32_16x16x32_bf16(ah[m], bh[n], acc[m][n], 0, 0, 0);
                acc[m][n] = __builtin_amdgcn_mfma_f32_16x16x32_bf16(ah[m], bl[n], acc[m][n], 0, 0, 0);
                acc[m][n] = __builtin_amdgcn_mfma_f32_16x16x32_bf16(al[m], bh[n], acc[m][n], 0, 0, 0);
            }
    }

    const int fr = lane & 15, fq = lane >> 4;
    const int n0 = by * 128;
    #pragma unroll
    for (int m = 0; m < 4; m++) {
        #pragma unroll
        for (int rr = 0; rr < 4; rr++) {
            int row = m0 + wr * 64 + m * 16 + fq * 4 + rr;
            if (row >= M) continue;
            #pragma unroll
            for (int n = 0; n < 4; n++) {
                int col = n0 + wc * 64 + n * 16 + fr;
                float v = acc[m][n][rr];
                size_t ci = (size_t)row * ldc + col;
                if (EPI == 0) {
                    ((float*)Cv)[ci] = v + bias[col];
                } else if (EPI == 1) {
                    ((float*)Cv)[ci] = v + bias[col] + res[ci];
                } else if (EPI == 5) {
                    v += bias[col];
                    v = 0.5f * v * (1.0f + erff(v * 0.70710678118654752f));
                    unsigned short hh = f2bf(v);
                    unsigned short ll = f2bf(v - bf2f(hh));
                    unsigned char* img = (unsigned char*)Cv +
                        (((size_t)(row >> 7) * (ldc >> 5) + (col >> 5)) << 14);
                    int r2 = row & 127, swz2 = (r2 & 7) << 4, kc = col & 31;
                    *(unsigned short*)(img + r2 * 128 + ((2 * kc) ^ swz2)) = hh;
                    *(unsigned short*)(img + r2 * 128 + ((64 + 2 * kc) ^ swz2)) = ll;
                } else { // 6: qkv scatter (head = (col>>6)-12 for K, -24 for V)
                    float v2 = v + bias[col];
                    if (col < 768) {
                        ((float*)Cv)[(size_t)row * 768 + col] = v2;
                    } else {
                        int b_local = row / SEQ;
                        int s = row - b_local * SEQ;
                        int dloc = col & 63;
                        int kt = s >> 6, r2 = s & 63;
                        unsigned short hh = f2bf(v2);
                        unsigned short ll = f2bf(v2 - bf2f(hh));
                        if (col < 1536) {
                            int hh_i = (col >> 6) - 12;
                            size_t imgi = (((size_t)b_local * NHEADS + hh_i) * NKT + kt) << 14;
                            unsigned char* img = (unsigned char*)Kimg + imgi;
                            int off = (2 * dloc) ^ ((r2 & 7) << 4);
                            *(unsigned short*)(img + r2 * 256 + off) = hh;
                            *(unsigned short*)(img + r2 * 256 + 128 + off) = ll;
                        } else {
                            int hh_i = (col >> 6) - 24;
                            size_t imgi = (((size_t)b_local * NHEADS + hh_i) * NKT + kt) << 14;
                            unsigned char* img = (unsigned char*)Vimg + imgi;
                            int off = (2 * r2) ^ ((dloc & 7) << 4);
                            *(unsigned short*)(img + dloc * 256 + off) = hh;
                            *(unsigned short*)(img + dloc * 256 + 128 + off) = ll;
                        }
                    }
                }
            }
        }
    }
}

// ---------------- GEMM, BOTH operands images, 64x64, counted-vmcnt pipeline ----
// EPI: 1 = +bias+res (res may alias C)
template<int EPI>
__global__ __launch_bounds__(256)
void gemm_pp(const unsigned short* __restrict__ Ap,
             const unsigned short* __restrict__ Bp,
             float* __restrict__ C, int ldc,
             const float* __restrict__ bias,
             const float* __restrict__ res,
             int M, int N, int K) {
    __shared__ unsigned short Asl[2][64 * 64];   // 16 KB
    __shared__ unsigned short Bsl[2][64 * 64];   // 16 KB
    int bx, by, bz;
    xcd_map_nf(bx, by, bz);
    const int t = threadIdx.x;
    const int lane = t & 63, wid = t >> 6;
    const int wr = wid >> 1, wc = wid & 1;
    const unsigned char* ApB = (const unsigned char*)Ap;
    const unsigned char* BpB = (const unsigned char*)Bp;

    f32x4 acc[2][2];
    #pragma unroll
    for (int i = 0; i < 2; i++)
        #pragma unroll
        for (int j = 0; j < 2; j++) {
            f32x4 z = {0.f, 0.f, 0.f, 0.f};
            acc[i][j] = z;
        }

    const int nsteps = K >> 5;
    const size_t offA = ((size_t)(bx >> 1) * nsteps << 14) + ((size_t)(bx & 1) << 13);
    const size_t offB = ((size_t)(by >> 1) * nsteps << 14) + ((size_t)(by & 1) << 13);
    // prologue: step-0 loads into buffer 0
    {
        #pragma unroll
        for (int i = 0; i < 2; i++) {
            int chunk = (i << 2) | wid;
            __builtin_amdgcn_global_load_lds((GAS_cv*)(ApB + offA + chunk * 1024 + lane * 16),
                (LAS_v*)((unsigned char*)Asl[0] + chunk * 1024), 16, 0, 0);
            __builtin_amdgcn_global_load_lds((GAS_cv*)(BpB + offB + chunk * 1024 + lane * 16),
                (LAS_v*)((unsigned char*)Bsl[0] + chunk * 1024), 16, 0, 0);
        }
    }
    for (int ks = 0; ks < nsteps; ks++) {
        const int kn = (ks + 1 < nsteps) ? ks + 1 : nsteps - 1;   // clamp: vmcnt const
        RAW_BAR();   // all waves done reading buffer (ks+1)&1 from iter ks-1
        {
            const unsigned char* imgA = ApB + offA + ((size_t)kn << 14);
            const unsigned char* imgB = BpB + offB + ((size_t)kn << 14);
            #pragma unroll
            for (int i = 0; i < 2; i++) {
                int chunk = (i << 2) | wid;
                __builtin_amdgcn_global_load_lds((GAS_cv*)(imgA + chunk * 1024 + lane * 16),
                    (LAS_v*)((unsigned char*)Asl[(ks + 1) & 1] + chunk * 1024), 16, 0, 0);
                __builtin_amdgcn_global_load_lds((GAS_cv*)(imgB + chunk * 1024 + lane * 16),
                    (LAS_v*)((unsigned char*)Bsl[(ks + 1) & 1] + chunk * 1024), 16, 0, 0);
            }
        }
        asm volatile("s_waitcnt vmcnt(4)" ::: "memory");   // step-ks loads done; 4 newer in flight
        __builtin_amdgcn_sched_barrier(0);
        RAW_BAR();   // buffers (ks&1) populated for all waves
        const int fr = lane & 15, kg = lane >> 4;
        bf16x8 ah[2], al[2], bh[2], bl[2];
        #pragma unroll
        for (int m = 0; m < 2; m++) {
            int r = wr * 32 + m * 16 + fr;
            int swz = (r & 7) << 4;
            const unsigned char* base = (const unsigned char*)Asl[ks & 1] + r * 128;
            ah[m] = *(const bf16x8*)(base + ((16 * kg) ^ swz));
            al[m] = *(const bf16x8*)(base + ((64 + 16 * kg) ^ swz));
        }
        #pragma unroll
        for (int n = 0; n < 2; n++) {
            int r = wc * 32 + n * 16 + fr;
            int swz = (r & 7) << 4;
            const unsigned char* base = (const unsigned char*)Bsl[ks & 1] + r * 128;
            bh[n] = *(const bf16x8*)(base + ((16 * kg) ^ swz));
            bl[n] = *(const bf16x8*)(base + ((64 + 16 * kg) ^ swz));
        }
        #pragma unroll
        for (int m = 0; m < 2; m++)
            #pragma unroll
            for (int n = 0; n < 2; n++) {
                acc[m][n] = __builtin_amdgcn_mfma_f32_16x16x32_bf16(ah[m], bh[n], acc[m][n], 0, 0, 0);
                acc[m][n] = __builtin_amdgcn_mfma_f32_16x16x32_bf16(ah[m], bl[n], acc[m][n], 0, 0, 0);
                acc[m][n] = __builtin_amdgcn_mfma_f32_16x16x32_bf16(al[m], bh[n], acc[m][n], 0, 0, 0);
            }
    }

    const int fr = lane & 15, fq = lane >> 4;
    const int m0 = bx * 64, n0 = by * 64;
    #pragma unroll
    for (int m = 0; m < 2; m++) {
        #pragma unroll
        for (int rr = 0; rr < 4; rr++) {
            int row = m0 + wr * 32 + m * 16 + fq * 4 + rr;
            if (row >= M) continue;
            #pragma unroll
            for (int n = 0; n < 2; n++) {
                int col = n0 + wc * 32 + n * 16 + fr;
                float v = acc[m][n][rr];
                size_t ci = (size_t)row * ldc + col;
                C[ci] = v + bias[col] + res[ci];
            }
        }
    }
}

// ---------------- fused-convert MFMA GEMM (sim) ----------------
template<int EPI>
__global__ __launch_bounds__(256)
void gemm_mfma(const float* __restrict__ A, long long sA, int lda,
               const float* __restrict__ Bm, long long sB, int ldb,
               float* __restrict__ C, long long sC, int ldc,
               const float* __restrict__ bias,
               const float* __restrict__ res,
               int M, int N, int K) {
    __shared__ unsigned short Asl[128 * 64];
    __shared__ unsigned short Bsl[128 * 64];
    int bx, by, bz;
    xcd_map_nf(bx, by, bz);
    A  += (size_t)bz * sA;
    Bm += (size_t)bz * sB;
    C  += (size_t)bz * sC;
    const int m0 = bx * 128, n0 = by * 128;
    const int t = threadIdx.x;
    const int lane = t & 63, wid = t >> 6;
    const int wr = wid >> 1, wc = wid & 1;
    const int srow = t >> 3;
    const int sj   = t & 7;

    const float* pa[4];
    const float* pb[4];
    #pragma unroll
    for (int i = 0; i < 4; i++) {
        int r = srow + i * 32;
        int ra = m0 + r; ra = ra < M ? ra : M - 1;
        int rb = n0 + r; rb = rb < N ? rb : N - 1;
        pa[i] = A  + (size_t)ra * lda + sj * 4;
        pb[i] = Bm + (size_t)rb * ldb + sj * 4;
    }

    f32x4 acc[4][4];
    #pragma unroll
    for (int i = 0; i < 4; i++)
        #pragma unroll
        for (int j = 0; j < 4; j++) {
            f32x4 z = {0.f, 0.f, 0.f, 0.f};
            acc[i][j] = z;
        }

    const int nsteps = K >> 5;
    float4 va[4], vb[4];
    #pragma unroll
    for (int i = 0; i < 4; i++) {
        va[i] = *(const float4*)(pa[i]);
        vb[i] = *(const float4*)(pb[i]);
    }

    for (int ks = 0; ks < nsteps; ks++) {
        ushort4 cah[4], cal[4], cbh[4], cbl[4];
        #pragma unroll
        for (int i = 0; i < 4; i++) {
            float aa[4] = {va[i].x, va[i].y, va[i].z, va[i].w};
            float bb[4] = {vb[i].x, vb[i].y, vb[i].z, vb[i].w};
            unsigned short h0 = f2bf(aa[0]), h1 = f2bf(aa[1]), h2 = f2bf(aa[2]), h3 = f2bf(aa[3]);
            cah[i] = make_ushort4(h0, h1, h2, h3);
            cal[i] = make_ushort4(f2bf(aa[0] - bf2f(h0)), f2bf(aa[1] - bf2f(h1)),
                                  f2bf(aa[2] - bf2f(h2)), f2bf(aa[3] - bf2f(h3)));
            unsigned short g0 = f2bf(bb[0]), g1 = f2bf(bb[1]), g2 = f2bf(bb[2]), g3 = f2bf(bb[3]);
            cbh[i] = make_ushort4(g0, g1, g2, g3);
            cbl[i] = make_ushort4(f2bf(bb[0] - bf2f(g0)), f2bf(bb[1] - bf2f(g1)),
                                  f2bf(bb[2] - bf2f(g2)), f2bf(bb[3] - bf2f(g3)));
        }
        if (ks + 1 < nsteps) {
            const int k0n = (ks + 1) << 5;
            #pragma unroll
            for (int i = 0; i < 4; i++) {
                va[i] = *(const float4*)(pa[i] + k0n);
                vb[i] = *(const float4*)(pb[i] + k0n);
            }
        }
        __syncthreads();
        #pragma unroll
        for (int i = 0; i < 4; i++) {
            int r = srow + i * 32;
            int swz = (r & 7) << 4;
            int ohi = ((8 * sj) ^ swz) >> 1;
            int olo = ((64 + 8 * sj) ^ swz) >> 1;
            *(ushort4*)&Asl[r * 64 + ohi] = cah[i];
            *(ushort4*)&Asl[r * 64 + olo] = cal[i];
            *(ushort4*)&Bsl[r * 64 + ohi] = cbh[i];
            *(ushort4*)&Bsl[r * 64 + olo] = cbl[i];
        }
        __syncthreads();
        const int fr = lane & 15, kg = lane >> 4;
        bf16x8 ah[4], al[4], bh[4], bl[4];
        #pragma unroll
        for (int m = 0; m < 4; m++) {
            int r = wr * 64 + m * 16 + fr;
            int swz = (r & 7) << 4;
            const unsigned char* base = (const unsigned char*)&Asl[r * 64];
            ah[m] = *(const bf16x8*)(base + ((16 * kg) ^ swz));
            al[m] = *(const bf16x8*)(base + ((64 + 16 * kg) ^ swz));
        }
        #pragma unroll
        for (int n = 0; n < 4; n++) {
            int r = wc * 64 + n * 16 + fr;
            int swz = (r & 7) << 4;
            const unsigned char* base = (const unsigned char*)&Bsl[r * 64];
            bh[n] = *(const bf16x8*)(base + ((16 * kg) ^ swz));
            bl[n] = *(const bf16x8*)(base + ((64 + 16 * kg) ^ swz));
        }
        #pragma unroll
        for (int m = 0; m < 4; m++)
            #pragma unroll
            for (int n = 0; n < 4; n++) {
                acc[m][n] = __builtin_amdgcn_mfma_f32_16x16x32_bf16(ah[m], bh[n], acc[m][n], 0, 0, 0);
                acc[m][n] = __builtin_amdgcn_mfma_f32_16x16x32_bf16(ah[m], bl[n], acc[m][n], 0, 0, 0);
                acc[m][n] = __builtin_amdgcn_mfma_f32_16x16x32_bf16(al[m], bh[n], acc[m][n], 0, 0, 0);
            }
    }

    const int fr = lane & 15, fq = lane >> 4;
    #pragma unroll
    for (int m = 0; m < 4; m++) {
        #pragma unroll
        for (int rr = 0; rr < 4; rr++) {
            int row = m0 + wr * 64 + m * 16 + fq * 4 + rr;
            if (row >= M) continue;
            #pragma unroll
            for (int n = 0; n < 4; n++) {
                int col = n0 + wc * 64 + n * 16 + fr;
                if (col >= N) continue;
                C[(size_t)row * ldc + col] = acc[m][n][rr];
            }
        }
    }
}

// ---------------- MFMA flash attention: K/Vt pre-split images via glds ----------------
__global__ __launch_bounds__(256) void attn_glds(const float* __restrict__ Qb,
        const unsigned short* __restrict__ Kimg, const unsigned short* __restrict__ Vimg,
        float* __restrict__ att) {
    int bx, by, bz;
    xcd_map(bx, by, bz);
    const int b = bz, h = by, q0 = bx * 64;
    const int t = threadIdx.x;
    const int lane = t & 63, wid = t >> 6;
    const int fr = lane & 15, kg = lane >> 4;
    __shared__ unsigned short Khl[64 * 128];
    __shared__ unsigned short Vt[64 * 128];
    __shared__ unsigned char Pbuf[16384];
    unsigned char* KhlB = (unsigned char*)Khl;
    unsigned char* VtB = (unsigned char*)Vt;
    unsigned char* PwB = Pbuf + wid * 4096;
    const unsigned char* KiB = (const unsigned char*)Kimg + (((size_t)b * NHEADS + h) * NKT << 14);
    const unsigned char* ViB = (const unsigned char*)Vimg + (((size_t)b * NHEADS + h) * NKT << 14);

    bf16x8 qh[2], qlo[2];
    {
        int qrow = q0 + wid * 16 + fr; qrow = qrow < SEQ ? qrow : SEQ - 1;
        const float* qbase = Qb + ((size_t)b * SEQ + qrow) * CDIM + h * DHEAD;
        #pragma unroll
        for (int ds = 0; ds < 2; ds++) {
            float tmp[8];
            *(float4*)(tmp)     = *(const float4*)(qbase + ds * 32 + kg * 8);
            *(float4*)(tmp + 4) = *(const float4*)(qbase + ds * 32 + kg * 8 + 4);
            #pragma unroll
            for (int j = 0; j < 8; j++) {
                unsigned short hh = f2bf(tmp[j]);
                qh[ds][j]  = (short)hh;
                qlo[ds][j] = (short)f2bf(tmp[j] - bf2f(hh));
            }
        }
    }

    f32x4 acc_o[4];
    #pragma unroll
    for (int i = 0; i < 4; i++) { f32x4 z = {0.f,0.f,0.f,0.f}; acc_o[i] = z; }
    float m_run[4] = {-1e30f, -1e30f, -1e30f, -1e30f};
    float l_run[4] = {0.f, 0.f, 0.f, 0.f};

    for (int kt = 0; kt < NKT; kt++) {
        const int c0 = kt * 64;
        __syncthreads();
        {
            const unsigned char* ki = KiB + ((size_t)kt << 14);
            const unsigned char* vi = ViB + ((size_t)kt << 14);
            #pragma unroll
            for (int i = 0; i < 4; i++) {
                int chunk = (i << 2) | wid;
                __builtin_amdgcn_global_load_lds((GAS_cv*)(ki + chunk * 1024 + lane * 16),
                    (LAS_v*)(KhlB + chunk * 1024), 16, 0, 0);
                __builtin_amdgcn_global_load_lds((GAS_cv*)(vi + chunk * 1024 + lane * 16),
                    (LAS_v*)(VtB + chunk * 1024), 16, 0, 0);
            }
        }
        __syncthreads();
        f32x4 s[4];
        #pragma unroll
        for (int i = 0; i < 4; i++) { f32x4 z = {0.f,0.f,0.f,0.f}; s[i] = z; }
        #pragma unroll
        for (int ds = 0; ds < 2; ds++) {
            #pragma unroll
            for (int n = 0; n < 4; n++) {
                int r = n * 16 + fr;
                int swz = (r & 7) << 4;
                const unsigned char* rb = KhlB + r * 256;
                bf16x8 kh = *(const bf16x8*)(rb + ((ds * 64 + kg * 16) ^ swz));
                bf16x8 kl = *(const bf16x8*)(rb + 128 + ((ds * 64 + kg * 16) ^ swz));
                s[n] = __builtin_amdgcn_mfma_f32_16x16x32_bf16(qh[ds], kh, s[n], 0, 0, 0);
                s[n] = __builtin_amdgcn_mfma_f32_16x16x32_bf16(qh[ds], kl, s[n], 0, 0, 0);
                s[n] = __builtin_amdgcn_mfma_f32_16x16x32_bf16(qlo[ds], kh, s[n], 0, 0, 0);
            }
        }
        float p[4][4];
        #pragma unroll
        for (int n = 0; n < 4; n++) {
            int kcol = c0 + n * 16 + fr;
            #pragma unroll
            for (int r = 0; r < 4; r++) {
                float sv = s[n][r] * 0.125f;
                if (kcol >= SEQ) sv = -1e30f;
                p[n][r] = sv;
            }
        }
        float corr[4];
        #pragma unroll
        for (int r = 0; r < 4; r++) {
            float mx = fmaxf(fmaxf(p[0][r], p[1][r]), fmaxf(p[2][r], p[3][r]));
            mx = fmaxf(mx, __shfl_xor(mx, 1));
            mx = fmaxf(mx, __shfl_xor(mx, 2));
            mx = fmaxf(mx, __shfl_xor(mx, 4));
            mx = fmaxf(mx, __shfl_xor(mx, 8));
            float mnew = fmaxf(m_run[r], mx);
            corr[r] = __expf(m_run[r] - mnew);
            m_run[r] = mnew;
            float ls = 0.f;
            #pragma unroll
            for (int n = 0; n < 4; n++) {
                p[n][r] = __expf(p[n][r] - mnew);
                ls += p[n][r];
            }
            ls += __shfl_xor(ls, 1);
            ls += __shfl_xor(ls, 2);
            ls += __shfl_xor(ls, 4);
            ls += __shfl_xor(ls, 8);
            l_run[r] = l_run[r] * corr[r] + ls;
        }
        #pragma unroll
        for (int nd = 0; nd < 4; nd++)
            #pragma unroll
            for (int r = 0; r < 4; r++)
                acc_o[nd][r] *= corr[r];
        {
            int qb = (lane >> 4) * 4;
            #pragma unroll
            for (int n = 0; n < 4; n++) {
                int kcol = n * 16 + fr;
                #pragma unroll
                for (int r = 0; r < 4; r++) {
                    int qq = qb + r;
                    unsigned short ph = f2bf(p[n][r]);
                    unsigned short pl = f2bf(p[n][r] - bf2f(ph));
                    int off = (kcol * 2) ^ ((qq & 7) << 4);
                    *(unsigned short*)(PwB + qq * 256 + off) = ph;
                    *(unsigned short*)(PwB + qq * 256 + 128 + off) = pl;
                }
            }
        }
        #pragma unroll
        for (int ks = 0; ks < 2; ks++) {
            int swzp = (fr & 7) << 4;
            bf16x8 pah = *(const bf16x8*)(PwB + fr * 256 + ((ks * 64 + kg * 16) ^ swzp));
            bf16x8 pal = *(const bf16x8*)(PwB + fr * 256 + 128 + ((ks * 64 + kg * 16) ^ swzp));
            #pragma unroll
            for (int nd = 0; nd < 4; nd++) {
                int rv = nd * 16 + fr;
                int swzv = (rv & 7) << 4;
                const unsigned char* rb = VtB + rv * 256;
                bf16x8 vh = *(const bf16x8*)(rb + ((ks * 64 + kg * 16) ^ swzv));
                bf16x8 vl = *(const bf16x8*)(rb + 128 + ((ks * 64 + kg * 16) ^ swzv));
                acc_o[nd] = __builtin_amdgcn_mfma_f32_16x16x32_bf16(pah, vh, acc_o[nd], 0, 0, 0);
                acc_o[nd] = __builtin_amdgcn_mfma_f32_16x16x32_bf16(pah, vl, acc_o[nd], 0, 0, 0);
                acc_o[nd] = __builtin_amdgcn_mfma_f32_16x16x32_bf16(pal, vh, acc_o[nd], 0, 0, 0);
            }
        }
    }
    #pragma unroll
    for (int r = 0; r < 4; r++) {
        int q = q0 + wid * 16 + (lane >> 4) * 4 + r;
        if (q >= SEQ) continue;
        float inv = 1.f / l_run[r];
        float* o = att + ((size_t)b * SEQ + q) * CDIM + h * DHEAD;
        #pragma unroll
        for (int nd = 0; nd < 4; nd++)
            o[nd * 16 + fr] = acc_o[nd][r] * inv;
    }
}

// ---------------- normalize img tokens ----------------
__global__ __launch_bounds__(256) void xn_kernel(const float* __restrict__ x2,
                                                 float* __restrict__ xn) {
    __shared__ float red[4];
    int tok = blockIdx.x;
    int b = tok / NIMG, n = tok % NIMG;
    const float* xr = x2 + ((size_t)b * SEQ + 1 + n) * CDIM;
    float* onr = xn + (size_t)tok * CDIM;
    int t = threadIdx.x;
    float v0 = xr[t], v1 = xr[t + 256], v2 = xr[t + 512];
    float ss = blk_sum256(v0 * v0 + v1 * v1 + v2 * v2, red);
    float nrm = fmaxf(sqrtf(ss), 1e-12f);
    float inv = 1.f / nrm;
    onr[t] = v0 * inv; onr[t + 256] = v1 * inv; onr[t + 512] = v2 * inv;
}

// ---------------- row max of symmetrized sim (excluding diagonal) ----------------
__global__ __launch_bounds__(64) void rowmax_kernel(const float* __restrict__ sim,
                                                    float* __restrict__ ms) {
    int row = blockIdx.x;
    int b = row / NIMG, n = row % NIMG;
    const float* sb = sim + (size_t)b * NIMG * NIMG;
    int lane = threadIdx.x;
    float mx = -1e30f;
    #pragma unroll
    for (int i = 0; i < NIMG / 64; i++) {
        int m = lane + i * 64;
        if (m != n) {
            float v = 0.5f * (sb[(size_t)n * NIMG + m] + sb[(size_t)m * NIMG + n]);
            mx = fmaxf(mx, v);
        }
    }
    #pragma unroll
    for (int o = 32; o; o >>= 1) mx = fmaxf(mx, __shfl_down(mx, o));
    if (lane == 0) ms[row] = mx;
}

// ---------------- exact top-k selection with lax.top_k tie semantics ----------------
__global__ __launch_bounds__(576) void select_kernel(const float* __restrict__ ms,
        int* __restrict__ mergemask, int* __restrict__ keeppos) {
    __shared__ float v[NIMG];
    __shared__ int keepf[NIMG];
    int b = blockIdx.x;
    int n = threadIdx.x;
    v[n] = ms[b * NIMG + n];
    __syncthreads();
    float vn = v[n];
    int rank_desc = 0, rank_asc = 0;
    for (int m = 0; m < NIMG; m++) {
        float vm = v[m];
        int tie_lo = (vm == vn && m < n);
        rank_desc += (vm > vn) || tie_lo;
        rank_asc  += (vm < vn) || tie_lo;
    }
    int merge = rank_desc < NMERGE;
    int keep  = rank_asc  < NMERGE;
    mergemask[b * NIMG + n] = merge;
    keepf[n] = keep;
    __syncthreads();
    if (keep) {
        int pos = 0;
        for (int m = 0; m < n; m++) pos += keepf[m];
        keeppos[b * NIMG + n] = pos;
    } else {
        keeppos[b * NIMG + n] = -1;
    }
}

// ---------------- average of merged tokens (parallelized) ----------------
__global__ __launch_bounds__(256) void avg_kernel(const float* __restrict__ x2,
        const int* __restrict__ mask, float* __restrict__ avg) {
    __shared__ float4 red[8][33];
    int b = blockIdx.x, cc = blockIdx.y;
    int t = threadIdx.x;
    int rr = t >> 5, c4 = t & 31;
    int c = cc * 128 + c4 * 4;
    const int* mb = mask + b * NIMG;
    float4 s = make_float4(0.f, 0.f, 0.f, 0.f);
    for (int n = rr; n < NIMG; n += 8) {
        if (mb[n]) {
            float4 v = *(const float4*)(x2 + ((size_t)b * SEQ + 1 + n) * CDIM + c);
            s.x += v.x; s.y += v.y; s.z += v.z; s.w += v.w;
        }
    }
    red[rr][c4] = s;
    __syncthreads();
    if (rr == 0) {
        float4 tot = red[0][c4];
        #pragma unroll
        for (int i = 1; i < 8; i++) {
            float4 v = red[i][c4];
            tot.x += v.x; tot.y += v.y; tot.z += v.z; tot.w += v.w;
        }
        float sc1 = 1.f / (float)NMERGE, sc2 = 1.f / (float)(NIMG - NMERGE);
        tot.x = (tot.x * sc1) * sc2; tot.y = (tot.y * sc1) * sc2;
        tot.z = (tot.z * sc1) * sc2; tot.w = (tot.w * sc1) * sc2;
        *(float4*)(avg + (size_t)b * CDIM + c) = tot;
    }
}

// ---------------- assemble output ----------------
__global__ __launch_bounds__(192) void assemble_kernel(const float* __restrict__ x2,
        const int* __restrict__ keeppos, const float* __restrict__ avg,
        float* __restrict__ out) {
    int g = blockIdx.x;
    int b = g / SEQ, s_ = g % SEQ;
    int t = threadIdx.x;
    const float4* src = (const float4*)(x2 + (size_t)g * CDIM);
    if (s_ == 0) {
        float4* dst = (float4*)(out + (size_t)b * 289 * CDIM);
        dst[t] = src[t];
    } else {
        int n = s_ - 1;
        int pos = keeppos[b * NIMG + n];
        if (pos < 0) return;
        const float4* av = (const float4*)(avg + (size_t)b * CDIM);
        float4 v = src[t], a = av[t];
        v.x += a.x; v.y += a.y; v.z += a.z; v.w += a.w;
        float4* dst = (float4*)(out + ((size_t)b * 289 + 1 + pos) * CDIM);
        dst[t] = v;
    }
}

extern "C" void kernel_launch(void* const* d_in, const int* in_sizes, int n_in,
                              void* d_out, int out_size, void* d_ws, size_t ws_size,
                              hipStream_t stream) {
    const float* x      = (const float*)d_in[0];
    const float* qkv_w  = (const float*)d_in[1];
    const float* qkv_b  = (const float*)d_in[2];
    const float* proj_w = (const float*)d_in[3];
    const float* proj_b = (const float*)d_in[4];
    const float* ln1_g  = (const float*)d_in[5];
    const float* ln1_b  = (const float*)d_in[6];
    const float* ln2_g  = (const float*)d_in[7];
    const float* ln2_b  = (const float*)d_in[8];
    const float* fc1_w  = (const float*)d_in[9];
    const float* fc1_b  = (const float*)d_in[10];
    const float* fc2_w  = (const float*)d_in[11];
    const float* fc2_b  = (const float*)d_in[12];

    if (ws_size < NEED_BYTES) return;

    float* ws   = (float*)d_ws;
    float* bh   = ws + O_BH;
    float* ba   = ws + O_BA;
    float* bq   = ws + O_BQ;
    float* qbuf = ws + O_BQ;                       // group Q rows
    unsigned short* kimg = (unsigned short*)(ws + O_KIMG);
    unsigned short* vimg = (unsigned short*)(ws + O_VIMG);
    float* ms   = ws + O_MS;
    int*   mask = (int*)(ws + O_MASK);
    int*   pos  = (int*)(ws + O_POS);
    float* avg  = ws + O_AVG;
    float* outp = (float*)d_out;

    unsigned short* qkvp  = (unsigned short*)(outp + OW_QKV);
    unsigned short* fc1p  = (unsigned short*)(outp + OW_FC1);
    unsigned short* fc2p  = (unsigned short*)(outp + OW_FC2);
    unsigned short* projp = (unsigned short*)(outp + OW_PROJ);

    // 0. split weights; zero V-image scratch (tail rows must be 0, not stale)
    wsplit_kernel<<<18 * 24, 256, 0, stream>>>(qkv_w, qkvp, 24, CDIM);
    wsplit_kernel<<<24 * 24, 256, 0, stream>>>(fc1_w, fc1p, 24, CDIM);
    wsplit_kernel<<<6 * 96, 256, 0, stream>>>(fc2_w, fc2p, 96, 3072);
    wsplit_kernel<<<6 * 24, 256, 0, stream>>>(proj_w, projp, 24, CDIM);
    hipMemsetAsync(vimg, 0, SZ_IMG * 4, stream);

    // 1. h = LN1(x)
    ln_kernel<<<MTOK, 256, 0, stream>>>(x, ln1_g, ln1_b, bh);

    // 2. per-group qkv GEMM (scatter epilogue: Q rows + K/Vt images) + attention
    for (int g = 0; g < NGROUP; g++) {
        const float* hg = bh + (size_t)g * MGRP * CDIM;
        float* attg = ba + (size_t)g * MGRP * CDIM;
        gemm_wp<6><<<dim3((MGRP + 127) / 128, 18), 256, 0, stream>>>(
            hg, CDIM, qkvp, 24, (void*)qbuf, 3 * CDIM, qkv_b, nullptr,
            MGRP, 3 * CDIM, CDIM, kimg, vimg);
        attn_glds<<<dim3(NKT, NHEADS, GB), 256, 0, stream>>>(
            qbuf, kimg, vimg, attg);
    }

    // 3. x1 = x + att @ proj_w^T + proj_b
    gemm_wp<1><<<dim3((MTOK + 127) / 128, 6), 256, 0, stream>>>(
        ba, CDIM, projp, 24, (void*)bh, CDIM, proj_b, x, MTOK, CDIM, CDIM,
        nullptr, nullptr);

    // 4. h2 = LN2(x1)
    ln_kernel<<<MTOK, 256, 0, stream>>>(bh, ln2_g, ln2_b, ba);

    // 5. MLP chunks: fc1 (gelu -> plane images in BQ), fc2 (dual-glds, 64x64)
    for (int c0 = 0; c0 < MTOK; c0 += MLPCH) {
        int mc = (MTOK - c0 < MLPCH) ? (MTOK - c0) : MLPCH;
        const float* h2c = ba + (size_t)c0 * CDIM;
        float* x1c = bh + (size_t)c0 * CDIM;
        gemm_wp<5><<<dim3((mc + 127) / 128, 24), 256, 0, stream>>>(
            h2c, CDIM, fc1p, 24, (void*)bq, 3072, fc1_b, nullptr, mc, 3072, CDIM,
            nullptr, nullptr);
        gemm_pp<1><<<dim3((mc + 63) / 64, 12), 256, 0, stream>>>(
            (const unsigned short*)bq, fc2p, x1c, CDIM, fc2_b, x1c,
            mc, CDIM, 3072);
    }

    // 6. normalize img tokens
    xn_kernel<<<NBATCH * NIMG, 256, 0, stream>>>(bh, ba);

    // 7. sim = xn @ xn^T per batch
    gemm_mfma<3><<<dim3(5, 5, NBATCH), 256, 0, stream>>>(
        ba, (long long)NIMG * CDIM, CDIM, ba, (long long)NIMG * CDIM, CDIM,
        bq, (long long)NIMG * NIMG, NIMG, nullptr, nullptr, NIMG, NIMG, CDIM);

    // 8. row max of symmetrized sim
    rowmax_kernel<<<NBATCH * NIMG, 64, 0, stream>>>(bq, ms);
    // 9. top-k selection
    select_kernel<<<NBATCH, NIMG, 0, stream>>>(ms, mask, pos);
    // 10. merged-token average (parallel)
    avg_kernel<<<dim3(NBATCH, 6), 256, 0, stream>>>(bh, mask, avg);
    // 11. assemble output (overwrites weight-plane scratch in d_out)
    assemble_kernel<<<MTOK, 192, 0, stream>>>(bh, pos, avg, outp);
}

// Round 16
// 1851.536 us; speedup vs baseline: 3.6133x; 1.0494x over previous
//
#include <hip/hip_runtime.h>
#include <math.h>

#define CDIM 768
#define NHEADS 12
#define DHEAD 64
#define SEQ 577
#define NBATCH 32
#define MTOK (NBATCH*SEQ)      // 18464
#define NIMG 576
#define NMERGE 288
#define GB 8                   // batches per qkv group
#define NGROUP (NBATCH/GB)     // 4
#define MGRP (GB*SEQ)          // 4616 rows per group
#define MLPCH 3456             // MLP chunk rows
#define NKT 10                 // k-tiles per (b,h) in attention

// ---- workspace layout (float offsets), peak ~159.4 MB ----
#define SZ_MC   ((size_t)MTOK*CDIM)              // 14,180,352
#define O_BH    ((size_t)0)                      // h -> x1/x2 (in-place)
#define O_BA    (SZ_MC)                          // att -> h2 -> xn
#define O_BQ    (2*SZ_MC)                        // Q+KV images / fc1o planes / sim
#define SZ_Q    ((size_t)MGRP*CDIM)              // 3,545,088
#define SZ_IMG  ((size_t)GB*NHEADS*NKT*4096)     // 3,932,160 floats (960 x 16KB)
#define O_KIMG  (O_BQ + SZ_Q)
#define O_VIMG  (O_KIMG + SZ_IMG)
#define O_SM    (O_VIMG + SZ_IMG)
#define O_MS    (O_SM)
#define O_MASK  (O_SM + (size_t)NBATCH*NIMG)
#define O_POS   (O_MASK + (size_t)NBATCH*NIMG)
#define O_AVG   (O_POS + (size_t)NBATCH*NIMG)
#define O_END   (O_AVG + (size_t)NBATCH*CDIM)
#define NEED_BYTES (O_END * 4)

// ---- weight-plane scratch inside d_out ----
#define OW_QKV  ((size_t)0)           // 18nt*24ks = 1,769,472 floats
#define OW_FC1  ((size_t)1769472)     // 24nt*24ks = 2,359,296 floats
#define OW_FC2  ((size_t)4128768)     // 6nt*96ks  = 2,359,296 floats
#define OW_PROJ ((size_t)6488064)     // 6nt*24ks  =   589,824 floats

typedef __attribute__((ext_vector_type(8))) short bf16x8;
typedef __attribute__((ext_vector_type(4))) float f32x4;
typedef __attribute__((address_space(1))) const void GAS_cv;
typedef __attribute__((address_space(3))) void LAS_v;

// raw barrier + compiler fences (used by gemm_pp counted-vmcnt pipeline)
#define RAW_BAR() do { asm volatile("" ::: "memory"); \
    __builtin_amdgcn_s_barrier(); asm volatile("" ::: "memory"); } while (0)

__device__ __forceinline__ unsigned short f2bf(float f) {
    unsigned int u = __float_as_uint(f);
    u += 0x7fff + ((u >> 16) & 1);           // RNE
    return (unsigned short)(u >> 16);
}
__device__ __forceinline__ float bf2f(unsigned short h) {
    return __uint_as_float(((unsigned int)h) << 16);
}

// ---- bijective XCD chunk remaps (m204) ----
__device__ __forceinline__ void xcd_map(int& bx, int& by, int& bz) {
    int gx = gridDim.x, gy = gridDim.y;
    int nwg = gx * gy * gridDim.z;
    int orig = blockIdx.x + gx * (blockIdx.y + gy * blockIdx.z);
    int q = nwg >> 3, r = nwg & 7;
    int xcd = orig & 7, pos = orig >> 3;
    int wg = (xcd < r ? xcd * (q + 1) : r * (q + 1) + (xcd - r) * q) + pos;
    bx = wg % gx;
    int t2 = wg / gx;
    by = t2 % gy;
    bz = t2 / gy;
}
__device__ __forceinline__ void xcd_map_nf(int& bx, int& by, int& bz) {
    int gx = gridDim.x, gy = gridDim.y;
    int nwg = gx * gy * gridDim.z;
    int orig = blockIdx.x + gx * (blockIdx.y + gy * blockIdx.z);
    int q = nwg >> 3, r = nwg & 7;
    int xcd = orig & 7, pos = orig >> 3;
    int wg = (xcd < r ? xcd * (q + 1) : r * (q + 1) + (xcd - r) * q) + pos;
    by = wg % gy;
    int t2 = wg / gy;
    bx = t2 % gx;
    bz = t2 / gx;
}

// ---------------- block reduce (256 threads) ----------------
__device__ __forceinline__ float blk_sum256(float v, float* red) {
    #pragma unroll
    for (int o = 32; o; o >>= 1) v += __shfl_down(v, o);
    if ((threadIdx.x & 63) == 0) red[threadIdx.x >> 6] = v;
    __syncthreads();
    float tot = red[0] + red[1] + red[2] + red[3];
    __syncthreads();
    return tot;
}

// ---------------- LayerNorm ----------------
__global__ __launch_bounds__(256) void ln_kernel(const float* __restrict__ x,
        const float* __restrict__ g, const float* __restrict__ b,
        float* __restrict__ out) {
    __shared__ float red[4];
    size_t row = blockIdx.x;
    const float* xr = x + row * CDIM;
    float* orow = out + row * CDIM;
    int t = threadIdx.x;
    float v0 = xr[t], v1 = xr[t + 256], v2 = xr[t + 512];
    float mu = blk_sum256(v0 + v1 + v2, red) * (1.f / CDIM);
    float d0 = v0 - mu, d1 = v1 - mu, d2 = v2 - mu;
    float var = blk_sum256(d0 * d0 + d1 * d1 + d2 * d2, red) * (1.f / CDIM);
    float e = var + 1e-5f;
    float rs = rsqrtf(e);
    rs = rs * (1.5f - 0.5f * e * rs * rs);
    orow[t]       = d0 * rs * g[t]       + b[t];
    orow[t + 256] = d1 * rs * g[t + 256] + b[t + 256];
    orow[t + 512] = d2 * rs * g[t + 512] + b[t + 512];
}

// ---------------- weight split: fp32 -> bf16 hi/lo LDS-image planes ----------------
__global__ __launch_bounds__(256) void wsplit_kernel(const float* __restrict__ w,
        unsigned short* __restrict__ wp, int nksteps, int ldw) {
    int bid = blockIdx.x;
    int nt = bid / nksteps, ks = bid % nksteps;
    int t = threadIdx.x;
    int srow = t >> 3, sj = t & 7;
    unsigned short* img = wp + ((size_t)bid << 13);
    #pragma unroll
    for (int i = 0; i < 4; i++) {
        int r = srow + i * 32;
        float4 v = *(const float4*)(w + (size_t)(nt * 128 + r) * ldw + ks * 32 + sj * 4);
        unsigned short h0 = f2bf(v.x), h1 = f2bf(v.y), h2 = f2bf(v.z), h3 = f2bf(v.w);
        ushort4 hv = make_ushort4(h0, h1, h2, h3);
        ushort4 lv = make_ushort4(f2bf(v.x - bf2f(h0)), f2bf(v.y - bf2f(h1)),
                                  f2bf(v.z - bf2f(h2)), f2bf(v.w - bf2f(h3)));
        int swz = (r & 7) << 4;
        int ohi = ((8 * sj) ^ swz) >> 1;
        int olo = ((64 + 8 * sj) ^ swz) >> 1;
        *(ushort4*)&img[r * 64 + ohi] = hv;
        *(ushort4*)&img[r * 64 + olo] = lv;
    }
}

// ---------------- GEMM 64x64, A fp32 fused-convert + B half-image glds ----------
// 4x the blocks of the 128x128 variant (occupancy: 2.5 -> ~8 blocks/CU).
// B 64-row sub-tile of a [128][128B] image = contiguous 8KB half-image;
// swizzle (r&7)<<4 invariant under 64-aligned slicing. Per-element K-walk
// and epilogue identical to previous rounds -> bit-identical results.
// EPI: 0 = +bias, 1 = +bias+res (res may alias C),
//      5 = gelu(+bias) -> plane images, 6 = qkv scatter (Q rows + K/Vt images)
template<int EPI>
__global__ __launch_bounds__(256)
void gemm_wp(const float* __restrict__ A, int lda,
             const unsigned short* __restrict__ Bp, int nksteps,
             void* __restrict__ Cv, int ldc,
             const float* __restrict__ bias,
             const float* __restrict__ res,
             int M, int N, int K,
             unsigned short* __restrict__ Kimg,
             unsigned short* __restrict__ Vimg) {
    __shared__ unsigned short Asl[64 * 64];   // 8 KB
    __shared__ unsigned short Bsl[64 * 64];   // 8 KB
    int bx, by, bz;
    xcd_map_nf(bx, by, bz);
    const int m0 = bx * 64;
    const int t = threadIdx.x;
    const int lane = t & 63, wid = t >> 6;
    const int wr = wid >> 1, wc = wid & 1;    // wave covers 32x32
    const int srow = t >> 2;                  // A staging row 0..63
    const int sj2  = (t & 3) * 2;             // first float4 index (0,2,4,6)
    const unsigned char* BpB = (const unsigned char*)Bp;

    const float* pa;
    {
        int ra = m0 + srow; ra = ra < M ? ra : M - 1;
        pa = A + (size_t)ra * lda + sj2 * 4;
    }

    f32x4 acc[2][2];
    #pragma unroll
    for (int i = 0; i < 2; i++)
        #pragma unroll
        for (int j = 0; j < 2; j++) {
            f32x4 z = {0.f, 0.f, 0.f, 0.f};
            acc[i][j] = z;
        }

    const int nsteps = K >> 5;
    const size_t offB = ((size_t)(by >> 1) * nksteps << 14) + ((size_t)(by & 1) << 13);
    float4 va[2];
    va[0] = *(const float4*)(pa);
    va[1] = *(const float4*)(pa + 4);

    for (int ks = 0; ks < nsteps; ks++) {
        // convert A(ks) in registers
        ushort4 cah[2], cal[2];
        #pragma unroll
        for (int i = 0; i < 2; i++) {
            float aa[4] = {va[i].x, va[i].y, va[i].z, va[i].w};
            unsigned short h0 = f2bf(aa[0]), h1 = f2bf(aa[1]), h2 = f2bf(aa[2]), h3 = f2bf(aa[3]);
            cah[i] = make_ushort4(h0, h1, h2, h3);
            cal[i] = make_ushort4(f2bf(aa[0] - bf2f(h0)), f2bf(aa[1] - bf2f(h1)),
                                  f2bf(aa[2] - bf2f(h2)), f2bf(aa[3] - bf2f(h3)));
        }
        __syncthreads();   // prev step's LDS reads complete
        // B: glds half-image (8 x 1KB chunks)
        {
            const unsigned char* img = BpB + offB + ((size_t)ks << 14);
            #pragma unroll
            for (int i = 0; i < 2; i++) {
                int chunk = (i << 2) | wid;
                __builtin_amdgcn_global_load_lds((GAS_cv*)(img + chunk * 1024 + lane * 16),
                    (LAS_v*)((unsigned char*)Bsl + chunk * 1024), 16, 0, 0);
            }
        }
        // A -> LDS (swizzled)
        {
            int swz = (srow & 7) << 4;
            #pragma unroll
            for (int i = 0; i < 2; i++) {
                int j = sj2 + i;
                int ohi = ((8 * j) ^ swz) >> 1;
                int olo = ((64 + 8 * j) ^ swz) >> 1;
                *(ushort4*)&Asl[srow * 64 + ohi] = cah[i];
                *(ushort4*)&Asl[srow * 64 + olo] = cal[i];
            }
        }
        __syncthreads();   // drains glds + ds_writes
        const int fr = lane & 15, kg = lane >> 4;
        bf16x8 ah[2], al[2], bh[2], bl[2];
        #pragma unroll
        for (int m = 0; m < 2; m++) {
            int r = wr * 32 + m * 16 + fr;
            int swz = (r & 7) << 4;
            const unsigned char* base = (const unsigned char*)&Asl[r * 64];
            ah[m] = *(const bf16x8*)(base + ((16 * kg) ^ swz));
            al[m] = *(const bf16x8*)(base + ((64 + 16 * kg) ^ swz));
        }
        #pragma unroll
        for (int n = 0; n < 2; n++) {
            int r = wc * 32 + n * 16 + fr;
            int swz = (r & 7) << 4;
            const unsigned char* base = (const unsigned char*)&Bsl[r * 64];
            bh[n] = *(const bf16x8*)(base + ((16 * kg) ^ swz));
            bl[n] = *(const bf16x8*)(base + ((64 + 16 * kg) ^ swz));
        }
        // A prefetch ks+1
        if (ks + 1 < nsteps) {
            const int k0n = (ks + 1) << 5;
            va[0] = *(const float4*)(pa + k0n);
            va[1] = *(const float4*)(pa + k0n + 4);
        }
        #pragma unroll
        for (int m = 0; m < 2; m++)
            #pragma unroll
            for (int n = 0; n < 2; n++) {
                acc[m][n] = __builtin_amdgcn_mfma_f32_16x16x32_bf16(ah[m], bh[n], acc[m][n], 0, 0, 0);
                acc[m][n] = __builtin_amdgcn_mfma_f32_16x16x32_bf16(ah[m], bl[n], acc[m][n], 0, 0, 0);
                acc[m][n] = __builtin_amdgcn_mfma_f32_16x16x32_bf16(al[m], bh[n], acc[m][n], 0, 0, 0);
            }
    }

    const int fr = lane & 15, fq = lane >> 4;
    const int n0 = by * 64;
    #pragma unroll
    for (int m = 0; m < 2; m++) {
        #pragma unroll
        for (int rr = 0; rr < 4; rr++) {
            int row = m0 + wr * 32 + m * 16 + fq * 4 + rr;
            if (row >= M) continue;
            #pragma unroll
            for (int n = 0; n < 2; n++) {
                int col = n0 + wc * 32 + n * 16 + fr;
                float v = acc[m][n][rr];
                size_t ci = (size_t)row * ldc + col;
                if (EPI == 0) {
                    ((float*)Cv)[ci] = v + bias[col];
                } else if (EPI == 1) {
                    ((float*)Cv)[ci] = v + bias[col] + res[ci];
                } else if (EPI == 5) {
                    v += bias[col];
                    v = 0.5f * v * (1.0f + erff(v * 0.70710678118654752f));
                    unsigned short hh = f2bf(v);
                    unsigned short ll = f2bf(v - bf2f(hh));
                    unsigned char* img = (unsigned char*)Cv +
                        (((size_t)(row >> 7) * (ldc >> 5) + (col >> 5)) << 14);
                    int r2 = row & 127, swz2 = (r2 & 7) << 4, kc = col & 31;
                    *(unsigned short*)(img + r2 * 128 + ((2 * kc) ^ swz2)) = hh;
                    *(unsigned short*)(img + r2 * 128 + ((64 + 2 * kc) ^ swz2)) = ll;
                } else { // 6: qkv scatter (head = (col>>6)-12 for K, -24 for V)
                    float v2 = v + bias[col];
                    if (col < 768) {
                        ((float*)Cv)[(size_t)row * 768 + col] = v2;
                    } else {
                        int b_local = row / SEQ;
                        int s = row - b_local * SEQ;
                        int dloc = col & 63;
                        int kt = s >> 6, r2 = s & 63;
                        unsigned short hh = f2bf(v2);
                        unsigned short ll = f2bf(v2 - bf2f(hh));
                        if (col < 1536) {
                            int hh_i = (col >> 6) - 12;
                            size_t imgi = (((size_t)b_local * NHEADS + hh_i) * NKT + kt) << 14;
                            unsigned char* img = (unsigned char*)Kimg + imgi;
                            int off = (2 * dloc) ^ ((r2 & 7) << 4);
                            *(unsigned short*)(img + r2 * 256 + off) = hh;
                            *(unsigned short*)(img + r2 * 256 + 128 + off) = ll;
                        } else {
                            int hh_i = (col >> 6) - 24;
                            size_t imgi = (((size_t)b_local * NHEADS + hh_i) * NKT + kt) << 14;
                            unsigned char* img = (unsigned char*)Vimg + imgi;
                            int off = (2 * r2) ^ ((dloc & 7) << 4);
                            *(unsigned short*)(img + dloc * 256 + off) = hh;
                            *(unsigned short*)(img + dloc * 256 + 128 + off) = ll;
                        }
                    }
                }
            }
        }
    }
}

// ---------------- GEMM, BOTH operands images, 64x64, counted-vmcnt pipeline ----
// EPI: 1 = +bias+res (res may alias C)
template<int EPI>
__global__ __launch_bounds__(256)
void gemm_pp(const unsigned short* __restrict__ Ap,
             const unsigned short* __restrict__ Bp,
             float* __restrict__ C, int ldc,
             const float* __restrict__ bias,
             const float* __restrict__ res,
             int M, int N, int K) {
    __shared__ unsigned short Asl[2][64 * 64];   // 16 KB
    __shared__ unsigned short Bsl[2][64 * 64];   // 16 KB
    int bx, by, bz;
    xcd_map_nf(bx, by, bz);
    const int t = threadIdx.x;
    const int lane = t & 63, wid = t >> 6;
    const int wr = wid >> 1, wc = wid & 1;
    const unsigned char* ApB = (const unsigned char*)Ap;
    const unsigned char* BpB = (const unsigned char*)Bp;

    f32x4 acc[2][2];
    #pragma unroll
    for (int i = 0; i < 2; i++)
        #pragma unroll
        for (int j = 0; j < 2; j++) {
            f32x4 z = {0.f, 0.f, 0.f, 0.f};
            acc[i][j] = z;
        }

    const int nsteps = K >> 5;
    const size_t offA = ((size_t)(bx >> 1) * nsteps << 14) + ((size_t)(bx & 1) << 13);
    const size_t offB = ((size_t)(by >> 1) * nsteps << 14) + ((size_t)(by & 1) << 13);
    {
        #pragma unroll
        for (int i = 0; i < 2; i++) {
            int chunk = (i << 2) | wid;
            __builtin_amdgcn_global_load_lds((GAS_cv*)(ApB + offA + chunk * 1024 + lane * 16),
                (LAS_v*)((unsigned char*)Asl[0] + chunk * 1024), 16, 0, 0);
            __builtin_amdgcn_global_load_lds((GAS_cv*)(BpB + offB + chunk * 1024 + lane * 16),
                (LAS_v*)((unsigned char*)Bsl[0] + chunk * 1024), 16, 0, 0);
        }
    }
    for (int ks = 0; ks < nsteps; ks++) {
        const int kn = (ks + 1 < nsteps) ? ks + 1 : nsteps - 1;   // clamp: vmcnt const
        RAW_BAR();
        {
            const unsigned char* imgA = ApB + offA + ((size_t)kn << 14);
            const unsigned char* imgB = BpB + offB + ((size_t)kn << 14);
            #pragma unroll
            for (int i = 0; i < 2; i++) {
                int chunk = (i << 2) | wid;
                __builtin_amdgcn_global_load_lds((GAS_cv*)(imgA + chunk * 1024 + lane * 16),
                    (LAS_v*)((unsigned char*)Asl[(ks + 1) & 1] + chunk * 1024), 16, 0, 0);
                __builtin_amdgcn_global_load_lds((GAS_cv*)(imgB + chunk * 1024 + lane * 16),
                    (LAS_v*)((unsigned char*)Bsl[(ks + 1) & 1] + chunk * 1024), 16, 0, 0);
            }
        }
        asm volatile("s_waitcnt vmcnt(4)" ::: "memory");
        __builtin_amdgcn_sched_barrier(0);
        RAW_BAR();
        const int fr = lane & 15, kg = lane >> 4;
        bf16x8 ah[2], al[2], bh[2], bl[2];
        #pragma unroll
        for (int m = 0; m < 2; m++) {
            int r = wr * 32 + m * 16 + fr;
            int swz = (r & 7) << 4;
            const unsigned char* base = (const unsigned char*)Asl[ks & 1] + r * 128;
            ah[m] = *(const bf16x8*)(base + ((16 * kg) ^ swz));
            al[m] = *(const bf16x8*)(base + ((64 + 16 * kg) ^ swz));
        }
        #pragma unroll
        for (int n = 0; n < 2; n++) {
            int r = wc * 32 + n * 16 + fr;
            int swz = (r & 7) << 4;
            const unsigned char* base = (const unsigned char*)Bsl[ks & 1] + r * 128;
            bh[n] = *(const bf16x8*)(base + ((16 * kg) ^ swz));
            bl[n] = *(const bf16x8*)(base + ((64 + 16 * kg) ^ swz));
        }
        #pragma unroll
        for (int m = 0; m < 2; m++)
            #pragma unroll
            for (int n = 0; n < 2; n++) {
                acc[m][n] = __builtin_amdgcn_mfma_f32_16x16x32_bf16(ah[m], bh[n], acc[m][n], 0, 0, 0);
                acc[m][n] = __builtin_amdgcn_mfma_f32_16x16x32_bf16(ah[m], bl[n], acc[m][n], 0, 0, 0);
                acc[m][n] = __builtin_amdgcn_mfma_f32_16x16x32_bf16(al[m], bh[n], acc[m][n], 0, 0, 0);
            }
    }

    const int fr = lane & 15, fq = lane >> 4;
    const int m0 = bx * 64, n0 = by * 64;
    #pragma unroll
    for (int m = 0; m < 2; m++) {
        #pragma unroll
        for (int rr = 0; rr < 4; rr++) {
            int row = m0 + wr * 32 + m * 16 + fq * 4 + rr;
            if (row >= M) continue;
            #pragma unroll
            for (int n = 0; n < 2; n++) {
                int col = n0 + wc * 32 + n * 16 + fr;
                float v = acc[m][n][rr];
                size_t ci = (size_t)row * ldc + col;
                C[ci] = v + bias[col] + res[ci];
            }
        }
    }
}

// ---------------- fused-convert MFMA GEMM (sim) ----------------
template<int EPI>
__global__ __launch_bounds__(256)
void gemm_mfma(const float* __restrict__ A, long long sA, int lda,
               const float* __restrict__ Bm, long long sB, int ldb,
               float* __restrict__ C, long long sC, int ldc,
               const float* __restrict__ bias,
               const float* __restrict__ res,
               int M, int N, int K) {
    __shared__ unsigned short Asl[128 * 64];
    __shared__ unsigned short Bsl[128 * 64];
    int bx, by, bz;
    xcd_map_nf(bx, by, bz);
    A  += (size_t)bz * sA;
    Bm += (size_t)bz * sB;
    C  += (size_t)bz * sC;
    const int m0 = bx * 128, n0 = by * 128;
    const int t = threadIdx.x;
    const int lane = t & 63, wid = t >> 6;
    const int wr = wid >> 1, wc = wid & 1;
    const int srow = t >> 3;
    const int sj   = t & 7;

    const float* pa[4];
    const float* pb[4];
    #pragma unroll
    for (int i = 0; i < 4; i++) {
        int r = srow + i * 32;
        int ra = m0 + r; ra = ra < M ? ra : M - 1;
        int rb = n0 + r; rb = rb < N ? rb : N - 1;
        pa[i] = A  + (size_t)ra * lda + sj * 4;
        pb[i] = Bm + (size_t)rb * ldb + sj * 4;
    }

    f32x4 acc[4][4];
    #pragma unroll
    for (int i = 0; i < 4; i++)
        #pragma unroll
        for (int j = 0; j < 4; j++) {
            f32x4 z = {0.f, 0.f, 0.f, 0.f};
            acc[i][j] = z;
        }

    const int nsteps = K >> 5;
    float4 va[4], vb[4];
    #pragma unroll
    for (int i = 0; i < 4; i++) {
        va[i] = *(const float4*)(pa[i]);
        vb[i] = *(const float4*)(pb[i]);
    }

    for (int ks = 0; ks < nsteps; ks++) {
        ushort4 cah[4], cal[4], cbh[4], cbl[4];
        #pragma unroll
        for (int i = 0; i < 4; i++) {
            float aa[4] = {va[i].x, va[i].y, va[i].z, va[i].w};
            float bb[4] = {vb[i].x, vb[i].y, vb[i].z, vb[i].w};
            unsigned short h0 = f2bf(aa[0]), h1 = f2bf(aa[1]), h2 = f2bf(aa[2]), h3 = f2bf(aa[3]);
            cah[i] = make_ushort4(h0, h1, h2, h3);
            cal[i] = make_ushort4(f2bf(aa[0] - bf2f(h0)), f2bf(aa[1] - bf2f(h1)),
                                  f2bf(aa[2] - bf2f(h2)), f2bf(aa[3] - bf2f(h3)));
            unsigned short g0 = f2bf(bb[0]), g1 = f2bf(bb[1]), g2 = f2bf(bb[2]), g3 = f2bf(bb[3]);
            cbh[i] = make_ushort4(g0, g1, g2, g3);
            cbl[i] = make_ushort4(f2bf(bb[0] - bf2f(g0)), f2bf(bb[1] - bf2f(g1)),
                                  f2bf(bb[2] - bf2f(g2)), f2bf(bb[3] - bf2f(g3)));
        }
        if (ks + 1 < nsteps) {
            const int k0n = (ks + 1) << 5;
            #pragma unroll
            for (int i = 0; i < 4; i++) {
                va[i] = *(const float4*)(pa[i] + k0n);
                vb[i] = *(const float4*)(pb[i] + k0n);
            }
        }
        __syncthreads();
        #pragma unroll
        for (int i = 0; i < 4; i++) {
            int r = srow + i * 32;
            int swz = (r & 7) << 4;
            int ohi = ((8 * sj) ^ swz) >> 1;
            int olo = ((64 + 8 * sj) ^ swz) >> 1;
            *(ushort4*)&Asl[r * 64 + ohi] = cah[i];
            *(ushort4*)&Asl[r * 64 + olo] = cal[i];
            *(ushort4*)&Bsl[r * 64 + ohi] = cbh[i];
            *(ushort4*)&Bsl[r * 64 + olo] = cbl[i];
        }
        __syncthreads();
        const int fr = lane & 15, kg = lane >> 4;
        bf16x8 ah[4], al[4], bh[4], bl[4];
        #pragma unroll
        for (int m = 0; m < 4; m++) {
            int r = wr * 64 + m * 16 + fr;
            int swz = (r & 7) << 4;
            const unsigned char* base = (const unsigned char*)&Asl[r * 64];
            ah[m] = *(const bf16x8*)(base + ((16 * kg) ^ swz));
            al[m] = *(const bf16x8*)(base + ((64 + 16 * kg) ^ swz));
        }
        #pragma unroll
        for (int n = 0; n < 4; n++) {
            int r = wc * 64 + n * 16 + fr;
            int swz = (r & 7) << 4;
            const unsigned char* base = (const unsigned char*)&Bsl[r * 64];
            bh[n] = *(const bf16x8*)(base + ((16 * kg) ^ swz));
            bl[n] = *(const bf16x8*)(base + ((64 + 16 * kg) ^ swz));
        }
        #pragma unroll
        for (int m = 0; m < 4; m++)
            #pragma unroll
            for (int n = 0; n < 4; n++) {
                acc[m][n] = __builtin_amdgcn_mfma_f32_16x16x32_bf16(ah[m], bh[n], acc[m][n], 0, 0, 0);
                acc[m][n] = __builtin_amdgcn_mfma_f32_16x16x32_bf16(ah[m], bl[n], acc[m][n], 0, 0, 0);
                acc[m][n] = __builtin_amdgcn_mfma_f32_16x16x32_bf16(al[m], bh[n], acc[m][n], 0, 0, 0);
            }
    }

    const int fr = lane & 15, fq = lane >> 4;
    #pragma unroll
    for (int m = 0; m < 4; m++) {
        #pragma unroll
        for (int rr = 0; rr < 4; rr++) {
            int row = m0 + wr * 64 + m * 16 + fq * 4 + rr;
            if (row >= M) continue;
            #pragma unroll
            for (int n = 0; n < 4; n++) {
                int col = n0 + wc * 64 + n * 16 + fr;
                if (col >= N) continue;
                C[(size_t)row * ldc + col] = acc[m][n][rr];
            }
        }
    }
}

// ---------------- MFMA flash attention: K/Vt pre-split images via glds ----------------
__global__ __launch_bounds__(256) void attn_glds(const float* __restrict__ Qb,
        const unsigned short* __restrict__ Kimg, const unsigned short* __restrict__ Vimg,
        float* __restrict__ att) {
    int bx, by, bz;
    xcd_map(bx, by, bz);
    const int b = bz, h = by, q0 = bx * 64;
    const int t = threadIdx.x;
    const int lane = t & 63, wid = t >> 6;
    const int fr = lane & 15, kg = lane >> 4;
    __shared__ unsigned short Khl[64 * 128];
    __shared__ unsigned short Vt[64 * 128];
    __shared__ unsigned char Pbuf[16384];
    unsigned char* KhlB = (unsigned char*)Khl;
    unsigned char* VtB = (unsigned char*)Vt;
    unsigned char* PwB = Pbuf + wid * 4096;
    const unsigned char* KiB = (const unsigned char*)Kimg + (((size_t)b * NHEADS + h) * NKT << 14);
    const unsigned char* ViB = (const unsigned char*)Vimg + (((size_t)b * NHEADS + h) * NKT << 14);

    bf16x8 qh[2], qlo[2];
    {
        int qrow = q0 + wid * 16 + fr; qrow = qrow < SEQ ? qrow : SEQ - 1;
        const float* qbase = Qb + ((size_t)b * SEQ + qrow) * CDIM + h * DHEAD;
        #pragma unroll
        for (int ds = 0; ds < 2; ds++) {
            float tmp[8];
            *(float4*)(tmp)     = *(const float4*)(qbase + ds * 32 + kg * 8);
            *(float4*)(tmp + 4) = *(const float4*)(qbase + ds * 32 + kg * 8 + 4);
            #pragma unroll
            for (int j = 0; j < 8; j++) {
                unsigned short hh = f2bf(tmp[j]);
                qh[ds][j]  = (short)hh;
                qlo[ds][j] = (short)f2bf(tmp[j] - bf2f(hh));
            }
        }
    }

    f32x4 acc_o[4];
    #pragma unroll
    for (int i = 0; i < 4; i++) { f32x4 z = {0.f,0.f,0.f,0.f}; acc_o[i] = z; }
    float m_run[4] = {-1e30f, -1e30f, -1e30f, -1e30f};
    float l_run[4] = {0.f, 0.f, 0.f, 0.f};

    for (int kt = 0; kt < NKT; kt++) {
        const int c0 = kt * 64;
        __syncthreads();
        {
            const unsigned char* ki = KiB + ((size_t)kt << 14);
            const unsigned char* vi = ViB + ((size_t)kt << 14);
            #pragma unroll
            for (int i = 0; i < 4; i++) {
                int chunk = (i << 2) | wid;
                __builtin_amdgcn_global_load_lds((GAS_cv*)(ki + chunk * 1024 + lane * 16),
                    (LAS_v*)(KhlB + chunk * 1024), 16, 0, 0);
                __builtin_amdgcn_global_load_lds((GAS_cv*)(vi + chunk * 1024 + lane * 16),
                    (LAS_v*)(VtB + chunk * 1024), 16, 0, 0);
            }
        }
        __syncthreads();
        f32x4 s[4];
        #pragma unroll
        for (int i = 0; i < 4; i++) { f32x4 z = {0.f,0.f,0.f,0.f}; s[i] = z; }
        #pragma unroll
        for (int ds = 0; ds < 2; ds++) {
            #pragma unroll
            for (int n = 0; n < 4; n++) {
                int r = n * 16 + fr;
                int swz = (r & 7) << 4;
                const unsigned char* rb = KhlB + r * 256;
                bf16x8 kh = *(const bf16x8*)(rb + ((ds * 64 + kg * 16) ^ swz));
                bf16x8 kl = *(const bf16x8*)(rb + 128 + ((ds * 64 + kg * 16) ^ swz));
                s[n] = __builtin_amdgcn_mfma_f32_16x16x32_bf16(qh[ds], kh, s[n], 0, 0, 0);
                s[n] = __builtin_amdgcn_mfma_f32_16x16x32_bf16(qh[ds], kl, s[n], 0, 0, 0);
                s[n] = __builtin_amdgcn_mfma_f32_16x16x32_bf16(qlo[ds], kh, s[n], 0, 0, 0);
            }
        }
        float p[4][4];
        #pragma unroll
        for (int n = 0; n < 4; n++) {
            int kcol = c0 + n * 16 + fr;
            #pragma unroll
            for (int r = 0; r < 4; r++) {
                float sv = s[n][r] * 0.125f;
                if (kcol >= SEQ) sv = -1e30f;
                p[n][r] = sv;
            }
        }
        float corr[4];
        #pragma unroll
        for (int r = 0; r < 4; r++) {
            float mx = fmaxf(fmaxf(p[0][r], p[1][r]), fmaxf(p[2][r], p[3][r]));
            mx = fmaxf(mx, __shfl_xor(mx, 1));
            mx = fmaxf(mx, __shfl_xor(mx, 2));
            mx = fmaxf(mx, __shfl_xor(mx, 4));
            mx = fmaxf(mx, __shfl_xor(mx, 8));
            float mnew = fmaxf(m_run[r], mx);
            corr[r] = __expf(m_run[r] - mnew);
            m_run[r] = mnew;
            float ls = 0.f;
            #pragma unroll
            for (int n = 0; n < 4; n++) {
                p[n][r] = __expf(p[n][r] - mnew);
                ls += p[n][r];
            }
            ls += __shfl_xor(ls, 1);
            ls += __shfl_xor(ls, 2);
            ls += __shfl_xor(ls, 4);
            ls += __shfl_xor(ls, 8);
            l_run[r] = l_run[r] * corr[r] + ls;
        }
        #pragma unroll
        for (int nd = 0; nd < 4; nd++)
            #pragma unroll
            for (int r = 0; r < 4; r++)
                acc_o[nd][r] *= corr[r];
        {
            int qb = (lane >> 4) * 4;
            #pragma unroll
            for (int n = 0; n < 4; n++) {
                int kcol = n * 16 + fr;
                #pragma unroll
                for (int r = 0; r < 4; r++) {
                    int qq = qb + r;
                    unsigned short ph = f2bf(p[n][r]);
                    unsigned short pl = f2bf(p[n][r] - bf2f(ph));
                    int off = (kcol * 2) ^ ((qq & 7) << 4);
                    *(unsigned short*)(PwB + qq * 256 + off) = ph;
                    *(unsigned short*)(PwB + qq * 256 + 128 + off) = pl;
                }
            }
        }
        #pragma unroll
        for (int ks = 0; ks < 2; ks++) {
            int swzp = (fr & 7) << 4;
            bf16x8 pah = *(const bf16x8*)(PwB + fr * 256 + ((ks * 64 + kg * 16) ^ swzp));
            bf16x8 pal = *(const bf16x8*)(PwB + fr * 256 + 128 + ((ks * 64 + kg * 16) ^ swzp));
            #pragma unroll
            for (int nd = 0; nd < 4; nd++) {
                int rv = nd * 16 + fr;
                int swzv = (rv & 7) << 4;
                const unsigned char* rb = VtB + rv * 256;
                bf16x8 vh = *(const bf16x8*)(rb + ((ks * 64 + kg * 16) ^ swzv));
                bf16x8 vl = *(const bf16x8*)(rb + 128 + ((ks * 64 + kg * 16) ^ swzv));
                acc_o[nd] = __builtin_amdgcn_mfma_f32_16x16x32_bf16(pah, vh, acc_o[nd], 0, 0, 0);
                acc_o[nd] = __builtin_amdgcn_mfma_f32_16x16x32_bf16(pah, vl, acc_o[nd], 0, 0, 0);
                acc_o[nd] = __builtin_amdgcn_mfma_f32_16x16x32_bf16(pal, vh, acc_o[nd], 0, 0, 0);
            }
        }
    }
    #pragma unroll
    for (int r = 0; r < 4; r++) {
        int q = q0 + wid * 16 + (lane >> 4) * 4 + r;
        if (q >= SEQ) continue;
        float inv = 1.f / l_run[r];
        float* o = att + ((size_t)b * SEQ + q) * CDIM + h * DHEAD;
        #pragma unroll
        for (int nd = 0; nd < 4; nd++)
            o[nd * 16 + fr] = acc_o[nd][r] * inv;
    }
}

// ---------------- normalize img tokens ----------------
__global__ __launch_bounds__(256) void xn_kernel(const float* __restrict__ x2,
                                                 float* __restrict__ xn) {
    __shared__ float red[4];
    int tok = blockIdx.x;
    int b = tok / NIMG, n = tok % NIMG;
    const float* xr = x2 + ((size_t)b * SEQ + 1 + n) * CDIM;
    float* onr = xn + (size_t)tok * CDIM;
    int t = threadIdx.x;
    float v0 = xr[t], v1 = xr[t + 256], v2 = xr[t + 512];
    float ss = blk_sum256(v0 * v0 + v1 * v1 + v2 * v2, red);
    float nrm = fmaxf(sqrtf(ss), 1e-12f);
    float inv = 1.f / nrm;
    onr[t] = v0 * inv; onr[t + 256] = v1 * inv; onr[t + 512] = v2 * inv;
}

// ---------------- row max of symmetrized sim (excluding diagonal) ----------------
__global__ __launch_bounds__(64) void rowmax_kernel(const float* __restrict__ sim,
                                                    float* __restrict__ ms) {
    int row = blockIdx.x;
    int b = row / NIMG, n = row % NIMG;
    const float* sb = sim + (size_t)b * NIMG * NIMG;
    int lane = threadIdx.x;
    float mx = -1e30f;
    #pragma unroll
    for (int i = 0; i < NIMG / 64; i++) {
        int m = lane + i * 64;
        if (m != n) {
            float v = 0.5f * (sb[(size_t)n * NIMG + m] + sb[(size_t)m * NIMG + n]);
            mx = fmaxf(mx, v);
        }
    }
    #pragma unroll
    for (int o = 32; o; o >>= 1) mx = fmaxf(mx, __shfl_down(mx, o));
    if (lane == 0) ms[row] = mx;
}

// ---------------- exact top-k selection with lax.top_k tie semantics ----------------
__global__ __launch_bounds__(576) void select_kernel(const float* __restrict__ ms,
        int* __restrict__ mergemask, int* __restrict__ keeppos) {
    __shared__ float v[NIMG];
    __shared__ int keepf[NIMG];
    int b = blockIdx.x;
    int n = threadIdx.x;
    v[n] = ms[b * NIMG + n];
    __syncthreads();
    float vn = v[n];
    int rank_desc = 0, rank_asc = 0;
    for (int m = 0; m < NIMG; m++) {
        float vm = v[m];
        int tie_lo = (vm == vn && m < n);
        rank_desc += (vm > vn) || tie_lo;
        rank_asc  += (vm < vn) || tie_lo;
    }
    int merge = rank_desc < NMERGE;
    int keep  = rank_asc  < NMERGE;
    mergemask[b * NIMG + n] = merge;
    keepf[n] = keep;
    __syncthreads();
    if (keep) {
        int pos = 0;
        for (int m = 0; m < n; m++) pos += keepf[m];
        keeppos[b * NIMG + n] = pos;
    } else {
        keeppos[b * NIMG + n] = -1;
    }
}

// ---------------- average of merged tokens (parallelized) ----------------
__global__ __launch_bounds__(256) void avg_kernel(const float* __restrict__ x2,
        const int* __restrict__ mask, float* __restrict__ avg) {
    __shared__ float4 red[8][33];
    int b = blockIdx.x, cc = blockIdx.y;
    int t = threadIdx.x;
    int rr = t >> 5, c4 = t & 31;
    int c = cc * 128 + c4 * 4;
    const int* mb = mask + b * NIMG;
    float4 s = make_float4(0.f, 0.f, 0.f, 0.f);
    for (int n = rr; n < NIMG; n += 8) {
        if (mb[n]) {
            float4 v = *(const float4*)(x2 + ((size_t)b * SEQ + 1 + n) * CDIM + c);
            s.x += v.x; s.y += v.y; s.z += v.z; s.w += v.w;
        }
    }
    red[rr][c4] = s;
    __syncthreads();
    if (rr == 0) {
        float4 tot = red[0][c4];
        #pragma unroll
        for (int i = 1; i < 8; i++) {
            float4 v = red[i][c4];
            tot.x += v.x; tot.y += v.y; tot.z += v.z; tot.w += v.w;
        }
        float sc1 = 1.f / (float)NMERGE, sc2 = 1.f / (float)(NIMG - NMERGE);
        tot.x = (tot.x * sc1) * sc2; tot.y = (tot.y * sc1) * sc2;
        tot.z = (tot.z * sc1) * sc2; tot.w = (tot.w * sc1) * sc2;
        *(float4*)(avg + (size_t)b * CDIM + c) = tot;
    }
}

// ---------------- assemble output ----------------
__global__ __launch_bounds__(192) void assemble_kernel(const float* __restrict__ x2,
        const int* __restrict__ keeppos, const float* __restrict__ avg,
        float* __restrict__ out) {
    int g = blockIdx.x;
    int b = g / SEQ, s_ = g % SEQ;
    int t = threadIdx.x;
    const float4* src = (const float4*)(x2 + (size_t)g * CDIM);
    if (s_ == 0) {
        float4* dst = (float4*)(out + (size_t)b * 289 * CDIM);
        dst[t] = src[t];
    } else {
        int n = s_ - 1;
        int pos = keeppos[b * NIMG + n];
        if (pos < 0) return;
        const float4* av = (const float4*)(avg + (size_t)b * CDIM);
        float4 v = src[t], a = av[t];
        v.x += a.x; v.y += a.y; v.z += a.z; v.w += a.w;
        float4* dst = (float4*)(out + ((size_t)b * 289 + 1 + pos) * CDIM);
        dst[t] = v;
    }
}

extern "C" void kernel_launch(void* const* d_in, const int* in_sizes, int n_in,
                              void* d_out, int out_size, void* d_ws, size_t ws_size,
                              hipStream_t stream) {
    const float* x      = (const float*)d_in[0];
    const float* qkv_w  = (const float*)d_in[1];
    const float* qkv_b  = (const float*)d_in[2];
    const float* proj_w = (const float*)d_in[3];
    const float* proj_b = (const float*)d_in[4];
    const float* ln1_g  = (const float*)d_in[5];
    const float* ln1_b  = (const float*)d_in[6];
    const float* ln2_g  = (const float*)d_in[7];
    const float* ln2_b  = (const float*)d_in[8];
    const float* fc1_w  = (const float*)d_in[9];
    const float* fc1_b  = (const float*)d_in[10];
    const float* fc2_w  = (const float*)d_in[11];
    const float* fc2_b  = (const float*)d_in[12];

    if (ws_size < NEED_BYTES) return;

    float* ws   = (float*)d_ws;
    float* bh   = ws + O_BH;
    float* ba   = ws + O_BA;
    float* bq   = ws + O_BQ;
    float* qbuf = ws + O_BQ;                       // group Q rows
    unsigned short* kimg = (unsigned short*)(ws + O_KIMG);
    unsigned short* vimg = (unsigned short*)(ws + O_VIMG);
    float* ms   = ws + O_MS;
    int*   mask = (int*)(ws + O_MASK);
    int*   pos  = (int*)(ws + O_POS);
    float* avg  = ws + O_AVG;
    float* outp = (float*)d_out;

    unsigned short* qkvp  = (unsigned short*)(outp + OW_QKV);
    unsigned short* fc1p  = (unsigned short*)(outp + OW_FC1);
    unsigned short* fc2p  = (unsigned short*)(outp + OW_FC2);
    unsigned short* projp = (unsigned short*)(outp + OW_PROJ);

    // 0. split weights; zero V-image scratch (tail rows must be 0, not stale)
    wsplit_kernel<<<18 * 24, 256, 0, stream>>>(qkv_w, qkvp, 24, CDIM);
    wsplit_kernel<<<24 * 24, 256, 0, stream>>>(fc1_w, fc1p, 24, CDIM);
    wsplit_kernel<<<6 * 96, 256, 0, stream>>>(fc2_w, fc2p, 96, 3072);
    wsplit_kernel<<<6 * 24, 256, 0, stream>>>(proj_w, projp, 24, CDIM);
    hipMemsetAsync(vimg, 0, SZ_IMG * 4, stream);

    // 1. h = LN1(x)
    ln_kernel<<<MTOK, 256, 0, stream>>>(x, ln1_g, ln1_b, bh);

    // 2. per-group qkv GEMM (64x64, scatter epilogue) + attention
    for (int g = 0; g < NGROUP; g++) {
        const float* hg = bh + (size_t)g * MGRP * CDIM;
        float* attg = ba + (size_t)g * MGRP * CDIM;
        gemm_wp<6><<<dim3((MGRP + 63) / 64, 36), 256, 0, stream>>>(
            hg, CDIM, qkvp, 24, (void*)qbuf, 3 * CDIM, qkv_b, nullptr,
            MGRP, 3 * CDIM, CDIM, kimg, vimg);
        attn_glds<<<dim3(NKT, NHEADS, GB), 256, 0, stream>>>(
            qbuf, kimg, vimg, attg);
    }

    // 3. x1 = x + att @ proj_w^T + proj_b (64x64)
    gemm_wp<1><<<dim3((MTOK + 63) / 64, 12), 256, 0, stream>>>(
        ba, CDIM, projp, 24, (void*)bh, CDIM, proj_b, x, MTOK, CDIM, CDIM,
        nullptr, nullptr);

    // 4. h2 = LN2(x1)
    ln_kernel<<<MTOK, 256, 0, stream>>>(bh, ln2_g, ln2_b, ba);

    // 5. MLP chunks: fc1 (64x64, gelu -> plane images), fc2 (dual-glds 64x64)
    for (int c0 = 0; c0 < MTOK; c0 += MLPCH) {
        int mc = (MTOK - c0 < MLPCH) ? (MTOK - c0) : MLPCH;
        const float* h2c = ba + (size_t)c0 * CDIM;
        float* x1c = bh + (size_t)c0 * CDIM;
        gemm_wp<5><<<dim3((mc + 63) / 64, 48), 256, 0, stream>>>(
            h2c, CDIM, fc1p, 24, (void*)bq, 3072, fc1_b, nullptr, mc, 3072, CDIM,
            nullptr, nullptr);
        gemm_pp<1><<<dim3((mc + 63) / 64, 12), 256, 0, stream>>>(
            (const unsigned short*)bq, fc2p, x1c, CDIM, fc2_b, x1c,
            mc, CDIM, 3072);
    }

    // 6. normalize img tokens
    xn_kernel<<<NBATCH * NIMG, 256, 0, stream>>>(bh, ba);

    // 7. sim = xn @ xn^T per batch
    gemm_mfma<3><<<dim3(5, 5, NBATCH), 256, 0, stream>>>(
        ba, (long long)NIMG * CDIM, CDIM, ba, (long long)NIMG * CDIM, CDIM,
        bq, (long long)NIMG * NIMG, NIMG, nullptr, nullptr, NIMG, NIMG, CDIM);

    // 8. row max of symmetrized sim
    rowmax_kernel<<<NBATCH * NIMG, 64, 0, stream>>>(bq, ms);
    // 9. top-k selection
    select_kernel<<<NBATCH, NIMG, 0, stream>>>(ms, mask, pos);
    // 10. merged-token average (parallel)
    avg_kernel<<<dim3(NBATCH, 6), 256, 0, stream>>>(bh, mask, avg);
    // 11. assemble output (overwrites weight-plane scratch in d_out)
    assemble_kernel<<<MTOK, 192, 0, stream>>>(bh, pos, avg, outp);
}

// Round 17
// 1695.112 us; speedup vs baseline: 3.9468x; 1.0923x over previous
//
#include <hip/hip_runtime.h>
#include <math.h>

#define CDIM 768
#define NHEADS 12
#define DHEAD 64
#define SEQ 577
#define NBATCH 32
#define MTOK (NBATCH*SEQ)      // 18464
#define NIMG 576
#define NMERGE 288
#define GB 8                   // batches per qkv group
#define NGROUP (NBATCH/GB)     // 4
#define MGRP (GB*SEQ)          // 4616 rows per group
#define MLPCH 3456             // MLP chunk rows (27x128, 64/128-aligned)
#define NKT 10                 // k-tiles per (b,h) in attention

// ---- workspace layout (float offsets), peak ~161.2 MB ----
#define SZ_BH   ((size_t)4*37*24*4096)           // 14,548,992  h images (grp-padded) / x1 / x2
#define O_BH    ((size_t)0)
#define O_BA    (SZ_BH)                          // att fp32 / h2 images / xn images
#define SZ_BA   ((size_t)145*24*4096)            // 14,254,080
#define O_BQ    (O_BA + SZ_BA)                   // Q rows + K/V images / fc1o images / sim half
#define SZ_Q    ((size_t)MGRP*CDIM)              // 3,545,088
#define SZ_IMG  ((size_t)GB*NHEADS*NKT*4096)     // 3,932,160
#define O_KIMG  (O_BQ + SZ_Q)
#define O_VIMG  (O_KIMG + SZ_IMG)
#define O_SM    (O_VIMG + SZ_IMG)
#define O_MS    (O_SM)
#define O_MASK  (O_SM + (size_t)NBATCH*NIMG)
#define O_POS   (O_MASK + (size_t)NBATCH*NIMG)
#define O_AVG   (O_POS + (size_t)NBATCH*NIMG)
#define O_END   (O_AVG + (size_t)NBATCH*CDIM)
#define NEED_BYTES (O_END * 4)

// ---- weight-plane scratch inside d_out ----
#define OW_QKV  ((size_t)0)           // 18nt*24ks = 1,769,472 floats
#define OW_FC1  ((size_t)1769472)     // 24nt*24ks = 2,359,296 floats
#define OW_FC2  ((size_t)4128768)     // 6nt*96ks  = 2,359,296 floats
#define OW_PROJ ((size_t)6488064)     // 6nt*24ks  =   589,824 floats

typedef __attribute__((ext_vector_type(8))) short bf16x8;
typedef __attribute__((ext_vector_type(4))) float f32x4;
typedef __attribute__((address_space(1))) const void GAS_cv;
typedef __attribute__((address_space(3))) void LAS_v;

#define RAW_BAR() do { asm volatile("" ::: "memory"); \
    __builtin_amdgcn_s_barrier(); asm volatile("" ::: "memory"); } while (0)

__device__ __forceinline__ unsigned short f2bf(float f) {
    unsigned int u = __float_as_uint(f);
    u += 0x7fff + ((u >> 16) & 1);           // RNE
    return (unsigned short)(u >> 16);
}
__device__ __forceinline__ float bf2f(unsigned short h) {
    return __uint_as_float(((unsigned int)h) << 16);
}

// ---- bijective XCD chunk remaps (m204) ----
__device__ __forceinline__ void xcd_map(int& bx, int& by, int& bz) {
    int gx = gridDim.x, gy = gridDim.y;
    int nwg = gx * gy * gridDim.z;
    int orig = blockIdx.x + gx * (blockIdx.y + gy * blockIdx.z);
    int q = nwg >> 3, r = nwg & 7;
    int xcd = orig & 7, pos = orig >> 3;
    int wg = (xcd < r ? xcd * (q + 1) : r * (q + 1) + (xcd - r) * q) + pos;
    bx = wg % gx;
    int t2 = wg / gx;
    by = t2 % gy;
    bz = t2 / gy;
}
__device__ __forceinline__ void xcd_map_nf(int& bx, int& by, int& bz) {
    int gx = gridDim.x, gy = gridDim.y;
    int nwg = gx * gy * gridDim.z;
    int orig = blockIdx.x + gx * (blockIdx.y + gy * blockIdx.z);
    int q = nwg >> 3, r = nwg & 7;
    int xcd = orig & 7, pos = orig >> 3;
    int wg = (xcd < r ? xcd * (q + 1) : r * (q + 1) + (xcd - r) * q) + pos;
    by = wg % gy;
    int t2 = wg / gy;
    bx = t2 % gx;
    bz = t2 / gx;
}

// ---------------- block reduce (256 threads) ----------------
__device__ __forceinline__ float blk_sum256(float v, float* red) {
    #pragma unroll
    for (int o = 32; o; o >>= 1) v += __shfl_down(v, o);
    if ((threadIdx.x & 63) == 0) red[threadIdx.x >> 6] = v;
    __syncthreads();
    float tot = red[0] + red[1] + red[2] + red[3];
    __syncthreads();
    return tot;
}

// ---------------- LayerNorm -> bf16 hi/lo plane IMAGES ----------------
// Image bytes identical to what the fused-convert GEMM staging built ->
// all downstream GEMMs bit-identical. Group-padded layout via rows_per_grp.
__global__ __launch_bounds__(256) void ln_split(const float* __restrict__ x,
        const float* __restrict__ g, const float* __restrict__ b,
        unsigned short* __restrict__ img, int rows_per_grp, int imgrows_per_grp) {
    __shared__ float red[4];
    int row = blockIdx.x;
    const float* xr = x + (size_t)row * CDIM;
    int t = threadIdx.x;
    float v0 = xr[t], v1 = xr[t + 256], v2 = xr[t + 512];
    float mu = blk_sum256(v0 + v1 + v2, red) * (1.f / CDIM);
    float d0 = v0 - mu, d1 = v1 - mu, d2 = v2 - mu;
    float var = blk_sum256(d0 * d0 + d1 * d1 + d2 * d2, red) * (1.f / CDIM);
    float e = var + 1e-5f;
    float rs = rsqrtf(e);
    rs = rs * (1.5f - 0.5f * e * rs * rs);
    float vals[3] = {d0 * rs * g[t] + b[t],
                     d1 * rs * g[t + 256] + b[t + 256],
                     d2 * rs * g[t + 512] + b[t + 512]};
    int grp = row / rows_per_grp;
    int local = row - grp * rows_per_grp;
    int r2 = local & 127;
    size_t ibase = ((size_t)grp * imgrows_per_grp + (local >> 7)) * 24;
    int swz = (r2 & 7) << 4;
    #pragma unroll
    for (int cc = 0; cc < 3; cc++) {
        int col = t + cc * 256;
        int ks = col >> 5, kc = col & 31;
        unsigned char* ip = (unsigned char*)img + ((ibase + ks) << 14) + r2 * 128;
        float v = vals[cc];
        unsigned short hh = f2bf(v);
        unsigned short ll = f2bf(v - bf2f(hh));
        *(unsigned short*)(ip + ((2 * kc) ^ swz)) = hh;
        *(unsigned short*)(ip + ((64 + 2 * kc) ^ swz)) = ll;
    }
}

// ---------------- normalize img tokens -> plane IMAGES (per batch-half) ------
__global__ __launch_bounds__(256) void xn_split(const float* __restrict__ x2,
        unsigned short* __restrict__ img, int b0) {
    __shared__ float red[4];
    int tok = blockIdx.x;                 // bl*576 + n, bl local 0..15
    int bl = tok / NIMG, n = tok % NIMG;
    const float* xr = x2 + ((size_t)(b0 + bl) * SEQ + 1 + n) * CDIM;
    int t = threadIdx.x;
    float v0 = xr[t], v1 = xr[t + 256], v2 = xr[t + 512];
    float ss = blk_sum256(v0 * v0 + v1 * v1 + v2 * v2, red);
    float nrm = fmaxf(sqrtf(ss), 1e-12f);
    float inv = 1.f / nrm;
    float vals[3] = {v0 * inv, v1 * inv, v2 * inv};
    int r2 = n & 127;
    size_t ibase = ((size_t)bl * 5 + (n >> 7)) * 24;
    int swz = (r2 & 7) << 4;
    #pragma unroll
    for (int cc = 0; cc < 3; cc++) {
        int col = t + cc * 256;
        int ks = col >> 5, kc = col & 31;
        unsigned char* ip = (unsigned char*)img + ((ibase + ks) << 14) + r2 * 128;
        float v = vals[cc];
        unsigned short hh = f2bf(v);
        unsigned short ll = f2bf(v - bf2f(hh));
        *(unsigned short*)(ip + ((2 * kc) ^ swz)) = hh;
        *(unsigned short*)(ip + ((64 + 2 * kc) ^ swz)) = ll;
    }
}

// ---------------- weight split: fp32 -> bf16 hi/lo LDS-image planes ----------------
__global__ __launch_bounds__(256) void wsplit_kernel(const float* __restrict__ w,
        unsigned short* __restrict__ wp, int nksteps, int ldw) {
    int bid = blockIdx.x;
    int nt = bid / nksteps, ks = bid % nksteps;
    int t = threadIdx.x;
    int srow = t >> 3, sj = t & 7;
    unsigned short* img = wp + ((size_t)bid << 13);
    #pragma unroll
    for (int i = 0; i < 4; i++) {
        int r = srow + i * 32;
        float4 v = *(const float4*)(w + (size_t)(nt * 128 + r) * ldw + ks * 32 + sj * 4);
        unsigned short h0 = f2bf(v.x), h1 = f2bf(v.y), h2 = f2bf(v.z), h3 = f2bf(v.w);
        ushort4 hv = make_ushort4(h0, h1, h2, h3);
        ushort4 lv = make_ushort4(f2bf(v.x - bf2f(h0)), f2bf(v.y - bf2f(h1)),
                                  f2bf(v.z - bf2f(h2)), f2bf(v.w - bf2f(h3)));
        int swz = (r & 7) << 4;
        int ohi = ((8 * sj) ^ swz) >> 1;
        int olo = ((64 + 8 * sj) ^ swz) >> 1;
        *(ushort4*)&img[r * 64 + ohi] = hv;
        *(ushort4*)&img[r * 64 + olo] = lv;
    }
}

// ---------------- GEMM, BOTH operands plane images, 64x64, counted-vmcnt ------
// Zero staging VALU, zero conversion. aBatch = A/B images per batch (sim),
// cBatch = C floats per batch; 0 / gridDim.z==1 otherwise.
// EPI: 1 = +bias+res fp32 (res may alias C), 4 = plain fp32 (batched sim),
//      5 = gelu(+bias) -> plane images, 6 = qkv scatter (Q rows + K/Vt images)
template<int EPI>
__global__ __launch_bounds__(256)
void gemm_ppx(const unsigned short* __restrict__ Ap,
              const unsigned short* __restrict__ Bp,
              void* __restrict__ Cv, int ldc,
              const float* __restrict__ bias,
              const float* __restrict__ res,
              int M, int N, int K,
              long long aBatch, long long cBatch,
              unsigned short* __restrict__ Kimg,
              unsigned short* __restrict__ Vimg) {
    __shared__ unsigned short Asl[2][64 * 64];
    __shared__ unsigned short Bsl[2][64 * 64];
    int bx, by, bz;
    xcd_map_nf(bx, by, bz);
    const int t = threadIdx.x;
    const int lane = t & 63, wid = t >> 6;
    const int wr = wid >> 1, wc = wid & 1;
    const unsigned char* ApB = (const unsigned char*)(Ap + ((size_t)bz * aBatch << 13));
    const unsigned char* BpB = (const unsigned char*)(Bp + ((size_t)bz * aBatch << 13));
    float* C = (float*)Cv + (EPI == 4 ? (size_t)bz * cBatch : 0);

    f32x4 acc[2][2];
    #pragma unroll
    for (int i = 0; i < 2; i++)
        #pragma unroll
        for (int j = 0; j < 2; j++) {
            f32x4 z = {0.f, 0.f, 0.f, 0.f};
            acc[i][j] = z;
        }

    const int nsteps = K >> 5;
    const size_t offA = ((size_t)(bx >> 1) * nsteps << 14) + ((size_t)(bx & 1) << 13);
    const size_t offB = ((size_t)(by >> 1) * nsteps << 14) + ((size_t)(by & 1) << 13);
    {
        #pragma unroll
        for (int i = 0; i < 2; i++) {
            int chunk = (i << 2) | wid;
            __builtin_amdgcn_global_load_lds((GAS_cv*)(ApB + offA + chunk * 1024 + lane * 16),
                (LAS_v*)((unsigned char*)Asl[0] + chunk * 1024), 16, 0, 0);
            __builtin_amdgcn_global_load_lds((GAS_cv*)(BpB + offB + chunk * 1024 + lane * 16),
                (LAS_v*)((unsigned char*)Bsl[0] + chunk * 1024), 16, 0, 0);
        }
    }
    for (int ks = 0; ks < nsteps; ks++) {
        const int kn = (ks + 1 < nsteps) ? ks + 1 : nsteps - 1;   // clamp: vmcnt const
        RAW_BAR();
        {
            const unsigned char* imgA = ApB + offA + ((size_t)kn << 14);
            const unsigned char* imgB = BpB + offB + ((size_t)kn << 14);
            #pragma unroll
            for (int i = 0; i < 2; i++) {
                int chunk = (i << 2) | wid;
                __builtin_amdgcn_global_load_lds((GAS_cv*)(imgA + chunk * 1024 + lane * 16),
                    (LAS_v*)((unsigned char*)Asl[(ks + 1) & 1] + chunk * 1024), 16, 0, 0);
                __builtin_amdgcn_global_load_lds((GAS_cv*)(imgB + chunk * 1024 + lane * 16),
                    (LAS_v*)((unsigned char*)Bsl[(ks + 1) & 1] + chunk * 1024), 16, 0, 0);
            }
        }
        asm volatile("s_waitcnt vmcnt(4)" ::: "memory");
        __builtin_amdgcn_sched_barrier(0);
        RAW_BAR();
        const int fr = lane & 15, kg = lane >> 4;
        bf16x8 ah[2], al[2], bh[2], bl[2];
        #pragma unroll
        for (int m = 0; m < 2; m++) {
            int r = wr * 32 + m * 16 + fr;
            int swz = (r & 7) << 4;
            const unsigned char* base = (const unsigned char*)Asl[ks & 1] + r * 128;
            ah[m] = *(const bf16x8*)(base + ((16 * kg) ^ swz));
            al[m] = *(const bf16x8*)(base + ((64 + 16 * kg) ^ swz));
        }
        #pragma unroll
        for (int n = 0; n < 2; n++) {
            int r = wc * 32 + n * 16 + fr;
            int swz = (r & 7) << 4;
            const unsigned char* base = (const unsigned char*)Bsl[ks & 1] + r * 128;
            bh[n] = *(const bf16x8*)(base + ((16 * kg) ^ swz));
            bl[n] = *(const bf16x8*)(base + ((64 + 16 * kg) ^ swz));
        }
        #pragma unroll
        for (int m = 0; m < 2; m++)
            #pragma unroll
            for (int n = 0; n < 2; n++) {
                acc[m][n] = __builtin_amdgcn_mfma_f32_16x16x32_bf16(ah[m], bh[n], acc[m][n], 0, 0, 0);
                acc[m][n] = __builtin_amdgcn_mfma_f32_16x16x32_bf16(ah[m], bl[n], acc[m][n], 0, 0, 0);
                acc[m][n] = __builtin_amdgcn_mfma_f32_16x16x32_bf16(al[m], bh[n], acc[m][n], 0, 0, 0);
            }
    }

    const int fr = lane & 15, fq = lane >> 4;
    const int m0 = bx * 64, n0 = by * 64;
    #pragma unroll
    for (int m = 0; m < 2; m++) {
        #pragma unroll
        for (int rr = 0; rr < 4; rr++) {
            int row = m0 + wr * 32 + m * 16 + fq * 4 + rr;
            if (row >= M) continue;
            #pragma unroll
            for (int n = 0; n < 2; n++) {
                int col = n0 + wc * 32 + n * 16 + fr;
                float v = acc[m][n][rr];
                size_t ci = (size_t)row * ldc + col;
                if (EPI == 1) {
                    C[ci] = v + bias[col] + res[ci];
                } else if (EPI == 4) {
                    C[ci] = v;
                } else if (EPI == 5) {
                    v += bias[col];
                    v = 0.5f * v * (1.0f + erff(v * 0.70710678118654752f));
                    unsigned short hh = f2bf(v);
                    unsigned short ll = f2bf(v - bf2f(hh));
                    unsigned char* img = (unsigned char*)Cv +
                        (((size_t)(row >> 7) * (ldc >> 5) + (col >> 5)) << 14);
                    int r2 = row & 127, swz2 = (r2 & 7) << 4, kc = col & 31;
                    *(unsigned short*)(img + r2 * 128 + ((2 * kc) ^ swz2)) = hh;
                    *(unsigned short*)(img + r2 * 128 + ((64 + 2 * kc) ^ swz2)) = ll;
                } else { // 6: qkv scatter (head = (col>>6)-12 for K, -24 for V)
                    float v2 = v + bias[col];
                    if (col < 768) {
                        ((float*)Cv)[(size_t)row * 768 + col] = v2;
                    } else {
                        int b_local = row / SEQ;
                        int s = row - b_local * SEQ;
                        int dloc = col & 63;
                        int kt = s >> 6, r2 = s & 63;
                        unsigned short hh = f2bf(v2);
                        unsigned short ll = f2bf(v2 - bf2f(hh));
                        if (col < 1536) {
                            int hh_i = (col >> 6) - 12;
                            size_t imgi = (((size_t)b_local * NHEADS + hh_i) * NKT + kt) << 14;
                            unsigned char* img = (unsigned char*)Kimg + imgi;
                            int off = (2 * dloc) ^ ((r2 & 7) << 4);
                            *(unsigned short*)(img + r2 * 256 + off) = hh;
                            *(unsigned short*)(img + r2 * 256 + 128 + off) = ll;
                        } else {
                            int hh_i = (col >> 6) - 24;
                            size_t imgi = (((size_t)b_local * NHEADS + hh_i) * NKT + kt) << 14;
                            unsigned char* img = (unsigned char*)Vimg + imgi;
                            int off = (2 * r2) ^ ((dloc & 7) << 4);
                            *(unsigned short*)(img + dloc * 256 + off) = hh;
                            *(unsigned short*)(img + dloc * 256 + 128 + off) = ll;
                        }
                    }
                }
            }
        }
    }
}

// ---------------- GEMM 64x64, A fp32 fused-convert + B half-image glds (proj) ----
// EPI: 1 = +bias+res (res may alias C)
template<int EPI>
__global__ __launch_bounds__(256)
void gemm_wp(const float* __restrict__ A, int lda,
             const unsigned short* __restrict__ Bp, int nksteps,
             void* __restrict__ Cv, int ldc,
             const float* __restrict__ bias,
             const float* __restrict__ res,
             int M, int N, int K) {
    __shared__ unsigned short Asl[64 * 64];
    __shared__ unsigned short Bsl[64 * 64];
    int bx, by, bz;
    xcd_map_nf(bx, by, bz);
    const int m0 = bx * 64;
    const int t = threadIdx.x;
    const int lane = t & 63, wid = t >> 6;
    const int wr = wid >> 1, wc = wid & 1;
    const int srow = t >> 2;
    const int sj2  = (t & 3) * 2;
    const unsigned char* BpB = (const unsigned char*)Bp;

    const float* pa;
    {
        int ra = m0 + srow; ra = ra < M ? ra : M - 1;
        pa = A + (size_t)ra * lda + sj2 * 4;
    }

    f32x4 acc[2][2];
    #pragma unroll
    for (int i = 0; i < 2; i++)
        #pragma unroll
        for (int j = 0; j < 2; j++) {
            f32x4 z = {0.f, 0.f, 0.f, 0.f};
            acc[i][j] = z;
        }

    const int nsteps = K >> 5;
    const size_t offB = ((size_t)(by >> 1) * nksteps << 14) + ((size_t)(by & 1) << 13);
    float4 va[2];
    va[0] = *(const float4*)(pa);
    va[1] = *(const float4*)(pa + 4);

    for (int ks = 0; ks < nsteps; ks++) {
        ushort4 cah[2], cal[2];
        #pragma unroll
        for (int i = 0; i < 2; i++) {
            float aa[4] = {va[i].x, va[i].y, va[i].z, va[i].w};
            unsigned short h0 = f2bf(aa[0]), h1 = f2bf(aa[1]), h2 = f2bf(aa[2]), h3 = f2bf(aa[3]);
            cah[i] = make_ushort4(h0, h1, h2, h3);
            cal[i] = make_ushort4(f2bf(aa[0] - bf2f(h0)), f2bf(aa[1] - bf2f(h1)),
                                  f2bf(aa[2] - bf2f(h2)), f2bf(aa[3] - bf2f(h3)));
        }
        __syncthreads();
        {
            const unsigned char* img = BpB + offB + ((size_t)ks << 14);
            #pragma unroll
            for (int i = 0; i < 2; i++) {
                int chunk = (i << 2) | wid;
                __builtin_amdgcn_global_load_lds((GAS_cv*)(img + chunk * 1024 + lane * 16),
                    (LAS_v*)((unsigned char*)Bsl + chunk * 1024), 16, 0, 0);
            }
        }
        {
            int swz = (srow & 7) << 4;
            #pragma unroll
            for (int i = 0; i < 2; i++) {
                int j = sj2 + i;
                int ohi = ((8 * j) ^ swz) >> 1;
                int olo = ((64 + 8 * j) ^ swz) >> 1;
                *(ushort4*)&Asl[srow * 64 + ohi] = cah[i];
                *(ushort4*)&Asl[srow * 64 + olo] = cal[i];
            }
        }
        __syncthreads();
        const int fr = lane & 15, kg = lane >> 4;
        bf16x8 ah[2], al[2], bh[2], bl[2];
        #pragma unroll
        for (int m = 0; m < 2; m++) {
            int r = wr * 32 + m * 16 + fr;
            int swz = (r & 7) << 4;
            const unsigned char* base = (const unsigned char*)&Asl[r * 64];
            ah[m] = *(const bf16x8*)(base + ((16 * kg) ^ swz));
            al[m] = *(const bf16x8*)(base + ((64 + 16 * kg) ^ swz));
        }
        #pragma unroll
        for (int n = 0; n < 2; n++) {
            int r = wc * 32 + n * 16 + fr;
            int swz = (r & 7) << 4;
            const unsigned char* base = (const unsigned char*)&Bsl[r * 64];
            bh[n] = *(const bf16x8*)(base + ((16 * kg) ^ swz));
            bl[n] = *(const bf16x8*)(base + ((64 + 16 * kg) ^ swz));
        }
        if (ks + 1 < nsteps) {
            const int k0n = (ks + 1) << 5;
            va[0] = *(const float4*)(pa + k0n);
            va[1] = *(const float4*)(pa + k0n + 4);
        }
        #pragma unroll
        for (int m = 0; m < 2; m++)
            #pragma unroll
            for (int n = 0; n < 2; n++) {
                acc[m][n] = __builtin_amdgcn_mfma_f32_16x16x32_bf16(ah[m], bh[n], acc[m][n], 0, 0, 0);
                acc[m][n] = __builtin_amdgcn_mfma_f32_16x16x32_bf16(ah[m], bl[n], acc[m][n], 0, 0, 0);
                acc[m][n] = __builtin_amdgcn_mfma_f32_16x16x32_bf16(al[m], bh[n], acc[m][n], 0, 0, 0);
            }
    }

    const int fr = lane & 15, fq = lane >> 4;
    const int n0 = by * 64;
    #pragma unroll
    for (int m = 0; m < 2; m++) {
        #pragma unroll
        for (int rr = 0; rr < 4; rr++) {
            int row = m0 + wr * 32 + m * 16 + fq * 4 + rr;
            if (row >= M) continue;
            #pragma unroll
            for (int n = 0; n < 2; n++) {
                int col = n0 + wc * 32 + n * 16 + fr;
                float v = acc[m][n][rr];
                size_t ci = (size_t)row * ldc + col;
                ((float*)Cv)[ci] = v + bias[col] + res[ci];
            }
        }
    }
}

// ---------------- MFMA flash attention: K/Vt pre-split images via glds ----------------
__global__ __launch_bounds__(256) void attn_glds(const float* __restrict__ Qb,
        const unsigned short* __restrict__ Kimg, const unsigned short* __restrict__ Vimg,
        float* __restrict__ att) {
    int bx, by, bz;
    xcd_map(bx, by, bz);
    const int b = bz, h = by, q0 = bx * 64;
    const int t = threadIdx.x;
    const int lane = t & 63, wid = t >> 6;
    const int fr = lane & 15, kg = lane >> 4;
    __shared__ unsigned short Khl[64 * 128];
    __shared__ unsigned short Vt[64 * 128];
    __shared__ unsigned char Pbuf[16384];
    unsigned char* KhlB = (unsigned char*)Khl;
    unsigned char* VtB = (unsigned char*)Vt;
    unsigned char* PwB = Pbuf + wid * 4096;
    const unsigned char* KiB = (const unsigned char*)Kimg + (((size_t)b * NHEADS + h) * NKT << 14);
    const unsigned char* ViB = (const unsigned char*)Vimg + (((size_t)b * NHEADS + h) * NKT << 14);

    bf16x8 qh[2], qlo[2];
    {
        int qrow = q0 + wid * 16 + fr; qrow = qrow < SEQ ? qrow : SEQ - 1;
        const float* qbase = Qb + ((size_t)b * SEQ + qrow) * CDIM + h * DHEAD;
        #pragma unroll
        for (int ds = 0; ds < 2; ds++) {
            float tmp[8];
            *(float4*)(tmp)     = *(const float4*)(qbase + ds * 32 + kg * 8);
            *(float4*)(tmp + 4) = *(const float4*)(qbase + ds * 32 + kg * 8 + 4);
            #pragma unroll
            for (int j = 0; j < 8; j++) {
                unsigned short hh = f2bf(tmp[j]);
                qh[ds][j]  = (short)hh;
                qlo[ds][j] = (short)f2bf(tmp[j] - bf2f(hh));
            }
        }
    }

    f32x4 acc_o[4];
    #pragma unroll
    for (int i = 0; i < 4; i++) { f32x4 z = {0.f,0.f,0.f,0.f}; acc_o[i] = z; }
    float m_run[4] = {-1e30f, -1e30f, -1e30f, -1e30f};
    float l_run[4] = {0.f, 0.f, 0.f, 0.f};

    for (int kt = 0; kt < NKT; kt++) {
        const int c0 = kt * 64;
        __syncthreads();
        {
            const unsigned char* ki = KiB + ((size_t)kt << 14);
            const unsigned char* vi = ViB + ((size_t)kt << 14);
            #pragma unroll
            for (int i = 0; i < 4; i++) {
                int chunk = (i << 2) | wid;
                __builtin_amdgcn_global_load_lds((GAS_cv*)(ki + chunk * 1024 + lane * 16),
                    (LAS_v*)(KhlB + chunk * 1024), 16, 0, 0);
                __builtin_amdgcn_global_load_lds((GAS_cv*)(vi + chunk * 1024 + lane * 16),
                    (LAS_v*)(VtB + chunk * 1024), 16, 0, 0);
            }
        }
        __syncthreads();
        f32x4 s[4];
        #pragma unroll
        for (int i = 0; i < 4; i++) { f32x4 z = {0.f,0.f,0.f,0.f}; s[i] = z; }
        #pragma unroll
        for (int ds = 0; ds < 2; ds++) {
            #pragma unroll
            for (int n = 0; n < 4; n++) {
                int r = n * 16 + fr;
                int swz = (r & 7) << 4;
                const unsigned char* rb = KhlB + r * 256;
                bf16x8 kh = *(const bf16x8*)(rb + ((ds * 64 + kg * 16) ^ swz));
                bf16x8 kl = *(const bf16x8*)(rb + 128 + ((ds * 64 + kg * 16) ^ swz));
                s[n] = __builtin_amdgcn_mfma_f32_16x16x32_bf16(qh[ds], kh, s[n], 0, 0, 0);
                s[n] = __builtin_amdgcn_mfma_f32_16x16x32_bf16(qh[ds], kl, s[n], 0, 0, 0);
                s[n] = __builtin_amdgcn_mfma_f32_16x16x32_bf16(qlo[ds], kh, s[n], 0, 0, 0);
            }
        }
        float p[4][4];
        #pragma unroll
        for (int n = 0; n < 4; n++) {
            int kcol = c0 + n * 16 + fr;
            #pragma unroll
            for (int r = 0; r < 4; r++) {
                float sv = s[n][r] * 0.125f;
                if (kcol >= SEQ) sv = -1e30f;
                p[n][r] = sv;
            }
        }
        float corr[4];
        #pragma unroll
        for (int r = 0; r < 4; r++) {
            float mx = fmaxf(fmaxf(p[0][r], p[1][r]), fmaxf(p[2][r], p[3][r]));
            mx = fmaxf(mx, __shfl_xor(mx, 1));
            mx = fmaxf(mx, __shfl_xor(mx, 2));
            mx = fmaxf(mx, __shfl_xor(mx, 4));
            mx = fmaxf(mx, __shfl_xor(mx, 8));
            float mnew = fmaxf(m_run[r], mx);
            corr[r] = __expf(m_run[r] - mnew);
            m_run[r] = mnew;
            float ls = 0.f;
            #pragma unroll
            for (int n = 0; n < 4; n++) {
                p[n][r] = __expf(p[n][r] - mnew);
                ls += p[n][r];
            }
            ls += __shfl_xor(ls, 1);
            ls += __shfl_xor(ls, 2);
            ls += __shfl_xor(ls, 4);
            ls += __shfl_xor(ls, 8);
            l_run[r] = l_run[r] * corr[r] + ls;
        }
        #pragma unroll
        for (int nd = 0; nd < 4; nd++)
            #pragma unroll
            for (int r = 0; r < 4; r++)
                acc_o[nd][r] *= corr[r];
        {
            int qb = (lane >> 4) * 4;
            #pragma unroll
            for (int n = 0; n < 4; n++) {
                int kcol = n * 16 + fr;
                #pragma unroll
                for (int r = 0; r < 4; r++) {
                    int qq = qb + r;
                    unsigned short ph = f2bf(p[n][r]);
                    unsigned short pl = f2bf(p[n][r] - bf2f(ph));
                    int off = (kcol * 2) ^ ((qq & 7) << 4);
                    *(unsigned short*)(PwB + qq * 256 + off) = ph;
                    *(unsigned short*)(PwB + qq * 256 + 128 + off) = pl;
                }
            }
        }
        #pragma unroll
        for (int ks = 0; ks < 2; ks++) {
            int swzp = (fr & 7) << 4;
            bf16x8 pah = *(const bf16x8*)(PwB + fr * 256 + ((ks * 64 + kg * 16) ^ swzp));
            bf16x8 pal = *(const bf16x8*)(PwB + fr * 256 + 128 + ((ks * 64 + kg * 16) ^ swzp));
            #pragma unroll
            for (int nd = 0; nd < 4; nd++) {
                int rv = nd * 16 + fr;
                int swzv = (rv & 7) << 4;
                const unsigned char* rb = VtB + rv * 256;
                bf16x8 vh = *(const bf16x8*)(rb + ((ks * 64 + kg * 16) ^ swzv));
                bf16x8 vl = *(const bf16x8*)(rb + 128 + ((ks * 64 + kg * 16) ^ swzv));
                acc_o[nd] = __builtin_amdgcn_mfma_f32_16x16x32_bf16(pah, vh, acc_o[nd], 0, 0, 0);
                acc_o[nd] = __builtin_amdgcn_mfma_f32_16x16x32_bf16(pah, vl, acc_o[nd], 0, 0, 0);
                acc_o[nd] = __builtin_amdgcn_mfma_f32_16x16x32_bf16(pal, vh, acc_o[nd], 0, 0, 0);
            }
        }
    }
    #pragma unroll
    for (int r = 0; r < 4; r++) {
        int q = q0 + wid * 16 + (lane >> 4) * 4 + r;
        if (q >= SEQ) continue;
        float inv = 1.f / l_run[r];
        float* o = att + ((size_t)b * SEQ + q) * CDIM + h * DHEAD;
        #pragma unroll
        for (int nd = 0; nd < 4; nd++)
            o[nd * 16 + fr] = acc_o[nd][r] * inv;
    }
}

// ---------------- row max of symmetrized sim (excluding diagonal) ----------------
__global__ __launch_bounds__(64) void rowmax_kernel(const float* __restrict__ sim,
                                                    float* __restrict__ ms) {
    int row = blockIdx.x;
    int b = row / NIMG, n = row % NIMG;
    const float* sb = sim + (size_t)b * NIMG * NIMG;
    int lane = threadIdx.x;
    float mx = -1e30f;
    #pragma unroll
    for (int i = 0; i < NIMG / 64; i++) {
        int m = lane + i * 64;
        if (m != n) {
            float v = 0.5f * (sb[(size_t)n * NIMG + m] + sb[(size_t)m * NIMG + n]);
            mx = fmaxf(mx, v);
        }
    }
    #pragma unroll
    for (int o = 32; o; o >>= 1) mx = fmaxf(mx, __shfl_down(mx, o));
    if (lane == 0) ms[row] = mx;
}

// ---------------- exact top-k selection with lax.top_k tie semantics ----------------
__global__ __launch_bounds__(576) void select_kernel(const float* __restrict__ ms,
        int* __restrict__ mergemask, int* __restrict__ keeppos) {
    __shared__ float v[NIMG];
    __shared__ int keepf[NIMG];
    int b = blockIdx.x;
    int n = threadIdx.x;
    v[n] = ms[b * NIMG + n];
    __syncthreads();
    float vn = v[n];
    int rank_desc = 0, rank_asc = 0;
    for (int m = 0; m < NIMG; m++) {
        float vm = v[m];
        int tie_lo = (vm == vn && m < n);
        rank_desc += (vm > vn) || tie_lo;
        rank_asc  += (vm < vn) || tie_lo;
    }
    int merge = rank_desc < NMERGE;
    int keep  = rank_asc  < NMERGE;
    mergemask[b * NIMG + n] = merge;
    keepf[n] = keep;
    __syncthreads();
    if (keep) {
        int pos = 0;
        for (int m = 0; m < n; m++) pos += keepf[m];
        keeppos[b * NIMG + n] = pos;
    } else {
        keeppos[b * NIMG + n] = -1;
    }
}

// ---------------- average of merged tokens (parallelized) ----------------
__global__ __launch_bounds__(256) void avg_kernel(const float* __restrict__ x2,
        const int* __restrict__ mask, float* __restrict__ avg) {
    __shared__ float4 red[8][33];
    int b = blockIdx.x, cc = blockIdx.y;
    int t = threadIdx.x;
    int rr = t >> 5, c4 = t & 31;
    int c = cc * 128 + c4 * 4;
    const int* mb = mask + b * NIMG;
    float4 s = make_float4(0.f, 0.f, 0.f, 0.f);
    for (int n = rr; n < NIMG; n += 8) {
        if (mb[n]) {
            float4 v = *(const float4*)(x2 + ((size_t)b * SEQ + 1 + n) * CDIM + c);
            s.x += v.x; s.y += v.y; s.z += v.z; s.w += v.w;
        }
    }
    red[rr][c4] = s;
    __syncthreads();
    if (rr == 0) {
        float4 tot = red[0][c4];
        #pragma unroll
        for (int i = 1; i < 8; i++) {
            float4 v = red[i][c4];
            tot.x += v.x; tot.y += v.y; tot.z += v.z; tot.w += v.w;
        }
        float sc1 = 1.f / (float)NMERGE, sc2 = 1.f / (float)(NIMG - NMERGE);
        tot.x = (tot.x * sc1) * sc2; tot.y = (tot.y * sc1) * sc2;
        tot.z = (tot.z * sc1) * sc2; tot.w = (tot.w * sc1) * sc2;
        *(float4*)(avg + (size_t)b * CDIM + c) = tot;
    }
}

// ---------------- assemble output ----------------
__global__ __launch_bounds__(192) void assemble_kernel(const float* __restrict__ x2,
        const int* __restrict__ keeppos, const float* __restrict__ avg,
        float* __restrict__ out) {
    int g = blockIdx.x;
    int b = g / SEQ, s_ = g % SEQ;
    int t = threadIdx.x;
    const float4* src = (const float4*)(x2 + (size_t)g * CDIM);
    if (s_ == 0) {
        float4* dst = (float4*)(out + (size_t)b * 289 * CDIM);
        dst[t] = src[t];
    } else {
        int n = s_ - 1;
        int pos = keeppos[b * NIMG + n];
        if (pos < 0) return;
        const float4* av = (const float4*)(avg + (size_t)b * CDIM);
        float4 v = src[t], a = av[t];
        v.x += a.x; v.y += a.y; v.z += a.z; v.w += a.w;
        float4* dst = (float4*)(out + ((size_t)b * 289 + 1 + pos) * CDIM);
        dst[t] = v;
    }
}

extern "C" void kernel_launch(void* const* d_in, const int* in_sizes, int n_in,
                              void* d_out, int out_size, void* d_ws, size_t ws_size,
                              hipStream_t stream) {
    const float* x      = (const float*)d_in[0];
    const float* qkv_w  = (const float*)d_in[1];
    const float* qkv_b  = (const float*)d_in[2];
    const float* proj_w = (const float*)d_in[3];
    const float* proj_b = (const float*)d_in[4];
    const float* ln1_g  = (const float*)d_in[5];
    const float* ln1_b  = (const float*)d_in[6];
    const float* ln2_g  = (const float*)d_in[7];
    const float* ln2_b  = (const float*)d_in[8];
    const float* fc1_w  = (const float*)d_in[9];
    const float* fc1_b  = (const float*)d_in[10];
    const float* fc2_w  = (const float*)d_in[11];
    const float* fc2_b  = (const float*)d_in[12];

    if (ws_size < NEED_BYTES) return;

    float* ws   = (float*)d_ws;
    float* bh   = ws + O_BH;                       // h images -> x1/x2 fp32
    float* ba   = ws + O_BA;                       // att -> h2 images -> xn images
    float* bq   = ws + O_BQ;                       // Q rows / fc1o images / sim half
    float* qbuf = ws + O_BQ;
    unsigned short* kimg = (unsigned short*)(ws + O_KIMG);
    unsigned short* vimg = (unsigned short*)(ws + O_VIMG);
    float* ms   = ws + O_MS;
    int*   mask = (int*)(ws + O_MASK);
    int*   pos  = (int*)(ws + O_POS);
    float* avg  = ws + O_AVG;
    float* outp = (float*)d_out;

    unsigned short* himg  = (unsigned short*)bh;
    unsigned short* h2img = (unsigned short*)ba;
    unsigned short* xnimg = (unsigned short*)ba;
    unsigned short* fopl  = (unsigned short*)bq;

    unsigned short* qkvp  = (unsigned short*)(outp + OW_QKV);
    unsigned short* fc1p  = (unsigned short*)(outp + OW_FC1);
    unsigned short* fc2p  = (unsigned short*)(outp + OW_FC2);
    unsigned short* projp = (unsigned short*)(outp + OW_PROJ);

    // 0. split weights; zero V-image scratch
    wsplit_kernel<<<18 * 24, 256, 0, stream>>>(qkv_w, qkvp, 24, CDIM);
    wsplit_kernel<<<24 * 24, 256, 0, stream>>>(fc1_w, fc1p, 24, CDIM);
    wsplit_kernel<<<6 * 96, 256, 0, stream>>>(fc2_w, fc2p, 96, 3072);
    wsplit_kernel<<<6 * 24, 256, 0, stream>>>(proj_w, projp, 24, CDIM);
    hipMemsetAsync(vimg, 0, SZ_IMG * 4, stream);

    // 1. h = LN1(x) -> group-padded plane images in BH (37 imgrows/group)
    ln_split<<<MTOK, 256, 0, stream>>>(x, ln1_g, ln1_b, himg, MGRP, 37);

    // 2. per-group qkv (dual-glds, scatter epilogue) + attention
    for (int g = 0; g < NGROUP; g++) {
        float* attg = ba + (size_t)g * MGRP * CDIM;
        gemm_ppx<6><<<dim3(73, 36), 256, 0, stream>>>(
            himg + (size_t)g * 37 * 24 * 8192, qkvp, (void*)qbuf, 3 * CDIM,
            qkv_b, nullptr, MGRP, 3 * CDIM, CDIM, 0, 0, kimg, vimg);
        attn_glds<<<dim3(NKT, NHEADS, GB), 256, 0, stream>>>(
            qbuf, kimg, vimg, attg);
    }

    // 3. x1 = x + att @ proj_w^T + proj_b (fused-A, 64x64) -> BH fp32 (h images dead)
    gemm_wp<1><<<dim3((MTOK + 63) / 64, 12), 256, 0, stream>>>(
        ba, CDIM, projp, 24, (void*)bh, CDIM, proj_b, x, MTOK, CDIM, CDIM);

    // 4. h2 = LN2(x1) -> global plane images in BA (att dead)
    ln_split<<<MTOK, 256, 0, stream>>>(bh, ln2_g, ln2_b, h2img, MTOK, 145);

    // 5. MLP chunks (MLPCH = 27x128, so image halves align): fc1 dual-glds
    //    (gelu -> fc1o images in BQ), fc2 dual-glds (+res in-place BH)
    for (int c0 = 0; c0 < MTOK; c0 += MLPCH) {
        int mc = (MTOK - c0 < MLPCH) ? (MTOK - c0) : MLPCH;
        float* x1c = bh + (size_t)c0 * CDIM;
        gemm_ppx<5><<<dim3((mc + 63) / 64, 48), 256, 0, stream>>>(
            h2img + (size_t)(c0 >> 7) * 24 * 8192, fc1p, (void*)fopl, 3072,
            fc1_b, nullptr, mc, 3072, CDIM, 0, 0, nullptr, nullptr);
        gemm_ppx<1><<<dim3((mc + 63) / 64, 12), 256, 0, stream>>>(
            fopl, fc2p, (void*)x1c, CDIM, fc2_b, x1c,
            mc, CDIM, 3072, 0, 0, nullptr, nullptr);
    }

    // 6-8. two batch-halves: xn images -> batched sim (dual-glds) -> rowmax
    for (int hf = 0; hf < 2; hf++) {
        xn_split<<<16 * NIMG, 256, 0, stream>>>(bh, xnimg, hf * 16);
        gemm_ppx<4><<<dim3(9, 9, 16), 256, 0, stream>>>(
            xnimg, xnimg, (void*)bq, NIMG, nullptr, nullptr,
            NIMG, NIMG, CDIM, 5 * 24, (long long)NIMG * NIMG, nullptr, nullptr);
        rowmax_kernel<<<16 * NIMG, 64, 0, stream>>>(bq, ms + (size_t)hf * 16 * NIMG);
    }

    // 9-11. selection, merged average, assemble
    select_kernel<<<NBATCH, NIMG, 0, stream>>>(ms, mask, pos);
    avg_kernel<<<dim3(NBATCH, 6), 256, 0, stream>>>(bh, mask, avg);
    assemble_kernel<<<MTOK, 192, 0, stream>>>(bh, pos, avg, outp);
}

// Round 18
// 1680.825 us; speedup vs baseline: 3.9803x; 1.0085x over previous
//
#include <hip/hip_runtime.h>
#include <math.h>

#define CDIM 768
#define NHEADS 12
#define DHEAD 64
#define SEQ 577
#define NBATCH 32
#define MTOK (NBATCH*SEQ)      // 18464
#define NIMG 576
#define NMERGE 288
#define GB 8                   // batches per qkv group
#define NGROUP (NBATCH/GB)     // 4
#define MGRP (GB*SEQ)          // 4616 rows per group
#define MLPCH 3456             // MLP chunk rows (27x128)
#define NKT 10                 // k-tiles per (b,h) in attention

// ---- workspace layout (float offsets), peak ~161.2 MB ----
#define SZ_BH   ((size_t)4*37*24*4096)           // 14,548,992  h images / x1/x2 fp32
#define O_BH    ((size_t)0)
#define O_BA    (SZ_BH)                          // att images / h2 images / xn images
#define SZ_BA   ((size_t)145*24*4096)            // 14,254,080
#define O_BQ    (O_BA + SZ_BA)                   // Q rows + K/V images / fc1o images / sim half
#define SZ_Q    ((size_t)MGRP*CDIM)              // 3,545,088
#define SZ_IMG  ((size_t)GB*NHEADS*NKT*4096)     // 3,932,160
#define O_KIMG  (O_BQ + SZ_Q)
#define O_VIMG  (O_KIMG + SZ_IMG)
#define O_SM    (O_VIMG + SZ_IMG)
#define O_MS    (O_SM)
#define O_MASK  (O_SM + (size_t)NBATCH*NIMG)
#define O_POS   (O_MASK + (size_t)NBATCH*NIMG)
#define O_AVG   (O_POS + (size_t)NBATCH*NIMG)
#define O_END   (O_AVG + (size_t)NBATCH*CDIM)
#define NEED_BYTES (O_END * 4)

// ---- weight-plane scratch inside d_out ----
#define OW_QKV  ((size_t)0)           // 18nt*24ks = 1,769,472 floats
#define OW_FC1  ((size_t)1769472)     // 24nt*24ks = 2,359,296 floats
#define OW_FC2  ((size_t)4128768)     // 6nt*96ks  = 2,359,296 floats
#define OW_PROJ ((size_t)6488064)     // 6nt*24ks  =   589,824 floats

typedef __attribute__((ext_vector_type(8))) short bf16x8;
typedef __attribute__((ext_vector_type(4))) float f32x4;
typedef __attribute__((address_space(1))) const void GAS_cv;
typedef __attribute__((address_space(3))) void LAS_v;

#define RAW_BAR() do { asm volatile("" ::: "memory"); \
    __builtin_amdgcn_s_barrier(); asm volatile("" ::: "memory"); } while (0)

__device__ __forceinline__ unsigned short f2bf(float f) {
    unsigned int u = __float_as_uint(f);
    u += 0x7fff + ((u >> 16) & 1);           // RNE
    return (unsigned short)(u >> 16);
}
__device__ __forceinline__ float bf2f(unsigned short h) {
    return __uint_as_float(((unsigned int)h) << 16);
}

// ---- bijective XCD chunk remaps (m204) ----
__device__ __forceinline__ void xcd_map(int& bx, int& by, int& bz) {
    int gx = gridDim.x, gy = gridDim.y;
    int nwg = gx * gy * gridDim.z;
    int orig = blockIdx.x + gx * (blockIdx.y + gy * blockIdx.z);
    int q = nwg >> 3, r = nwg & 7;
    int xcd = orig & 7, pos = orig >> 3;
    int wg = (xcd < r ? xcd * (q + 1) : r * (q + 1) + (xcd - r) * q) + pos;
    bx = wg % gx;
    int t2 = wg / gx;
    by = t2 % gy;
    bz = t2 / gy;
}
__device__ __forceinline__ void xcd_map_nf(int& bx, int& by, int& bz) {
    int gx = gridDim.x, gy = gridDim.y;
    int nwg = gx * gy * gridDim.z;
    int orig = blockIdx.x + gx * (blockIdx.y + gy * blockIdx.z);
    int q = nwg >> 3, r = nwg & 7;
    int xcd = orig & 7, pos = orig >> 3;
    int wg = (xcd < r ? xcd * (q + 1) : r * (q + 1) + (xcd - r) * q) + pos;
    by = wg % gy;
    int t2 = wg / gy;
    bx = t2 % gx;
    bz = t2 / gx;
}

// ---------------- block reduce (256 threads) ----------------
__device__ __forceinline__ float blk_sum256(float v, float* red) {
    #pragma unroll
    for (int o = 32; o; o >>= 1) v += __shfl_down(v, o);
    if ((threadIdx.x & 63) == 0) red[threadIdx.x >> 6] = v;
    __syncthreads();
    float tot = red[0] + red[1] + red[2] + red[3];
    __syncthreads();
    return tot;
}

// ---------------- LayerNorm -> bf16 hi/lo plane IMAGES ----------------
__global__ __launch_bounds__(256) void ln_split(const float* __restrict__ x,
        const float* __restrict__ g, const float* __restrict__ b,
        unsigned short* __restrict__ img, int rows_per_grp, int imgrows_per_grp) {
    __shared__ float red[4];
    int row = blockIdx.x;
    const float* xr = x + (size_t)row * CDIM;
    int t = threadIdx.x;
    float v0 = xr[t], v1 = xr[t + 256], v2 = xr[t + 512];
    float mu = blk_sum256(v0 + v1 + v2, red) * (1.f / CDIM);
    float d0 = v0 - mu, d1 = v1 - mu, d2 = v2 - mu;
    float var = blk_sum256(d0 * d0 + d1 * d1 + d2 * d2, red) * (1.f / CDIM);
    float e = var + 1e-5f;
    float rs = rsqrtf(e);
    rs = rs * (1.5f - 0.5f * e * rs * rs);
    float vals[3] = {d0 * rs * g[t] + b[t],
                     d1 * rs * g[t + 256] + b[t + 256],
                     d2 * rs * g[t + 512] + b[t + 512]};
    int grp = row / rows_per_grp;
    int local = row - grp * rows_per_grp;
    int r2 = local & 127;
    size_t ibase = ((size_t)grp * imgrows_per_grp + (local >> 7)) * 24;
    int swz = (r2 & 7) << 4;
    #pragma unroll
    for (int cc = 0; cc < 3; cc++) {
        int col = t + cc * 256;
        int ks = col >> 5, kc = col & 31;
        unsigned char* ip = (unsigned char*)img + ((ibase + ks) << 14) + r2 * 128;
        float v = vals[cc];
        unsigned short hh = f2bf(v);
        unsigned short ll = f2bf(v - bf2f(hh));
        *(unsigned short*)(ip + ((2 * kc) ^ swz)) = hh;
        *(unsigned short*)(ip + ((64 + 2 * kc) ^ swz)) = ll;
    }
}

// ---------------- normalize img tokens -> plane IMAGES (per batch-half) ------
__global__ __launch_bounds__(256) void xn_split(const float* __restrict__ x2,
        unsigned short* __restrict__ img, int b0) {
    __shared__ float red[4];
    int tok = blockIdx.x;
    int bl = tok / NIMG, n = tok % NIMG;
    const float* xr = x2 + ((size_t)(b0 + bl) * SEQ + 1 + n) * CDIM;
    int t = threadIdx.x;
    float v0 = xr[t], v1 = xr[t + 256], v2 = xr[t + 512];
    float ss = blk_sum256(v0 * v0 + v1 * v1 + v2 * v2, red);
    float nrm = fmaxf(sqrtf(ss), 1e-12f);
    float inv = 1.f / nrm;
    float vals[3] = {v0 * inv, v1 * inv, v2 * inv};
    int r2 = n & 127;
    size_t ibase = ((size_t)bl * 5 + (n >> 7)) * 24;
    int swz = (r2 & 7) << 4;
    #pragma unroll
    for (int cc = 0; cc < 3; cc++) {
        int col = t + cc * 256;
        int ks = col >> 5, kc = col & 31;
        unsigned char* ip = (unsigned char*)img + ((ibase + ks) << 14) + r2 * 128;
        float v = vals[cc];
        unsigned short hh = f2bf(v);
        unsigned short ll = f2bf(v - bf2f(hh));
        *(unsigned short*)(ip + ((2 * kc) ^ swz)) = hh;
        *(unsigned short*)(ip + ((64 + 2 * kc) ^ swz)) = ll;
    }
}

// ---------------- weight split: fp32 -> bf16 hi/lo LDS-image planes ----------------
__global__ __launch_bounds__(256) void wsplit_kernel(const float* __restrict__ w,
        unsigned short* __restrict__ wp, int nksteps, int ldw) {
    int bid = blockIdx.x;
    int nt = bid / nksteps, ks = bid % nksteps;
    int t = threadIdx.x;
    int srow = t >> 3, sj = t & 7;
    unsigned short* img = wp + ((size_t)bid << 13);
    #pragma unroll
    for (int i = 0; i < 4; i++) {
        int r = srow + i * 32;
        float4 v = *(const float4*)(w + (size_t)(nt * 128 + r) * ldw + ks * 32 + sj * 4);
        unsigned short h0 = f2bf(v.x), h1 = f2bf(v.y), h2 = f2bf(v.z), h3 = f2bf(v.w);
        ushort4 hv = make_ushort4(h0, h1, h2, h3);
        ushort4 lv = make_ushort4(f2bf(v.x - bf2f(h0)), f2bf(v.y - bf2f(h1)),
                                  f2bf(v.z - bf2f(h2)), f2bf(v.w - bf2f(h3)));
        int swz = (r & 7) << 4;
        int ohi = ((8 * sj) ^ swz) >> 1;
        int olo = ((64 + 8 * sj) ^ swz) >> 1;
        *(ushort4*)&img[r * 64 + ohi] = hv;
        *(ushort4*)&img[r * 64 + olo] = lv;
    }
}

// ---------------- GEMM, BOTH operands plane images, 64x64, counted-vmcnt ------
// EPI: 1 = +bias+res fp32 (res may alias C), 4 = plain fp32 (batched sim),
//      5 = gelu(+bias) -> plane images, 6 = qkv scatter (Q rows + K/Vt images)
template<int EPI>
__global__ __launch_bounds__(256)
void gemm_ppx(const unsigned short* __restrict__ Ap,
              const unsigned short* __restrict__ Bp,
              void* __restrict__ Cv, int ldc,
              const float* __restrict__ bias,
              const float* __restrict__ res,
              int M, int N, int K,
              long long aBatch, long long cBatch,
              unsigned short* __restrict__ Kimg,
              unsigned short* __restrict__ Vimg) {
    __shared__ unsigned short Asl[2][64 * 64];
    __shared__ unsigned short Bsl[2][64 * 64];
    int bx, by, bz;
    xcd_map_nf(bx, by, bz);
    const int t = threadIdx.x;
    const int lane = t & 63, wid = t >> 6;
    const int wr = wid >> 1, wc = wid & 1;
    const unsigned char* ApB = (const unsigned char*)(Ap + ((size_t)bz * aBatch << 13));
    const unsigned char* BpB = (const unsigned char*)(Bp + ((size_t)bz * aBatch << 13));
    float* C = (float*)Cv + (EPI == 4 ? (size_t)bz * cBatch : 0);

    f32x4 acc[2][2];
    #pragma unroll
    for (int i = 0; i < 2; i++)
        #pragma unroll
        for (int j = 0; j < 2; j++) {
            f32x4 z = {0.f, 0.f, 0.f, 0.f};
            acc[i][j] = z;
        }

    const int nsteps = K >> 5;
    const size_t offA = ((size_t)(bx >> 1) * nsteps << 14) + ((size_t)(bx & 1) << 13);
    const size_t offB = ((size_t)(by >> 1) * nsteps << 14) + ((size_t)(by & 1) << 13);
    {
        #pragma unroll
        for (int i = 0; i < 2; i++) {
            int chunk = (i << 2) | wid;
            __builtin_amdgcn_global_load_lds((GAS_cv*)(ApB + offA + chunk * 1024 + lane * 16),
                (LAS_v*)((unsigned char*)Asl[0] + chunk * 1024), 16, 0, 0);
            __builtin_amdgcn_global_load_lds((GAS_cv*)(BpB + offB + chunk * 1024 + lane * 16),
                (LAS_v*)((unsigned char*)Bsl[0] + chunk * 1024), 16, 0, 0);
        }
    }
    for (int ks = 0; ks < nsteps; ks++) {
        const int kn = (ks + 1 < nsteps) ? ks + 1 : nsteps - 1;   // clamp: vmcnt const
        RAW_BAR();
        {
            const unsigned char* imgA = ApB + offA + ((size_t)kn << 14);
            const unsigned char* imgB = BpB + offB + ((size_t)kn << 14);
            #pragma unroll
            for (int i = 0; i < 2; i++) {
                int chunk = (i << 2) | wid;
                __builtin_amdgcn_global_load_lds((GAS_cv*)(imgA + chunk * 1024 + lane * 16),
                    (LAS_v*)((unsigned char*)Asl[(ks + 1) & 1] + chunk * 1024), 16, 0, 0);
                __builtin_amdgcn_global_load_lds((GAS_cv*)(imgB + chunk * 1024 + lane * 16),
                    (LAS_v*)((unsigned char*)Bsl[(ks + 1) & 1] + chunk * 1024), 16, 0, 0);
            }
        }
        asm volatile("s_waitcnt vmcnt(4)" ::: "memory");
        __builtin_amdgcn_sched_barrier(0);
        RAW_BAR();
        const int fr = lane & 15, kg = lane >> 4;
        bf16x8 ah[2], al[2], bh[2], bl[2];
        #pragma unroll
        for (int m = 0; m < 2; m++) {
            int r = wr * 32 + m * 16 + fr;
            int swz = (r & 7) << 4;
            const unsigned char* base = (const unsigned char*)Asl[ks & 1] + r * 128;
            ah[m] = *(const bf16x8*)(base + ((16 * kg) ^ swz));
            al[m] = *(const bf16x8*)(base + ((64 + 16 * kg) ^ swz));
        }
        #pragma unroll
        for (int n = 0; n < 2; n++) {
            int r = wc * 32 + n * 16 + fr;
            int swz = (r & 7) << 4;
            const unsigned char* base = (const unsigned char*)Bsl[ks & 1] + r * 128;
            bh[n] = *(const bf16x8*)(base + ((16 * kg) ^ swz));
            bl[n] = *(const bf16x8*)(base + ((64 + 16 * kg) ^ swz));
        }
        #pragma unroll
        for (int m = 0; m < 2; m++)
            #pragma unroll
            for (int n = 0; n < 2; n++) {
                acc[m][n] = __builtin_amdgcn_mfma_f32_16x16x32_bf16(ah[m], bh[n], acc[m][n], 0, 0, 0);
                acc[m][n] = __builtin_amdgcn_mfma_f32_16x16x32_bf16(ah[m], bl[n], acc[m][n], 0, 0, 0);
                acc[m][n] = __builtin_amdgcn_mfma_f32_16x16x32_bf16(al[m], bh[n], acc[m][n], 0, 0, 0);
            }
    }

    const int fr = lane & 15, fq = lane >> 4;
    const int m0 = bx * 64, n0 = by * 64;
    #pragma unroll
    for (int m = 0; m < 2; m++) {
        #pragma unroll
        for (int rr = 0; rr < 4; rr++) {
            int row = m0 + wr * 32 + m * 16 + fq * 4 + rr;
            if (row >= M) continue;
            #pragma unroll
            for (int n = 0; n < 2; n++) {
                int col = n0 + wc * 32 + n * 16 + fr;
                float v = acc[m][n][rr];
                size_t ci = (size_t)row * ldc + col;
                if (EPI == 1) {
                    C[ci] = v + bias[col] + res[ci];
                } else if (EPI == 4) {
                    C[ci] = v;
                } else if (EPI == 5) {
                    v += bias[col];
                    v = 0.5f * v * (1.0f + erff(v * 0.70710678118654752f));
                    unsigned short hh = f2bf(v);
                    unsigned short ll = f2bf(v - bf2f(hh));
                    unsigned char* img = (unsigned char*)Cv +
                        (((size_t)(row >> 7) * (ldc >> 5) + (col >> 5)) << 14);
                    int r2 = row & 127, swz2 = (r2 & 7) << 4, kc = col & 31;
                    *(unsigned short*)(img + r2 * 128 + ((2 * kc) ^ swz2)) = hh;
                    *(unsigned short*)(img + r2 * 128 + ((64 + 2 * kc) ^ swz2)) = ll;
                } else { // 6: qkv scatter (head = (col>>6)-12 for K, -24 for V)
                    float v2 = v + bias[col];
                    if (col < 768) {
                        ((float*)Cv)[(size_t)row * 768 + col] = v2;
                    } else {
                        int b_local = row / SEQ;
                        int s = row - b_local * SEQ;
                        int dloc = col & 63;
                        int kt = s >> 6, r2 = s & 63;
                        unsigned short hh = f2bf(v2);
                        unsigned short ll = f2bf(v2 - bf2f(hh));
                        if (col < 1536) {
                            int hh_i = (col >> 6) - 12;
                            size_t imgi = (((size_t)b_local * NHEADS + hh_i) * NKT + kt) << 14;
                            unsigned char* img = (unsigned char*)Kimg + imgi;
                            int off = (2 * dloc) ^ ((r2 & 7) << 4);
                            *(unsigned short*)(img + r2 * 256 + off) = hh;
                            *(unsigned short*)(img + r2 * 256 + 128 + off) = ll;
                        } else {
                            int hh_i = (col >> 6) - 24;
                            size_t imgi = (((size_t)b_local * NHEADS + hh_i) * NKT + kt) << 14;
                            unsigned char* img = (unsigned char*)Vimg + imgi;
                            int off = (2 * r2) ^ ((dloc & 7) << 4);
                            *(unsigned short*)(img + dloc * 256 + off) = hh;
                            *(unsigned short*)(img + dloc * 256 + 128 + off) = ll;
                        }
                    }
                }
            }
        }
    }
}

// ---------------- MFMA flash attention: K/Vt images in, O images out ----------------
// Output written directly as plane images (row = row0 + bz*SEQ + q, col = h*64+d),
// byte-identical to what the fused-convert proj staging would have built.
__global__ __launch_bounds__(256) void attn_glds(const float* __restrict__ Qb,
        const unsigned short* __restrict__ Kimg, const unsigned short* __restrict__ Vimg,
        unsigned short* __restrict__ attimg, int row0) {
    int bx, by, bz;
    xcd_map(bx, by, bz);
    const int b = bz, h = by, q0 = bx * 64;
    const int t = threadIdx.x;
    const int lane = t & 63, wid = t >> 6;
    const int fr = lane & 15, kg = lane >> 4;
    __shared__ unsigned short Khl[64 * 128];
    __shared__ unsigned short Vt[64 * 128];
    __shared__ unsigned char Pbuf[16384];
    unsigned char* KhlB = (unsigned char*)Khl;
    unsigned char* VtB = (unsigned char*)Vt;
    unsigned char* PwB = Pbuf + wid * 4096;
    const unsigned char* KiB = (const unsigned char*)Kimg + (((size_t)b * NHEADS + h) * NKT << 14);
    const unsigned char* ViB = (const unsigned char*)Vimg + (((size_t)b * NHEADS + h) * NKT << 14);

    bf16x8 qh[2], qlo[2];
    {
        int qrow = q0 + wid * 16 + fr; qrow = qrow < SEQ ? qrow : SEQ - 1;
        const float* qbase = Qb + ((size_t)b * SEQ + qrow) * CDIM + h * DHEAD;
        #pragma unroll
        for (int ds = 0; ds < 2; ds++) {
            float tmp[8];
            *(float4*)(tmp)     = *(const float4*)(qbase + ds * 32 + kg * 8);
            *(float4*)(tmp + 4) = *(const float4*)(qbase + ds * 32 + kg * 8 + 4);
            #pragma unroll
            for (int j = 0; j < 8; j++) {
                unsigned short hh = f2bf(tmp[j]);
                qh[ds][j]  = (short)hh;
                qlo[ds][j] = (short)f2bf(tmp[j] - bf2f(hh));
            }
        }
    }

    f32x4 acc_o[4];
    #pragma unroll
    for (int i = 0; i < 4; i++) { f32x4 z = {0.f,0.f,0.f,0.f}; acc_o[i] = z; }
    float m_run[4] = {-1e30f, -1e30f, -1e30f, -1e30f};
    float l_run[4] = {0.f, 0.f, 0.f, 0.f};

    for (int kt = 0; kt < NKT; kt++) {
        const int c0 = kt * 64;
        __syncthreads();
        {
            const unsigned char* ki = KiB + ((size_t)kt << 14);
            const unsigned char* vi = ViB + ((size_t)kt << 14);
            #pragma unroll
            for (int i = 0; i < 4; i++) {
                int chunk = (i << 2) | wid;
                __builtin_amdgcn_global_load_lds((GAS_cv*)(ki + chunk * 1024 + lane * 16),
                    (LAS_v*)(KhlB + chunk * 1024), 16, 0, 0);
                __builtin_amdgcn_global_load_lds((GAS_cv*)(vi + chunk * 1024 + lane * 16),
                    (LAS_v*)(VtB + chunk * 1024), 16, 0, 0);
            }
        }
        __syncthreads();
        f32x4 s[4];
        #pragma unroll
        for (int i = 0; i < 4; i++) { f32x4 z = {0.f,0.f,0.f,0.f}; s[i] = z; }
        #pragma unroll
        for (int ds = 0; ds < 2; ds++) {
            #pragma unroll
            for (int n = 0; n < 4; n++) {
                int r = n * 16 + fr;
                int swz = (r & 7) << 4;
                const unsigned char* rb = KhlB + r * 256;
                bf16x8 kh = *(const bf16x8*)(rb + ((ds * 64 + kg * 16) ^ swz));
                bf16x8 kl = *(const bf16x8*)(rb + 128 + ((ds * 64 + kg * 16) ^ swz));
                s[n] = __builtin_amdgcn_mfma_f32_16x16x32_bf16(qh[ds], kh, s[n], 0, 0, 0);
                s[n] = __builtin_amdgcn_mfma_f32_16x16x32_bf16(qh[ds], kl, s[n], 0, 0, 0);
                s[n] = __builtin_amdgcn_mfma_f32_16x16x32_bf16(qlo[ds], kh, s[n], 0, 0, 0);
            }
        }
        float p[4][4];
        #pragma unroll
        for (int n = 0; n < 4; n++) {
            int kcol = c0 + n * 16 + fr;
            #pragma unroll
            for (int r = 0; r < 4; r++) {
                float sv = s[n][r] * 0.125f;
                if (kcol >= SEQ) sv = -1e30f;
                p[n][r] = sv;
            }
        }
        float corr[4];
        #pragma unroll
        for (int r = 0; r < 4; r++) {
            float mx = fmaxf(fmaxf(p[0][r], p[1][r]), fmaxf(p[2][r], p[3][r]));
            mx = fmaxf(mx, __shfl_xor(mx, 1));
            mx = fmaxf(mx, __shfl_xor(mx, 2));
            mx = fmaxf(mx, __shfl_xor(mx, 4));
            mx = fmaxf(mx, __shfl_xor(mx, 8));
            float mnew = fmaxf(m_run[r], mx);
            corr[r] = __expf(m_run[r] - mnew);
            m_run[r] = mnew;
            float ls = 0.f;
            #pragma unroll
            for (int n = 0; n < 4; n++) {
                p[n][r] = __expf(p[n][r] - mnew);
                ls += p[n][r];
            }
            ls += __shfl_xor(ls, 1);
            ls += __shfl_xor(ls, 2);
            ls += __shfl_xor(ls, 4);
            ls += __shfl_xor(ls, 8);
            l_run[r] = l_run[r] * corr[r] + ls;
        }
        #pragma unroll
        for (int nd = 0; nd < 4; nd++)
            #pragma unroll
            for (int r = 0; r < 4; r++)
                acc_o[nd][r] *= corr[r];
        {
            int qb = (lane >> 4) * 4;
            #pragma unroll
            for (int n = 0; n < 4; n++) {
                int kcol = n * 16 + fr;
                #pragma unroll
                for (int r = 0; r < 4; r++) {
                    int qq = qb + r;
                    unsigned short ph = f2bf(p[n][r]);
                    unsigned short pl = f2bf(p[n][r] - bf2f(ph));
                    int off = (kcol * 2) ^ ((qq & 7) << 4);
                    *(unsigned short*)(PwB + qq * 256 + off) = ph;
                    *(unsigned short*)(PwB + qq * 256 + 128 + off) = pl;
                }
            }
        }
        #pragma unroll
        for (int ks = 0; ks < 2; ks++) {
            int swzp = (fr & 7) << 4;
            bf16x8 pah = *(const bf16x8*)(PwB + fr * 256 + ((ks * 64 + kg * 16) ^ swzp));
            bf16x8 pal = *(const bf16x8*)(PwB + fr * 256 + 128 + ((ks * 64 + kg * 16) ^ swzp));
            #pragma unroll
            for (int nd = 0; nd < 4; nd++) {
                int rv = nd * 16 + fr;
                int swzv = (rv & 7) << 4;
                const unsigned char* rb = VtB + rv * 256;
                bf16x8 vh = *(const bf16x8*)(rb + ((ks * 64 + kg * 16) ^ swzv));
                bf16x8 vl = *(const bf16x8*)(rb + 128 + ((ks * 64 + kg * 16) ^ swzv));
                acc_o[nd] = __builtin_amdgcn_mfma_f32_16x16x32_bf16(pah, vh, acc_o[nd], 0, 0, 0);
                acc_o[nd] = __builtin_amdgcn_mfma_f32_16x16x32_bf16(pah, vl, acc_o[nd], 0, 0, 0);
                acc_o[nd] = __builtin_amdgcn_mfma_f32_16x16x32_bf16(pal, vh, acc_o[nd], 0, 0, 0);
            }
        }
    }
    // epilogue: O -> plane images (global row index)
    #pragma unroll
    for (int r = 0; r < 4; r++) {
        int q = q0 + wid * 16 + (lane >> 4) * 4 + r;
        if (q >= SEQ) continue;
        float inv = 1.f / l_run[r];
        int grow = row0 + b * SEQ + q;
        int r2 = grow & 127;
        size_t ibase = (size_t)(grow >> 7) * 24;
        int swz = (r2 & 7) << 4;
        #pragma unroll
        for (int nd = 0; nd < 4; nd++) {
            int col = h * DHEAD + nd * 16 + fr;
            float v = acc_o[nd][r] * inv;
            unsigned short hh = f2bf(v);
            unsigned short ll = f2bf(v - bf2f(hh));
            unsigned char* ip = (unsigned char*)attimg + ((ibase + (col >> 5)) << 14) + r2 * 128;
            int kc = col & 31;
            *(unsigned short*)(ip + ((2 * kc) ^ swz)) = hh;
            *(unsigned short*)(ip + ((64 + 2 * kc) ^ swz)) = ll;
        }
    }
}

// ---------------- row max of symmetrized sim (excluding diagonal) ----------------
__global__ __launch_bounds__(64) void rowmax_kernel(const float* __restrict__ sim,
                                                    float* __restrict__ ms) {
    int row = blockIdx.x;
    int b = row / NIMG, n = row % NIMG;
    const float* sb = sim + (size_t)b * NIMG * NIMG;
    int lane = threadIdx.x;
    float mx = -1e30f;
    #pragma unroll
    for (int i = 0; i < NIMG / 64; i++) {
        int m = lane + i * 64;
        if (m != n) {
            float v = 0.5f * (sb[(size_t)n * NIMG + m] + sb[(size_t)m * NIMG + n]);
            mx = fmaxf(mx, v);
        }
    }
    #pragma unroll
    for (int o = 32; o; o >>= 1) mx = fmaxf(mx, __shfl_down(mx, o));
    if (lane == 0) ms[row] = mx;
}

// ---------------- exact top-k selection with lax.top_k tie semantics ----------------
__global__ __launch_bounds__(576) void select_kernel(const float* __restrict__ ms,
        int* __restrict__ mergemask, int* __restrict__ keeppos) {
    __shared__ float v[NIMG];
    __shared__ int keepf[NIMG];
    int b = blockIdx.x;
    int n = threadIdx.x;
    v[n] = ms[b * NIMG + n];
    __syncthreads();
    float vn = v[n];
    int rank_desc = 0, rank_asc = 0;
    for (int m = 0; m < NIMG; m++) {
        float vm = v[m];
        int tie_lo = (vm == vn && m < n);
        rank_desc += (vm > vn) || tie_lo;
        rank_asc  += (vm < vn) || tie_lo;
    }
    int merge = rank_desc < NMERGE;
    int keep  = rank_asc  < NMERGE;
    mergemask[b * NIMG + n] = merge;
    keepf[n] = keep;
    __syncthreads();
    if (keep) {
        int pos = 0;
        for (int m = 0; m < n; m++) pos += keepf[m];
        keeppos[b * NIMG + n] = pos;
    } else {
        keeppos[b * NIMG + n] = -1;
    }
}

// ---------------- average of merged tokens (parallelized) ----------------
__global__ __launch_bounds__(256) void avg_kernel(const float* __restrict__ x2,
        const int* __restrict__ mask, float* __restrict__ avg) {
    __shared__ float4 red[8][33];
    int b = blockIdx.x, cc = blockIdx.y;
    int t = threadIdx.x;
    int rr = t >> 5, c4 = t & 31;
    int c = cc * 128 + c4 * 4;
    const int* mb = mask + b * NIMG;
    float4 s = make_float4(0.f, 0.f, 0.f, 0.f);
    for (int n = rr; n < NIMG; n += 8) {
        if (mb[n]) {
            float4 v = *(const float4*)(x2 + ((size_t)b * SEQ + 1 + n) * CDIM + c);
            s.x += v.x; s.y += v.y; s.z += v.z; s.w += v.w;
        }
    }
    red[rr][c4] = s;
    __syncthreads();
    if (rr == 0) {
        float4 tot = red[0][c4];
        #pragma unroll
        for (int i = 1; i < 8; i++) {
            float4 v = red[i][c4];
            tot.x += v.x; tot.y += v.y; tot.z += v.z; tot.w += v.w;
        }
        float sc1 = 1.f / (float)NMERGE, sc2 = 1.f / (float)(NIMG - NMERGE);
        tot.x = (tot.x * sc1) * sc2; tot.y = (tot.y * sc1) * sc2;
        tot.z = (tot.z * sc1) * sc2; tot.w = (tot.w * sc1) * sc2;
        *(float4*)(avg + (size_t)b * CDIM + c) = tot;
    }
}

// ---------------- assemble output ----------------
__global__ __launch_bounds__(192) void assemble_kernel(const float* __restrict__ x2,
        const int* __restrict__ keeppos, const float* __restrict__ avg,
        float* __restrict__ out) {
    int g = blockIdx.x;
    int b = g / SEQ, s_ = g % SEQ;
    int t = threadIdx.x;
    const float4* src = (const float4*)(x2 + (size_t)g * CDIM);
    if (s_ == 0) {
        float4* dst = (float4*)(out + (size_t)b * 289 * CDIM);
        dst[t] = src[t];
    } else {
        int n = s_ - 1;
        int pos = keeppos[b * NIMG + n];
        if (pos < 0) return;
        const float4* av = (const float4*)(avg + (size_t)b * CDIM);
        float4 v = src[t], a = av[t];
        v.x += a.x; v.y += a.y; v.z += a.z; v.w += a.w;
        float4* dst = (float4*)(out + ((size_t)b * 289 + 1 + pos) * CDIM);
        dst[t] = v;
    }
}

extern "C" void kernel_launch(void* const* d_in, const int* in_sizes, int n_in,
                              void* d_out, int out_size, void* d_ws, size_t ws_size,
                              hipStream_t stream) {
    const float* x      = (const float*)d_in[0];
    const float* qkv_w  = (const float*)d_in[1];
    const float* qkv_b  = (const float*)d_in[2];
    const float* proj_w = (const float*)d_in[3];
    const float* proj_b = (const float*)d_in[4];
    const float* ln1_g  = (const float*)d_in[5];
    const float* ln1_b  = (const float*)d_in[6];
    const float* ln2_g  = (const float*)d_in[7];
    const float* ln2_b  = (const float*)d_in[8];
    const float* fc1_w  = (const float*)d_in[9];
    const float* fc1_b  = (const float*)d_in[10];
    const float* fc2_w  = (const float*)d_in[11];
    const float* fc2_b  = (const float*)d_in[12];

    if (ws_size < NEED_BYTES) return;

    float* ws   = (float*)d_ws;
    float* bh   = ws + O_BH;                       // h images -> x1/x2 fp32
    float* ba   = ws + O_BA;                       // att images -> h2 images -> xn images
    float* bq   = ws + O_BQ;                       // Q rows / fc1o images / sim half
    float* qbuf = ws + O_BQ;
    unsigned short* kimg = (unsigned short*)(ws + O_KIMG);
    unsigned short* vimg = (unsigned short*)(ws + O_VIMG);
    float* ms   = ws + O_MS;
    int*   mask = (int*)(ws + O_MASK);
    int*   pos  = (int*)(ws + O_POS);
    float* avg  = ws + O_AVG;
    float* outp = (float*)d_out;

    unsigned short* himg   = (unsigned short*)bh;
    unsigned short* attimg = (unsigned short*)ba;
    unsigned short* h2img  = (unsigned short*)ba;
    unsigned short* xnimg  = (unsigned short*)ba;
    unsigned short* fopl   = (unsigned short*)bq;

    unsigned short* qkvp  = (unsigned short*)(outp + OW_QKV);
    unsigned short* fc1p  = (unsigned short*)(outp + OW_FC1);
    unsigned short* fc2p  = (unsigned short*)(outp + OW_FC2);
    unsigned short* projp = (unsigned short*)(outp + OW_PROJ);

    // 0. split weights; zero V-image scratch
    wsplit_kernel<<<18 * 24, 256, 0, stream>>>(qkv_w, qkvp, 24, CDIM);
    wsplit_kernel<<<24 * 24, 256, 0, stream>>>(fc1_w, fc1p, 24, CDIM);
    wsplit_kernel<<<6 * 96, 256, 0, stream>>>(fc2_w, fc2p, 96, 3072);
    wsplit_kernel<<<6 * 24, 256, 0, stream>>>(proj_w, projp, 24, CDIM);
    hipMemsetAsync(vimg, 0, SZ_IMG * 4, stream);

    // 1. h = LN1(x) -> group-padded plane images in BH (37 imgrows/group)
    ln_split<<<MTOK, 256, 0, stream>>>(x, ln1_g, ln1_b, himg, MGRP, 37);

    // 2. per-group qkv (dual-glds, scatter epilogue) + attention -> att images in BA
    for (int g = 0; g < NGROUP; g++) {
        gemm_ppx<6><<<dim3(73, 36), 256, 0, stream>>>(
            himg + (size_t)g * 37 * 24 * 8192, qkvp, (void*)qbuf, 3 * CDIM,
            qkv_b, nullptr, MGRP, 3 * CDIM, CDIM, 0, 0, kimg, vimg);
        attn_glds<<<dim3(NKT, NHEADS, GB), 256, 0, stream>>>(
            qbuf, kimg, vimg, attimg, g * MGRP);
    }

    // 3. x1 = x + att @ proj_w^T + proj_b (dual-glds) -> BH fp32 (h images dead)
    gemm_ppx<1><<<dim3((MTOK + 63) / 64, 12), 256, 0, stream>>>(
        attimg, projp, (void*)bh, CDIM, proj_b, x, MTOK, CDIM, CDIM,
        0, 0, nullptr, nullptr);

    // 4. h2 = LN2(x1) -> global plane images in BA (att images dead)
    ln_split<<<MTOK, 256, 0, stream>>>(bh, ln2_g, ln2_b, h2img, MTOK, 145);

    // 5. MLP chunks: fc1 dual-glds (gelu -> fc1o images), fc2 dual-glds (+res BH)
    for (int c0 = 0; c0 < MTOK; c0 += MLPCH) {
        int mc = (MTOK - c0 < MLPCH) ? (MTOK - c0) : MLPCH;
        float* x1c = bh + (size_t)c0 * CDIM;
        gemm_ppx<5><<<dim3((mc + 63) / 64, 48), 256, 0, stream>>>(
            h2img + (size_t)(c0 >> 7) * 24 * 8192, fc1p, (void*)fopl, 3072,
            fc1_b, nullptr, mc, 3072, CDIM, 0, 0, nullptr, nullptr);
        gemm_ppx<1><<<dim3((mc + 63) / 64, 12), 256, 0, stream>>>(
            fopl, fc2p, (void*)x1c, CDIM, fc2_b, x1c,
            mc, CDIM, 3072, 0, 0, nullptr, nullptr);
    }

    // 6-8. two batch-halves: xn images -> batched sim (dual-glds) -> rowmax
    for (int hf = 0; hf < 2; hf++) {
        xn_split<<<16 * NIMG, 256, 0, stream>>>(bh, xnimg, hf * 16);
        gemm_ppx<4><<<dim3(9, 9, 16), 256, 0, stream>>>(
            xnimg, xnimg, (void*)bq, NIMG, nullptr, nullptr,
            NIMG, NIMG, CDIM, 5 * 24, (long long)NIMG * NIMG, nullptr, nullptr);
        rowmax_kernel<<<16 * NIMG, 64, 0, stream>>>(bq, ms + (size_t)hf * 16 * NIMG);
    }

    // 9-11. selection, merged average, assemble
    select_kernel<<<NBATCH, NIMG, 0, stream>>>(ms, mask, pos);
    avg_kernel<<<dim3(NBATCH, 6), 256, 0, stream>>>(bh, mask, avg);
    assemble_kernel<<<MTOK, 192, 0, stream>>>(bh, pos, avg, outp);
}